// Round 17
// baseline (1225.937 us; speedup 1.0000x reference)
//
#include <hip/hip_runtime.h>
#include <math.h>

#define DI __device__ __forceinline__

constexpr int B_ = 8, C_ = 128, H_ = 4, S_ = 80, N_ = 6400;
constexpr int P_ = B_ * N_;                 // 51200 spatial positions
constexpr int NSPL = 2;                     // n-chunks for attention partials
constexpr float PI2 = 6.283185307179586f;
constexpr float BN_SC = 0.9999950000374997f;  // 1/sqrt(1+1e-5)

typedef __attribute__((ext_vector_type(8))) short bf16x8;
typedef __attribute__((ext_vector_type(4))) float f32x4;

DI void cfma(float2& a, float2 u, float2 v) {
  a.x = fmaf(u.x, v.x, a.x); a.x = fmaf(-u.y, v.y, a.x);
  a.y = fmaf(u.x, v.y, a.y); a.y = fmaf(u.y, v.x, a.y);
}
DI float2 cmul(float2 u, float2 v) {
  return make_float2(u.x * v.x - u.y * v.y, u.x * v.y + u.y * v.x);
}
DI float gelu_mul(float m) {  // gelu(m, exact) * m
  return 0.5f * m * (1.f + erff(m * 0.7071067811865476f)) * m;
}
DI unsigned short bf16_rn(float f) {  // round-to-nearest-even fp32 -> bf16
  union { float f; unsigned int u; } v; v.f = f;
  unsigned int u = v.u;
  return (unsigned short)((u + 0x7fffu + ((u >> 16) & 1u)) >> 16);
}

// ---------------- LayerNorm over channel dim (4-way channel-split, 800 blocks) ----------------
__global__ __launch_bounds__(256) void k_layernorm(const float* __restrict__ in,
    const float* __restrict__ w, const float* __restrict__ bb, float* __restrict__ out) {
  __shared__ float redS[4][64], redS2[4][64];
  __shared__ float muv[64], invv[64];
  const int tid = threadIdx.x;
  const int g = tid >> 6, l = tid & 63;
  const int p = blockIdx.x * 64 + l;
  const int b = p / N_, n = p % N_;
  const float* xp = in + (size_t)b * C_ * N_ + n;
  float s = 0.f, s2 = 0.f;
  for (int c = g * 32; c < g * 32 + 32; c++) {
    float v = xp[(size_t)c * N_];
    s += v; s2 = fmaf(v, v, s2);
  }
  redS[g][l] = s; redS2[g][l] = s2;
  __syncthreads();
  if (g == 0) {
    float ts  = redS[0][l] + redS[1][l] + redS[2][l] + redS[3][l];
    float ts2 = redS2[0][l] + redS2[1][l] + redS2[2][l] + redS2[3][l];
    float mu = ts * (1.f / C_);
    float var = ts2 * (1.f / C_) - mu * mu;
    muv[l] = mu; invv[l] = rsqrtf(var + 1e-5f);
  }
  __syncthreads();
  const float mu = muv[l], inv = invv[l];
  float* op = out + (size_t)b * C_ * N_ + n;
  for (int c = g * 32; c < g * 32 + 32; c++) {
    float v = xp[(size_t)c * N_];
    op[(size_t)c * N_] = (v - mu) * inv * w[c] + bb[c];
  }
}

// ============ register-tiled 80x80 2D DFT kernels ============

// ---------------- 2D FFT (80x80) real->complex; Hermitian-compressed LDS (41 cols, 26.9 KB -> 6 blocks/CU) ----------------
__global__ __launch_bounds__(256) void k_fft2_r2c(const float* __restrict__ in, float2* __restrict__ out,
                                                  int nCh, int inCtot, int inCoff,
                                                  float2* __restrict__ out2, int inCoff2, int nimg,
                                                  float* __restrict__ nrm) {
  __shared__ float2 data41[80 * 41];   // 26.2 KB; pass1 aliases first 25.6 KB as real input
  __shared__ float2 tw[80];
  int img = blockIdx.x;
  float2* op;
  int coff;
  if (img >= nimg) { img -= nimg; op = out2 + (size_t)img * N_; coff = inCoff2; }
  else { op = out + (size_t)img * N_; coff = inCoff; }
  const int b = img / nCh, ch = img % nCh;
  const float* ip = in + ((size_t)b * inCtot + coff + ch) * N_;
  const int tid = threadIdx.x;
  float* dataR = (float*)data41;
  if (tid < 80) { float a = -PI2 * (float)tid * (1.f / 80.f); float sv, cv; sincosf(a, &sv, &cv); tw[tid] = make_float2(cv, sv); }
  for (int i = tid; i < N_; i += 256) dataR[i] = ip[i];
  __syncthreads();
  // pass1: A[r][k] = sum_c x[r][c] tw[(ck)%80]; keep only k<=40 (A Hermitian in k)
  const int r0 = (tid >> 4) * 5;
  const int cg = tid & 15;
  float2 a1[5][3];
  for (int j = 0; j < 5; j++)
    for (int i = 0; i < 3; i++) a1[j][i] = make_float2(0.f, 0.f);
  {
    int idx[3] = {0, 0, 0};
    for (int c = 0; c < 80; ++c) {
      float d[5]; float2 t[3];
      #pragma unroll
      for (int j = 0; j < 5; j++) d[j] = dataR[(r0 + j) * 80 + c];
      #pragma unroll
      for (int i = 0; i < 3; i++) t[i] = tw[idx[i]];
      #pragma unroll
      for (int j = 0; j < 5; j++) {
        #pragma unroll
        for (int i = 0; i < 3; i++) {
          a1[j][i].x = fmaf(d[j], t[i].x, a1[j][i].x);
          a1[j][i].y = fmaf(d[j], t[i].y, a1[j][i].y);
        }
      }
      #pragma unroll
      for (int i = 0; i < 3; i++) { idx[i] += cg + 16 * i; if (idx[i] >= 80) idx[i] -= 80; }
    }
  }
  __syncthreads();
  #pragma unroll
  for (int i = 0; i < 3; i++) {
    const int k = cg + 16 * i;
    if (k <= 40) {
      #pragma unroll
      for (int j = 0; j < 5; j++) data41[(r0 + j) * 41 + k] = a1[j][i];
    }
  }
  __syncthreads();
  // pass2: Y[k1][k2] = sum_r A[r][k2] tw[(r k1)%80]; A cols >40 via conj(80-k2); compute k1<=40, mirror rest
  const int k0 = (tid & 15) * 5;
  const int rg = tid >> 4;
  int c41[5]; float sgn[5];
  #pragma unroll
  for (int i = 0; i < 5; i++) {
    const int k2 = k0 + i;
    if (k2 <= 40) { c41[i] = k2; sgn[i] = 1.f; }
    else { c41[i] = 80 - k2; sgn[i] = -1.f; }
  }
  float2 a2[3][5];
  for (int j = 0; j < 3; j++)
    for (int i = 0; i < 5; i++) a2[j][i] = make_float2(0.f, 0.f);
  {
    int idx[3] = {0, 0, 0};
    for (int r = 0; r < 80; ++r) {
      float2 d[5]; float2 t[3];
      #pragma unroll
      for (int i = 0; i < 5; i++) {
        float2 v = data41[r * 41 + c41[i]];
        d[i] = make_float2(v.x, v.y * sgn[i]);
      }
      #pragma unroll
      for (int j = 0; j < 3; j++) t[j] = tw[idx[j]];
      #pragma unroll
      for (int j = 0; j < 3; j++) {
        #pragma unroll
        for (int i = 0; i < 5; i++) cfma(a2[j][i], d[i], t[j]);
      }
      #pragma unroll
      for (int j = 0; j < 3; j++) { idx[j] += rg + 16 * j; if (idx[j] >= 80) idx[j] -= 80; }
    }
  }
  #pragma unroll
  for (int j = 0; j < 3; j++) {
    const int k1 = rg + 16 * j;
    #pragma unroll
    for (int i = 0; i < 5; i++) {
      const int k2 = k0 + i;
      if (k1 <= 40) op[k1 * 80 + k2] = a2[j][i];
      if (k1 >= 1 && k1 <= 39) {
        const int m2 = (k2 == 0) ? 0 : 80 - k2;
        op[(80 - k1) * 80 + m2] = make_float2(a2[j][i].x, -a2[j][i].y);
      }
    }
  }
  if (nrm) {   // fused per-image L2 norm (mirrored halves contribute 2x)
    float s = 0.f;
    #pragma unroll
    for (int j = 0; j < 3; j++) {
      const int k1 = rg + 16 * j;
      if (k1 <= 40) {
        const float wgt = (k1 == 0 || k1 == 40) ? 1.f : 2.f;
        #pragma unroll
        for (int i = 0; i < 5; i++)
          s += wgt * (a2[j][i].x * a2[j][i].x + a2[j][i].y * a2[j][i].y);
      }
    }
    __syncthreads();
    float* red = (float*)data41;
    red[tid] = s;
    __syncthreads();
    for (int st = 128; st > 0; st >>= 1) { if (tid < st) red[tid] += red[tid + st]; __syncthreads(); }
    if (tid == 0) nrm[img] = fmaxf(sqrtf(red[0]), 1e-12f);
  }
}

// ---------------- 2D IFFT (80x80) of HERMITIAN input -> |real| (optional 2nd input set) ----------------
__global__ __launch_bounds__(256) void k_ifft2_abs(const float2* __restrict__ in, float* __restrict__ out,
                                                   int inC, int outCtot, int outCoff,
                                                   const float2* __restrict__ in2, int outCoff2, int nimg) {
  __shared__ float2 data[N_];
  __shared__ float2 tw[80];
  int img = blockIdx.x;
  const float2* ip;
  int coff;
  if (img >= nimg) { img -= nimg; ip = in2 + (size_t)img * N_; coff = outCoff2; }
  else { ip = in + (size_t)img * N_; coff = outCoff; }
  const int b = img / inC, ch = img % inC;
  float* op = out + ((size_t)b * outCtot + coff + ch) * N_;
  const int tid = threadIdx.x;
  if (tid < 80) { float a = PI2 * (float)tid * (1.f / 80.f); float sv, cv; sincosf(a, &sv, &cv); tw[tid] = make_float2(cv, sv); }
  for (int i = tid; i < N_; i += 256) data[i] = ip[i];
  __syncthreads();
  const int rg = tid >> 4;
  const int cg = tid & 15;
  float2 E[3][3], O[3][3];
  for (int j = 0; j < 3; j++)
    for (int i = 0; i < 3; i++) { E[j][i] = make_float2(0.f, 0.f); O[j][i] = make_float2(0.f, 0.f); }
  {
    int idx[3], inc[3];
    #pragma unroll
    for (int i = 0; i < 3; i++) { idx[i] = 0; inc[i] = (2 * (cg + 16 * i)) % 80; }
    for (int m = 0; m < 40; ++m) {
      float4 z[3]; float2 t[3];
      #pragma unroll
      for (int j = 0; j < 3; j++) z[j] = *(const float4*)&data[(rg + 16 * j) * 80 + 2 * m];
      #pragma unroll
      for (int i = 0; i < 3; i++) t[i] = tw[idx[i]];
      #pragma unroll
      for (int j = 0; j < 3; j++) {
        float2 ze = make_float2(z[j].x, z[j].y);
        float2 zo = make_float2(z[j].z, z[j].w);
        #pragma unroll
        for (int i = 0; i < 3; i++) { cfma(E[j][i], ze, t[i]); cfma(O[j][i], zo, t[i]); }
      }
      #pragma unroll
      for (int i = 0; i < 3; i++) { idx[i] += inc[i]; if (idx[i] >= 80) idx[i] -= 80; }
    }
  }
  __syncthreads();
  #pragma unroll
  for (int j = 0; j < 3; j++) {
    const int r = rg + 16 * j;
    if (r <= 40) {
      #pragma unroll
      for (int i = 0; i < 3; i++) {
        const int n2 = cg + 16 * i;
        if (n2 < 40) {
          float2 u = cmul(tw[n2], O[j][i]);
          data[r * 80 + n2]      = make_float2(E[j][i].x + u.x, E[j][i].y + u.y);
          data[r * 80 + n2 + 40] = make_float2(E[j][i].x - u.x, E[j][i].y - u.y);
        }
      }
    }
  }
  __syncthreads();
  const int r0 = (tid >> 4) * 5;
  const int k0 = (tid & 15) * 5;
  float accR[5][5];
  for (int j = 0; j < 5; j++)
    for (int i = 0; i < 5; i++) accR[j][i] = 0.f;
  {
    int idx[5];
    #pragma unroll
    for (int j = 0; j < 5; j++) idx[j] = r0 + j;
    for (int r = 1; r <= 39; ++r) {
      float2 d[5]; float2 t[5];
      #pragma unroll
      for (int i = 0; i < 5; i++) d[i] = data[r * 80 + k0 + i];
      #pragma unroll
      for (int j = 0; j < 5; j++) t[j] = tw[idx[j]];
      #pragma unroll
      for (int j = 0; j < 5; j++) {
        #pragma unroll
        for (int i = 0; i < 5; i++) {
          accR[j][i] = fmaf(t[j].x, d[i].x, accR[j][i]);
          accR[j][i] = fmaf(-t[j].y, d[i].y, accR[j][i]);
        }
      }
      #pragma unroll
      for (int j = 0; j < 5; j++) { idx[j] += r0 + j; if (idx[j] >= 80) idx[j] -= 80; }
    }
  }
  #pragma unroll
  for (int i = 0; i < 5; i++) {
    float2 b0 = data[k0 + i];
    float2 b40 = data[40 * 80 + k0 + i];
    #pragma unroll
    for (int j = 0; j < 5; j++) {
      float s40 = ((r0 + j) & 1) ? -b40.x : b40.x;
      float res = 2.f * accR[j][i] + b0.x + s40;
      op[(r0 + j) * 80 + k0 + i] = fabsf(res) * (1.f / (float)N_);
    }
  }
}

// ---------------- combo: blocks <1024 do 6400-pt IDFT+abs; blocks >=1024 do Hermitian ifft2+abs ----------------
__global__ __launch_bounds__(256) void k_iff_combo(const float2* __restrict__ in6400, float* __restrict__ out6400,
                                                   const float2* __restrict__ inF, float* __restrict__ outF) {
  __shared__ float2 data[N_];
  __shared__ float2 tw[80];
  __shared__ float2 tws[80];
  const int tid = threadIdx.x;
  if (blockIdx.x < (unsigned)(B_ * C_)) {
    // ---- idft6400_abs body ----
    const int row = blockIdx.x;
    const float2* ip = in6400 + (size_t)row * N_;
    float* op = out6400 + (size_t)row * N_;
    if (tid < 80) {
      float a = PI2 * (float)tid * (1.f / 80.f); float sv, cv; sincosf(a, &sv, &cv); tw[tid] = make_float2(cv, sv);
      float a2 = PI2 * (float)tid * (1.f / 6400.f); sincosf(a2, &sv, &cv); tws[tid] = make_float2(cv, sv);
    }
    for (int i = tid; i < N_; i += 256) data[i] = ip[i];
    __syncthreads();
    {
      const int r0 = (tid >> 4) * 5;
      const int cg = tid & 15;
      float2 E[5][3], O[5][3];
      for (int j = 0; j < 5; j++)
        for (int i = 0; i < 3; i++) { E[j][i] = make_float2(0.f, 0.f); O[j][i] = make_float2(0.f, 0.f); }
      int idx[3], inc[3];
      #pragma unroll
      for (int i = 0; i < 3; i++) { idx[i] = 0; inc[i] = (2 * (cg + 16 * i)) % 80; }
      for (int m = 0; m < 40; ++m) {
        float2 xe[5], xo[5], t[3];
        #pragma unroll
        for (int j = 0; j < 5; j++) {
          xe[j] = data[(r0 + j) + 160 * m];
          xo[j] = data[(r0 + j) + 160 * m + 80];
        }
        #pragma unroll
        for (int i = 0; i < 3; i++) t[i] = tw[idx[i]];
        #pragma unroll
        for (int j = 0; j < 5; j++) {
          #pragma unroll
          for (int i = 0; i < 3; i++) { cfma(E[j][i], xe[j], t[i]); cfma(O[j][i], xo[j], t[i]); }
        }
        #pragma unroll
        for (int i = 0; i < 3; i++) { idx[i] += inc[i]; if (idx[i] >= 80) idx[i] -= 80; }
      }
      __syncthreads();
      #pragma unroll
      for (int j = 0; j < 5; j++) {
        const int k1 = r0 + j;
        #pragma unroll
        for (int i = 0; i < 3; i++) {
          const int n2 = cg + 16 * i;
          if (n2 < 40) {
            float2 u = cmul(tw[n2], O[j][i]);
            float2 Ap = make_float2(E[j][i].x + u.x, E[j][i].y + u.y);
            float2 Am = make_float2(E[j][i].x - u.x, E[j][i].y - u.y);
            int t6 = k1 * n2; int q = t6 / 80, s6 = t6 - q * 80;
            data[k1 * 80 + n2] = cmul(Ap, cmul(tw[q], tws[s6]));
            int t6b = k1 * (n2 + 40); int qb = t6b / 80, sb = t6b - qb * 80;
            data[k1 * 80 + n2 + 40] = cmul(Am, cmul(tw[qb], tws[sb]));
          }
        }
      }
    }
    __syncthreads();
    {
      const int rg5 = tid >> 3;
      const int cg5 = tid & 7;
      float2 E2[5][3], O2[5][3];
      for (int i = 0; i < 5; i++)
        for (int j = 0; j < 3; j++) { E2[i][j] = make_float2(0.f, 0.f); O2[i][j] = make_float2(0.f, 0.f); }
      int idx[5], inc[5];
      #pragma unroll
      for (int i = 0; i < 5; i++) { idx[i] = 0; inc[i] = (2 * (cg5 * 5 + i)) % 80; }
      int n2c[3];
      #pragma unroll
      for (int j = 0; j < 3; j++) { int n2 = rg5 + 32 * j; n2c[j] = (n2 < 80) ? n2 : 0; }
      for (int m = 0; m < 40; ++m) {
        float2 ae[3], ao[3], t[5];
        #pragma unroll
        for (int j = 0; j < 3; j++) {
          ae[j] = data[(2 * m) * 80 + n2c[j]];
          ao[j] = data[(2 * m + 1) * 80 + n2c[j]];
        }
        #pragma unroll
        for (int i = 0; i < 5; i++) t[i] = tw[idx[i]];
        #pragma unroll
        for (int i = 0; i < 5; i++) {
          #pragma unroll
          for (int j = 0; j < 3; j++) { cfma(E2[i][j], ae[j], t[i]); cfma(O2[i][j], ao[j], t[i]); }
        }
        #pragma unroll
        for (int i = 0; i < 5; i++) { idx[i] += inc[i]; if (idx[i] >= 80) idx[i] -= 80; }
      }
      #pragma unroll
      for (int i = 0; i < 5; i++) {
        const int n1 = cg5 * 5 + i;
        #pragma unroll
        for (int j = 0; j < 3; j++) {
          const int n2 = rg5 + 32 * j;
          if (n2 < 80) {
            float2 u = cmul(tw[n1], O2[i][j]);
            float2 o1 = make_float2(E2[i][j].x + u.x, E2[i][j].y + u.y);
            float2 o2 = make_float2(E2[i][j].x - u.x, E2[i][j].y - u.y);
            op[n1 * 80 + n2] = sqrtf(o1.x * o1.x + o1.y * o1.y) * (1.f / 6400.f);
            op[(n1 + 40) * 80 + n2] = sqrtf(o2.x * o2.x + o2.y * o2.y) * (1.f / 6400.f);
          }
        }
      }
    }
  } else {
    // ---- Hermitian ifft2_abs body ----
    const int img = blockIdx.x - B_ * C_;
    const float2* ip = inF + (size_t)img * N_;
    float* op = outF + (size_t)img * N_;
    if (tid < 80) { float a = PI2 * (float)tid * (1.f / 80.f); float sv, cv; sincosf(a, &sv, &cv); tw[tid] = make_float2(cv, sv); }
    for (int i = tid; i < N_; i += 256) data[i] = ip[i];
    __syncthreads();
    const int rg = tid >> 4;
    const int cg = tid & 15;
    float2 E[3][3], O[3][3];
    for (int j = 0; j < 3; j++)
      for (int i = 0; i < 3; i++) { E[j][i] = make_float2(0.f, 0.f); O[j][i] = make_float2(0.f, 0.f); }
    {
      int idx[3], inc[3];
      #pragma unroll
      for (int i = 0; i < 3; i++) { idx[i] = 0; inc[i] = (2 * (cg + 16 * i)) % 80; }
      for (int m = 0; m < 40; ++m) {
        float4 z[3]; float2 t[3];
        #pragma unroll
        for (int j = 0; j < 3; j++) z[j] = *(const float4*)&data[(rg + 16 * j) * 80 + 2 * m];
        #pragma unroll
        for (int i = 0; i < 3; i++) t[i] = tw[idx[i]];
        #pragma unroll
        for (int j = 0; j < 3; j++) {
          float2 ze = make_float2(z[j].x, z[j].y);
          float2 zo = make_float2(z[j].z, z[j].w);
          #pragma unroll
          for (int i = 0; i < 3; i++) { cfma(E[j][i], ze, t[i]); cfma(O[j][i], zo, t[i]); }
        }
        #pragma unroll
        for (int i = 0; i < 3; i++) { idx[i] += inc[i]; if (idx[i] >= 80) idx[i] -= 80; }
      }
    }
    __syncthreads();
    #pragma unroll
    for (int j = 0; j < 3; j++) {
      const int r = rg + 16 * j;
      if (r <= 40) {
        #pragma unroll
        for (int i = 0; i < 3; i++) {
          const int n2 = cg + 16 * i;
          if (n2 < 40) {
            float2 u = cmul(tw[n2], O[j][i]);
            data[r * 80 + n2]      = make_float2(E[j][i].x + u.x, E[j][i].y + u.y);
            data[r * 80 + n2 + 40] = make_float2(E[j][i].x - u.x, E[j][i].y - u.y);
          }
        }
      }
    }
    __syncthreads();
    const int r0 = (tid >> 4) * 5;
    const int k0 = (tid & 15) * 5;
    float accR[5][5];
    for (int j = 0; j < 5; j++)
      for (int i = 0; i < 5; i++) accR[j][i] = 0.f;
    {
      int idx[5];
      #pragma unroll
      for (int j = 0; j < 5; j++) idx[j] = r0 + j;
      for (int r = 1; r <= 39; ++r) {
        float2 d[5]; float2 t[5];
        #pragma unroll
        for (int i = 0; i < 5; i++) d[i] = data[r * 80 + k0 + i];
        #pragma unroll
        for (int j = 0; j < 5; j++) t[j] = tw[idx[j]];
        #pragma unroll
        for (int j = 0; j < 5; j++) {
          #pragma unroll
          for (int i = 0; i < 5; i++) {
            accR[j][i] = fmaf(t[j].x, d[i].x, accR[j][i]);
            accR[j][i] = fmaf(-t[j].y, d[i].y, accR[j][i]);
          }
        }
        #pragma unroll
        for (int j = 0; j < 5; j++) { idx[j] += r0 + j; if (idx[j] >= 80) idx[j] -= 80; }
      }
    }
    #pragma unroll
    for (int i = 0; i < 5; i++) {
      float2 b0 = data[k0 + i];
      float2 b40 = data[40 * 80 + k0 + i];
      #pragma unroll
      for (int j = 0; j < 5; j++) {
        float s40 = ((r0 + j) & 1) ? -b40.x : b40.x;
        float res = 2.f * accR[j][i] + b0.x + s40;
        op[(r0 + j) * 80 + k0 + i] = fabsf(res) * (1.f / (float)N_);
      }
    }
  }
}

// ---------------- 32-point IDFT along channel-within-head (radix-2) ----------------
__global__ __launch_bounds__(256) void k_idft32(const float2* __restrict__ in, float2* __restrict__ out) {
  __shared__ float2 tile[32][64];
  __shared__ float2 tw[32];
  const int bh = blockIdx.x;
  const int b = bh / H_, h = bh % H_;
  const int n0 = blockIdx.y * 64;
  const int tid = threadIdx.x;
  if (tid < 32) { float a = PI2 * (float)tid * (1.f / 32.f); float sv, cv; sincosf(a, &sv, &cv); tw[tid] = make_float2(cv, sv); }
  const float2* ip = in + ((size_t)b * C_ + h * 32) * N_ + n0;
  for (int i = tid; i < 2048; i += 256) { int c = i / 64, pp = i % 64; tile[c][pp] = ip[(size_t)c * N_ + pp]; }
  __syncthreads();
  const int pp = tid & 63, grp = tid >> 6;   // 4 groups x 4 pairs (cp, cp+16)
  float2 E[4], O[4];
  #pragma unroll
  for (int j = 0; j < 4; j++) { E[j] = make_float2(0.f, 0.f); O[j] = make_float2(0.f, 0.f); }
  int idx[4], inc[4];
  #pragma unroll
  for (int j = 0; j < 4; j++) { idx[j] = 0; inc[j] = (2 * (grp * 4 + j)) & 31; }
  for (int m = 0; m < 16; m++) {
    float2 ve = tile[2 * m][pp];
    float2 vo = tile[2 * m + 1][pp];
    #pragma unroll
    for (int j = 0; j < 4; j++) {
      cfma(E[j], ve, tw[idx[j]]);
      cfma(O[j], vo, tw[idx[j]]);
      idx[j] = (idx[j] + inc[j]) & 31;
    }
  }
  float2* op = out + ((size_t)b * C_ + h * 32) * N_ + n0;
  #pragma unroll
  for (int j = 0; j < 4; j++) {
    const int cp = grp * 4 + j;
    float2 u = cmul(tw[cp], O[j]);
    op[(size_t)cp * N_ + pp]        = make_float2((E[j].x + u.x) * (1.f / 32.f), (E[j].y + u.y) * (1.f / 32.f));
    op[(size_t)(cp + 16) * N_ + pp] = make_float2((E[j].x - u.x) * (1.f / 32.f), (E[j].y - u.y) * (1.f / 32.f));
  }
}

// ---------------- gate stage A (4-way channel-split, 800 blocks) ----------------
__global__ __launch_bounds__(256) void k_gateA(const float2* __restrict__ zA, const float2* __restrict__ zB,
    int split, int Cin, const float* __restrict__ W1, const float* __restrict__ b1,
    const float* __restrict__ g, const float* __restrict__ bt, float* __restrict__ hid) {
  __shared__ float w[8 * 256];
  __shared__ float red[4][64][9];  // padded to 9 to avoid bank conflicts
  const int tid = threadIdx.x;
  const int grp = tid >> 6, l = tid & 63;
  for (int i = tid; i < 8 * Cin; i += 256) w[i] = W1[i];
  __syncthreads();
  const int p = blockIdx.x * 64 + l;
  const int b = p / N_, n = p % N_;
  const int cpg = Cin / 4;
  float acc[8] = {0.f, 0.f, 0.f, 0.f, 0.f, 0.f, 0.f, 0.f};
  for (int ci = grp * cpg; ci < (grp + 1) * cpg; ci++) {
    const float2* src = (ci < split) ? (zA + ((size_t)b * split + ci) * N_ + n)
                                     : (zB + ((size_t)b * (Cin - split) + (ci - split)) * N_ + n);
    float v = src->x;
    #pragma unroll
    for (int j = 0; j < 8; j++) acc[j] = fmaf(w[j * Cin + ci], v, acc[j]);
  }
  #pragma unroll
  for (int j = 0; j < 8; j++) red[grp][l][j] = acc[j];
  __syncthreads();
  if (grp == 0) {
    #pragma unroll
    for (int j = 0; j < 8; j++) {
      float t = red[0][l][j] + red[1][l][j] + red[2][l][j] + red[3][l][j];
      float y = (t + b1[j]) * (g[j] * BN_SC) + bt[j];
      hid[((size_t)b * 8 + j) * N_ + n] = fmaxf(y, 0.f);
    }
  }
}

// ---------------- gate stage B (co-split over gridDim.y, 64 co per block) ----------------
template <int MODE>
__global__ __launch_bounds__(256) void k_gateB(float2* __restrict__ zA, float2* __restrict__ zB,
    int split, int Cout, const float* __restrict__ W2, const float* __restrict__ b2,
    const float* __restrict__ hid, float* __restrict__ outR, int outCtot, int outCoff) {
  __shared__ float w[64 * 8];
  __shared__ float bb[64];
  const int tid = threadIdx.x;
  const int cobase = blockIdx.y * 64;
  for (int i = tid; i < 64 * 8; i += 256) w[i] = W2[cobase * 8 + i];
  for (int i = tid; i < 64; i += 256) bb[i] = b2[cobase + i];
  __syncthreads();
  const int p = blockIdx.x * 256 + tid;
  const int b = p / N_, n = p % N_;
  float h[8];
  #pragma unroll
  for (int j = 0; j < 8; j++) h[j] = hid[((size_t)b * 8 + j) * N_ + n];
  for (int co = 0; co < 64; co++) {
    const int gco = cobase + co;
    float t = bb[co];
    #pragma unroll
    for (int j = 0; j < 8; j++) t = fmaf(w[co * 8 + j], h[j], t);
    float sg = 1.f / (1.f + expf(-t));
    float2* zp = (gco < split) ? (zA + ((size_t)b * split + gco) * N_ + n)
                               : (zB + ((size_t)b * (Cout - split) + (gco - split)) * N_ + n);
    float2 z = *zp;
    if (MODE == 0) {
      zp->x = z.x * sg; zp->y = z.y * sg;
    } else {
      float m = sg * sqrtf(z.x * z.x + z.y * z.y);
      outR[((size_t)b * outCtot + outCoff + gco) * N_ + n] = gelu_mul(m);
    }
  }
}

// ---------------- 1x1 conv as bf16 MFMA GEMM: 128co x 64pos per block ----------------
__global__ __launch_bounds__(256) void k_conv1x1(const float* __restrict__ inA, const float* __restrict__ inB,
    int split, int Cin, int Cout, const float* __restrict__ W, const float* __restrict__ bias,
    const float* __restrict__ resid, float* __restrict__ out) {
  __shared__ unsigned int xlds[16][68];    // 4.25 KB
  const int tid = threadIdx.x;
  const int lane = tid & 63, wv = tid >> 6;
  const int p0 = blockIdx.x * 64;
  const int b = p0 / N_, n0 = p0 % N_;
  const int laneco = lane & 15, lanek = lane >> 4;
  const int kA = lanek * 8;
  f32x4 acc[2][4];
  #pragma unroll
  for (int g = 0; g < 2; g++)
    #pragma unroll
    for (int f = 0; f < 4; f++) acc[g][f] = (f32x4){0.f, 0.f, 0.f, 0.f};
  for (int cb = 0; cb < Cin; cb += 32) {
    const float* src = (cb < split) ? (inA + ((size_t)b * split + cb) * N_)
                                    : (inB + ((size_t)b * (Cin - split) + (cb - split)) * N_);
    bf16x8 af[2];
    #pragma unroll
    for (int g = 0; g < 2; g++) {
      const float* wp = W + (size_t)(wv * 32 + g * 16 + laneco) * Cin + cb + kA;
      float4 w0 = *(const float4*)wp;
      float4 w1 = *(const float4*)(wp + 4);
      af[g][0] = (short)bf16_rn(w0.x); af[g][1] = (short)bf16_rn(w0.y);
      af[g][2] = (short)bf16_rn(w0.z); af[g][3] = (short)bf16_rn(w0.w);
      af[g][4] = (short)bf16_rn(w1.x); af[g][5] = (short)bf16_rn(w1.y);
      af[g][6] = (short)bf16_rn(w1.z); af[g][7] = (short)bf16_rn(w1.w);
    }
    __syncthreads();   // previous-iter xlds reads complete
    #pragma unroll
    for (int r = 0; r < 4; r++) {
      const int kb = wv * 4 + r;
      float e = src[(size_t)(2 * kb) * N_ + n0 + lane];
      float o = src[(size_t)(2 * kb + 1) * N_ + n0 + lane];
      xlds[kb][lane] = (unsigned int)bf16_rn(e) | ((unsigned int)bf16_rn(o) << 16);
    }
    __syncthreads();
    #pragma unroll
    for (int f = 0; f < 4; f++) {
      const int pos = f * 16 + laneco;
      const int kb0 = lanek * 4;
      union { bf16x8 v; unsigned int u[4]; } bu;
      bu.u[0] = xlds[kb0 + 0][pos];
      bu.u[1] = xlds[kb0 + 1][pos];
      bu.u[2] = xlds[kb0 + 2][pos];
      bu.u[3] = xlds[kb0 + 3][pos];
      #pragma unroll
      for (int g = 0; g < 2; g++)
        acc[g][f] = __builtin_amdgcn_mfma_f32_16x16x32_bf16(af[g], bu.v, acc[g][f], 0, 0, 0);
    }
  }
  #pragma unroll
  for (int g = 0; g < 2; g++) {
    #pragma unroll
    for (int f = 0; f < 4; f++) {
      #pragma unroll
      for (int r = 0; r < 4; r++) {
        const int co = wv * 32 + g * 16 + lanek * 4 + r;
        float v = acc[g][f][r];
        if (bias) v += bias[co];
        const size_t off = ((size_t)b * Cout + co) * N_ + n0 + f * 16 + laneco;
        if (resid) v += resid[off];
        out[off] = v;
      }
    }
  }
}

// ---------------- grouped conv 3x3(pad1) + 5x5(pad2), groups=64: zero-padded halo, 40-row halves ----------------
__global__ __launch_bounds__(256) void k_gconv35(const float* __restrict__ in,
    const float* __restrict__ w3, const float* __restrict__ w5, float* __restrict__ out) {
  __shared__ float tt[2][44][84];
  const int blk = blockIdx.x;
  const int b = blk / 128;
  const int rem = blk % 128;
  const int o = rem >> 1, half = rem & 1;
  const int y0 = half * 40;
  const float* i0 = in + ((size_t)b * C_ + 2 * o) * N_;
  const int tid = threadIdx.x;
  for (int i = tid; i < 2 * 44 * 84; i += 256) {
    int ic = i / (44 * 84);
    int r = (i % (44 * 84)) / 84;
    int cc = i % 84;
    int gy = y0 + r - 2, gx = cc - 2;
    float v = 0.f;
    if (gy >= 0 && gy < 80 && gx >= 0 && gx < 80) v = i0[(size_t)ic * N_ + gy * 80 + gx];
    tt[ic][r][cc] = v;
  }
  float w3r[2][9], w5r[2][25];
  #pragma unroll
  for (int ic = 0; ic < 2; ic++) {
    #pragma unroll
    for (int k = 0; k < 9; k++) w3r[ic][k] = w3[(o * 2 + ic) * 9 + k];
    #pragma unroll
    for (int k = 0; k < 25; k++) w5r[ic][k] = w5[(o * 2 + ic) * 25 + k];
  }
  __syncthreads();
  for (int p = tid; p < 3200; p += 256) {
    const int ly = p / 80, x = p % 80;
    float a3 = 0.f, a5 = 0.f;
    #pragma unroll
    for (int ky = 0; ky < 5; ky++) {
      #pragma unroll
      for (int kx = 0; kx < 5; kx++) {
        float v0 = tt[0][ly + ky][x + kx];
        float v1 = tt[1][ly + ky][x + kx];
        a5 = fmaf(v0, w5r[0][ky * 5 + kx], a5);
        a5 = fmaf(v1, w5r[1][ky * 5 + kx], a5);
        if (ky >= 1 && ky < 4 && kx >= 1 && kx < 4) {
          int k3 = (ky - 1) * 3 + (kx - 1);
          a3 = fmaf(v0, w3r[0][k3], a3);
          a3 = fmaf(v1, w3r[1][k3], a3);
        }
      }
    }
    const int yy = y0 + ly;
    out[((size_t)b * C_ + o) * N_ + yy * 80 + x] = a3;
    out[((size_t)b * C_ + 64 + o) * N_ + yy * 80 + x] = a5;
  }
}

// ---------------- depthwise conv3x3 (pad1) + gelu(x)*x: zero-padded halo, 40-row halves ----------------
__global__ __launch_bounds__(256) void k_dwconv3_gelu(const float* __restrict__ in, const float* __restrict__ w,
    float* __restrict__ out, int Cn, int outCtot, int outCoff) {
  __shared__ float tt[42][82];
  const int blk = blockIdx.x;
  const int b = blk / (2 * Cn);
  const int rem = blk % (2 * Cn);
  const int c = rem >> 1, half = rem & 1;
  const int y0 = half * 40;
  const float* ip = in + ((size_t)b * Cn + c) * N_;
  const int tid = threadIdx.x;
  for (int i = tid; i < 42 * 82; i += 256) {
    int r = i / 82, cc = i % 82;
    int gy = y0 + r - 1, gx = cc - 1;
    float v = 0.f;
    if (gy >= 0 && gy < 80 && gx >= 0 && gx < 80) v = ip[gy * 80 + gx];
    tt[r][cc] = v;
  }
  float wr[9];
  #pragma unroll
  for (int k = 0; k < 9; k++) wr[k] = w[c * 9 + k];
  __syncthreads();
  float* op = out + ((size_t)b * outCtot + outCoff + c) * N_;
  for (int p = tid; p < 3200; p += 256) {
    const int ly = p / 80, x = p % 80;
    float a = 0.f;
    #pragma unroll
    for (int ky = 0; ky < 3; ky++) {
      #pragma unroll
      for (int kx = 0; kx < 3; kx++)
        a = fmaf(tt[ly + ky][x + kx], wr[ky * 3 + kx], a);
    }
    op[(y0 + ly) * 80 + x] = gelu_mul(a);
  }
}

// ---------------- ff_dw2: groups=128, 2-in/2-out per group, 3x3 pad1: zero-padded halo, halves ----------------
__global__ __launch_bounds__(256) void k_ffdw2(const float* __restrict__ in, const float* __restrict__ w,
                                               float* __restrict__ out) {
  __shared__ float tt[2][42][82];
  const int blk = blockIdx.x;
  const int b = blk / 256;
  const int rem = blk % 256;
  const int g = rem >> 1, half = rem & 1;
  const int y0 = half * 40;
  const float* i0 = in + ((size_t)b * 256 + 2 * g) * N_;
  const int tid = threadIdx.x;
  for (int i = tid; i < 2 * 42 * 82; i += 256) {
    int ic = i / (42 * 82);
    int r = (i % (42 * 82)) / 82;
    int cc = i % 82;
    int gy = y0 + r - 1, gx = cc - 1;
    float v = 0.f;
    if (gy >= 0 && gy < 80 && gx >= 0 && gx < 80) v = i0[(size_t)ic * N_ + gy * 80 + gx];
    tt[ic][r][cc] = v;
  }
  float w0[2][9], w1[2][9];
  #pragma unroll
  for (int ic = 0; ic < 2; ic++) {
    #pragma unroll
    for (int k = 0; k < 9; k++) {
      w0[ic][k] = w[((2 * g) * 2 + ic) * 9 + k];
      w1[ic][k] = w[((2 * g + 1) * 2 + ic) * 9 + k];
    }
  }
  __syncthreads();
  for (int p = tid; p < 3200; p += 256) {
    const int ly = p / 80, x = p % 80;
    float a0 = 0.f, a1 = 0.f;
    #pragma unroll
    for (int ky = 0; ky < 3; ky++) {
      #pragma unroll
      for (int kx = 0; kx < 3; kx++) {
        float v0 = tt[0][ly + ky][x + kx], v1 = tt[1][ly + ky][x + kx];
        int k = ky * 3 + kx;
        a0 = fmaf(v0, w0[0][k], a0); a0 = fmaf(v1, w0[1][k], a0);
        a1 = fmaf(v0, w1[0][k], a1); a1 = fmaf(v1, w1[1][k], a1);
      }
    }
    const int yy = y0 + ly;
    out[((size_t)b * 256 + 2 * g) * N_ + yy * 80 + x] = a0;
    out[((size_t)b * 256 + 2 * g + 1) * N_ + yy * 80 + x] = a1;
  }
}

// ---------------- per-row L2 norm (real) ----------------
__global__ __launch_bounds__(256) void k_rownorm_r(const float* __restrict__ in, float* __restrict__ nrm) {
  __shared__ float red[256];
  const int row = blockIdx.x;
  const float* p = in + (size_t)row * N_;
  float s = 0.f;
  for (int i = threadIdx.x; i < N_; i += 256) { float v = p[i]; s = fmaf(v, v, s); }
  red[threadIdx.x] = s; __syncthreads();
  for (int st = 128; st > 0; st >>= 1) { if (threadIdx.x < st) red[threadIdx.x] += red[threadIdx.x + st]; __syncthreads(); }
  if (threadIdx.x == 0) nrm[row] = fmaxf(sqrtf(red[0]), 1e-12f);
}

// ---------------- attention partials: coalesced wave-per-tile ----------------
__global__ __launch_bounds__(256) void k_attn_part_c(const float2* __restrict__ Ab, const float2* __restrict__ Bb,
                                                     float2* __restrict__ part) {
  const int bh = blockIdx.z;
  const int b = bh / H_, h = bh % H_;
  const int wave = threadIdx.x >> 6, lane = threadIdx.x & 63;
  const int tile = blockIdx.x * 4 + wave;      // 0..63
  const int c0 = (tile >> 3) * 4, d0 = (tile & 7) * 4;
  const size_t hb = ((size_t)b * C_ + h * 32) * N_;
  const float2* Ap = Ab + hb;
  const float2* Bp = Bb + hb;
  float2 acc[4][4];
  #pragma unroll
  for (int j = 0; j < 4; j++)
    #pragma unroll
    for (int i = 0; i < 4; i++) acc[j][i] = make_float2(0.f, 0.f);
  const int nb = blockIdx.y * (N_ / NSPL) + lane;
  for (int it = 0; it < (N_ / NSPL) / 64; ++it) {
    const int n = nb + it * 64;
    float2 av[4], bv[4];
    #pragma unroll
    for (int j = 0; j < 4; j++) av[j] = Ap[(size_t)(c0 + j) * N_ + n];
    #pragma unroll
    for (int i = 0; i < 4; i++) bv[i] = Bp[(size_t)(d0 + i) * N_ + n];
    #pragma unroll
    for (int j = 0; j < 4; j++)
      #pragma unroll
      for (int i = 0; i < 4; i++) cfma(acc[j][i], av[j], bv[i]);
  }
  float2* pp = part + (size_t)(bh * NSPL + blockIdx.y) * 1024;
  #pragma unroll
  for (int j = 0; j < 4; j++) {
    #pragma unroll
    for (int i = 0; i < 4; i++) {
      float rx = acc[j][i].x, ry = acc[j][i].y;
      for (int off = 32; off; off >>= 1) { rx += __shfl_xor(rx, off); ry += __shfl_xor(ry, off); }
      if (lane == 0) pp[(c0 + j) * 32 + d0 + i] = make_float2(rx, ry);
    }
  }
}
__global__ __launch_bounds__(256) void k_attn_part_r(const float* __restrict__ Ab, const float* __restrict__ Bb,
                                                     float* __restrict__ part) {
  const int bh = blockIdx.z;
  const int b = bh / H_, h = bh % H_;
  const int wave = threadIdx.x >> 6, lane = threadIdx.x & 63;
  const int tile = blockIdx.x * 4 + wave;
  const int c0 = (tile >> 3) * 4, d0 = (tile & 7) * 4;
  const size_t hb = ((size_t)b * C_ + h * 32) * N_;
  const float* Ap = Ab + hb;
  const float* Bp = Bb + hb;
  float acc[4][4];
  #pragma unroll
  for (int j = 0; j < 4; j++)
    #pragma unroll
    for (int i = 0; i < 4; i++) acc[j][i] = 0.f;
  const int nb = blockIdx.y * (N_ / NSPL) + lane;
  for (int it = 0; it < (N_ / NSPL) / 64; ++it) {
    const int n = nb + it * 64;
    float av[4], bv[4];
    #pragma unroll
    for (int j = 0; j < 4; j++) av[j] = Ap[(size_t)(c0 + j) * N_ + n];
    #pragma unroll
    for (int i = 0; i < 4; i++) bv[i] = Bp[(size_t)(d0 + i) * N_ + n];
    #pragma unroll
    for (int j = 0; j < 4; j++)
      #pragma unroll
      for (int i = 0; i < 4; i++) acc[j][i] = fmaf(av[j], bv[i], acc[j][i]);
  }
  float* pp = part + (size_t)(bh * NSPL + blockIdx.y) * 1024;
  #pragma unroll
  for (int j = 0; j < 4; j++) {
    #pragma unroll
    for (int i = 0; i < 4; i++) {
      float r = acc[j][i];
      for (int off = 32; off; off >>= 1) r += __shfl_xor(r, off);
      if (lane == 0) pp[(c0 + j) * 32 + d0 + i] = r;
    }
  }
}

// ---------------- reduce partials, scale, softmax ----------------
template <int CPLX>
__global__ void k_attn_soft(const float* __restrict__ part, const float* __restrict__ nA,
                            const float* __restrict__ nB, const float* __restrict__ temp,
                            float* __restrict__ attn) {
  const int rc = blockIdx.x;          // bh*32 + c
  const int bh = rc >> 5, c = rc & 31;
  const int b = bh / H_, h = bh % H_;
  const int d = threadIdx.x;          // 64 threads; group >=32 unused
  float re = -1e30f, im = -1e30f;
  if (d < 32) {
    re = 0.f; im = 0.f;
    if (CPLX) {
      const float2* pp = (const float2*)part;
      for (int kc = 0; kc < NSPL; kc++) { float2 v = pp[(size_t)(bh * NSPL + kc) * 1024 + c * 32 + d]; re += v.x; im += v.y; }
    } else {
      for (int kc = 0; kc < NSPL; kc++) re += part[(size_t)(bh * NSPL + kc) * 1024 + c * 32 + d];
    }
    float sc = temp[h] / (nA[b * C_ + h * 32 + c] * nB[b * C_ + h * 32 + d]);
    re *= sc; im *= sc;
  }
  float m = re;
  for (int o = 16; o; o >>= 1) m = fmaxf(m, __shfl_xor(m, o, 32));
  float e = expf(re - m);
  float s = e;
  for (int o = 16; o; o >>= 1) s += __shfl_xor(s, o, 32);
  float vr = e / s;
  float mi = im;
  for (int o = 16; o; o >>= 1) mi = fmaxf(mi, __shfl_xor(mi, o, 32));
  float ei = expf(im - mi);
  float si = ei;
  for (int o = 16; o; o >>= 1) si += __shfl_xor(si, o, 32);
  float vi = ei / si;
  if (d < 32) {
    if (CPLX) ((float2*)attn)[(size_t)(bh * 32 + c) * 32 + d] = make_float2(vr, vi);
    else attn[(size_t)(bh * 32 + c) * 32 + d] = vr;
  }
}

// ---------------- out[c,n] = sum_d attn[c,d] * V[d,n] ----------------
__global__ __launch_bounds__(256) void k_pv_c(const float2* __restrict__ attn, const float2* __restrict__ V,
                                              float2* __restrict__ out) {
  __shared__ float2 at[32][32];
  const int bh = blockIdx.x;
  const int b = bh / H_, h = bh % H_;
  const int n = blockIdx.y * 256 + threadIdx.x;
  for (int i = threadIdx.x; i < 1024; i += 256) at[i >> 5][i & 31] = attn[(size_t)bh * 1024 + i];
  __syncthreads();
  const size_t hb = ((size_t)b * C_ + h * 32) * N_;
  const float2* Vp = V + hb;
  float2 acc[32];
  #pragma unroll
  for (int c = 0; c < 32; c++) acc[c] = make_float2(0.f, 0.f);
  for (int dd = 0; dd < 32; dd++) {
    float2 v = Vp[(size_t)dd * N_ + n];
    #pragma unroll
    for (int c = 0; c < 32; c++) cfma(acc[c], at[c][dd], v);
  }
  float2* Op = out + hb;
  #pragma unroll
  for (int c = 0; c < 32; c++) Op[(size_t)c * N_ + n] = acc[c];
}
__global__ __launch_bounds__(256) void k_pv_r(const float* __restrict__ attn, const float* __restrict__ V,
                                              float* __restrict__ out) {
  __shared__ float at[32][32];
  const int bh = blockIdx.x;
  const int b = bh / H_, h = bh % H_;
  const int n = blockIdx.y * 256 + threadIdx.x;
  for (int i = threadIdx.x; i < 1024; i += 256) at[i >> 5][i & 31] = attn[(size_t)bh * 1024 + i];
  __syncthreads();
  const size_t hb = ((size_t)b * C_ + h * 32) * N_;
  const float* Vp = V + hb;
  float acc[32];
  #pragma unroll
  for (int c = 0; c < 32; c++) acc[c] = 0.f;
  for (int dd = 0; dd < 32; dd++) {
    float v = Vp[(size_t)dd * N_ + n];
    #pragma unroll
    for (int c = 0; c < 32; c++) acc[c] = fmaf(at[c][dd], v, acc[c]);
  }
  float* Op = out + hb;
  #pragma unroll
  for (int c = 0; c < 32; c++) Op[(size_t)c * N_ + n] = acc[c];
}

extern "C" void kernel_launch(void* const* d_in, const int* in_sizes, int n_in,
                              void* d_out, int out_size, void* d_ws, size_t ws_size,
                              hipStream_t stream) {
  (void)in_sizes; (void)n_in; (void)out_size; (void)ws_size;
  const float* x       = (const float*)d_in[0];
  const float* ln1_w   = (const float*)d_in[1];
  const float* ln2_w   = (const float*)d_in[2];
  const float* ln1_b   = (const float*)d_in[3];
  const float* ln2_b   = (const float*)d_in[4];
  const float* f_temp  = (const float*)d_in[5];
  const float* s_temp  = (const float*)d_in[6];
  const float* f_proj  = (const float*)d_in[7];
  const float* s_proj  = (const float*)d_in[8];
  const float* f_w1    = (const float*)d_in[9];
  const float* f_wb1   = (const float*)d_in[10];
  const float* f_bng   = (const float*)d_in[11];
  const float* f_bnb   = (const float*)d_in[12];
  const float* f_w2    = (const float*)d_in[13];
  const float* f_wb2   = (const float*)d_in[14];
  const float* s_q1_w  = (const float*)d_in[15];
  const float* s_q1_b  = (const float*)d_in[16];
  const float* s_k1_w  = (const float*)d_in[17];
  const float* s_k1_b  = (const float*)d_in[18];
  const float* s_v1_w  = (const float*)d_in[19];
  const float* s_v1_b  = (const float*)d_in[20];
  const float* s_q3_w  = (const float*)d_in[21];
  const float* s_k3_w  = (const float*)d_in[22];
  const float* s_v3_w  = (const float*)d_in[23];
  const float* s_c3_w  = (const float*)d_in[24];
  const float* s_q5_w  = (const float*)d_in[25];
  const float* s_k5_w  = (const float*)d_in[26];
  const float* s_v5_w  = (const float*)d_in[27];
  const float* s_c5_w  = (const float*)d_in[28];
  const float* ffdw1_w = (const float*)d_in[29];
  const float* ffdw2_w = (const float*)d_in[30];
  const float* ffproj  = (const float*)d_in[31];
  const float* ffg_w1  = (const float*)d_in[32];
  const float* ffg_b1  = (const float*)d_in[33];
  const float* ffg_bng = (const float*)d_in[34];
  const float* ffg_bnb = (const float*)d_in[35];
  const float* ffg_w2  = (const float*)d_in[36];
  const float* ffg_b2  = (const float*)d_in[37];
  const float* ffg1_w1 = (const float*)d_in[38];
  const float* ffg1_b1 = (const float*)d_in[39];
  const float* ffg1_bng= (const float*)d_in[40];
  const float* ffg1_bnb= (const float*)d_in[41];
  const float* ffg1_w2 = (const float*)d_in[42];
  const float* ffg1_b2 = (const float*)d_in[43];

  // workspace layout (floats). Requires ~267 MB of d_ws.
  float* ws = (float*)d_ws;
  const size_t R = (size_t)B_ * C_ * N_;   // 6,553,600 floats per [B,128,N] image set
  float* xn   = ws;            // R
  float* acc  = ws + R;        // R
  float* bufA = ws + 2 * R;    // 2R (complex [B,128,N] or real [B,256,N])
  float* bufB = ws + 4 * R;    // 2R
  float* bufC = ws + 6 * R;    // 2R
  float* bufD = ws + 8 * R;    // 2R
  float* sm   = ws + 10 * R;   // small pool
  float* nrmQ = sm;                    // 1024
  float* nrmK = sm + 1024;             // 1024
  float* hid  = sm + 2048;             // B*8*N = 409600
  float* part = sm + 2048 + 409600;    // 524288 (float2[131072] used for cplx)
  float* attb = part + 524288;         // 65536 (float2[32768] for cplx)

  dim3 blk(256);
  const int GCONV = P_ / 64;   // 800 blocks, 128co x 64pos MFMA tiles
  const int GLN = P_ / 64;     // 800 blocks for layernorm / gateA
  const int NIMG = B_ * C_;    // 1024
  const dim3 gattn(16, NSPL, B_ * H_);

  // ===== xn = LayerNorm(x) ; xf = fft2(xn) with fused row-norm =====
  k_layernorm<<<GLN, blk, 0, stream>>>(x, ln1_w, ln1_b, xn);
  k_fft2_r2c<<<NIMG, blk, 0, stream>>>(xn, (float2*)bufA, C_, C_, 0, nullptr, 0, NIMG, nrmQ);

  // ===== Attention_F =====
  k_attn_part_c<<<gattn, blk, 0, stream>>>((const float2*)bufA, (const float2*)bufA, (float2*)part);
  k_attn_soft<1><<<B_ * C_, 64, 0, stream>>>(part, nrmQ, nrmQ, f_temp, attb);
  k_pv_c<<<dim3(B_ * H_, N_ / 256), blk, 0, stream>>>((const float2*)attb, (const float2*)bufA, (float2*)bufB);
  k_idft32<<<dim3(B_ * H_, N_ / 64), blk, 0, stream>>>((const float2*)bufB, (float2*)bufC);
  // gated branch first (reads bufA pre/post scale), then merged idft6400+ifft2
  k_gateA<<<GLN, blk, 0, stream>>>((const float2*)bufA, (const float2*)bufA, C_, C_, f_w1, f_wb1, f_bng, f_bnb, hid);
  k_gateB<0><<<dim3(P_ / 256, 2), blk, 0, stream>>>((float2*)bufA, (float2*)bufA, C_, C_, f_w2, f_wb2, hid, nullptr, 0, 0);
  k_iff_combo<<<2 * NIMG, blk, 0, stream>>>((const float2*)bufC, bufD, (const float2*)bufA, bufD + R);
  // a_f: acc = x + f_proj(concat(out_f, out_f_l))
  k_conv1x1<<<GCONV, blk, 0, stream>>>(bufD, bufD + R, 128, 256, 128, f_proj, nullptr, x, acc);

  // ===== Attention_S =====
  k_conv1x1<<<GCONV, blk, 0, stream>>>(xn, xn, 128, 128, 128, s_q1_w, s_q1_b, nullptr, bufA);     // q1
  k_conv1x1<<<GCONV, blk, 0, stream>>>(xn, xn, 128, 128, 128, s_k1_w, s_k1_b, nullptr, bufA + R); // k1
  k_conv1x1<<<GCONV, blk, 0, stream>>>(xn, xn, 128, 128, 128, s_v1_w, s_v1_b, nullptr, bufB);     // v1
  k_gconv35<<<B_ * 128, blk, 0, stream>>>(bufA,     s_q3_w, s_q5_w, bufB + R); // qs
  k_gconv35<<<B_ * 128, blk, 0, stream>>>(bufA + R, s_k3_w, s_k5_w, bufC);     // ks
  k_gconv35<<<B_ * 128, blk, 0, stream>>>(bufB,     s_v3_w, s_v5_w, bufC + R); // vs
  k_rownorm_r<<<B_ * C_, blk, 0, stream>>>(bufB + R, nrmQ);
  k_rownorm_r<<<B_ * C_, blk, 0, stream>>>(bufC, nrmK);
  k_attn_part_r<<<gattn, blk, 0, stream>>>(bufB + R, bufC, part);
  k_attn_soft<0><<<B_ * C_, 64, 0, stream>>>(part, nrmQ, nrmK, s_temp, attb);
  k_pv_r<<<dim3(B_ * H_, N_ / 256), blk, 0, stream>>>(attb, bufC + R, bufA);      // out_s -> A.lo
  k_gconv35<<<B_ * 128, blk, 0, stream>>>(xn, s_c3_w, s_c5_w, bufA + R);          // out_s_l -> A.hi
  // a_s: acc += s_proj(concat(out_s, out_s_l))
  k_conv1x1<<<GCONV, blk, 0, stream>>>(bufA, bufA + R, 128, 256, 128, s_proj, nullptr, acc, acc);

  // ===== FeedForward =====
  k_layernorm<<<GLN, blk, 0, stream>>>(acc, ln2_w, ln2_b, xn);                    // xn2
  k_fft2_r2c<<<NIMG, blk, 0, stream>>>(xn, (float2*)bufA, C_, C_, 0, nullptr, 0, NIMG, nullptr);  // xf2
  k_gateA<<<GLN, blk, 0, stream>>>((const float2*)bufA, (const float2*)bufA, C_, C_, ffg_w1, ffg_b1, ffg_bng, ffg_bnb, hid);
  k_gateB<1><<<dim3(P_ / 256, 2), blk, 0, stream>>>((float2*)bufA, (float2*)bufA, C_, C_, ffg_w2, ffg_b2, hid, bufB, 256, 0); // x_f_g -> cat.lo
  k_dwconv3_gelu<<<B_ * 256, blk, 0, stream>>>(xn, ffdw1_w, bufB, 128, 256, 128); // x_s_g -> cat.hi
  // cf = fft2(cat): one merged 2048-block dispatch (lo -> bufA, hi -> bufC)
  k_fft2_r2c<<<2 * NIMG, blk, 0, stream>>>(bufB, (float2*)bufA, 128, 256, 0, (float2*)bufC, 128, NIMG, nullptr);
  k_gateA<<<GLN, blk, 0, stream>>>((const float2*)bufA, (const float2*)bufC, 128, 256, ffg1_w1, ffg1_b1, ffg1_bng, ffg1_bnb, hid);
  k_gateB<0><<<dim3(P_ / 256, 4), blk, 0, stream>>>((float2*)bufA, (float2*)bufC, 128, 256, ffg1_w2, ffg1_b2, hid, nullptr, 0, 0);
  // x_f2b: merged 2048-block ifft2 pair (bufA -> bufD coff0, bufC -> bufD coff128)
  k_ifft2_abs<<<2 * NIMG, blk, 0, stream>>>((const float2*)bufA, bufD, 128, 256, 0, (const float2*)bufC, 128, NIMG);
  k_ffdw2<<<B_ * 256, blk, 0, stream>>>(bufB, ffdw2_w, bufA);                     // x_s2b (real [B,256,N] in A)
  // out = x1 + ff_proj(concat(x_f2b, x_s2b))
  k_conv1x1<<<GCONV, blk, 0, stream>>>(bufD, bufA, 256, 512, 128, ffproj, nullptr, acc, (float*)d_out);
}

// Round 18
// 1167.173 us; speedup vs baseline: 1.0503x; 1.0503x over previous
//
#include <hip/hip_runtime.h>
#include <math.h>

#define DI __device__ __forceinline__

constexpr int B_ = 8, C_ = 128, H_ = 4, S_ = 80, N_ = 6400;
constexpr int P_ = B_ * N_;                 // 51200 spatial positions
constexpr int NSPL = 2;                     // n-chunks for attention partials
constexpr float PI2 = 6.283185307179586f;
constexpr float BN_SC = 0.9999950000374997f;  // 1/sqrt(1+1e-5)

typedef __attribute__((ext_vector_type(8))) short bf16x8;
typedef __attribute__((ext_vector_type(4))) float f32x4;

DI void cfma(float2& a, float2 u, float2 v) {
  a.x = fmaf(u.x, v.x, a.x); a.x = fmaf(-u.y, v.y, a.x);
  a.y = fmaf(u.x, v.y, a.y); a.y = fmaf(u.y, v.x, a.y);
}
DI float2 cmul(float2 u, float2 v) {
  return make_float2(u.x * v.x - u.y * v.y, u.x * v.y + u.y * v.x);
}
DI float gelu_mul(float m) {  // gelu(m, exact) * m
  return 0.5f * m * (1.f + erff(m * 0.7071067811865476f)) * m;
}
DI unsigned short bf16_rn(float f) {  // round-to-nearest-even fp32 -> bf16
  union { float f; unsigned int u; } v; v.f = f;
  unsigned int u = v.u;
  return (unsigned short)((u + 0x7fffu + ((u >> 16) & 1u)) >> 16);
}

// ---------------- LayerNorm over channel dim (4-way channel-split, 800 blocks) ----------------
__global__ __launch_bounds__(256) void k_layernorm(const float* __restrict__ in,
    const float* __restrict__ w, const float* __restrict__ bb, float* __restrict__ out) {
  __shared__ float redS[4][64], redS2[4][64];
  __shared__ float muv[64], invv[64];
  const int tid = threadIdx.x;
  const int g = tid >> 6, l = tid & 63;
  const int p = blockIdx.x * 64 + l;
  const int b = p / N_, n = p % N_;
  const float* xp = in + (size_t)b * C_ * N_ + n;
  float s = 0.f, s2 = 0.f;
  for (int c = g * 32; c < g * 32 + 32; c++) {
    float v = xp[(size_t)c * N_];
    s += v; s2 = fmaf(v, v, s2);
  }
  redS[g][l] = s; redS2[g][l] = s2;
  __syncthreads();
  if (g == 0) {
    float ts  = redS[0][l] + redS[1][l] + redS[2][l] + redS[3][l];
    float ts2 = redS2[0][l] + redS2[1][l] + redS2[2][l] + redS2[3][l];
    float mu = ts * (1.f / C_);
    float var = ts2 * (1.f / C_) - mu * mu;
    muv[l] = mu; invv[l] = rsqrtf(var + 1e-5f);
  }
  __syncthreads();
  const float mu = muv[l], inv = invv[l];
  float* op = out + (size_t)b * C_ * N_ + n;
  for (int c = g * 32; c < g * 32 + 32; c++) {
    float v = xp[(size_t)c * N_];
    op[(size_t)c * N_] = (v - mu) * inv * w[c] + bb[c];
  }
}

// ============ register-tiled 80x80 2D DFT kernels ============

// ---------------- 2D FFT (80x80) real->complex; Hermitian mirrored; optional 2nd output set; optional row-norm ----------------
__global__ __launch_bounds__(256) void k_fft2_r2c(const float* __restrict__ in, float2* __restrict__ out,
                                                  int nCh, int inCtot, int inCoff,
                                                  float2* __restrict__ out2, int inCoff2, int nimg,
                                                  float* __restrict__ nrm) {
  __shared__ float2 data[N_];
  __shared__ float2 tw[80];
  int img = blockIdx.x;
  float2* op;
  int coff;
  if (img >= nimg) { img -= nimg; op = out2 + (size_t)img * N_; coff = inCoff2; }
  else { op = out + (size_t)img * N_; coff = inCoff; }
  const int b = img / nCh, ch = img % nCh;
  const float* ip = in + ((size_t)b * inCtot + coff + ch) * N_;
  const int tid = threadIdx.x;
  float* dataR = (float*)data;
  if (tid < 80) { float a = -PI2 * (float)tid * (1.f / 80.f); float sv, cv; sincosf(a, &sv, &cv); tw[tid] = make_float2(cv, sv); }
  for (int i = tid; i < N_; i += 256) dataR[i] = ip[i];
  __syncthreads();
  const int r0 = (tid >> 4) * 5;
  const int cg = tid & 15;
  float2 a1[5][3];
  for (int j = 0; j < 5; j++)
    for (int i = 0; i < 3; i++) a1[j][i] = make_float2(0.f, 0.f);
  {
    int idx[3] = {0, 0, 0};
    for (int c = 0; c < 80; ++c) {
      float d[5]; float2 t[3];
      #pragma unroll
      for (int j = 0; j < 5; j++) d[j] = dataR[(r0 + j) * 80 + c];
      #pragma unroll
      for (int i = 0; i < 3; i++) t[i] = tw[idx[i]];
      #pragma unroll
      for (int j = 0; j < 5; j++) {
        #pragma unroll
        for (int i = 0; i < 3; i++) {
          a1[j][i].x = fmaf(d[j], t[i].x, a1[j][i].x);
          a1[j][i].y = fmaf(d[j], t[i].y, a1[j][i].y);
        }
      }
      #pragma unroll
      for (int i = 0; i < 3; i++) { idx[i] += cg + 16 * i; if (idx[i] >= 80) idx[i] -= 80; }
    }
  }
  __syncthreads();
  #pragma unroll
  for (int i = 0; i < 3; i++) {
    const int k = cg + 16 * i;
    #pragma unroll
    for (int j = 0; j < 5; j++) {
      if (k <= 40) data[(r0 + j) * 80 + k] = a1[j][i];
      if (k >= 1 && k <= 39) data[(r0 + j) * 80 + 80 - k] = make_float2(a1[j][i].x, -a1[j][i].y);
    }
  }
  __syncthreads();
  const int k0 = (tid & 15) * 5;
  const int rg = tid >> 4;
  float2 a2[3][5];
  for (int j = 0; j < 3; j++)
    for (int i = 0; i < 5; i++) a2[j][i] = make_float2(0.f, 0.f);
  {
    int idx[3] = {0, 0, 0};
    for (int r = 0; r < 80; ++r) {
      float2 d[5]; float2 t[3];
      #pragma unroll
      for (int i = 0; i < 5; i++) d[i] = data[r * 80 + k0 + i];
      #pragma unroll
      for (int j = 0; j < 3; j++) t[j] = tw[idx[j]];
      #pragma unroll
      for (int j = 0; j < 3; j++) {
        #pragma unroll
        for (int i = 0; i < 5; i++) cfma(a2[j][i], d[i], t[j]);
      }
      #pragma unroll
      for (int j = 0; j < 3; j++) { idx[j] += rg + 16 * j; if (idx[j] >= 80) idx[j] -= 80; }
    }
  }
  #pragma unroll
  for (int j = 0; j < 3; j++) {
    const int k1 = rg + 16 * j;
    #pragma unroll
    for (int i = 0; i < 5; i++) {
      const int k2 = k0 + i;
      if (k1 <= 40) op[k1 * 80 + k2] = a2[j][i];
      if (k1 >= 1 && k1 <= 39) {
        const int m2 = (k2 == 0) ? 0 : 80 - k2;
        op[(80 - k1) * 80 + m2] = make_float2(a2[j][i].x, -a2[j][i].y);
      }
    }
  }
  if (nrm) {   // fused per-image L2 norm (mirrored halves contribute 2x)
    float s = 0.f;
    #pragma unroll
    for (int j = 0; j < 3; j++) {
      const int k1 = rg + 16 * j;
      if (k1 <= 40) {
        const float wgt = (k1 == 0 || k1 == 40) ? 1.f : 2.f;
        #pragma unroll
        for (int i = 0; i < 5; i++)
          s += wgt * (a2[j][i].x * a2[j][i].x + a2[j][i].y * a2[j][i].y);
      }
    }
    __syncthreads();
    float* red = (float*)data;
    red[tid] = s;
    __syncthreads();
    for (int st = 128; st > 0; st >>= 1) { if (tid < st) red[tid] += red[tid + st]; __syncthreads(); }
    if (tid == 0) nrm[img] = fmaxf(sqrtf(red[0]), 1e-12f);
  }
}

// ---------------- 2D IFFT (80x80) of HERMITIAN input -> |real| (optional 2nd input set) ----------------
__global__ __launch_bounds__(256) void k_ifft2_abs(const float2* __restrict__ in, float* __restrict__ out,
                                                   int inC, int outCtot, int outCoff,
                                                   const float2* __restrict__ in2, int outCoff2, int nimg) {
  __shared__ float2 data[N_];
  __shared__ float2 tw[80];
  int img = blockIdx.x;
  const float2* ip;
  int coff;
  if (img >= nimg) { img -= nimg; ip = in2 + (size_t)img * N_; coff = outCoff2; }
  else { ip = in + (size_t)img * N_; coff = outCoff; }
  const int b = img / inC, ch = img % inC;
  float* op = out + ((size_t)b * outCtot + coff + ch) * N_;
  const int tid = threadIdx.x;
  if (tid < 80) { float a = PI2 * (float)tid * (1.f / 80.f); float sv, cv; sincosf(a, &sv, &cv); tw[tid] = make_float2(cv, sv); }
  for (int i = tid; i < N_; i += 256) data[i] = ip[i];
  __syncthreads();
  const int rg = tid >> 4;
  const int cg = tid & 15;
  float2 E[3][3], O[3][3];
  for (int j = 0; j < 3; j++)
    for (int i = 0; i < 3; i++) { E[j][i] = make_float2(0.f, 0.f); O[j][i] = make_float2(0.f, 0.f); }
  {
    int idx[3], inc[3];
    #pragma unroll
    for (int i = 0; i < 3; i++) { idx[i] = 0; inc[i] = (2 * (cg + 16 * i)) % 80; }
    for (int m = 0; m < 40; ++m) {
      float4 z[3]; float2 t[3];
      #pragma unroll
      for (int j = 0; j < 3; j++) z[j] = *(const float4*)&data[(rg + 16 * j) * 80 + 2 * m];
      #pragma unroll
      for (int i = 0; i < 3; i++) t[i] = tw[idx[i]];
      #pragma unroll
      for (int j = 0; j < 3; j++) {
        float2 ze = make_float2(z[j].x, z[j].y);
        float2 zo = make_float2(z[j].z, z[j].w);
        #pragma unroll
        for (int i = 0; i < 3; i++) { cfma(E[j][i], ze, t[i]); cfma(O[j][i], zo, t[i]); }
      }
      #pragma unroll
      for (int i = 0; i < 3; i++) { idx[i] += inc[i]; if (idx[i] >= 80) idx[i] -= 80; }
    }
  }
  __syncthreads();
  #pragma unroll
  for (int j = 0; j < 3; j++) {
    const int r = rg + 16 * j;
    if (r <= 40) {
      #pragma unroll
      for (int i = 0; i < 3; i++) {
        const int n2 = cg + 16 * i;
        if (n2 < 40) {
          float2 u = cmul(tw[n2], O[j][i]);
          data[r * 80 + n2]      = make_float2(E[j][i].x + u.x, E[j][i].y + u.y);
          data[r * 80 + n2 + 40] = make_float2(E[j][i].x - u.x, E[j][i].y - u.y);
        }
      }
    }
  }
  __syncthreads();
  const int r0 = (tid >> 4) * 5;
  const int k0 = (tid & 15) * 5;
  float accR[5][5];
  for (int j = 0; j < 5; j++)
    for (int i = 0; i < 5; i++) accR[j][i] = 0.f;
  {
    int idx[5];
    #pragma unroll
    for (int j = 0; j < 5; j++) idx[j] = r0 + j;
    for (int r = 1; r <= 39; ++r) {
      float2 d[5]; float2 t[5];
      #pragma unroll
      for (int i = 0; i < 5; i++) d[i] = data[r * 80 + k0 + i];
      #pragma unroll
      for (int j = 0; j < 5; j++) t[j] = tw[idx[j]];
      #pragma unroll
      for (int j = 0; j < 5; j++) {
        #pragma unroll
        for (int i = 0; i < 5; i++) {
          accR[j][i] = fmaf(t[j].x, d[i].x, accR[j][i]);
          accR[j][i] = fmaf(-t[j].y, d[i].y, accR[j][i]);
        }
      }
      #pragma unroll
      for (int j = 0; j < 5; j++) { idx[j] += r0 + j; if (idx[j] >= 80) idx[j] -= 80; }
    }
  }
  #pragma unroll
  for (int i = 0; i < 5; i++) {
    float2 b0 = data[k0 + i];
    float2 b40 = data[40 * 80 + k0 + i];
    #pragma unroll
    for (int j = 0; j < 5; j++) {
      float s40 = ((r0 + j) & 1) ? -b40.x : b40.x;
      float res = 2.f * accR[j][i] + b0.x + s40;
      op[(r0 + j) * 80 + k0 + i] = fabsf(res) * (1.f / (float)N_);
    }
  }
}

// ---------------- combo: blocks <1024 do 6400-pt IDFT+abs; blocks >=1024 do Hermitian ifft2+abs ----------------
__global__ __launch_bounds__(256) void k_iff_combo(const float2* __restrict__ in6400, float* __restrict__ out6400,
                                                   const float2* __restrict__ inF, float* __restrict__ outF) {
  __shared__ float2 data[N_];
  __shared__ float2 tw[80];
  __shared__ float2 tws[80];
  const int tid = threadIdx.x;
  if (blockIdx.x < (unsigned)(B_ * C_)) {
    // ---- idft6400_abs body ----
    const int row = blockIdx.x;
    const float2* ip = in6400 + (size_t)row * N_;
    float* op = out6400 + (size_t)row * N_;
    if (tid < 80) {
      float a = PI2 * (float)tid * (1.f / 80.f); float sv, cv; sincosf(a, &sv, &cv); tw[tid] = make_float2(cv, sv);
      float a2 = PI2 * (float)tid * (1.f / 6400.f); sincosf(a2, &sv, &cv); tws[tid] = make_float2(cv, sv);
    }
    for (int i = tid; i < N_; i += 256) data[i] = ip[i];
    __syncthreads();
    {
      const int r0 = (tid >> 4) * 5;
      const int cg = tid & 15;
      float2 E[5][3], O[5][3];
      for (int j = 0; j < 5; j++)
        for (int i = 0; i < 3; i++) { E[j][i] = make_float2(0.f, 0.f); O[j][i] = make_float2(0.f, 0.f); }
      int idx[3], inc[3];
      #pragma unroll
      for (int i = 0; i < 3; i++) { idx[i] = 0; inc[i] = (2 * (cg + 16 * i)) % 80; }
      for (int m = 0; m < 40; ++m) {
        float2 xe[5], xo[5], t[3];
        #pragma unroll
        for (int j = 0; j < 5; j++) {
          xe[j] = data[(r0 + j) + 160 * m];
          xo[j] = data[(r0 + j) + 160 * m + 80];
        }
        #pragma unroll
        for (int i = 0; i < 3; i++) t[i] = tw[idx[i]];
        #pragma unroll
        for (int j = 0; j < 5; j++) {
          #pragma unroll
          for (int i = 0; i < 3; i++) { cfma(E[j][i], xe[j], t[i]); cfma(O[j][i], xo[j], t[i]); }
        }
        #pragma unroll
        for (int i = 0; i < 3; i++) { idx[i] += inc[i]; if (idx[i] >= 80) idx[i] -= 80; }
      }
      __syncthreads();
      #pragma unroll
      for (int j = 0; j < 5; j++) {
        const int k1 = r0 + j;
        #pragma unroll
        for (int i = 0; i < 3; i++) {
          const int n2 = cg + 16 * i;
          if (n2 < 40) {
            float2 u = cmul(tw[n2], O[j][i]);
            float2 Ap = make_float2(E[j][i].x + u.x, E[j][i].y + u.y);
            float2 Am = make_float2(E[j][i].x - u.x, E[j][i].y - u.y);
            int t6 = k1 * n2; int q = t6 / 80, s6 = t6 - q * 80;
            data[k1 * 80 + n2] = cmul(Ap, cmul(tw[q], tws[s6]));
            int t6b = k1 * (n2 + 40); int qb = t6b / 80, sb = t6b - qb * 80;
            data[k1 * 80 + n2 + 40] = cmul(Am, cmul(tw[qb], tws[sb]));
          }
        }
      }
    }
    __syncthreads();
    {
      const int rg5 = tid >> 3;
      const int cg5 = tid & 7;
      float2 E2[5][3], O2[5][3];
      for (int i = 0; i < 5; i++)
        for (int j = 0; j < 3; j++) { E2[i][j] = make_float2(0.f, 0.f); O2[i][j] = make_float2(0.f, 0.f); }
      int idx[5], inc[5];
      #pragma unroll
      for (int i = 0; i < 5; i++) { idx[i] = 0; inc[i] = (2 * (cg5 * 5 + i)) % 80; }
      int n2c[3];
      #pragma unroll
      for (int j = 0; j < 3; j++) { int n2 = rg5 + 32 * j; n2c[j] = (n2 < 80) ? n2 : 0; }
      for (int m = 0; m < 40; ++m) {
        float2 ae[3], ao[3], t[5];
        #pragma unroll
        for (int j = 0; j < 3; j++) {
          ae[j] = data[(2 * m) * 80 + n2c[j]];
          ao[j] = data[(2 * m + 1) * 80 + n2c[j]];
        }
        #pragma unroll
        for (int i = 0; i < 5; i++) t[i] = tw[idx[i]];
        #pragma unroll
        for (int i = 0; i < 5; i++) {
          #pragma unroll
          for (int j = 0; j < 3; j++) { cfma(E2[i][j], ae[j], t[i]); cfma(O2[i][j], ao[j], t[i]); }
        }
        #pragma unroll
        for (int i = 0; i < 5; i++) { idx[i] += inc[i]; if (idx[i] >= 80) idx[i] -= 80; }
      }
      #pragma unroll
      for (int i = 0; i < 5; i++) {
        const int n1 = cg5 * 5 + i;
        #pragma unroll
        for (int j = 0; j < 3; j++) {
          const int n2 = rg5 + 32 * j;
          if (n2 < 80) {
            float2 u = cmul(tw[n1], O2[i][j]);
            float2 o1 = make_float2(E2[i][j].x + u.x, E2[i][j].y + u.y);
            float2 o2 = make_float2(E2[i][j].x - u.x, E2[i][j].y - u.y);
            op[n1 * 80 + n2] = sqrtf(o1.x * o1.x + o1.y * o1.y) * (1.f / 6400.f);
            op[(n1 + 40) * 80 + n2] = sqrtf(o2.x * o2.x + o2.y * o2.y) * (1.f / 6400.f);
          }
        }
      }
    }
  } else {
    // ---- Hermitian ifft2_abs body (img = blk - 1024; out = outF + img*N_) ----
    const int img = blockIdx.x - B_ * C_;
    const float2* ip = inF + (size_t)img * N_;
    float* op = outF + (size_t)img * N_;
    if (tid < 80) { float a = PI2 * (float)tid * (1.f / 80.f); float sv, cv; sincosf(a, &sv, &cv); tw[tid] = make_float2(cv, sv); }
    for (int i = tid; i < N_; i += 256) data[i] = ip[i];
    __syncthreads();
    const int rg = tid >> 4;
    const int cg = tid & 15;
    float2 E[3][3], O[3][3];
    for (int j = 0; j < 3; j++)
      for (int i = 0; i < 3; i++) { E[j][i] = make_float2(0.f, 0.f); O[j][i] = make_float2(0.f, 0.f); }
    {
      int idx[3], inc[3];
      #pragma unroll
      for (int i = 0; i < 3; i++) { idx[i] = 0; inc[i] = (2 * (cg + 16 * i)) % 80; }
      for (int m = 0; m < 40; ++m) {
        float4 z[3]; float2 t[3];
        #pragma unroll
        for (int j = 0; j < 3; j++) z[j] = *(const float4*)&data[(rg + 16 * j) * 80 + 2 * m];
        #pragma unroll
        for (int i = 0; i < 3; i++) t[i] = tw[idx[i]];
        #pragma unroll
        for (int j = 0; j < 3; j++) {
          float2 ze = make_float2(z[j].x, z[j].y);
          float2 zo = make_float2(z[j].z, z[j].w);
          #pragma unroll
          for (int i = 0; i < 3; i++) { cfma(E[j][i], ze, t[i]); cfma(O[j][i], zo, t[i]); }
        }
        #pragma unroll
        for (int i = 0; i < 3; i++) { idx[i] += inc[i]; if (idx[i] >= 80) idx[i] -= 80; }
      }
    }
    __syncthreads();
    #pragma unroll
    for (int j = 0; j < 3; j++) {
      const int r = rg + 16 * j;
      if (r <= 40) {
        #pragma unroll
        for (int i = 0; i < 3; i++) {
          const int n2 = cg + 16 * i;
          if (n2 < 40) {
            float2 u = cmul(tw[n2], O[j][i]);
            data[r * 80 + n2]      = make_float2(E[j][i].x + u.x, E[j][i].y + u.y);
            data[r * 80 + n2 + 40] = make_float2(E[j][i].x - u.x, E[j][i].y - u.y);
          }
        }
      }
    }
    __syncthreads();
    const int r0 = (tid >> 4) * 5;
    const int k0 = (tid & 15) * 5;
    float accR[5][5];
    for (int j = 0; j < 5; j++)
      for (int i = 0; i < 5; i++) accR[j][i] = 0.f;
    {
      int idx[5];
      #pragma unroll
      for (int j = 0; j < 5; j++) idx[j] = r0 + j;
      for (int r = 1; r <= 39; ++r) {
        float2 d[5]; float2 t[5];
        #pragma unroll
        for (int i = 0; i < 5; i++) d[i] = data[r * 80 + k0 + i];
        #pragma unroll
        for (int j = 0; j < 5; j++) t[j] = tw[idx[j]];
        #pragma unroll
        for (int j = 0; j < 5; j++) {
          #pragma unroll
          for (int i = 0; i < 5; i++) {
            accR[j][i] = fmaf(t[j].x, d[i].x, accR[j][i]);
            accR[j][i] = fmaf(-t[j].y, d[i].y, accR[j][i]);
          }
        }
        #pragma unroll
        for (int j = 0; j < 5; j++) { idx[j] += r0 + j; if (idx[j] >= 80) idx[j] -= 80; }
      }
    }
    #pragma unroll
    for (int i = 0; i < 5; i++) {
      float2 b0 = data[k0 + i];
      float2 b40 = data[40 * 80 + k0 + i];
      #pragma unroll
      for (int j = 0; j < 5; j++) {
        float s40 = ((r0 + j) & 1) ? -b40.x : b40.x;
        float res = 2.f * accR[j][i] + b0.x + s40;
        op[(r0 + j) * 80 + k0 + i] = fabsf(res) * (1.f / (float)N_);
      }
    }
  }
}

// ---------------- 32-point IDFT along channel-within-head (radix-2) ----------------
__global__ __launch_bounds__(256) void k_idft32(const float2* __restrict__ in, float2* __restrict__ out) {
  __shared__ float2 tile[32][64];
  __shared__ float2 tw[32];
  const int bh = blockIdx.x;
  const int b = bh / H_, h = bh % H_;
  const int n0 = blockIdx.y * 64;
  const int tid = threadIdx.x;
  if (tid < 32) { float a = PI2 * (float)tid * (1.f / 32.f); float sv, cv; sincosf(a, &sv, &cv); tw[tid] = make_float2(cv, sv); }
  const float2* ip = in + ((size_t)b * C_ + h * 32) * N_ + n0;
  for (int i = tid; i < 2048; i += 256) { int c = i / 64, pp = i % 64; tile[c][pp] = ip[(size_t)c * N_ + pp]; }
  __syncthreads();
  const int pp = tid & 63, grp = tid >> 6;   // 4 groups x 4 pairs (cp, cp+16)
  float2 E[4], O[4];
  #pragma unroll
  for (int j = 0; j < 4; j++) { E[j] = make_float2(0.f, 0.f); O[j] = make_float2(0.f, 0.f); }
  int idx[4], inc[4];
  #pragma unroll
  for (int j = 0; j < 4; j++) { idx[j] = 0; inc[j] = (2 * (grp * 4 + j)) & 31; }
  for (int m = 0; m < 16; m++) {
    float2 ve = tile[2 * m][pp];
    float2 vo = tile[2 * m + 1][pp];
    #pragma unroll
    for (int j = 0; j < 4; j++) {
      cfma(E[j], ve, tw[idx[j]]);
      cfma(O[j], vo, tw[idx[j]]);
      idx[j] = (idx[j] + inc[j]) & 31;
    }
  }
  float2* op = out + ((size_t)b * C_ + h * 32) * N_ + n0;
  #pragma unroll
  for (int j = 0; j < 4; j++) {
    const int cp = grp * 4 + j;
    float2 u = cmul(tw[cp], O[j]);
    op[(size_t)cp * N_ + pp]        = make_float2((E[j].x + u.x) * (1.f / 32.f), (E[j].y + u.y) * (1.f / 32.f));
    op[(size_t)(cp + 16) * N_ + pp] = make_float2((E[j].x - u.x) * (1.f / 32.f), (E[j].y - u.y) * (1.f / 32.f));
  }
}

// ---------------- gate stage A (4-way channel-split, 800 blocks) ----------------
__global__ __launch_bounds__(256) void k_gateA(const float2* __restrict__ zA, const float2* __restrict__ zB,
    int split, int Cin, const float* __restrict__ W1, const float* __restrict__ b1,
    const float* __restrict__ g, const float* __restrict__ bt, float* __restrict__ hid) {
  __shared__ float w[8 * 256];
  __shared__ float red[4][64][9];  // padded to 9 to avoid bank conflicts
  const int tid = threadIdx.x;
  const int grp = tid >> 6, l = tid & 63;
  for (int i = tid; i < 8 * Cin; i += 256) w[i] = W1[i];
  __syncthreads();
  const int p = blockIdx.x * 64 + l;
  const int b = p / N_, n = p % N_;
  const int cpg = Cin / 4;
  float acc[8] = {0.f, 0.f, 0.f, 0.f, 0.f, 0.f, 0.f, 0.f};
  for (int ci = grp * cpg; ci < (grp + 1) * cpg; ci++) {
    const float2* src = (ci < split) ? (zA + ((size_t)b * split + ci) * N_ + n)
                                     : (zB + ((size_t)b * (Cin - split) + (ci - split)) * N_ + n);
    float v = src->x;
    #pragma unroll
    for (int j = 0; j < 8; j++) acc[j] = fmaf(w[j * Cin + ci], v, acc[j]);
  }
  #pragma unroll
  for (int j = 0; j < 8; j++) red[grp][l][j] = acc[j];
  __syncthreads();
  if (grp == 0) {
    #pragma unroll
    for (int j = 0; j < 8; j++) {
      float t = red[0][l][j] + red[1][l][j] + red[2][l][j] + red[3][l][j];
      float y = (t + b1[j]) * (g[j] * BN_SC) + bt[j];
      hid[((size_t)b * 8 + j) * N_ + n] = fmaxf(y, 0.f);
    }
  }
}

// ---------------- gate stage B (co-split over gridDim.y, 64 co per block) ----------------
template <int MODE>
__global__ __launch_bounds__(256) void k_gateB(float2* __restrict__ zA, float2* __restrict__ zB,
    int split, int Cout, const float* __restrict__ W2, const float* __restrict__ b2,
    const float* __restrict__ hid, float* __restrict__ outR, int outCtot, int outCoff) {
  __shared__ float w[64 * 8];
  __shared__ float bb[64];
  const int tid = threadIdx.x;
  const int cobase = blockIdx.y * 64;
  for (int i = tid; i < 64 * 8; i += 256) w[i] = W2[cobase * 8 + i];
  for (int i = tid; i < 64; i += 256) bb[i] = b2[cobase + i];
  __syncthreads();
  const int p = blockIdx.x * 256 + tid;
  const int b = p / N_, n = p % N_;
  float h[8];
  #pragma unroll
  for (int j = 0; j < 8; j++) h[j] = hid[((size_t)b * 8 + j) * N_ + n];
  for (int co = 0; co < 64; co++) {
    const int gco = cobase + co;
    float t = bb[co];
    #pragma unroll
    for (int j = 0; j < 8; j++) t = fmaf(w[co * 8 + j], h[j], t);
    float sg = 1.f / (1.f + expf(-t));
    float2* zp = (gco < split) ? (zA + ((size_t)b * split + gco) * N_ + n)
                               : (zB + ((size_t)b * (Cout - split) + (gco - split)) * N_ + n);
    float2 z = *zp;
    if (MODE == 0) {
      zp->x = z.x * sg; zp->y = z.y * sg;
    } else {
      float m = sg * sqrtf(z.x * z.x + z.y * z.y);
      outR[((size_t)b * outCtot + outCoff + gco) * N_ + n] = gelu_mul(m);
    }
  }
}

// ---------------- 1x1 conv as bf16 MFMA GEMM: 128co x 64pos per block ----------------
__global__ __launch_bounds__(256) void k_conv1x1(const float* __restrict__ inA, const float* __restrict__ inB,
    int split, int Cin, int Cout, const float* __restrict__ W, const float* __restrict__ bias,
    const float* __restrict__ resid, float* __restrict__ out) {
  __shared__ unsigned int xlds[16][68];    // 4.25 KB
  const int tid = threadIdx.x;
  const int lane = tid & 63, wv = tid >> 6;
  const int p0 = blockIdx.x * 64;
  const int b = p0 / N_, n0 = p0 % N_;
  const int laneco = lane & 15, lanek = lane >> 4;
  const int kA = lanek * 8;
  f32x4 acc[2][4];
  #pragma unroll
  for (int g = 0; g < 2; g++)
    #pragma unroll
    for (int f = 0; f < 4; f++) acc[g][f] = (f32x4){0.f, 0.f, 0.f, 0.f};
  for (int cb = 0; cb < Cin; cb += 32) {
    const float* src = (cb < split) ? (inA + ((size_t)b * split + cb) * N_)
                                    : (inB + ((size_t)b * (Cin - split) + (cb - split)) * N_);
    bf16x8 af[2];
    #pragma unroll
    for (int g = 0; g < 2; g++) {
      const float* wp = W + (size_t)(wv * 32 + g * 16 + laneco) * Cin + cb + kA;
      float4 w0 = *(const float4*)wp;
      float4 w1 = *(const float4*)(wp + 4);
      af[g][0] = (short)bf16_rn(w0.x); af[g][1] = (short)bf16_rn(w0.y);
      af[g][2] = (short)bf16_rn(w0.z); af[g][3] = (short)bf16_rn(w0.w);
      af[g][4] = (short)bf16_rn(w1.x); af[g][5] = (short)bf16_rn(w1.y);
      af[g][6] = (short)bf16_rn(w1.z); af[g][7] = (short)bf16_rn(w1.w);
    }
    __syncthreads();   // previous-iter xlds reads complete
    #pragma unroll
    for (int r = 0; r < 4; r++) {
      const int kb = wv * 4 + r;
      float e = src[(size_t)(2 * kb) * N_ + n0 + lane];
      float o = src[(size_t)(2 * kb + 1) * N_ + n0 + lane];
      xlds[kb][lane] = (unsigned int)bf16_rn(e) | ((unsigned int)bf16_rn(o) << 16);
    }
    __syncthreads();
    #pragma unroll
    for (int f = 0; f < 4; f++) {
      const int pos = f * 16 + laneco;
      const int kb0 = lanek * 4;
      union { bf16x8 v; unsigned int u[4]; } bu;
      bu.u[0] = xlds[kb0 + 0][pos];
      bu.u[1] = xlds[kb0 + 1][pos];
      bu.u[2] = xlds[kb0 + 2][pos];
      bu.u[3] = xlds[kb0 + 3][pos];
      #pragma unroll
      for (int g = 0; g < 2; g++)
        acc[g][f] = __builtin_amdgcn_mfma_f32_16x16x32_bf16(af[g], bu.v, acc[g][f], 0, 0, 0);
    }
  }
  #pragma unroll
  for (int g = 0; g < 2; g++) {
    #pragma unroll
    for (int f = 0; f < 4; f++) {
      #pragma unroll
      for (int r = 0; r < 4; r++) {
        const int co = wv * 32 + g * 16 + lanek * 4 + r;
        float v = acc[g][f][r];
        if (bias) v += bias[co];
        const size_t off = ((size_t)b * Cout + co) * N_ + n0 + f * 16 + laneco;
        if (resid) v += resid[off];
        out[off] = v;
      }
    }
  }
}

// ---------------- fused q1/k1/v1 1x1 convs: blockIdx.y selects weight/output set ----------------
__global__ __launch_bounds__(256) void k_conv1x1_qkv(const float* __restrict__ in,
    const float* __restrict__ W0, const float* __restrict__ b0, float* __restrict__ o0,
    const float* __restrict__ W1, const float* __restrict__ b1, float* __restrict__ o1,
    const float* __restrict__ W2, const float* __restrict__ b2, float* __restrict__ o2) {
  __shared__ unsigned int xlds[16][68];
  const float* W    = (blockIdx.y == 0) ? W0 : (blockIdx.y == 1) ? W1 : W2;
  const float* bias = (blockIdx.y == 0) ? b0 : (blockIdx.y == 1) ? b1 : b2;
  float* out        = (blockIdx.y == 0) ? o0 : (blockIdx.y == 1) ? o1 : o2;
  const int tid = threadIdx.x;
  const int lane = tid & 63, wv = tid >> 6;
  const int p0 = blockIdx.x * 64;
  const int b = p0 / N_, n0 = p0 % N_;
  const int laneco = lane & 15, lanek = lane >> 4;
  const int kA = lanek * 8;
  f32x4 acc[2][4];
  #pragma unroll
  for (int g = 0; g < 2; g++)
    #pragma unroll
    for (int f = 0; f < 4; f++) acc[g][f] = (f32x4){0.f, 0.f, 0.f, 0.f};
  for (int cb = 0; cb < 128; cb += 32) {
    const float* src = in + ((size_t)b * 128 + cb) * N_;
    bf16x8 af[2];
    #pragma unroll
    for (int g = 0; g < 2; g++) {
      const float* wp = W + (size_t)(wv * 32 + g * 16 + laneco) * 128 + cb + kA;
      float4 w0 = *(const float4*)wp;
      float4 w1 = *(const float4*)(wp + 4);
      af[g][0] = (short)bf16_rn(w0.x); af[g][1] = (short)bf16_rn(w0.y);
      af[g][2] = (short)bf16_rn(w0.z); af[g][3] = (short)bf16_rn(w0.w);
      af[g][4] = (short)bf16_rn(w1.x); af[g][5] = (short)bf16_rn(w1.y);
      af[g][6] = (short)bf16_rn(w1.z); af[g][7] = (short)bf16_rn(w1.w);
    }
    __syncthreads();
    #pragma unroll
    for (int r = 0; r < 4; r++) {
      const int kb = wv * 4 + r;
      float e = src[(size_t)(2 * kb) * N_ + n0 + lane];
      float o = src[(size_t)(2 * kb + 1) * N_ + n0 + lane];
      xlds[kb][lane] = (unsigned int)bf16_rn(e) | ((unsigned int)bf16_rn(o) << 16);
    }
    __syncthreads();
    #pragma unroll
    for (int f = 0; f < 4; f++) {
      const int pos = f * 16 + laneco;
      const int kb0 = lanek * 4;
      union { bf16x8 v; unsigned int u[4]; } bu;
      bu.u[0] = xlds[kb0 + 0][pos];
      bu.u[1] = xlds[kb0 + 1][pos];
      bu.u[2] = xlds[kb0 + 2][pos];
      bu.u[3] = xlds[kb0 + 3][pos];
      #pragma unroll
      for (int g = 0; g < 2; g++)
        acc[g][f] = __builtin_amdgcn_mfma_f32_16x16x32_bf16(af[g], bu.v, acc[g][f], 0, 0, 0);
    }
  }
  #pragma unroll
  for (int g = 0; g < 2; g++) {
    #pragma unroll
    for (int f = 0; f < 4; f++) {
      #pragma unroll
      for (int r = 0; r < 4; r++) {
        const int co = wv * 32 + g * 16 + lanek * 4 + r;
        float v = acc[g][f][r] + bias[co];
        out[((size_t)b * 128 + co) * N_ + n0 + f * 16 + laneco] = v;
      }
    }
  }
}

// ---------------- grouped conv 3x3(pad1) + 5x5(pad2), groups=64: zero-padded halo, 40-row halves ----------------
template <int NSETS>
__global__ __launch_bounds__(256) void k_gconv35(const float* __restrict__ inQ,
    const float* __restrict__ w3Q, const float* __restrict__ w5Q, float* __restrict__ outQ,
    const float* __restrict__ inK, const float* __restrict__ w3K, const float* __restrict__ w5K, float* __restrict__ outK,
    const float* __restrict__ inV, const float* __restrict__ w3V, const float* __restrict__ w5V, float* __restrict__ outV) {
  __shared__ float tt[2][44][84];
  const float* in = inQ; const float* w3 = w3Q; const float* w5 = w5Q; float* out = outQ;
  if (NSETS == 3) {
    if (blockIdx.y == 1) { in = inK; w3 = w3K; w5 = w5K; out = outK; }
    else if (blockIdx.y == 2) { in = inV; w3 = w3V; w5 = w5V; out = outV; }
  }
  const int blk = blockIdx.x;
  const int b = blk / 128;
  const int rem = blk % 128;
  const int o = rem >> 1, half = rem & 1;
  const int y0 = half * 40;
  const float* i0 = in + ((size_t)b * C_ + 2 * o) * N_;
  const int tid = threadIdx.x;
  for (int i = tid; i < 2 * 44 * 84; i += 256) {
    int ic = i / (44 * 84);
    int r = (i % (44 * 84)) / 84;
    int cc = i % 84;
    int gy = y0 + r - 2, gx = cc - 2;
    float v = 0.f;
    if (gy >= 0 && gy < 80 && gx >= 0 && gx < 80) v = i0[(size_t)ic * N_ + gy * 80 + gx];
    tt[ic][r][cc] = v;
  }
  float w3r[2][9], w5r[2][25];
  #pragma unroll
  for (int ic = 0; ic < 2; ic++) {
    #pragma unroll
    for (int k = 0; k < 9; k++) w3r[ic][k] = w3[(o * 2 + ic) * 9 + k];
    #pragma unroll
    for (int k = 0; k < 25; k++) w5r[ic][k] = w5[(o * 2 + ic) * 25 + k];
  }
  __syncthreads();
  for (int p = tid; p < 3200; p += 256) {
    const int ly = p / 80, x = p % 80;
    float a3 = 0.f, a5 = 0.f;
    #pragma unroll
    for (int ky = 0; ky < 5; ky++) {
      #pragma unroll
      for (int kx = 0; kx < 5; kx++) {
        float v0 = tt[0][ly + ky][x + kx];
        float v1 = tt[1][ly + ky][x + kx];
        a5 = fmaf(v0, w5r[0][ky * 5 + kx], a5);
        a5 = fmaf(v1, w5r[1][ky * 5 + kx], a5);
        if (ky >= 1 && ky < 4 && kx >= 1 && kx < 4) {
          int k3 = (ky - 1) * 3 + (kx - 1);
          a3 = fmaf(v0, w3r[0][k3], a3);
          a3 = fmaf(v1, w3r[1][k3], a3);
        }
      }
    }
    const int yy = y0 + ly;
    out[((size_t)b * C_ + o) * N_ + yy * 80 + x] = a3;
    out[((size_t)b * C_ + 64 + o) * N_ + yy * 80 + x] = a5;
  }
}

// ---------------- depthwise conv3x3 (pad1) + gelu(x)*x: zero-padded halo, 40-row halves ----------------
__global__ __launch_bounds__(256) void k_dwconv3_gelu(const float* __restrict__ in, const float* __restrict__ w,
    float* __restrict__ out, int Cn, int outCtot, int outCoff) {
  __shared__ float tt[42][82];
  const int blk = blockIdx.x;
  const int b = blk / (2 * Cn);
  const int rem = blk % (2 * Cn);
  const int c = rem >> 1, half = rem & 1;
  const int y0 = half * 40;
  const float* ip = in + ((size_t)b * Cn + c) * N_;
  const int tid = threadIdx.x;
  for (int i = tid; i < 42 * 82; i += 256) {
    int r = i / 82, cc = i % 82;
    int gy = y0 + r - 1, gx = cc - 1;
    float v = 0.f;
    if (gy >= 0 && gy < 80 && gx >= 0 && gx < 80) v = ip[gy * 80 + gx];
    tt[r][cc] = v;
  }
  float wr[9];
  #pragma unroll
  for (int k = 0; k < 9; k++) wr[k] = w[c * 9 + k];
  __syncthreads();
  float* op = out + ((size_t)b * outCtot + outCoff + c) * N_;
  for (int p = tid; p < 3200; p += 256) {
    const int ly = p / 80, x = p % 80;
    float a = 0.f;
    #pragma unroll
    for (int ky = 0; ky < 3; ky++) {
      #pragma unroll
      for (int kx = 0; kx < 3; kx++)
        a = fmaf(tt[ly + ky][x + kx], wr[ky * 3 + kx], a);
    }
    op[(y0 + ly) * 80 + x] = gelu_mul(a);
  }
}

// ---------------- ff_dw2: groups=128, 2-in/2-out per group, 3x3 pad1: zero-padded halo, halves ----------------
__global__ __launch_bounds__(256) void k_ffdw2(const float* __restrict__ in, const float* __restrict__ w,
                                               float* __restrict__ out) {
  __shared__ float tt[2][42][82];
  const int blk = blockIdx.x;
  const int b = blk / 256;
  const int rem = blk % 256;
  const int g = rem >> 1, half = rem & 1;
  const int y0 = half * 40;
  const float* i0 = in + ((size_t)b * 256 + 2 * g) * N_;
  const int tid = threadIdx.x;
  for (int i = tid; i < 2 * 42 * 82; i += 256) {
    int ic = i / (42 * 82);
    int r = (i % (42 * 82)) / 82;
    int cc = i % 82;
    int gy = y0 + r - 1, gx = cc - 1;
    float v = 0.f;
    if (gy >= 0 && gy < 80 && gx >= 0 && gx < 80) v = i0[(size_t)ic * N_ + gy * 80 + gx];
    tt[ic][r][cc] = v;
  }
  float w0[2][9], w1[2][9];
  #pragma unroll
  for (int ic = 0; ic < 2; ic++) {
    #pragma unroll
    for (int k = 0; k < 9; k++) {
      w0[ic][k] = w[((2 * g) * 2 + ic) * 9 + k];
      w1[ic][k] = w[((2 * g + 1) * 2 + ic) * 9 + k];
    }
  }
  __syncthreads();
  for (int p = tid; p < 3200; p += 256) {
    const int ly = p / 80, x = p % 80;
    float a0 = 0.f, a1 = 0.f;
    #pragma unroll
    for (int ky = 0; ky < 3; ky++) {
      #pragma unroll
      for (int kx = 0; kx < 3; kx++) {
        float v0 = tt[0][ly + ky][x + kx], v1 = tt[1][ly + ky][x + kx];
        int k = ky * 3 + kx;
        a0 = fmaf(v0, w0[0][k], a0); a0 = fmaf(v1, w0[1][k], a0);
        a1 = fmaf(v0, w1[0][k], a1); a1 = fmaf(v1, w1[1][k], a1);
      }
    }
    const int yy = y0 + ly;
    out[((size_t)b * 256 + 2 * g) * N_ + yy * 80 + x] = a0;
    out[((size_t)b * 256 + 2 * g + 1) * N_ + yy * 80 + x] = a1;
  }
}

// ---------------- per-row L2 norm (real) ----------------
__global__ __launch_bounds__(256) void k_rownorm_r(const float* __restrict__ in, float* __restrict__ nrm) {
  __shared__ float red[256];
  const int row = blockIdx.x;
  const float* p = in + (size_t)row * N_;
  float s = 0.f;
  for (int i = threadIdx.x; i < N_; i += 256) { float v = p[i]; s = fmaf(v, v, s); }
  red[threadIdx.x] = s; __syncthreads();
  for (int st = 128; st > 0; st >>= 1) { if (threadIdx.x < st) red[threadIdx.x] += red[threadIdx.x + st]; __syncthreads(); }
  if (threadIdx.x == 0) nrm[row] = fmaxf(sqrtf(red[0]), 1e-12f);
}

// ---------------- attention partials: coalesced wave-per-tile ----------------
__global__ __launch_bounds__(256) void k_attn_part_c(const float2* __restrict__ Ab, const float2* __restrict__ Bb,
                                                     float2* __restrict__ part) {
  const int bh = blockIdx.z;
  const int b = bh / H_, h = bh % H_;
  const int wave = threadIdx.x >> 6, lane = threadIdx.x & 63;
  const int tile = blockIdx.x * 4 + wave;      // 0..63
  const int c0 = (tile >> 3) * 4, d0 = (tile & 7) * 4;
  const size_t hb = ((size_t)b * C_ + h * 32) * N_;
  const float2* Ap = Ab + hb;
  const float2* Bp = Bb + hb;
  float2 acc[4][4];
  #pragma unroll
  for (int j = 0; j < 4; j++)
    #pragma unroll
    for (int i = 0; i < 4; i++) acc[j][i] = make_float2(0.f, 0.f);
  const int nb = blockIdx.y * (N_ / NSPL) + lane;
  for (int it = 0; it < (N_ / NSPL) / 64; ++it) {
    const int n = nb + it * 64;
    float2 av[4], bv[4];
    #pragma unroll
    for (int j = 0; j < 4; j++) av[j] = Ap[(size_t)(c0 + j) * N_ + n];
    #pragma unroll
    for (int i = 0; i < 4; i++) bv[i] = Bp[(size_t)(d0 + i) * N_ + n];
    #pragma unroll
    for (int j = 0; j < 4; j++)
      #pragma unroll
      for (int i = 0; i < 4; i++) cfma(acc[j][i], av[j], bv[i]);
  }
  float2* pp = part + (size_t)(bh * NSPL + blockIdx.y) * 1024;
  #pragma unroll
  for (int j = 0; j < 4; j++) {
    #pragma unroll
    for (int i = 0; i < 4; i++) {
      float rx = acc[j][i].x, ry = acc[j][i].y;
      for (int off = 32; off; off >>= 1) { rx += __shfl_xor(rx, off); ry += __shfl_xor(ry, off); }
      if (lane == 0) pp[(c0 + j) * 32 + d0 + i] = make_float2(rx, ry);
    }
  }
}
__global__ __launch_bounds__(256) void k_attn_part_r(const float* __restrict__ Ab, const float* __restrict__ Bb,
                                                     float* __restrict__ part) {
  const int bh = blockIdx.z;
  const int b = bh / H_, h = bh % H_;
  const int wave = threadIdx.x >> 6, lane = threadIdx.x & 63;
  const int tile = blockIdx.x * 4 + wave;
  const int c0 = (tile >> 3) * 4, d0 = (tile & 7) * 4;
  const size_t hb = ((size_t)b * C_ + h * 32) * N_;
  const float* Ap = Ab + hb;
  const float* Bp = Bb + hb;
  float acc[4][4];
  #pragma unroll
  for (int j = 0; j < 4; j++)
    #pragma unroll
    for (int i = 0; i < 4; i++) acc[j][i] = 0.f;
  const int nb = blockIdx.y * (N_ / NSPL) + lane;
  for (int it = 0; it < (N_ / NSPL) / 64; ++it) {
    const int n = nb + it * 64;
    float av[4], bv[4];
    #pragma unroll
    for (int j = 0; j < 4; j++) av[j] = Ap[(size_t)(c0 + j) * N_ + n];
    #pragma unroll
    for (int i = 0; i < 4; i++) bv[i] = Bp[(size_t)(d0 + i) * N_ + n];
    #pragma unroll
    for (int j = 0; j < 4; j++)
      #pragma unroll
      for (int i = 0; i < 4; i++) acc[j][i] = fmaf(av[j], bv[i], acc[j][i]);
  }
  float* pp = part + (size_t)(bh * NSPL + blockIdx.y) * 1024;
  #pragma unroll
  for (int j = 0; j < 4; j++) {
    #pragma unroll
    for (int i = 0; i < 4; i++) {
      float r = acc[j][i];
      for (int off = 32; off; off >>= 1) r += __shfl_xor(r, off);
      if (lane == 0) pp[(c0 + j) * 32 + d0 + i] = r;
    }
  }
}

// ---------------- reduce partials, scale, softmax ----------------
template <int CPLX>
__global__ void k_attn_soft(const float* __restrict__ part, const float* __restrict__ nA,
                            const float* __restrict__ nB, const float* __restrict__ temp,
                            float* __restrict__ attn) {
  const int rc = blockIdx.x;          // bh*32 + c
  const int bh = rc >> 5, c = rc & 31;
  const int b = bh / H_, h = bh % H_;
  const int d = threadIdx.x;          // 64 threads; group >=32 unused
  float re = -1e30f, im = -1e30f;
  if (d < 32) {
    re = 0.f; im = 0.f;
    if (CPLX) {
      const float2* pp = (const float2*)part;
      for (int kc = 0; kc < NSPL; kc++) { float2 v = pp[(size_t)(bh * NSPL + kc) * 1024 + c * 32 + d]; re += v.x; im += v.y; }
    } else {
      for (int kc = 0; kc < NSPL; kc++) re += part[(size_t)(bh * NSPL + kc) * 1024 + c * 32 + d];
    }
    float sc = temp[h] / (nA[b * C_ + h * 32 + c] * nB[b * C_ + h * 32 + d]);
    re *= sc; im *= sc;
  }
  float m = re;
  for (int o = 16; o; o >>= 1) m = fmaxf(m, __shfl_xor(m, o, 32));
  float e = expf(re - m);
  float s = e;
  for (int o = 16; o; o >>= 1) s += __shfl_xor(s, o, 32);
  float vr = e / s;
  float mi = im;
  for (int o = 16; o; o >>= 1) mi = fmaxf(mi, __shfl_xor(mi, o, 32));
  float ei = expf(im - mi);
  float si = ei;
  for (int o = 16; o; o >>= 1) si += __shfl_xor(si, o, 32);
  float vi = ei / si;
  if (d < 32) {
    if (CPLX) ((float2*)attn)[(size_t)(bh * 32 + c) * 32 + d] = make_float2(vr, vi);
    else attn[(size_t)(bh * 32 + c) * 32 + d] = vr;
  }
}

// ---------------- out[c,n] = sum_d attn[c,d] * V[d,n] ----------------
__global__ __launch_bounds__(256) void k_pv_c(const float2* __restrict__ attn, const float2* __restrict__ V,
                                              float2* __restrict__ out) {
  __shared__ float2 at[32][32];
  const int bh = blockIdx.x;
  const int b = bh / H_, h = bh % H_;
  const int n = blockIdx.y * 256 + threadIdx.x;
  for (int i = threadIdx.x; i < 1024; i += 256) at[i >> 5][i & 31] = attn[(size_t)bh * 1024 + i];
  __syncthreads();
  const size_t hb = ((size_t)b * C_ + h * 32) * N_;
  const float2* Vp = V + hb;
  float2 acc[32];
  #pragma unroll
  for (int c = 0; c < 32; c++) acc[c] = make_float2(0.f, 0.f);
  for (int dd = 0; dd < 32; dd++) {
    float2 v = Vp[(size_t)dd * N_ + n];
    #pragma unroll
    for (int c = 0; c < 32; c++) cfma(acc[c], at[c][dd], v);
  }
  float2* Op = out + hb;
  #pragma unroll
  for (int c = 0; c < 32; c++) Op[(size_t)c * N_ + n] = acc[c];
}
__global__ __launch_bounds__(256) void k_pv_r(const float* __restrict__ attn, const float* __restrict__ V,
                                              float* __restrict__ out) {
  __shared__ float at[32][32];
  const int bh = blockIdx.x;
  const int b = bh / H_, h = bh % H_;
  const int n = blockIdx.y * 256 + threadIdx.x;
  for (int i = threadIdx.x; i < 1024; i += 256) at[i >> 5][i & 31] = attn[(size_t)bh * 1024 + i];
  __syncthreads();
  const size_t hb = ((size_t)b * C_ + h * 32) * N_;
  const float* Vp = V + hb;
  float acc[32];
  #pragma unroll
  for (int c = 0; c < 32; c++) acc[c] = 0.f;
  for (int dd = 0; dd < 32; dd++) {
    float v = Vp[(size_t)dd * N_ + n];
    #pragma unroll
    for (int c = 0; c < 32; c++) acc[c] = fmaf(at[c][dd], v, acc[c]);
  }
  float* Op = out + hb;
  #pragma unroll
  for (int c = 0; c < 32; c++) Op[(size_t)c * N_ + n] = acc[c];
}

extern "C" void kernel_launch(void* const* d_in, const int* in_sizes, int n_in,
                              void* d_out, int out_size, void* d_ws, size_t ws_size,
                              hipStream_t stream) {
  (void)in_sizes; (void)n_in; (void)out_size; (void)ws_size;
  const float* x       = (const float*)d_in[0];
  const float* ln1_w   = (const float*)d_in[1];
  const float* ln2_w   = (const float*)d_in[2];
  const float* ln1_b   = (const float*)d_in[3];
  const float* ln2_b   = (const float*)d_in[4];
  const float* f_temp  = (const float*)d_in[5];
  const float* s_temp  = (const float*)d_in[6];
  const float* f_proj  = (const float*)d_in[7];
  const float* s_proj  = (const float*)d_in[8];
  const float* f_w1    = (const float*)d_in[9];
  const float* f_wb1   = (const float*)d_in[10];
  const float* f_bng   = (const float*)d_in[11];
  const float* f_bnb   = (const float*)d_in[12];
  const float* f_w2    = (const float*)d_in[13];
  const float* f_wb2   = (const float*)d_in[14];
  const float* s_q1_w  = (const float*)d_in[15];
  const float* s_q1_b  = (const float*)d_in[16];
  const float* s_k1_w  = (const float*)d_in[17];
  const float* s_k1_b  = (const float*)d_in[18];
  const float* s_v1_w  = (const float*)d_in[19];
  const float* s_v1_b  = (const float*)d_in[20];
  const float* s_q3_w  = (const float*)d_in[21];
  const float* s_k3_w  = (const float*)d_in[22];
  const float* s_v3_w  = (const float*)d_in[23];
  const float* s_c3_w  = (const float*)d_in[24];
  const float* s_q5_w  = (const float*)d_in[25];
  const float* s_k5_w  = (const float*)d_in[26];
  const float* s_v5_w  = (const float*)d_in[27];
  const float* s_c5_w  = (const float*)d_in[28];
  const float* ffdw1_w = (const float*)d_in[29];
  const float* ffdw2_w = (const float*)d_in[30];
  const float* ffproj  = (const float*)d_in[31];
  const float* ffg_w1  = (const float*)d_in[32];
  const float* ffg_b1  = (const float*)d_in[33];
  const float* ffg_bng = (const float*)d_in[34];
  const float* ffg_bnb = (const float*)d_in[35];
  const float* ffg_w2  = (const float*)d_in[36];
  const float* ffg_b2  = (const float*)d_in[37];
  const float* ffg1_w1 = (const float*)d_in[38];
  const float* ffg1_b1 = (const float*)d_in[39];
  const float* ffg1_bng= (const float*)d_in[40];
  const float* ffg1_bnb= (const float*)d_in[41];
  const float* ffg1_w2 = (const float*)d_in[42];
  const float* ffg1_b2 = (const float*)d_in[43];

  // workspace layout (floats). Requires ~267 MB of d_ws.
  float* ws = (float*)d_ws;
  const size_t R = (size_t)B_ * C_ * N_;   // 6,553,600 floats per [B,128,N] image set
  float* xn   = ws;            // R
  float* acc  = ws + R;        // R
  float* bufA = ws + 2 * R;    // 2R (complex [B,128,N] or real [B,256,N])
  float* bufB = ws + 4 * R;    // 2R
  float* bufC = ws + 6 * R;    // 2R
  float* bufD = ws + 8 * R;    // 2R
  float* sm   = ws + 10 * R;   // small pool
  float* nrmQ = sm;                    // 1024
  float* nrmK = sm + 1024;             // 1024
  float* hid  = sm + 2048;             // B*8*N = 409600
  float* part = sm + 2048 + 409600;    // 524288 (float2[131072] used for cplx)
  float* attb = part + 524288;         // 65536 (float2[32768] for cplx)

  dim3 blk(256);
  const int GCONV = P_ / 64;   // 800 blocks, 128co x 64pos MFMA tiles
  const int GLN = P_ / 64;     // 800 blocks for layernorm / gateA
  const int NIMG = B_ * C_;    // 1024
  const dim3 gattn(16, NSPL, B_ * H_);

  // ===== xn = LayerNorm(x) ; xf = fft2(xn) with fused row-norm =====
  k_layernorm<<<GLN, blk, 0, stream>>>(x, ln1_w, ln1_b, xn);
  k_fft2_r2c<<<NIMG, blk, 0, stream>>>(xn, (float2*)bufA, C_, C_, 0, nullptr, 0, NIMG, nrmQ);

  // ===== Attention_F =====
  k_attn_part_c<<<gattn, blk, 0, stream>>>((const float2*)bufA, (const float2*)bufA, (float2*)part);
  k_attn_soft<1><<<B_ * C_, 64, 0, stream>>>(part, nrmQ, nrmQ, f_temp, attb);
  k_pv_c<<<dim3(B_ * H_, N_ / 256), blk, 0, stream>>>((const float2*)attb, (const float2*)bufA, (float2*)bufB);
  k_idft32<<<dim3(B_ * H_, N_ / 64), blk, 0, stream>>>((const float2*)bufB, (float2*)bufC);
  // gated branch first (reads bufA pre/post scale), then merged idft6400+ifft2
  k_gateA<<<GLN, blk, 0, stream>>>((const float2*)bufA, (const float2*)bufA, C_, C_, f_w1, f_wb1, f_bng, f_bnb, hid);
  k_gateB<0><<<dim3(P_ / 256, 2), blk, 0, stream>>>((float2*)bufA, (float2*)bufA, C_, C_, f_w2, f_wb2, hid, nullptr, 0, 0);
  k_iff_combo<<<2 * NIMG, blk, 0, stream>>>((const float2*)bufC, bufD, (const float2*)bufA, bufD + R);
  // a_f: acc = x + f_proj(concat(out_f, out_f_l))
  k_conv1x1<<<GCONV, blk, 0, stream>>>(bufD, bufD + R, 128, 256, 128, f_proj, nullptr, x, acc);

  // ===== Attention_S =====
  // fused q1/k1/v1 (one 2400-block dispatch; blockIdx.y routes weight/output set)
  k_conv1x1_qkv<<<dim3(GCONV, 3), blk, 0, stream>>>(xn,
      s_q1_w, s_q1_b, bufA, s_k1_w, s_k1_b, bufA + R, s_v1_w, s_v1_b, bufB);
  // fused qs/ks/vs grouped convs (disjoint in/out buffers -> safe 3-way merge)
  k_gconv35<3><<<dim3(B_ * 128, 3), blk, 0, stream>>>(
      bufA,     s_q3_w, s_q5_w, bufB + R,
      bufA + R, s_k3_w, s_k5_w, bufC,
      bufB,     s_v3_w, s_v5_w, bufC + R);
  k_rownorm_r<<<B_ * C_, blk, 0, stream>>>(bufB + R, nrmQ);
  k_rownorm_r<<<B_ * C_, blk, 0, stream>>>(bufC, nrmK);
  k_attn_part_r<<<gattn, blk, 0, stream>>>(bufB + R, bufC, part);
  k_attn_soft<0><<<B_ * C_, 64, 0, stream>>>(part, nrmQ, nrmK, s_temp, attb);
  k_pv_r<<<dim3(B_ * H_, N_ / 256), blk, 0, stream>>>(attb, bufC + R, bufA);      // out_s -> A.lo
  k_gconv35<1><<<B_ * 128, blk, 0, stream>>>(xn, s_c3_w, s_c5_w, bufA + R,
      nullptr, nullptr, nullptr, nullptr, nullptr, nullptr, nullptr, nullptr);    // out_s_l -> A.hi
  // a_s: acc += s_proj(concat(out_s, out_s_l))
  k_conv1x1<<<GCONV, blk, 0, stream>>>(bufA, bufA + R, 128, 256, 128, s_proj, nullptr, acc, acc);

  // ===== FeedForward =====
  k_layernorm<<<GLN, blk, 0, stream>>>(acc, ln2_w, ln2_b, xn);                    // xn2
  k_fft2_r2c<<<NIMG, blk, 0, stream>>>(xn, (float2*)bufA, C_, C_, 0, nullptr, 0, NIMG, nullptr);  // xf2
  k_gateA<<<GLN, blk, 0, stream>>>((const float2*)bufA, (const float2*)bufA, C_, C_, ffg_w1, ffg_b1, ffg_bng, ffg_bnb, hid);
  k_gateB<1><<<dim3(P_ / 256, 2), blk, 0, stream>>>((float2*)bufA, (float2*)bufA, C_, C_, ffg_w2, ffg_b2, hid, bufB, 256, 0); // x_f_g -> cat.lo
  k_dwconv3_gelu<<<B_ * 256, blk, 0, stream>>>(xn, ffdw1_w, bufB, 128, 256, 128); // x_s_g -> cat.hi
  // cf = fft2(cat): one merged 2048-block dispatch (lo -> bufA, hi -> bufC)
  k_fft2_r2c<<<2 * NIMG, blk, 0, stream>>>(bufB, (float2*)bufA, 128, 256, 0, (float2*)bufC, 128, NIMG, nullptr);
  k_gateA<<<GLN, blk, 0, stream>>>((const float2*)bufA, (const float2*)bufC, 128, 256, ffg1_w1, ffg1_b1, ffg1_bng, ffg1_bnb, hid);
  k_gateB<0><<<dim3(P_ / 256, 4), blk, 0, stream>>>((float2*)bufA, (float2*)bufC, 128, 256, ffg1_w2, ffg1_b2, hid, nullptr, 0, 0);
  // x_f2b: merged 2048-block ifft2 pair (bufA -> bufD coff0, bufC -> bufD coff128)
  k_ifft2_abs<<<2 * NIMG, blk, 0, stream>>>((const float2*)bufA, bufD, 128, 256, 0, (const float2*)bufC, 128, NIMG);
  k_ffdw2<<<B_ * 256, blk, 0, stream>>>(bufB, ffdw2_w, bufA);                     // x_s2b (real [B,256,N] in A)
  // out = x1 + ff_proj(concat(x_f2b, x_s2b))
  k_conv1x1<<<GCONV, blk, 0, stream>>>(bufD, bufA, 256, 512, 128, ffproj, nullptr, acc, (float*)d_out);
}

// Round 19
// 1127.465 us; speedup vs baseline: 1.0873x; 1.0352x over previous
//
#include <hip/hip_runtime.h>
#include <math.h>

#define DI __device__ __forceinline__

constexpr int B_ = 8, C_ = 128, H_ = 4, S_ = 80, N_ = 6400;
constexpr int P_ = B_ * N_;                 // 51200 spatial positions
constexpr int NSPL = 2;                     // n-chunks for attention partials
constexpr float PI2 = 6.283185307179586f;
constexpr float BN_SC = 0.9999950000374997f;  // 1/sqrt(1+1e-5)

typedef __attribute__((ext_vector_type(8))) short bf16x8;
typedef __attribute__((ext_vector_type(4))) float f32x4;

DI void cfma(float2& a, float2 u, float2 v) {
  a.x = fmaf(u.x, v.x, a.x); a.x = fmaf(-u.y, v.y, a.x);
  a.y = fmaf(u.x, v.y, a.y); a.y = fmaf(u.y, v.x, a.y);
}
DI float2 cmul(float2 u, float2 v) {
  return make_float2(u.x * v.x - u.y * v.y, u.x * v.y + u.y * v.x);
}
DI float gelu_mul(float m) {  // gelu(m, exact) * m
  return 0.5f * m * (1.f + erff(m * 0.7071067811865476f)) * m;
}
DI unsigned short bf16_rn(float f) {  // round-to-nearest-even fp32 -> bf16
  union { float f; unsigned int u; } v; v.f = f;
  unsigned int u = v.u;
  return (unsigned short)((u + 0x7fffu + ((u >> 16) & 1u)) >> 16);
}

// ---------------- LayerNorm over channel dim (4-way channel-split, 800 blocks) ----------------
__global__ __launch_bounds__(256) void k_layernorm(const float* __restrict__ in,
    const float* __restrict__ w, const float* __restrict__ bb, float* __restrict__ out) {
  __shared__ float redS[4][64], redS2[4][64];
  __shared__ float muv[64], invv[64];
  const int tid = threadIdx.x;
  const int g = tid >> 6, l = tid & 63;
  const int p = blockIdx.x * 64 + l;
  const int b = p / N_, n = p % N_;
  const float* xp = in + (size_t)b * C_ * N_ + n;
  float s = 0.f, s2 = 0.f;
  for (int c = g * 32; c < g * 32 + 32; c++) {
    float v = xp[(size_t)c * N_];
    s += v; s2 = fmaf(v, v, s2);
  }
  redS[g][l] = s; redS2[g][l] = s2;
  __syncthreads();
  if (g == 0) {
    float ts  = redS[0][l] + redS[1][l] + redS[2][l] + redS[3][l];
    float ts2 = redS2[0][l] + redS2[1][l] + redS2[2][l] + redS2[3][l];
    float mu = ts * (1.f / C_);
    float var = ts2 * (1.f / C_) - mu * mu;
    muv[l] = mu; invv[l] = rsqrtf(var + 1e-5f);
  }
  __syncthreads();
  const float mu = muv[l], inv = invv[l];
  float* op = out + (size_t)b * C_ * N_ + n;
  for (int c = g * 32; c < g * 32 + 32; c++) {
    float v = xp[(size_t)c * N_];
    op[(size_t)c * N_] = (v - mu) * inv * w[c] + bb[c];
  }
}

// ============ register-tiled 80x80 2D DFT kernels ============

// ---------------- 2D FFT (80x80) real->complex; Hermitian mirrored; optional 2nd output set; optional row-norm ----------------
__global__ __launch_bounds__(256) void k_fft2_r2c(const float* __restrict__ in, float2* __restrict__ out,
                                                  int nCh, int inCtot, int inCoff,
                                                  float2* __restrict__ out2, int inCoff2, int nimg,
                                                  float* __restrict__ nrm) {
  __shared__ float2 data[N_];
  __shared__ float2 tw[80];
  int img = blockIdx.x;
  float2* op;
  int coff;
  if (img >= nimg) { img -= nimg; op = out2 + (size_t)img * N_; coff = inCoff2; }
  else { op = out + (size_t)img * N_; coff = inCoff; }
  const int b = img / nCh, ch = img % nCh;
  const float* ip = in + ((size_t)b * inCtot + coff + ch) * N_;
  const int tid = threadIdx.x;
  float* dataR = (float*)data;
  if (tid < 80) { float a = -PI2 * (float)tid * (1.f / 80.f); float sv, cv; sincosf(a, &sv, &cv); tw[tid] = make_float2(cv, sv); }
  for (int i = tid; i < N_; i += 256) dataR[i] = ip[i];
  __syncthreads();
  const int r0 = (tid >> 4) * 5;
  const int cg = tid & 15;
  float2 a1[5][3];
  for (int j = 0; j < 5; j++)
    for (int i = 0; i < 3; i++) a1[j][i] = make_float2(0.f, 0.f);
  {
    int idx[3] = {0, 0, 0};
    for (int c = 0; c < 80; ++c) {
      float d[5]; float2 t[3];
      #pragma unroll
      for (int j = 0; j < 5; j++) d[j] = dataR[(r0 + j) * 80 + c];
      #pragma unroll
      for (int i = 0; i < 3; i++) t[i] = tw[idx[i]];
      #pragma unroll
      for (int j = 0; j < 5; j++) {
        #pragma unroll
        for (int i = 0; i < 3; i++) {
          a1[j][i].x = fmaf(d[j], t[i].x, a1[j][i].x);
          a1[j][i].y = fmaf(d[j], t[i].y, a1[j][i].y);
        }
      }
      #pragma unroll
      for (int i = 0; i < 3; i++) { idx[i] += cg + 16 * i; if (idx[i] >= 80) idx[i] -= 80; }
    }
  }
  __syncthreads();
  #pragma unroll
  for (int i = 0; i < 3; i++) {
    const int k = cg + 16 * i;
    #pragma unroll
    for (int j = 0; j < 5; j++) {
      if (k <= 40) data[(r0 + j) * 80 + k] = a1[j][i];
      if (k >= 1 && k <= 39) data[(r0 + j) * 80 + 80 - k] = make_float2(a1[j][i].x, -a1[j][i].y);
    }
  }
  __syncthreads();
  const int k0 = (tid & 15) * 5;
  const int rg = tid >> 4;
  float2 a2[3][5];
  for (int j = 0; j < 3; j++)
    for (int i = 0; i < 5; i++) a2[j][i] = make_float2(0.f, 0.f);
  {
    int idx[3] = {0, 0, 0};
    for (int r = 0; r < 80; ++r) {
      float2 d[5]; float2 t[3];
      #pragma unroll
      for (int i = 0; i < 5; i++) d[i] = data[r * 80 + k0 + i];
      #pragma unroll
      for (int j = 0; j < 3; j++) t[j] = tw[idx[j]];
      #pragma unroll
      for (int j = 0; j < 3; j++) {
        #pragma unroll
        for (int i = 0; i < 5; i++) cfma(a2[j][i], d[i], t[j]);
      }
      #pragma unroll
      for (int j = 0; j < 3; j++) { idx[j] += rg + 16 * j; if (idx[j] >= 80) idx[j] -= 80; }
    }
  }
  #pragma unroll
  for (int j = 0; j < 3; j++) {
    const int k1 = rg + 16 * j;
    #pragma unroll
    for (int i = 0; i < 5; i++) {
      const int k2 = k0 + i;
      if (k1 <= 40) op[k1 * 80 + k2] = a2[j][i];
      if (k1 >= 1 && k1 <= 39) {
        const int m2 = (k2 == 0) ? 0 : 80 - k2;
        op[(80 - k1) * 80 + m2] = make_float2(a2[j][i].x, -a2[j][i].y);
      }
    }
  }
  if (nrm) {   // fused per-image L2 norm (mirrored halves contribute 2x)
    float s = 0.f;
    #pragma unroll
    for (int j = 0; j < 3; j++) {
      const int k1 = rg + 16 * j;
      if (k1 <= 40) {
        const float wgt = (k1 == 0 || k1 == 40) ? 1.f : 2.f;
        #pragma unroll
        for (int i = 0; i < 5; i++)
          s += wgt * (a2[j][i].x * a2[j][i].x + a2[j][i].y * a2[j][i].y);
      }
    }
    __syncthreads();
    float* red = (float*)data;
    red[tid] = s;
    __syncthreads();
    for (int st = 128; st > 0; st >>= 1) { if (tid < st) red[tid] += red[tid + st]; __syncthreads(); }
    if (tid == 0) nrm[img] = fmaxf(sqrtf(red[0]), 1e-12f);
  }
}

// ---------------- 2D IFFT (80x80) of HERMITIAN input -> |real| (optional 2nd input set) ----------------
__global__ __launch_bounds__(256) void k_ifft2_abs(const float2* __restrict__ in, float* __restrict__ out,
                                                   int inC, int outCtot, int outCoff,
                                                   const float2* __restrict__ in2, int outCoff2, int nimg) {
  __shared__ float2 data[N_];
  __shared__ float2 tw[80];
  int img = blockIdx.x;
  const float2* ip;
  int coff;
  if (img >= nimg) { img -= nimg; ip = in2 + (size_t)img * N_; coff = outCoff2; }
  else { ip = in + (size_t)img * N_; coff = outCoff; }
  const int b = img / inC, ch = img % inC;
  float* op = out + ((size_t)b * outCtot + coff + ch) * N_;
  const int tid = threadIdx.x;
  if (tid < 80) { float a = PI2 * (float)tid * (1.f / 80.f); float sv, cv; sincosf(a, &sv, &cv); tw[tid] = make_float2(cv, sv); }
  for (int i = tid; i < N_; i += 256) data[i] = ip[i];
  __syncthreads();
  const int rg = tid >> 4;
  const int cg = tid & 15;
  float2 E[3][3], O[3][3];
  for (int j = 0; j < 3; j++)
    for (int i = 0; i < 3; i++) { E[j][i] = make_float2(0.f, 0.f); O[j][i] = make_float2(0.f, 0.f); }
  {
    int idx[3], inc[3];
    #pragma unroll
    for (int i = 0; i < 3; i++) { idx[i] = 0; inc[i] = (2 * (cg + 16 * i)) % 80; }
    for (int m = 0; m < 40; ++m) {
      float4 z[3]; float2 t[3];
      #pragma unroll
      for (int j = 0; j < 3; j++) z[j] = *(const float4*)&data[(rg + 16 * j) * 80 + 2 * m];
      #pragma unroll
      for (int i = 0; i < 3; i++) t[i] = tw[idx[i]];
      #pragma unroll
      for (int j = 0; j < 3; j++) {
        float2 ze = make_float2(z[j].x, z[j].y);
        float2 zo = make_float2(z[j].z, z[j].w);
        #pragma unroll
        for (int i = 0; i < 3; i++) { cfma(E[j][i], ze, t[i]); cfma(O[j][i], zo, t[i]); }
      }
      #pragma unroll
      for (int i = 0; i < 3; i++) { idx[i] += inc[i]; if (idx[i] >= 80) idx[i] -= 80; }
    }
  }
  __syncthreads();
  #pragma unroll
  for (int j = 0; j < 3; j++) {
    const int r = rg + 16 * j;
    if (r <= 40) {
      #pragma unroll
      for (int i = 0; i < 3; i++) {
        const int n2 = cg + 16 * i;
        if (n2 < 40) {
          float2 u = cmul(tw[n2], O[j][i]);
          data[r * 80 + n2]      = make_float2(E[j][i].x + u.x, E[j][i].y + u.y);
          data[r * 80 + n2 + 40] = make_float2(E[j][i].x - u.x, E[j][i].y - u.y);
        }
      }
    }
  }
  __syncthreads();
  const int r0 = (tid >> 4) * 5;
  const int k0 = (tid & 15) * 5;
  float accR[5][5];
  for (int j = 0; j < 5; j++)
    for (int i = 0; i < 5; i++) accR[j][i] = 0.f;
  {
    int idx[5];
    #pragma unroll
    for (int j = 0; j < 5; j++) idx[j] = r0 + j;
    for (int r = 1; r <= 39; ++r) {
      float2 d[5]; float2 t[5];
      #pragma unroll
      for (int i = 0; i < 5; i++) d[i] = data[r * 80 + k0 + i];
      #pragma unroll
      for (int j = 0; j < 5; j++) t[j] = tw[idx[j]];
      #pragma unroll
      for (int j = 0; j < 5; j++) {
        #pragma unroll
        for (int i = 0; i < 5; i++) {
          accR[j][i] = fmaf(t[j].x, d[i].x, accR[j][i]);
          accR[j][i] = fmaf(-t[j].y, d[i].y, accR[j][i]);
        }
      }
      #pragma unroll
      for (int j = 0; j < 5; j++) { idx[j] += r0 + j; if (idx[j] >= 80) idx[j] -= 80; }
    }
  }
  #pragma unroll
  for (int i = 0; i < 5; i++) {
    float2 b0 = data[k0 + i];
    float2 b40 = data[40 * 80 + k0 + i];
    #pragma unroll
    for (int j = 0; j < 5; j++) {
      float s40 = ((r0 + j) & 1) ? -b40.x : b40.x;
      float res = 2.f * accR[j][i] + b0.x + s40;
      op[(r0 + j) * 80 + k0 + i] = fabsf(res) * (1.f / (float)N_);
    }
  }
}

// ---------------- combo: blocks <1024 do 6400-pt IDFT+abs; blocks >=1024 do Hermitian ifft2+abs ----------------
__global__ __launch_bounds__(256) void k_iff_combo(const float2* __restrict__ in6400, float* __restrict__ out6400,
                                                   const float2* __restrict__ inF, float* __restrict__ outF) {
  __shared__ float2 data[N_];
  __shared__ float2 tw[80];
  __shared__ float2 tws[80];
  const int tid = threadIdx.x;
  if (blockIdx.x < (unsigned)(B_ * C_)) {
    // ---- idft6400_abs body ----
    const int row = blockIdx.x;
    const float2* ip = in6400 + (size_t)row * N_;
    float* op = out6400 + (size_t)row * N_;
    if (tid < 80) {
      float a = PI2 * (float)tid * (1.f / 80.f); float sv, cv; sincosf(a, &sv, &cv); tw[tid] = make_float2(cv, sv);
      float a2 = PI2 * (float)tid * (1.f / 6400.f); sincosf(a2, &sv, &cv); tws[tid] = make_float2(cv, sv);
    }
    for (int i = tid; i < N_; i += 256) data[i] = ip[i];
    __syncthreads();
    {
      const int r0 = (tid >> 4) * 5;
      const int cg = tid & 15;
      float2 E[5][3], O[5][3];
      for (int j = 0; j < 5; j++)
        for (int i = 0; i < 3; i++) { E[j][i] = make_float2(0.f, 0.f); O[j][i] = make_float2(0.f, 0.f); }
      int idx[3], inc[3];
      #pragma unroll
      for (int i = 0; i < 3; i++) { idx[i] = 0; inc[i] = (2 * (cg + 16 * i)) % 80; }
      for (int m = 0; m < 40; ++m) {
        float2 xe[5], xo[5], t[3];
        #pragma unroll
        for (int j = 0; j < 5; j++) {
          xe[j] = data[(r0 + j) + 160 * m];
          xo[j] = data[(r0 + j) + 160 * m + 80];
        }
        #pragma unroll
        for (int i = 0; i < 3; i++) t[i] = tw[idx[i]];
        #pragma unroll
        for (int j = 0; j < 5; j++) {
          #pragma unroll
          for (int i = 0; i < 3; i++) { cfma(E[j][i], xe[j], t[i]); cfma(O[j][i], xo[j], t[i]); }
        }
        #pragma unroll
        for (int i = 0; i < 3; i++) { idx[i] += inc[i]; if (idx[i] >= 80) idx[i] -= 80; }
      }
      __syncthreads();
      #pragma unroll
      for (int j = 0; j < 5; j++) {
        const int k1 = r0 + j;
        #pragma unroll
        for (int i = 0; i < 3; i++) {
          const int n2 = cg + 16 * i;
          if (n2 < 40) {
            float2 u = cmul(tw[n2], O[j][i]);
            float2 Ap = make_float2(E[j][i].x + u.x, E[j][i].y + u.y);
            float2 Am = make_float2(E[j][i].x - u.x, E[j][i].y - u.y);
            int t6 = k1 * n2; int q = t6 / 80, s6 = t6 - q * 80;
            data[k1 * 80 + n2] = cmul(Ap, cmul(tw[q], tws[s6]));
            int t6b = k1 * (n2 + 40); int qb = t6b / 80, sb = t6b - qb * 80;
            data[k1 * 80 + n2 + 40] = cmul(Am, cmul(tw[qb], tws[sb]));
          }
        }
      }
    }
    __syncthreads();
    {
      const int rg5 = tid >> 3;
      const int cg5 = tid & 7;
      float2 E2[5][3], O2[5][3];
      for (int i = 0; i < 5; i++)
        for (int j = 0; j < 3; j++) { E2[i][j] = make_float2(0.f, 0.f); O2[i][j] = make_float2(0.f, 0.f); }
      int idx[5], inc[5];
      #pragma unroll
      for (int i = 0; i < 5; i++) { idx[i] = 0; inc[i] = (2 * (cg5 * 5 + i)) % 80; }
      int n2c[3];
      #pragma unroll
      for (int j = 0; j < 3; j++) { int n2 = rg5 + 32 * j; n2c[j] = (n2 < 80) ? n2 : 0; }
      for (int m = 0; m < 40; ++m) {
        float2 ae[3], ao[3], t[5];
        #pragma unroll
        for (int j = 0; j < 3; j++) {
          ae[j] = data[(2 * m) * 80 + n2c[j]];
          ao[j] = data[(2 * m + 1) * 80 + n2c[j]];
        }
        #pragma unroll
        for (int i = 0; i < 5; i++) t[i] = tw[idx[i]];
        #pragma unroll
        for (int i = 0; i < 5; i++) {
          #pragma unroll
          for (int j = 0; j < 3; j++) { cfma(E2[i][j], ae[j], t[i]); cfma(O2[i][j], ao[j], t[i]); }
        }
        #pragma unroll
        for (int i = 0; i < 5; i++) { idx[i] += inc[i]; if (idx[i] >= 80) idx[i] -= 80; }
      }
      #pragma unroll
      for (int i = 0; i < 5; i++) {
        const int n1 = cg5 * 5 + i;
        #pragma unroll
        for (int j = 0; j < 3; j++) {
          const int n2 = rg5 + 32 * j;
          if (n2 < 80) {
            float2 u = cmul(tw[n1], O2[i][j]);
            float2 o1 = make_float2(E2[i][j].x + u.x, E2[i][j].y + u.y);
            float2 o2 = make_float2(E2[i][j].x - u.x, E2[i][j].y - u.y);
            op[n1 * 80 + n2] = sqrtf(o1.x * o1.x + o1.y * o1.y) * (1.f / 6400.f);
            op[(n1 + 40) * 80 + n2] = sqrtf(o2.x * o2.x + o2.y * o2.y) * (1.f / 6400.f);
          }
        }
      }
    }
  } else {
    // ---- Hermitian ifft2_abs body (img = blk - 1024; out = outF + img*N_) ----
    const int img = blockIdx.x - B_ * C_;
    const float2* ip = inF + (size_t)img * N_;
    float* op = outF + (size_t)img * N_;
    if (tid < 80) { float a = PI2 * (float)tid * (1.f / 80.f); float sv, cv; sincosf(a, &sv, &cv); tw[tid] = make_float2(cv, sv); }
    for (int i = tid; i < N_; i += 256) data[i] = ip[i];
    __syncthreads();
    const int rg = tid >> 4;
    const int cg = tid & 15;
    float2 E[3][3], O[3][3];
    for (int j = 0; j < 3; j++)
      for (int i = 0; i < 3; i++) { E[j][i] = make_float2(0.f, 0.f); O[j][i] = make_float2(0.f, 0.f); }
    {
      int idx[3], inc[3];
      #pragma unroll
      for (int i = 0; i < 3; i++) { idx[i] = 0; inc[i] = (2 * (cg + 16 * i)) % 80; }
      for (int m = 0; m < 40; ++m) {
        float4 z[3]; float2 t[3];
        #pragma unroll
        for (int j = 0; j < 3; j++) z[j] = *(const float4*)&data[(rg + 16 * j) * 80 + 2 * m];
        #pragma unroll
        for (int i = 0; i < 3; i++) t[i] = tw[idx[i]];
        #pragma unroll
        for (int j = 0; j < 3; j++) {
          float2 ze = make_float2(z[j].x, z[j].y);
          float2 zo = make_float2(z[j].z, z[j].w);
          #pragma unroll
          for (int i = 0; i < 3; i++) { cfma(E[j][i], ze, t[i]); cfma(O[j][i], zo, t[i]); }
        }
        #pragma unroll
        for (int i = 0; i < 3; i++) { idx[i] += inc[i]; if (idx[i] >= 80) idx[i] -= 80; }
      }
    }
    __syncthreads();
    #pragma unroll
    for (int j = 0; j < 3; j++) {
      const int r = rg + 16 * j;
      if (r <= 40) {
        #pragma unroll
        for (int i = 0; i < 3; i++) {
          const int n2 = cg + 16 * i;
          if (n2 < 40) {
            float2 u = cmul(tw[n2], O[j][i]);
            data[r * 80 + n2]      = make_float2(E[j][i].x + u.x, E[j][i].y + u.y);
            data[r * 80 + n2 + 40] = make_float2(E[j][i].x - u.x, E[j][i].y - u.y);
          }
        }
      }
    }
    __syncthreads();
    const int r0 = (tid >> 4) * 5;
    const int k0 = (tid & 15) * 5;
    float accR[5][5];
    for (int j = 0; j < 5; j++)
      for (int i = 0; i < 5; i++) accR[j][i] = 0.f;
    {
      int idx[5];
      #pragma unroll
      for (int j = 0; j < 5; j++) idx[j] = r0 + j;
      for (int r = 1; r <= 39; ++r) {
        float2 d[5]; float2 t[5];
        #pragma unroll
        for (int i = 0; i < 5; i++) d[i] = data[r * 80 + k0 + i];
        #pragma unroll
        for (int j = 0; j < 5; j++) t[j] = tw[idx[j]];
        #pragma unroll
        for (int j = 0; j < 5; j++) {
          #pragma unroll
          for (int i = 0; i < 5; i++) {
            accR[j][i] = fmaf(t[j].x, d[i].x, accR[j][i]);
            accR[j][i] = fmaf(-t[j].y, d[i].y, accR[j][i]);
          }
        }
        #pragma unroll
        for (int j = 0; j < 5; j++) { idx[j] += r0 + j; if (idx[j] >= 80) idx[j] -= 80; }
      }
    }
    #pragma unroll
    for (int i = 0; i < 5; i++) {
      float2 b0 = data[k0 + i];
      float2 b40 = data[40 * 80 + k0 + i];
      #pragma unroll
      for (int j = 0; j < 5; j++) {
        float s40 = ((r0 + j) & 1) ? -b40.x : b40.x;
        float res = 2.f * accR[j][i] + b0.x + s40;
        op[(r0 + j) * 80 + k0 + i] = fabsf(res) * (1.f / (float)N_);
      }
    }
  }
}

// ---------------- gate stage A (4-way channel-split, 800 blocks) ----------------
__global__ __launch_bounds__(256) void k_gateA(const float2* __restrict__ zA, const float2* __restrict__ zB,
    int split, int Cin, const float* __restrict__ W1, const float* __restrict__ b1,
    const float* __restrict__ g, const float* __restrict__ bt, float* __restrict__ hid) {
  __shared__ float w[8 * 256];
  __shared__ float red[4][64][9];  // padded to 9 to avoid bank conflicts
  const int tid = threadIdx.x;
  const int grp = tid >> 6, l = tid & 63;
  for (int i = tid; i < 8 * Cin; i += 256) w[i] = W1[i];
  __syncthreads();
  const int p = blockIdx.x * 64 + l;
  const int b = p / N_, n = p % N_;
  const int cpg = Cin / 4;
  float acc[8] = {0.f, 0.f, 0.f, 0.f, 0.f, 0.f, 0.f, 0.f};
  for (int ci = grp * cpg; ci < (grp + 1) * cpg; ci++) {
    const float2* src = (ci < split) ? (zA + ((size_t)b * split + ci) * N_ + n)
                                     : (zB + ((size_t)b * (Cin - split) + (ci - split)) * N_ + n);
    float v = src->x;
    #pragma unroll
    for (int j = 0; j < 8; j++) acc[j] = fmaf(w[j * Cin + ci], v, acc[j]);
  }
  #pragma unroll
  for (int j = 0; j < 8; j++) red[grp][l][j] = acc[j];
  __syncthreads();
  if (grp == 0) {
    #pragma unroll
    for (int j = 0; j < 8; j++) {
      float t = red[0][l][j] + red[1][l][j] + red[2][l][j] + red[3][l][j];
      float y = (t + b1[j]) * (g[j] * BN_SC) + bt[j];
      hid[((size_t)b * 8 + j) * N_ + n] = fmaxf(y, 0.f);
    }
  }
}

// ---------------- gate stage B (co-split over gridDim.y, 64 co per block) ----------------
template <int MODE>
__global__ __launch_bounds__(256) void k_gateB(float2* __restrict__ zA, float2* __restrict__ zB,
    int split, int Cout, const float* __restrict__ W2, const float* __restrict__ b2,
    const float* __restrict__ hid, float* __restrict__ outR, int outCtot, int outCoff) {
  __shared__ float w[64 * 8];
  __shared__ float bb[64];
  const int tid = threadIdx.x;
  const int cobase = blockIdx.y * 64;
  for (int i = tid; i < 64 * 8; i += 256) w[i] = W2[cobase * 8 + i];
  for (int i = tid; i < 64; i += 256) bb[i] = b2[cobase + i];
  __syncthreads();
  const int p = blockIdx.x * 256 + tid;
  const int b = p / N_, n = p % N_;
  float h[8];
  #pragma unroll
  for (int j = 0; j < 8; j++) h[j] = hid[((size_t)b * 8 + j) * N_ + n];
  for (int co = 0; co < 64; co++) {
    const int gco = cobase + co;
    float t = bb[co];
    #pragma unroll
    for (int j = 0; j < 8; j++) t = fmaf(w[co * 8 + j], h[j], t);
    float sg = 1.f / (1.f + expf(-t));
    float2* zp = (gco < split) ? (zA + ((size_t)b * split + gco) * N_ + n)
                               : (zB + ((size_t)b * (Cout - split) + (gco - split)) * N_ + n);
    float2 z = *zp;
    if (MODE == 0) {
      zp->x = z.x * sg; zp->y = z.y * sg;
    } else {
      float m = sg * sqrtf(z.x * z.x + z.y * z.y);
      outR[((size_t)b * outCtot + outCoff + gco) * N_ + n] = gelu_mul(m);
    }
  }
}

// ---------------- 1x1 conv as bf16 MFMA GEMM: 128co x 64pos per block ----------------
__global__ __launch_bounds__(256) void k_conv1x1(const float* __restrict__ inA, const float* __restrict__ inB,
    int split, int Cin, int Cout, const float* __restrict__ W, const float* __restrict__ bias,
    const float* __restrict__ resid, float* __restrict__ out) {
  __shared__ unsigned int xlds[16][68];    // 4.25 KB
  const int tid = threadIdx.x;
  const int lane = tid & 63, wv = tid >> 6;
  const int p0 = blockIdx.x * 64;
  const int b = p0 / N_, n0 = p0 % N_;
  const int laneco = lane & 15, lanek = lane >> 4;
  const int kA = lanek * 8;
  f32x4 acc[2][4];
  #pragma unroll
  for (int g = 0; g < 2; g++)
    #pragma unroll
    for (int f = 0; f < 4; f++) acc[g][f] = (f32x4){0.f, 0.f, 0.f, 0.f};
  for (int cb = 0; cb < Cin; cb += 32) {
    const float* src = (cb < split) ? (inA + ((size_t)b * split + cb) * N_)
                                    : (inB + ((size_t)b * (Cin - split) + (cb - split)) * N_);
    bf16x8 af[2];
    #pragma unroll
    for (int g = 0; g < 2; g++) {
      const float* wp = W + (size_t)(wv * 32 + g * 16 + laneco) * Cin + cb + kA;
      float4 w0 = *(const float4*)wp;
      float4 w1 = *(const float4*)(wp + 4);
      af[g][0] = (short)bf16_rn(w0.x); af[g][1] = (short)bf16_rn(w0.y);
      af[g][2] = (short)bf16_rn(w0.z); af[g][3] = (short)bf16_rn(w0.w);
      af[g][4] = (short)bf16_rn(w1.x); af[g][5] = (short)bf16_rn(w1.y);
      af[g][6] = (short)bf16_rn(w1.z); af[g][7] = (short)bf16_rn(w1.w);
    }
    __syncthreads();   // previous-iter xlds reads complete
    #pragma unroll
    for (int r = 0; r < 4; r++) {
      const int kb = wv * 4 + r;
      float e = src[(size_t)(2 * kb) * N_ + n0 + lane];
      float o = src[(size_t)(2 * kb + 1) * N_ + n0 + lane];
      xlds[kb][lane] = (unsigned int)bf16_rn(e) | ((unsigned int)bf16_rn(o) << 16);
    }
    __syncthreads();
    #pragma unroll
    for (int f = 0; f < 4; f++) {
      const int pos = f * 16 + laneco;
      const int kb0 = lanek * 4;
      union { bf16x8 v; unsigned int u[4]; } bu;
      bu.u[0] = xlds[kb0 + 0][pos];
      bu.u[1] = xlds[kb0 + 1][pos];
      bu.u[2] = xlds[kb0 + 2][pos];
      bu.u[3] = xlds[kb0 + 3][pos];
      #pragma unroll
      for (int g = 0; g < 2; g++)
        acc[g][f] = __builtin_amdgcn_mfma_f32_16x16x32_bf16(af[g], bu.v, acc[g][f], 0, 0, 0);
    }
  }
  #pragma unroll
  for (int g = 0; g < 2; g++) {
    #pragma unroll
    for (int f = 0; f < 4; f++) {
      #pragma unroll
      for (int r = 0; r < 4; r++) {
        const int co = wv * 32 + g * 16 + lanek * 4 + r;
        float v = acc[g][f][r];
        if (bias) v += bias[co];
        const size_t off = ((size_t)b * Cout + co) * N_ + n0 + f * 16 + laneco;
        if (resid) v += resid[off];
        out[off] = v;
      }
    }
  }
}

// ---------------- fused q1/k1/v1 1x1 convs: blockIdx.y selects weight/output set ----------------
__global__ __launch_bounds__(256) void k_conv1x1_qkv(const float* __restrict__ in,
    const float* __restrict__ W0, const float* __restrict__ b0, float* __restrict__ o0,
    const float* __restrict__ W1, const float* __restrict__ b1, float* __restrict__ o1,
    const float* __restrict__ W2, const float* __restrict__ b2, float* __restrict__ o2) {
  __shared__ unsigned int xlds[16][68];
  const float* W    = (blockIdx.y == 0) ? W0 : (blockIdx.y == 1) ? W1 : W2;
  const float* bias = (blockIdx.y == 0) ? b0 : (blockIdx.y == 1) ? b1 : b2;
  float* out        = (blockIdx.y == 0) ? o0 : (blockIdx.y == 1) ? o1 : o2;
  const int tid = threadIdx.x;
  const int lane = tid & 63, wv = tid >> 6;
  const int p0 = blockIdx.x * 64;
  const int b = p0 / N_, n0 = p0 % N_;
  const int laneco = lane & 15, lanek = lane >> 4;
  const int kA = lanek * 8;
  f32x4 acc[2][4];
  #pragma unroll
  for (int g = 0; g < 2; g++)
    #pragma unroll
    for (int f = 0; f < 4; f++) acc[g][f] = (f32x4){0.f, 0.f, 0.f, 0.f};
  for (int cb = 0; cb < 128; cb += 32) {
    const float* src = in + ((size_t)b * 128 + cb) * N_;
    bf16x8 af[2];
    #pragma unroll
    for (int g = 0; g < 2; g++) {
      const float* wp = W + (size_t)(wv * 32 + g * 16 + laneco) * 128 + cb + kA;
      float4 w0 = *(const float4*)wp;
      float4 w1 = *(const float4*)(wp + 4);
      af[g][0] = (short)bf16_rn(w0.x); af[g][1] = (short)bf16_rn(w0.y);
      af[g][2] = (short)bf16_rn(w0.z); af[g][3] = (short)bf16_rn(w0.w);
      af[g][4] = (short)bf16_rn(w1.x); af[g][5] = (short)bf16_rn(w1.y);
      af[g][6] = (short)bf16_rn(w1.z); af[g][7] = (short)bf16_rn(w1.w);
    }
    __syncthreads();
    #pragma unroll
    for (int r = 0; r < 4; r++) {
      const int kb = wv * 4 + r;
      float e = src[(size_t)(2 * kb) * N_ + n0 + lane];
      float o = src[(size_t)(2 * kb + 1) * N_ + n0 + lane];
      xlds[kb][lane] = (unsigned int)bf16_rn(e) | ((unsigned int)bf16_rn(o) << 16);
    }
    __syncthreads();
    #pragma unroll
    for (int f = 0; f < 4; f++) {
      const int pos = f * 16 + laneco;
      const int kb0 = lanek * 4;
      union { bf16x8 v; unsigned int u[4]; } bu;
      bu.u[0] = xlds[kb0 + 0][pos];
      bu.u[1] = xlds[kb0 + 1][pos];
      bu.u[2] = xlds[kb0 + 2][pos];
      bu.u[3] = xlds[kb0 + 3][pos];
      #pragma unroll
      for (int g = 0; g < 2; g++)
        acc[g][f] = __builtin_amdgcn_mfma_f32_16x16x32_bf16(af[g], bu.v, acc[g][f], 0, 0, 0);
    }
  }
  #pragma unroll
  for (int g = 0; g < 2; g++) {
    #pragma unroll
    for (int f = 0; f < 4; f++) {
      #pragma unroll
      for (int r = 0; r < 4; r++) {
        const int co = wv * 32 + g * 16 + lanek * 4 + r;
        float v = acc[g][f][r] + bias[co];
        out[((size_t)b * 128 + co) * N_ + n0 + f * 16 + laneco] = v;
      }
    }
  }
}

// ---------------- grouped conv 3x3(pad1) + 5x5(pad2), groups=64: 4 sets via blockIdx.y ----------------
__global__ __launch_bounds__(256) void k_gconv35_4(
    const float* __restrict__ inQ, const float* __restrict__ w3Q, const float* __restrict__ w5Q, float* __restrict__ outQ,
    const float* __restrict__ inK, const float* __restrict__ w3K, const float* __restrict__ w5K, float* __restrict__ outK,
    const float* __restrict__ inV, const float* __restrict__ w3V, const float* __restrict__ w5V, float* __restrict__ outV,
    const float* __restrict__ inC2, const float* __restrict__ w3C, const float* __restrict__ w5C, float* __restrict__ outC2) {
  __shared__ float tt[2][44][84];
  const float* in; const float* w3; const float* w5; float* out;
  if (blockIdx.y == 0)      { in = inQ;  w3 = w3Q; w5 = w5Q; out = outQ; }
  else if (blockIdx.y == 1) { in = inK;  w3 = w3K; w5 = w5K; out = outK; }
  else if (blockIdx.y == 2) { in = inV;  w3 = w3V; w5 = w5V; out = outV; }
  else                      { in = inC2; w3 = w3C; w5 = w5C; out = outC2; }
  const int blk = blockIdx.x;
  const int b = blk / 128;
  const int rem = blk % 128;
  const int o = rem >> 1, half = rem & 1;
  const int y0 = half * 40;
  const float* i0 = in + ((size_t)b * C_ + 2 * o) * N_;
  const int tid = threadIdx.x;
  for (int i = tid; i < 2 * 44 * 84; i += 256) {
    int ic = i / (44 * 84);
    int r = (i % (44 * 84)) / 84;
    int cc = i % 84;
    int gy = y0 + r - 2, gx = cc - 2;
    float v = 0.f;
    if (gy >= 0 && gy < 80 && gx >= 0 && gx < 80) v = i0[(size_t)ic * N_ + gy * 80 + gx];
    tt[ic][r][cc] = v;
  }
  float w3r[2][9], w5r[2][25];
  #pragma unroll
  for (int ic = 0; ic < 2; ic++) {
    #pragma unroll
    for (int k = 0; k < 9; k++) w3r[ic][k] = w3[(o * 2 + ic) * 9 + k];
    #pragma unroll
    for (int k = 0; k < 25; k++) w5r[ic][k] = w5[(o * 2 + ic) * 25 + k];
  }
  __syncthreads();
  for (int p = tid; p < 3200; p += 256) {
    const int ly = p / 80, x = p % 80;
    float a3 = 0.f, a5 = 0.f;
    #pragma unroll
    for (int ky = 0; ky < 5; ky++) {
      #pragma unroll
      for (int kx = 0; kx < 5; kx++) {
        float v0 = tt[0][ly + ky][x + kx];
        float v1 = tt[1][ly + ky][x + kx];
        a5 = fmaf(v0, w5r[0][ky * 5 + kx], a5);
        a5 = fmaf(v1, w5r[1][ky * 5 + kx], a5);
        if (ky >= 1 && ky < 4 && kx >= 1 && kx < 4) {
          int k3 = (ky - 1) * 3 + (kx - 1);
          a3 = fmaf(v0, w3r[0][k3], a3);
          a3 = fmaf(v1, w3r[1][k3], a3);
        }
      }
    }
    const int yy = y0 + ly;
    out[((size_t)b * C_ + o) * N_ + yy * 80 + x] = a3;
    out[((size_t)b * C_ + 64 + o) * N_ + yy * 80 + x] = a5;
  }
}

// ---------------- depthwise conv3x3 (pad1) + gelu(x)*x: zero-padded halo, 40-row halves ----------------
__global__ __launch_bounds__(256) void k_dwconv3_gelu(const float* __restrict__ in, const float* __restrict__ w,
    float* __restrict__ out, int Cn, int outCtot, int outCoff) {
  __shared__ float tt[42][82];
  const int blk = blockIdx.x;
  const int b = blk / (2 * Cn);
  const int rem = blk % (2 * Cn);
  const int c = rem >> 1, half = rem & 1;
  const int y0 = half * 40;
  const float* ip = in + ((size_t)b * Cn + c) * N_;
  const int tid = threadIdx.x;
  for (int i = tid; i < 42 * 82; i += 256) {
    int r = i / 82, cc = i % 82;
    int gy = y0 + r - 1, gx = cc - 1;
    float v = 0.f;
    if (gy >= 0 && gy < 80 && gx >= 0 && gx < 80) v = ip[gy * 80 + gx];
    tt[r][cc] = v;
  }
  float wr[9];
  #pragma unroll
  for (int k = 0; k < 9; k++) wr[k] = w[c * 9 + k];
  __syncthreads();
  float* op = out + ((size_t)b * outCtot + outCoff + c) * N_;
  for (int p = tid; p < 3200; p += 256) {
    const int ly = p / 80, x = p % 80;
    float a = 0.f;
    #pragma unroll
    for (int ky = 0; ky < 3; ky++) {
      #pragma unroll
      for (int kx = 0; kx < 3; kx++)
        a = fmaf(tt[ly + ky][x + kx], wr[ky * 3 + kx], a);
    }
    op[(y0 + ly) * 80 + x] = gelu_mul(a);
  }
}

// ---------------- ff_dw2: groups=128, 2-in/2-out per group, 3x3 pad1: zero-padded halo, halves ----------------
__global__ __launch_bounds__(256) void k_ffdw2(const float* __restrict__ in, const float* __restrict__ w,
                                               float* __restrict__ out) {
  __shared__ float tt[2][42][82];
  const int blk = blockIdx.x;
  const int b = blk / 256;
  const int rem = blk % 256;
  const int g = rem >> 1, half = rem & 1;
  const int y0 = half * 40;
  const float* i0 = in + ((size_t)b * 256 + 2 * g) * N_;
  const int tid = threadIdx.x;
  for (int i = tid; i < 2 * 42 * 82; i += 256) {
    int ic = i / (42 * 82);
    int r = (i % (42 * 82)) / 82;
    int cc = i % 82;
    int gy = y0 + r - 1, gx = cc - 1;
    float v = 0.f;
    if (gy >= 0 && gy < 80 && gx >= 0 && gx < 80) v = i0[(size_t)ic * N_ + gy * 80 + gx];
    tt[ic][r][cc] = v;
  }
  float w0[2][9], w1[2][9];
  #pragma unroll
  for (int ic = 0; ic < 2; ic++) {
    #pragma unroll
    for (int k = 0; k < 9; k++) {
      w0[ic][k] = w[((2 * g) * 2 + ic) * 9 + k];
      w1[ic][k] = w[((2 * g + 1) * 2 + ic) * 9 + k];
    }
  }
  __syncthreads();
  for (int p = tid; p < 3200; p += 256) {
    const int ly = p / 80, x = p % 80;
    float a0 = 0.f, a1 = 0.f;
    #pragma unroll
    for (int ky = 0; ky < 3; ky++) {
      #pragma unroll
      for (int kx = 0; kx < 3; kx++) {
        float v0 = tt[0][ly + ky][x + kx], v1 = tt[1][ly + ky][x + kx];
        int k = ky * 3 + kx;
        a0 = fmaf(v0, w0[0][k], a0); a0 = fmaf(v1, w0[1][k], a0);
        a1 = fmaf(v0, w1[0][k], a1); a1 = fmaf(v1, w1[1][k], a1);
      }
    }
    const int yy = y0 + ly;
    out[((size_t)b * 256 + 2 * g) * N_ + yy * 80 + x] = a0;
    out[((size_t)b * 256 + 2 * g + 1) * N_ + yy * 80 + x] = a1;
  }
}

// ---------------- merged per-row L2 norms (two input sets via blockIdx routing) ----------------
__global__ __launch_bounds__(256) void k_rownorm_r2(const float* __restrict__ inA, float* __restrict__ nrmA,
                                                    const float* __restrict__ inB, float* __restrict__ nrmB) {
  __shared__ float red[256];
  int row = blockIdx.x;
  const float* p; float* o;
  if (row < B_ * C_) { p = inA + (size_t)row * N_; o = nrmA + row; }
  else { row -= B_ * C_; p = inB + (size_t)row * N_; o = nrmB + row; }
  float s = 0.f;
  for (int i = threadIdx.x; i < N_; i += 256) { float v = p[i]; s = fmaf(v, v, s); }
  red[threadIdx.x] = s; __syncthreads();
  for (int st = 128; st > 0; st >>= 1) { if (threadIdx.x < st) red[threadIdx.x] += red[threadIdx.x + st]; __syncthreads(); }
  if (threadIdx.x == 0) *o = fmaxf(sqrtf(red[0]), 1e-12f);
}

// ---------------- attention partials: coalesced wave-per-tile ----------------
__global__ __launch_bounds__(256) void k_attn_part_c(const float2* __restrict__ Ab, const float2* __restrict__ Bb,
                                                     float2* __restrict__ part) {
  const int bh = blockIdx.z;
  const int b = bh / H_, h = bh % H_;
  const int wave = threadIdx.x >> 6, lane = threadIdx.x & 63;
  const int tile = blockIdx.x * 4 + wave;      // 0..63
  const int c0 = (tile >> 3) * 4, d0 = (tile & 7) * 4;
  const size_t hb = ((size_t)b * C_ + h * 32) * N_;
  const float2* Ap = Ab + hb;
  const float2* Bp = Bb + hb;
  float2 acc[4][4];
  #pragma unroll
  for (int j = 0; j < 4; j++)
    #pragma unroll
    for (int i = 0; i < 4; i++) acc[j][i] = make_float2(0.f, 0.f);
  const int nb = blockIdx.y * (N_ / NSPL) + lane;
  for (int it = 0; it < (N_ / NSPL) / 64; ++it) {
    const int n = nb + it * 64;
    float2 av[4], bv[4];
    #pragma unroll
    for (int j = 0; j < 4; j++) av[j] = Ap[(size_t)(c0 + j) * N_ + n];
    #pragma unroll
    for (int i = 0; i < 4; i++) bv[i] = Bp[(size_t)(d0 + i) * N_ + n];
    #pragma unroll
    for (int j = 0; j < 4; j++)
      #pragma unroll
      for (int i = 0; i < 4; i++) cfma(acc[j][i], av[j], bv[i]);
  }
  float2* pp = part + (size_t)(bh * NSPL + blockIdx.y) * 1024;
  #pragma unroll
  for (int j = 0; j < 4; j++) {
    #pragma unroll
    for (int i = 0; i < 4; i++) {
      float rx = acc[j][i].x, ry = acc[j][i].y;
      for (int off = 32; off; off >>= 1) { rx += __shfl_xor(rx, off); ry += __shfl_xor(ry, off); }
      if (lane == 0) pp[(c0 + j) * 32 + d0 + i] = make_float2(rx, ry);
    }
  }
}
__global__ __launch_bounds__(256) void k_attn_part_r(const float* __restrict__ Ab, const float* __restrict__ Bb,
                                                     float* __restrict__ part) {
  const int bh = blockIdx.z;
  const int b = bh / H_, h = bh % H_;
  const int wave = threadIdx.x >> 6, lane = threadIdx.x & 63;
  const int tile = blockIdx.x * 4 + wave;
  const int c0 = (tile >> 3) * 4, d0 = (tile & 7) * 4;
  const size_t hb = ((size_t)b * C_ + h * 32) * N_;
  const float* Ap = Ab + hb;
  const float* Bp = Bb + hb;
  float acc[4][4];
  #pragma unroll
  for (int j = 0; j < 4; j++)
    #pragma unroll
    for (int i = 0; i < 4; i++) acc[j][i] = 0.f;
  const int nb = blockIdx.y * (N_ / NSPL) + lane;
  for (int it = 0; it < (N_ / NSPL) / 64; ++it) {
    const int n = nb + it * 64;
    float av[4], bv[4];
    #pragma unroll
    for (int j = 0; j < 4; j++) av[j] = Ap[(size_t)(c0 + j) * N_ + n];
    #pragma unroll
    for (int i = 0; i < 4; i++) bv[i] = Bp[(size_t)(d0 + i) * N_ + n];
    #pragma unroll
    for (int j = 0; j < 4; j++)
      #pragma unroll
      for (int i = 0; i < 4; i++) acc[j][i] = fmaf(av[j], bv[i], acc[j][i]);
  }
  float* pp = part + (size_t)(bh * NSPL + blockIdx.y) * 1024;
  #pragma unroll
  for (int j = 0; j < 4; j++) {
    #pragma unroll
    for (int i = 0; i < 4; i++) {
      float r = acc[j][i];
      for (int off = 32; off; off >>= 1) r += __shfl_xor(r, off);
      if (lane == 0) pp[(c0 + j) * 32 + d0 + i] = r;
    }
  }
}

// ---------------- reduce partials, scale, softmax ----------------
template <int CPLX>
__global__ void k_attn_soft(const float* __restrict__ part, const float* __restrict__ nA,
                            const float* __restrict__ nB, const float* __restrict__ temp,
                            float* __restrict__ attn) {
  const int rc = blockIdx.x;          // bh*32 + c
  const int bh = rc >> 5, c = rc & 31;
  const int b = bh / H_, h = bh % H_;
  const int d = threadIdx.x;          // 64 threads; group >=32 unused
  float re = -1e30f, im = -1e30f;
  if (d < 32) {
    re = 0.f; im = 0.f;
    if (CPLX) {
      const float2* pp = (const float2*)part;
      for (int kc = 0; kc < NSPL; kc++) { float2 v = pp[(size_t)(bh * NSPL + kc) * 1024 + c * 32 + d]; re += v.x; im += v.y; }
    } else {
      for (int kc = 0; kc < NSPL; kc++) re += part[(size_t)(bh * NSPL + kc) * 1024 + c * 32 + d];
    }
    float sc = temp[h] / (nA[b * C_ + h * 32 + c] * nB[b * C_ + h * 32 + d]);
    re *= sc; im *= sc;
  }
  float m = re;
  for (int o = 16; o; o >>= 1) m = fmaxf(m, __shfl_xor(m, o, 32));
  float e = expf(re - m);
  float s = e;
  for (int o = 16; o; o >>= 1) s += __shfl_xor(s, o, 32);
  float vr = e / s;
  float mi = im;
  for (int o = 16; o; o >>= 1) mi = fmaxf(mi, __shfl_xor(mi, o, 32));
  float ei = expf(im - mi);
  float si = ei;
  for (int o = 16; o; o >>= 1) si += __shfl_xor(si, o, 32);
  float vi = ei / si;
  if (d < 32) {
    if (CPLX) ((float2*)attn)[(size_t)(bh * 32 + c) * 32 + d] = make_float2(vr, vi);
    else attn[(size_t)(bh * 32 + c) * 32 + d] = vr;
  }
}

// ---------------- fused PV + 32-point IDFT along c: out[cp,n] = (1/32) sum_c pv[c,n] e^{2pi i c cp/32} ----------------
__global__ __launch_bounds__(256) void k_pv_idft32(const float2* __restrict__ attn, const float2* __restrict__ V,
                                                   float2* __restrict__ out) {
  __shared__ float2 at[32][32];
  __shared__ float2 tw[32];
  const int bh = blockIdx.x;
  const int b = bh / H_, h = bh % H_;
  const int n = blockIdx.y * 256 + threadIdx.x;
  if (threadIdx.x < 32) { float a = PI2 * (float)threadIdx.x * (1.f / 32.f); float sv, cv; sincosf(a, &sv, &cv); tw[threadIdx.x] = make_float2(cv, sv); }
  for (int i = threadIdx.x; i < 1024; i += 256) at[i >> 5][i & 31] = attn[(size_t)bh * 1024 + i];
  __syncthreads();
  const size_t hb = ((size_t)b * C_ + h * 32) * N_;
  const float2* Vp = V + hb;
  float2 acc[32];
  #pragma unroll
  for (int c = 0; c < 32; c++) acc[c] = make_float2(0.f, 0.f);
  for (int dd = 0; dd < 32; dd++) {
    float2 v = Vp[(size_t)dd * N_ + n];
    #pragma unroll
    for (int c = 0; c < 32; c++) cfma(acc[c], at[c][dd], v);
  }
  // in-register radix-2 32-point IDFT along c (same summation order as the old k_idft32)
  float2* Op = out + hb;
  for (int cp = 0; cp < 16; cp++) {
    float2 E = make_float2(0.f, 0.f), O = make_float2(0.f, 0.f);
    const int inc = (2 * cp) & 31;
    int idx = 0;
    #pragma unroll
    for (int m = 0; m < 16; m++) {
      cfma(E, acc[2 * m], tw[idx]);
      cfma(O, acc[2 * m + 1], tw[idx]);
      idx = (idx + inc) & 31;
    }
    float2 u = cmul(tw[cp], O);
    Op[(size_t)cp * N_ + n]        = make_float2((E.x + u.x) * (1.f / 32.f), (E.y + u.y) * (1.f / 32.f));
    Op[(size_t)(cp + 16) * N_ + n] = make_float2((E.x - u.x) * (1.f / 32.f), (E.y - u.y) * (1.f / 32.f));
  }
}

__global__ __launch_bounds__(256) void k_pv_r(const float* __restrict__ attn, const float* __restrict__ V,
                                              float* __restrict__ out) {
  __shared__ float at[32][32];
  const int bh = blockIdx.x;
  const int b = bh / H_, h = bh % H_;
  const int n = blockIdx.y * 256 + threadIdx.x;
  for (int i = threadIdx.x; i < 1024; i += 256) at[i >> 5][i & 31] = attn[(size_t)bh * 1024 + i];
  __syncthreads();
  const size_t hb = ((size_t)b * C_ + h * 32) * N_;
  const float* Vp = V + hb;
  float acc[32];
  #pragma unroll
  for (int c = 0; c < 32; c++) acc[c] = 0.f;
  for (int dd = 0; dd < 32; dd++) {
    float v = Vp[(size_t)dd * N_ + n];
    #pragma unroll
    for (int c = 0; c < 32; c++) acc[c] = fmaf(at[c][dd], v, acc[c]);
  }
  float* Op = out + hb;
  #pragma unroll
  for (int c = 0; c < 32; c++) Op[(size_t)c * N_ + n] = acc[c];
}

extern "C" void kernel_launch(void* const* d_in, const int* in_sizes, int n_in,
                              void* d_out, int out_size, void* d_ws, size_t ws_size,
                              hipStream_t stream) {
  (void)in_sizes; (void)n_in; (void)out_size; (void)ws_size;
  const float* x       = (const float*)d_in[0];
  const float* ln1_w   = (const float*)d_in[1];
  const float* ln2_w   = (const float*)d_in[2];
  const float* ln1_b   = (const float*)d_in[3];
  const float* ln2_b   = (const float*)d_in[4];
  const float* f_temp  = (const float*)d_in[5];
  const float* s_temp  = (const float*)d_in[6];
  const float* f_proj  = (const float*)d_in[7];
  const float* s_proj  = (const float*)d_in[8];
  const float* f_w1    = (const float*)d_in[9];
  const float* f_wb1   = (const float*)d_in[10];
  const float* f_bng   = (const float*)d_in[11];
  const float* f_bnb   = (const float*)d_in[12];
  const float* f_w2    = (const float*)d_in[13];
  const float* f_wb2   = (const float*)d_in[14];
  const float* s_q1_w  = (const float*)d_in[15];
  const float* s_q1_b  = (const float*)d_in[16];
  const float* s_k1_w  = (const float*)d_in[17];
  const float* s_k1_b  = (const float*)d_in[18];
  const float* s_v1_w  = (const float*)d_in[19];
  const float* s_v1_b  = (const float*)d_in[20];
  const float* s_q3_w  = (const float*)d_in[21];
  const float* s_k3_w  = (const float*)d_in[22];
  const float* s_v3_w  = (const float*)d_in[23];
  const float* s_c3_w  = (const float*)d_in[24];
  const float* s_q5_w  = (const float*)d_in[25];
  const float* s_k5_w  = (const float*)d_in[26];
  const float* s_v5_w  = (const float*)d_in[27];
  const float* s_c5_w  = (const float*)d_in[28];
  const float* ffdw1_w = (const float*)d_in[29];
  const float* ffdw2_w = (const float*)d_in[30];
  const float* ffproj  = (const float*)d_in[31];
  const float* ffg_w1  = (const float*)d_in[32];
  const float* ffg_b1  = (const float*)d_in[33];
  const float* ffg_bng = (const float*)d_in[34];
  const float* ffg_bnb = (const float*)d_in[35];
  const float* ffg_w2  = (const float*)d_in[36];
  const float* ffg_b2  = (const float*)d_in[37];
  const float* ffg1_w1 = (const float*)d_in[38];
  const float* ffg1_b1 = (const float*)d_in[39];
  const float* ffg1_bng= (const float*)d_in[40];
  const float* ffg1_bnb= (const float*)d_in[41];
  const float* ffg1_w2 = (const float*)d_in[42];
  const float* ffg1_b2 = (const float*)d_in[43];

  // workspace layout (floats). Requires ~267 MB of d_ws.
  float* ws = (float*)d_ws;
  const size_t R = (size_t)B_ * C_ * N_;   // 6,553,600 floats per [B,128,N] image set
  float* xn   = ws;            // R
  float* acc  = ws + R;        // R
  float* bufA = ws + 2 * R;    // 2R (complex [B,128,N] or real [B,256,N])
  float* bufB = ws + 4 * R;    // 2R
  float* bufC = ws + 6 * R;    // 2R
  float* bufD = ws + 8 * R;    // 2R
  float* sm   = ws + 10 * R;   // small pool
  float* nrmQ = sm;                    // 1024
  float* nrmK = sm + 1024;             // 1024
  float* hid  = sm + 2048;             // B*8*N = 409600
  float* part = sm + 2048 + 409600;    // 524288 (float2[131072] used for cplx)
  float* attb = part + 524288;         // 65536 (float2[32768] for cplx)

  dim3 blk(256);
  const int GCONV = P_ / 64;   // 800 blocks, 128co x 64pos MFMA tiles
  const int GLN = P_ / 64;     // 800 blocks for layernorm / gateA
  const int NIMG = B_ * C_;    // 1024
  const dim3 gattn(16, NSPL, B_ * H_);

  // ===== xn = LayerNorm(x) ; xf = fft2(xn) with fused row-norm =====
  k_layernorm<<<GLN, blk, 0, stream>>>(x, ln1_w, ln1_b, xn);
  k_fft2_r2c<<<NIMG, blk, 0, stream>>>(xn, (float2*)bufA, C_, C_, 0, nullptr, 0, NIMG, nrmQ);

  // ===== Attention_F =====
  k_attn_part_c<<<gattn, blk, 0, stream>>>((const float2*)bufA, (const float2*)bufA, (float2*)part);
  k_attn_soft<1><<<B_ * C_, 64, 0, stream>>>(part, nrmQ, nrmQ, f_temp, attb);
  // fused PV + idft32: writes bufC directly (bufB roundtrip eliminated)
  k_pv_idft32<<<dim3(B_ * H_, N_ / 256), blk, 0, stream>>>((const float2*)attb, (const float2*)bufA, (float2*)bufC);
  // gated branch first (reads bufA pre/post scale), then merged idft6400+ifft2
  k_gateA<<<GLN, blk, 0, stream>>>((const float2*)bufA, (const float2*)bufA, C_, C_, f_w1, f_wb1, f_bng, f_bnb, hid);
  k_gateB<0><<<dim3(P_ / 256, 2), blk, 0, stream>>>((float2*)bufA, (float2*)bufA, C_, C_, f_w2, f_wb2, hid, nullptr, 0, 0);
  k_iff_combo<<<2 * NIMG, blk, 0, stream>>>((const float2*)bufC, bufD, (const float2*)bufA, bufD + R);
  // a_f: acc = x + f_proj(concat(out_f, out_f_l))
  k_conv1x1<<<GCONV, blk, 0, stream>>>(bufD, bufD + R, 128, 256, 128, f_proj, nullptr, x, acc);

  // ===== Attention_S =====
  // fused q1/k1/v1 (one 2400-block dispatch; blockIdx.y routes weight/output set)
  k_conv1x1_qkv<<<dim3(GCONV, 3), blk, 0, stream>>>(xn,
      s_q1_w, s_q1_b, bufA, s_k1_w, s_k1_b, bufA + R, s_v1_w, s_v1_b, bufB);
  // fused qs/ks/vs/cs grouped convs (4 sets; cs output redirected to bufD+R -> no conflicts)
  k_gconv35_4<<<dim3(B_ * 128, 4), blk, 0, stream>>>(
      bufA,     s_q3_w, s_q5_w, bufB + R,
      bufA + R, s_k3_w, s_k5_w, bufC,
      bufB,     s_v3_w, s_v5_w, bufC + R,
      xn,       s_c3_w, s_c5_w, bufD + R);
  // merged rownorms (qs -> nrmQ, ks -> nrmK)
  k_rownorm_r2<<<2 * B_ * C_, blk, 0, stream>>>(bufB + R, nrmQ, bufC, nrmK);
  k_attn_part_r<<<gattn, blk, 0, stream>>>(bufB + R, bufC, part);
  k_attn_soft<0><<<B_ * C_, 64, 0, stream>>>(part, nrmQ, nrmK, s_temp, attb);
  k_pv_r<<<dim3(B_ * H_, N_ / 256), blk, 0, stream>>>(attb, bufC + R, bufA);      // out_s -> A.lo
  // a_s: acc += s_proj(concat(out_s, out_s_l))  (out_s_l lives in bufD+R)
  k_conv1x1<<<GCONV, blk, 0, stream>>>(bufA, bufD + R, 128, 256, 128, s_proj, nullptr, acc, acc);

  // ===== FeedForward =====
  k_layernorm<<<GLN, blk, 0, stream>>>(acc, ln2_w, ln2_b, xn);                    // xn2
  k_fft2_r2c<<<NIMG, blk, 0, stream>>>(xn, (float2*)bufA, C_, C_, 0, nullptr, 0, NIMG, nullptr);  // xf2
  k_gateA<<<GLN, blk, 0, stream>>>((const float2*)bufA, (const float2*)bufA, C_, C_, ffg_w1, ffg_b1, ffg_bng, ffg_bnb, hid);
  k_gateB<1><<<dim3(P_ / 256, 2), blk, 0, stream>>>((float2*)bufA, (float2*)bufA, C_, C_, ffg_w2, ffg_b2, hid, bufB, 256, 0); // x_f_g -> cat.lo
  k_dwconv3_gelu<<<B_ * 256, blk, 0, stream>>>(xn, ffdw1_w, bufB, 128, 256, 128); // x_s_g -> cat.hi
  // cf = fft2(cat): one merged 2048-block dispatch (lo -> bufA, hi -> bufC)
  k_fft2_r2c<<<2 * NIMG, blk, 0, stream>>>(bufB, (float2*)bufA, 128, 256, 0, (float2*)bufC, 128, NIMG, nullptr);
  k_gateA<<<GLN, blk, 0, stream>>>((const float2*)bufA, (const float2*)bufC, 128, 256, ffg1_w1, ffg1_b1, ffg1_bng, ffg1_bnb, hid);
  k_gateB<0><<<dim3(P_ / 256, 4), blk, 0, stream>>>((float2*)bufA, (float2*)bufC, 128, 256, ffg1_w2, ffg1_b2, hid, nullptr, 0, 0);
  // x_f2b: merged 2048-block ifft2 pair (bufA -> bufD coff0, bufC -> bufD coff128)
  k_ifft2_abs<<<2 * NIMG, blk, 0, stream>>>((const float2*)bufA, bufD, 128, 256, 0, (const float2*)bufC, 128, NIMG);
  k_ffdw2<<<B_ * 256, blk, 0, stream>>>(bufB, ffdw2_w, bufA);                     // x_s2b (real [B,256,N] in A)
  // out = x1 + ff_proj(concat(x_f2b, x_s2b))
  k_conv1x1<<<GCONV, blk, 0, stream>>>(bufD, bufA, 256, 512, 128, ffproj, nullptr, acc, (float*)d_out);
}

// Round 20
// 1040.949 us; speedup vs baseline: 1.1777x; 1.0831x over previous
//
#include <hip/hip_runtime.h>
#include <math.h>

#define DI __device__ __forceinline__

constexpr int B_ = 8, C_ = 128, H_ = 4, S_ = 80, N_ = 6400;
constexpr int P_ = B_ * N_;                 // 51200 spatial positions
constexpr int NSPL = 2;                     // n-chunks for attention partials
constexpr float PI2 = 6.283185307179586f;
constexpr float BN_SC = 0.9999950000374997f;  // 1/sqrt(1+1e-5)

typedef __attribute__((ext_vector_type(8))) short bf16x8;
typedef __attribute__((ext_vector_type(4))) float f32x4;

DI void cfma(float2& a, float2 u, float2 v) {
  a.x = fmaf(u.x, v.x, a.x); a.x = fmaf(-u.y, v.y, a.x);
  a.y = fmaf(u.x, v.y, a.y); a.y = fmaf(u.y, v.x, a.y);
}
DI float2 cmul(float2 u, float2 v) {
  return make_float2(u.x * v.x - u.y * v.y, u.x * v.y + u.y * v.x);
}
DI float gelu_mul(float m) {  // gelu(m, exact) * m
  return 0.5f * m * (1.f + erff(m * 0.7071067811865476f)) * m;
}
DI unsigned short bf16_rn(float f) {  // round-to-nearest-even fp32 -> bf16
  union { float f; unsigned int u; } v; v.f = f;
  unsigned int u = v.u;
  return (unsigned short)((u + 0x7fffu + ((u >> 16) & 1u)) >> 16);
}

// ---------------- LayerNorm over channel dim (4-way channel-split, 800 blocks) ----------------
__global__ __launch_bounds__(256) void k_layernorm(const float* __restrict__ in,
    const float* __restrict__ w, const float* __restrict__ bb, float* __restrict__ out) {
  __shared__ float redS[4][64], redS2[4][64];
  __shared__ float muv[64], invv[64];
  const int tid = threadIdx.x;
  const int g = tid >> 6, l = tid & 63;
  const int p = blockIdx.x * 64 + l;
  const int b = p / N_, n = p % N_;
  const float* xp = in + (size_t)b * C_ * N_ + n;
  float s = 0.f, s2 = 0.f;
  for (int c = g * 32; c < g * 32 + 32; c++) {
    float v = xp[(size_t)c * N_];
    s += v; s2 = fmaf(v, v, s2);
  }
  redS[g][l] = s; redS2[g][l] = s2;
  __syncthreads();
  if (g == 0) {
    float ts  = redS[0][l] + redS[1][l] + redS[2][l] + redS[3][l];
    float ts2 = redS2[0][l] + redS2[1][l] + redS2[2][l] + redS2[3][l];
    float mu = ts * (1.f / C_);
    float var = ts2 * (1.f / C_) - mu * mu;
    muv[l] = mu; invv[l] = rsqrtf(var + 1e-5f);
  }
  __syncthreads();
  const float mu = muv[l], inv = invv[l];
  float* op = out + (size_t)b * C_ * N_ + n;
  for (int c = g * 32; c < g * 32 + 32; c++) {
    float v = xp[(size_t)c * N_];
    op[(size_t)c * N_] = (v - mu) * inv * w[c] + bb[c];
  }
}

// ============ register-tiled 80x80 2D DFT kernels ============

// ---------------- 2D FFT (80x80) real->complex, 5x16 Cooley-Tukey both passes ----------------
// A[k] = sum_q tw80[(qk)%80] * F_q[k%16],  F_q[kap] = sum_m x[5m+q] tw80[5*((m*kap)%16)]
__global__ __launch_bounds__(256) void k_fft2_r2c(const float* __restrict__ in, float2* __restrict__ out,
                                                  int nCh, int inCtot, int inCoff,
                                                  float2* __restrict__ out2, int inCoff2, int nimg,
                                                  float* __restrict__ nrm) {
  __shared__ float2 data[N_];
  __shared__ float2 tw[80];
  int img = blockIdx.x;
  float2* op;
  int coff;
  if (img >= nimg) { img -= nimg; op = out2 + (size_t)img * N_; coff = inCoff2; }
  else { op = out + (size_t)img * N_; coff = inCoff; }
  const int b = img / nCh, ch = img % nCh;
  const float* ip = in + ((size_t)b * inCtot + coff + ch) * N_;
  const int tid = threadIdx.x;
  float* dataR = (float*)data;
  if (tid < 80) { float a = -PI2 * (float)tid * (1.f / 80.f); float sv, cv; sincosf(a, &sv, &cv); tw[tid] = make_float2(cv, sv); }
  for (int i = tid; i < N_; i += 256) dataR[i] = ip[i];
  __syncthreads();
  // ---- pass 1: rows. thread = (rg: 5 rows, kap in [0,16)) ----
  const int rg = tid >> 4;
  const int kap = tid & 15;
  const int r0 = rg * 5;
  {
    float2 F[5][5];   // [j][q]
    #pragma unroll
    for (int j = 0; j < 5; j++)
      #pragma unroll
      for (int q = 0; q < 5; q++) F[j][q] = make_float2(0.f, 0.f);
    int m16 = 0;
    for (int m = 0; m < 16; ++m) {
      float2 t = tw[5 * m16];
      #pragma unroll
      for (int j = 0; j < 5; j++) {
        const float* row = &dataR[(r0 + j) * 80 + 5 * m];
        #pragma unroll
        for (int q = 0; q < 5; q++) {
          float xv = row[q];
          F[j][q].x = fmaf(xv, t.x, F[j][q].x);
          F[j][q].y = fmaf(xv, t.y, F[j][q].y);
        }
      }
      m16 += kap; if (m16 >= 16) m16 -= 16;
    }
    __syncthreads();   // all real reads done before complex overwrite
    #pragma unroll
    for (int s = 0; s < 5; ++s) {
      const int k = kap + 16 * s;
      if (k <= 40) {
        float2 t1 = tw[k];
        float2 t2 = tw[(2 * k) % 80];
        float2 t3 = tw[(3 * k) % 80];
        float2 t4 = tw[(4 * k) % 80];
        #pragma unroll
        for (int j = 0; j < 5; j++) {
          float2 a = F[j][0];
          cfma(a, F[j][1], t1);
          cfma(a, F[j][2], t2);
          cfma(a, F[j][3], t3);
          cfma(a, F[j][4], t4);
          data[(r0 + j) * 80 + k] = a;
          if (k >= 1 && k <= 39) data[(r0 + j) * 80 + 80 - k] = make_float2(a.x, -a.y);
        }
      }
    }
  }
  __syncthreads();
  // ---- pass 2: columns. thread = (k0: 5 cols, kap2 in [0,16)) ----
  const int k0 = (tid & 15) * 5;
  const int kap2 = tid >> 4;
  float snrm = 0.f;
  {
    float2 G[5][5];   // [q][i]
    #pragma unroll
    for (int q = 0; q < 5; q++)
      #pragma unroll
      for (int i = 0; i < 5; i++) G[q][i] = make_float2(0.f, 0.f);
    int m16 = 0;
    for (int m = 0; m < 16; ++m) {
      float2 t = tw[5 * m16];
      #pragma unroll
      for (int q = 0; q < 5; q++) {
        const float2* rowp = &data[(5 * m + q) * 80 + k0];
        #pragma unroll
        for (int i = 0; i < 5; i++) cfma(G[q][i], rowp[i], t);
      }
      m16 += kap2; if (m16 >= 16) m16 -= 16;
    }
    #pragma unroll
    for (int s = 0; s < 5; ++s) {
      const int k1 = kap2 + 16 * s;
      if (k1 <= 40) {
        float2 t1 = tw[k1];
        float2 t2 = tw[(2 * k1) % 80];
        float2 t3 = tw[(3 * k1) % 80];
        float2 t4 = tw[(4 * k1) % 80];
        const float wgt = (k1 == 0 || k1 == 40) ? 1.f : 2.f;
        #pragma unroll
        for (int i = 0; i < 5; i++) {
          float2 y = G[0][i];
          cfma(y, G[1][i], t1);
          cfma(y, G[2][i], t2);
          cfma(y, G[3][i], t3);
          cfma(y, G[4][i], t4);
          const int k2 = k0 + i;
          op[k1 * 80 + k2] = y;
          if (k1 >= 1 && k1 <= 39) {
            const int m2 = (k2 == 0) ? 0 : 80 - k2;
            op[(80 - k1) * 80 + m2] = make_float2(y.x, -y.y);
          }
          snrm += wgt * (y.x * y.x + y.y * y.y);
        }
      }
    }
  }
  if (nrm) {   // fused per-image L2 norm (mirrored halves contribute 2x)
    __syncthreads();
    float* red = (float*)data;
    red[tid] = snrm;
    __syncthreads();
    for (int st = 128; st > 0; st >>= 1) { if (tid < st) red[tid] += red[tid + st]; __syncthreads(); }
    if (tid == 0) nrm[img] = fmaxf(sqrtf(red[0]), 1e-12f);
  }
}

// ---------------- 2D IFFT (80x80) of HERMITIAN input -> |real| (optional 2nd input set) ----------------
__global__ __launch_bounds__(256) void k_ifft2_abs(const float2* __restrict__ in, float* __restrict__ out,
                                                   int inC, int outCtot, int outCoff,
                                                   const float2* __restrict__ in2, int outCoff2, int nimg) {
  __shared__ float2 data[N_];
  __shared__ float2 tw[80];
  int img = blockIdx.x;
  const float2* ip;
  int coff;
  if (img >= nimg) { img -= nimg; ip = in2 + (size_t)img * N_; coff = outCoff2; }
  else { ip = in + (size_t)img * N_; coff = outCoff; }
  const int b = img / inC, ch = img % inC;
  float* op = out + ((size_t)b * outCtot + coff + ch) * N_;
  const int tid = threadIdx.x;
  if (tid < 80) { float a = PI2 * (float)tid * (1.f / 80.f); float sv, cv; sincosf(a, &sv, &cv); tw[tid] = make_float2(cv, sv); }
  for (int i = tid; i < N_; i += 256) data[i] = ip[i];
  __syncthreads();
  const int rg = tid >> 4;
  const int cg = tid & 15;
  float2 E[3][3], O[3][3];
  for (int j = 0; j < 3; j++)
    for (int i = 0; i < 3; i++) { E[j][i] = make_float2(0.f, 0.f); O[j][i] = make_float2(0.f, 0.f); }
  {
    int idx[3], inc[3];
    #pragma unroll
    for (int i = 0; i < 3; i++) { idx[i] = 0; inc[i] = (2 * (cg + 16 * i)) % 80; }
    for (int m = 0; m < 40; ++m) {
      float4 z[3]; float2 t[3];
      #pragma unroll
      for (int j = 0; j < 3; j++) z[j] = *(const float4*)&data[(rg + 16 * j) * 80 + 2 * m];
      #pragma unroll
      for (int i = 0; i < 3; i++) t[i] = tw[idx[i]];
      #pragma unroll
      for (int j = 0; j < 3; j++) {
        float2 ze = make_float2(z[j].x, z[j].y);
        float2 zo = make_float2(z[j].z, z[j].w);
        #pragma unroll
        for (int i = 0; i < 3; i++) { cfma(E[j][i], ze, t[i]); cfma(O[j][i], zo, t[i]); }
      }
      #pragma unroll
      for (int i = 0; i < 3; i++) { idx[i] += inc[i]; if (idx[i] >= 80) idx[i] -= 80; }
    }
  }
  __syncthreads();
  #pragma unroll
  for (int j = 0; j < 3; j++) {
    const int r = rg + 16 * j;
    if (r <= 40) {
      #pragma unroll
      for (int i = 0; i < 3; i++) {
        const int n2 = cg + 16 * i;
        if (n2 < 40) {
          float2 u = cmul(tw[n2], O[j][i]);
          data[r * 80 + n2]      = make_float2(E[j][i].x + u.x, E[j][i].y + u.y);
          data[r * 80 + n2 + 40] = make_float2(E[j][i].x - u.x, E[j][i].y - u.y);
        }
      }
    }
  }
  __syncthreads();
  const int r0 = (tid >> 4) * 5;
  const int k0 = (tid & 15) * 5;
  float accR[5][5];
  for (int j = 0; j < 5; j++)
    for (int i = 0; i < 5; i++) accR[j][i] = 0.f;
  {
    int idx[5];
    #pragma unroll
    for (int j = 0; j < 5; j++) idx[j] = r0 + j;
    for (int r = 1; r <= 39; ++r) {
      float2 d[5]; float2 t[5];
      #pragma unroll
      for (int i = 0; i < 5; i++) d[i] = data[r * 80 + k0 + i];
      #pragma unroll
      for (int j = 0; j < 5; j++) t[j] = tw[idx[j]];
      #pragma unroll
      for (int j = 0; j < 5; j++) {
        #pragma unroll
        for (int i = 0; i < 5; i++) {
          accR[j][i] = fmaf(t[j].x, d[i].x, accR[j][i]);
          accR[j][i] = fmaf(-t[j].y, d[i].y, accR[j][i]);
        }
      }
      #pragma unroll
      for (int j = 0; j < 5; j++) { idx[j] += r0 + j; if (idx[j] >= 80) idx[j] -= 80; }
    }
  }
  #pragma unroll
  for (int i = 0; i < 5; i++) {
    float2 b0 = data[k0 + i];
    float2 b40 = data[40 * 80 + k0 + i];
    #pragma unroll
    for (int j = 0; j < 5; j++) {
      float s40 = ((r0 + j) & 1) ? -b40.x : b40.x;
      float res = 2.f * accR[j][i] + b0.x + s40;
      op[(r0 + j) * 80 + k0 + i] = fabsf(res) * (1.f / (float)N_);
    }
  }
}

// ---------------- combo: blocks <1024 do 6400-pt IDFT+abs; blocks >=1024 do Hermitian ifft2+abs ----------------
__global__ __launch_bounds__(256) void k_iff_combo(const float2* __restrict__ in6400, float* __restrict__ out6400,
                                                   const float2* __restrict__ inF, float* __restrict__ outF) {
  __shared__ float2 data[N_];
  __shared__ float2 tw[80];
  __shared__ float2 tws[80];
  const int tid = threadIdx.x;
  if (blockIdx.x < (unsigned)(B_ * C_)) {
    // ---- idft6400_abs body ----
    const int row = blockIdx.x;
    const float2* ip = in6400 + (size_t)row * N_;
    float* op = out6400 + (size_t)row * N_;
    if (tid < 80) {
      float a = PI2 * (float)tid * (1.f / 80.f); float sv, cv; sincosf(a, &sv, &cv); tw[tid] = make_float2(cv, sv);
      float a2 = PI2 * (float)tid * (1.f / 6400.f); sincosf(a2, &sv, &cv); tws[tid] = make_float2(cv, sv);
    }
    for (int i = tid; i < N_; i += 256) data[i] = ip[i];
    __syncthreads();
    {
      const int r0 = (tid >> 4) * 5;
      const int cg = tid & 15;
      float2 E[5][3], O[5][3];
      for (int j = 0; j < 5; j++)
        for (int i = 0; i < 3; i++) { E[j][i] = make_float2(0.f, 0.f); O[j][i] = make_float2(0.f, 0.f); }
      int idx[3], inc[3];
      #pragma unroll
      for (int i = 0; i < 3; i++) { idx[i] = 0; inc[i] = (2 * (cg + 16 * i)) % 80; }
      for (int m = 0; m < 40; ++m) {
        float2 xe[5], xo[5], t[3];
        #pragma unroll
        for (int j = 0; j < 5; j++) {
          xe[j] = data[(r0 + j) + 160 * m];
          xo[j] = data[(r0 + j) + 160 * m + 80];
        }
        #pragma unroll
        for (int i = 0; i < 3; i++) t[i] = tw[idx[i]];
        #pragma unroll
        for (int j = 0; j < 5; j++) {
          #pragma unroll
          for (int i = 0; i < 3; i++) { cfma(E[j][i], xe[j], t[i]); cfma(O[j][i], xo[j], t[i]); }
        }
        #pragma unroll
        for (int i = 0; i < 3; i++) { idx[i] += inc[i]; if (idx[i] >= 80) idx[i] -= 80; }
      }
      __syncthreads();
      #pragma unroll
      for (int j = 0; j < 5; j++) {
        const int k1 = r0 + j;
        #pragma unroll
        for (int i = 0; i < 3; i++) {
          const int n2 = cg + 16 * i;
          if (n2 < 40) {
            float2 u = cmul(tw[n2], O[j][i]);
            float2 Ap = make_float2(E[j][i].x + u.x, E[j][i].y + u.y);
            float2 Am = make_float2(E[j][i].x - u.x, E[j][i].y - u.y);
            int t6 = k1 * n2; int q = t6 / 80, s6 = t6 - q * 80;
            data[k1 * 80 + n2] = cmul(Ap, cmul(tw[q], tws[s6]));
            int t6b = k1 * (n2 + 40); int qb = t6b / 80, sb = t6b - qb * 80;
            data[k1 * 80 + n2 + 40] = cmul(Am, cmul(tw[qb], tws[sb]));
          }
        }
      }
    }
    __syncthreads();
    {
      const int rg5 = tid >> 3;
      const int cg5 = tid & 7;
      float2 E2[5][3], O2[5][3];
      for (int i = 0; i < 5; i++)
        for (int j = 0; j < 3; j++) { E2[i][j] = make_float2(0.f, 0.f); O2[i][j] = make_float2(0.f, 0.f); }
      int idx[5], inc[5];
      #pragma unroll
      for (int i = 0; i < 5; i++) { idx[i] = 0; inc[i] = (2 * (cg5 * 5 + i)) % 80; }
      int n2c[3];
      #pragma unroll
      for (int j = 0; j < 3; j++) { int n2 = rg5 + 32 * j; n2c[j] = (n2 < 80) ? n2 : 0; }
      for (int m = 0; m < 40; ++m) {
        float2 ae[3], ao[3], t[5];
        #pragma unroll
        for (int j = 0; j < 3; j++) {
          ae[j] = data[(2 * m) * 80 + n2c[j]];
          ao[j] = data[(2 * m + 1) * 80 + n2c[j]];
        }
        #pragma unroll
        for (int i = 0; i < 5; i++) t[i] = tw[idx[i]];
        #pragma unroll
        for (int i = 0; i < 5; i++) {
          #pragma unroll
          for (int j = 0; j < 3; j++) { cfma(E2[i][j], ae[j], t[i]); cfma(O2[i][j], ao[j], t[i]); }
        }
        #pragma unroll
        for (int i = 0; i < 5; i++) { idx[i] += inc[i]; if (idx[i] >= 80) idx[i] -= 80; }
      }
      #pragma unroll
      for (int i = 0; i < 5; i++) {
        const int n1 = cg5 * 5 + i;
        #pragma unroll
        for (int j = 0; j < 3; j++) {
          const int n2 = rg5 + 32 * j;
          if (n2 < 80) {
            float2 u = cmul(tw[n1], O2[i][j]);
            float2 o1 = make_float2(E2[i][j].x + u.x, E2[i][j].y + u.y);
            float2 o2 = make_float2(E2[i][j].x - u.x, E2[i][j].y - u.y);
            op[n1 * 80 + n2] = sqrtf(o1.x * o1.x + o1.y * o1.y) * (1.f / 6400.f);
            op[(n1 + 40) * 80 + n2] = sqrtf(o2.x * o2.x + o2.y * o2.y) * (1.f / 6400.f);
          }
        }
      }
    }
  } else {
    // ---- Hermitian ifft2_abs body (img = blk - 1024; out = outF + img*N_) ----
    const int img = blockIdx.x - B_ * C_;
    const float2* ip = inF + (size_t)img * N_;
    float* op = outF + (size_t)img * N_;
    if (tid < 80) { float a = PI2 * (float)tid * (1.f / 80.f); float sv, cv; sincosf(a, &sv, &cv); tw[tid] = make_float2(cv, sv); }
    for (int i = tid; i < N_; i += 256) data[i] = ip[i];
    __syncthreads();
    const int rg = tid >> 4;
    const int cg = tid & 15;
    float2 E[3][3], O[3][3];
    for (int j = 0; j < 3; j++)
      for (int i = 0; i < 3; i++) { E[j][i] = make_float2(0.f, 0.f); O[j][i] = make_float2(0.f, 0.f); }
    {
      int idx[3], inc[3];
      #pragma unroll
      for (int i = 0; i < 3; i++) { idx[i] = 0; inc[i] = (2 * (cg + 16 * i)) % 80; }
      for (int m = 0; m < 40; ++m) {
        float4 z[3]; float2 t[3];
        #pragma unroll
        for (int j = 0; j < 3; j++) z[j] = *(const float4*)&data[(rg + 16 * j) * 80 + 2 * m];
        #pragma unroll
        for (int i = 0; i < 3; i++) t[i] = tw[idx[i]];
        #pragma unroll
        for (int j = 0; j < 3; j++) {
          float2 ze = make_float2(z[j].x, z[j].y);
          float2 zo = make_float2(z[j].z, z[j].w);
          #pragma unroll
          for (int i = 0; i < 3; i++) { cfma(E[j][i], ze, t[i]); cfma(O[j][i], zo, t[i]); }
        }
        #pragma unroll
        for (int i = 0; i < 3; i++) { idx[i] += inc[i]; if (idx[i] >= 80) idx[i] -= 80; }
      }
    }
    __syncthreads();
    #pragma unroll
    for (int j = 0; j < 3; j++) {
      const int r = rg + 16 * j;
      if (r <= 40) {
        #pragma unroll
        for (int i = 0; i < 3; i++) {
          const int n2 = cg + 16 * i;
          if (n2 < 40) {
            float2 u = cmul(tw[n2], O[j][i]);
            data[r * 80 + n2]      = make_float2(E[j][i].x + u.x, E[j][i].y + u.y);
            data[r * 80 + n2 + 40] = make_float2(E[j][i].x - u.x, E[j][i].y - u.y);
          }
        }
      }
    }
    __syncthreads();
    const int r0 = (tid >> 4) * 5;
    const int k0 = (tid & 15) * 5;
    float accR[5][5];
    for (int j = 0; j < 5; j++)
      for (int i = 0; i < 5; i++) accR[j][i] = 0.f;
    {
      int idx[5];
      #pragma unroll
      for (int j = 0; j < 5; j++) idx[j] = r0 + j;
      for (int r = 1; r <= 39; ++r) {
        float2 d[5]; float2 t[5];
        #pragma unroll
        for (int i = 0; i < 5; i++) d[i] = data[r * 80 + k0 + i];
        #pragma unroll
        for (int j = 0; j < 5; j++) t[j] = tw[idx[j]];
        #pragma unroll
        for (int j = 0; j < 5; j++) {
          #pragma unroll
          for (int i = 0; i < 5; i++) {
            accR[j][i] = fmaf(t[j].x, d[i].x, accR[j][i]);
            accR[j][i] = fmaf(-t[j].y, d[i].y, accR[j][i]);
          }
        }
        #pragma unroll
        for (int j = 0; j < 5; j++) { idx[j] += r0 + j; if (idx[j] >= 80) idx[j] -= 80; }
      }
    }
    #pragma unroll
    for (int i = 0; i < 5; i++) {
      float2 b0 = data[k0 + i];
      float2 b40 = data[40 * 80 + k0 + i];
      #pragma unroll
      for (int j = 0; j < 5; j++) {
        float s40 = ((r0 + j) & 1) ? -b40.x : b40.x;
        float res = 2.f * accR[j][i] + b0.x + s40;
        op[(r0 + j) * 80 + k0 + i] = fabsf(res) * (1.f / (float)N_);
      }
    }
  }
}

// ---------------- gate stage A (4-way channel-split, 800 blocks) ----------------
__global__ __launch_bounds__(256) void k_gateA(const float2* __restrict__ zA, const float2* __restrict__ zB,
    int split, int Cin, const float* __restrict__ W1, const float* __restrict__ b1,
    const float* __restrict__ g, const float* __restrict__ bt, float* __restrict__ hid) {
  __shared__ float w[8 * 256];
  __shared__ float red[4][64][9];  // padded to 9 to avoid bank conflicts
  const int tid = threadIdx.x;
  const int grp = tid >> 6, l = tid & 63;
  for (int i = tid; i < 8 * Cin; i += 256) w[i] = W1[i];
  __syncthreads();
  const int p = blockIdx.x * 64 + l;
  const int b = p / N_, n = p % N_;
  const int cpg = Cin / 4;
  float acc[8] = {0.f, 0.f, 0.f, 0.f, 0.f, 0.f, 0.f, 0.f};
  for (int ci = grp * cpg; ci < (grp + 1) * cpg; ci++) {
    const float2* src = (ci < split) ? (zA + ((size_t)b * split + ci) * N_ + n)
                                     : (zB + ((size_t)b * (Cin - split) + (ci - split)) * N_ + n);
    float v = src->x;
    #pragma unroll
    for (int j = 0; j < 8; j++) acc[j] = fmaf(w[j * Cin + ci], v, acc[j]);
  }
  #pragma unroll
  for (int j = 0; j < 8; j++) red[grp][l][j] = acc[j];
  __syncthreads();
  if (grp == 0) {
    #pragma unroll
    for (int j = 0; j < 8; j++) {
      float t = red[0][l][j] + red[1][l][j] + red[2][l][j] + red[3][l][j];
      float y = (t + b1[j]) * (g[j] * BN_SC) + bt[j];
      hid[((size_t)b * 8 + j) * N_ + n] = fmaxf(y, 0.f);
    }
  }
}

// ---------------- gate stage B (co-split over gridDim.y, 64 co per block) ----------------
template <int MODE>
__global__ __launch_bounds__(256) void k_gateB(float2* __restrict__ zA, float2* __restrict__ zB,
    int split, int Cout, const float* __restrict__ W2, const float* __restrict__ b2,
    const float* __restrict__ hid, float* __restrict__ outR, int outCtot, int outCoff) {
  __shared__ float w[64 * 8];
  __shared__ float bb[64];
  const int tid = threadIdx.x;
  const int cobase = blockIdx.y * 64;
  for (int i = tid; i < 64 * 8; i += 256) w[i] = W2[cobase * 8 + i];
  for (int i = tid; i < 64; i += 256) bb[i] = b2[cobase + i];
  __syncthreads();
  const int p = blockIdx.x * 256 + tid;
  const int b = p / N_, n = p % N_;
  float h[8];
  #pragma unroll
  for (int j = 0; j < 8; j++) h[j] = hid[((size_t)b * 8 + j) * N_ + n];
  for (int co = 0; co < 64; co++) {
    const int gco = cobase + co;
    float t = bb[co];
    #pragma unroll
    for (int j = 0; j < 8; j++) t = fmaf(w[co * 8 + j], h[j], t);
    float sg = 1.f / (1.f + expf(-t));
    float2* zp = (gco < split) ? (zA + ((size_t)b * split + gco) * N_ + n)
                               : (zB + ((size_t)b * (Cout - split) + (gco - split)) * N_ + n);
    float2 z = *zp;
    if (MODE == 0) {
      zp->x = z.x * sg; zp->y = z.y * sg;
    } else {
      float m = sg * sqrtf(z.x * z.x + z.y * z.y);
      outR[((size_t)b * outCtot + outCoff + gco) * N_ + n] = gelu_mul(m);
    }
  }
}

// ---------------- 1x1 conv as bf16 MFMA GEMM: 128co x 64pos per block ----------------
__global__ __launch_bounds__(256) void k_conv1x1(const float* __restrict__ inA, const float* __restrict__ inB,
    int split, int Cin, int Cout, const float* __restrict__ W, const float* __restrict__ bias,
    const float* __restrict__ resid, float* __restrict__ out) {
  __shared__ unsigned int xlds[16][68];    // 4.25 KB
  const int tid = threadIdx.x;
  const int lane = tid & 63, wv = tid >> 6;
  const int p0 = blockIdx.x * 64;
  const int b = p0 / N_, n0 = p0 % N_;
  const int laneco = lane & 15, lanek = lane >> 4;
  const int kA = lanek * 8;
  f32x4 acc[2][4];
  #pragma unroll
  for (int g = 0; g < 2; g++)
    #pragma unroll
    for (int f = 0; f < 4; f++) acc[g][f] = (f32x4){0.f, 0.f, 0.f, 0.f};
  for (int cb = 0; cb < Cin; cb += 32) {
    const float* src = (cb < split) ? (inA + ((size_t)b * split + cb) * N_)
                                    : (inB + ((size_t)b * (Cin - split) + (cb - split)) * N_);
    bf16x8 af[2];
    #pragma unroll
    for (int g = 0; g < 2; g++) {
      const float* wp = W + (size_t)(wv * 32 + g * 16 + laneco) * Cin + cb + kA;
      float4 w0 = *(const float4*)wp;
      float4 w1 = *(const float4*)(wp + 4);
      af[g][0] = (short)bf16_rn(w0.x); af[g][1] = (short)bf16_rn(w0.y);
      af[g][2] = (short)bf16_rn(w0.z); af[g][3] = (short)bf16_rn(w0.w);
      af[g][4] = (short)bf16_rn(w1.x); af[g][5] = (short)bf16_rn(w1.y);
      af[g][6] = (short)bf16_rn(w1.z); af[g][7] = (short)bf16_rn(w1.w);
    }
    __syncthreads();   // previous-iter xlds reads complete
    #pragma unroll
    for (int r = 0; r < 4; r++) {
      const int kb = wv * 4 + r;
      float e = src[(size_t)(2 * kb) * N_ + n0 + lane];
      float o = src[(size_t)(2 * kb + 1) * N_ + n0 + lane];
      xlds[kb][lane] = (unsigned int)bf16_rn(e) | ((unsigned int)bf16_rn(o) << 16);
    }
    __syncthreads();
    #pragma unroll
    for (int f = 0; f < 4; f++) {
      const int pos = f * 16 + laneco;
      const int kb0 = lanek * 4;
      union { bf16x8 v; unsigned int u[4]; } bu;
      bu.u[0] = xlds[kb0 + 0][pos];
      bu.u[1] = xlds[kb0 + 1][pos];
      bu.u[2] = xlds[kb0 + 2][pos];
      bu.u[3] = xlds[kb0 + 3][pos];
      #pragma unroll
      for (int g = 0; g < 2; g++)
        acc[g][f] = __builtin_amdgcn_mfma_f32_16x16x32_bf16(af[g], bu.v, acc[g][f], 0, 0, 0);
    }
  }
  #pragma unroll
  for (int g = 0; g < 2; g++) {
    #pragma unroll
    for (int f = 0; f < 4; f++) {
      #pragma unroll
      for (int r = 0; r < 4; r++) {
        const int co = wv * 32 + g * 16 + lanek * 4 + r;
        float v = acc[g][f][r];
        if (bias) v += bias[co];
        const size_t off = ((size_t)b * Cout + co) * N_ + n0 + f * 16 + laneco;
        if (resid) v += resid[off];
        out[off] = v;
      }
    }
  }
}

// ---------------- fused q1/k1/v1 1x1 convs: blockIdx.y selects weight/output set ----------------
__global__ __launch_bounds__(256) void k_conv1x1_qkv(const float* __restrict__ in,
    const float* __restrict__ W0, const float* __restrict__ b0, float* __restrict__ o0,
    const float* __restrict__ W1, const float* __restrict__ b1, float* __restrict__ o1,
    const float* __restrict__ W2, const float* __restrict__ b2, float* __restrict__ o2) {
  __shared__ unsigned int xlds[16][68];
  const float* W    = (blockIdx.y == 0) ? W0 : (blockIdx.y == 1) ? W1 : W2;
  const float* bias = (blockIdx.y == 0) ? b0 : (blockIdx.y == 1) ? b1 : b2;
  float* out        = (blockIdx.y == 0) ? o0 : (blockIdx.y == 1) ? o1 : o2;
  const int tid = threadIdx.x;
  const int lane = tid & 63, wv = tid >> 6;
  const int p0 = blockIdx.x * 64;
  const int b = p0 / N_, n0 = p0 % N_;
  const int laneco = lane & 15, lanek = lane >> 4;
  const int kA = lanek * 8;
  f32x4 acc[2][4];
  #pragma unroll
  for (int g = 0; g < 2; g++)
    #pragma unroll
    for (int f = 0; f < 4; f++) acc[g][f] = (f32x4){0.f, 0.f, 0.f, 0.f};
  for (int cb = 0; cb < 128; cb += 32) {
    const float* src = in + ((size_t)b * 128 + cb) * N_;
    bf16x8 af[2];
    #pragma unroll
    for (int g = 0; g < 2; g++) {
      const float* wp = W + (size_t)(wv * 32 + g * 16 + laneco) * 128 + cb + kA;
      float4 w0 = *(const float4*)wp;
      float4 w1 = *(const float4*)(wp + 4);
      af[g][0] = (short)bf16_rn(w0.x); af[g][1] = (short)bf16_rn(w0.y);
      af[g][2] = (short)bf16_rn(w0.z); af[g][3] = (short)bf16_rn(w0.w);
      af[g][4] = (short)bf16_rn(w1.x); af[g][5] = (short)bf16_rn(w1.y);
      af[g][6] = (short)bf16_rn(w1.z); af[g][7] = (short)bf16_rn(w1.w);
    }
    __syncthreads();
    #pragma unroll
    for (int r = 0; r < 4; r++) {
      const int kb = wv * 4 + r;
      float e = src[(size_t)(2 * kb) * N_ + n0 + lane];
      float o = src[(size_t)(2 * kb + 1) * N_ + n0 + lane];
      xlds[kb][lane] = (unsigned int)bf16_rn(e) | ((unsigned int)bf16_rn(o) << 16);
    }
    __syncthreads();
    #pragma unroll
    for (int f = 0; f < 4; f++) {
      const int pos = f * 16 + laneco;
      const int kb0 = lanek * 4;
      union { bf16x8 v; unsigned int u[4]; } bu;
      bu.u[0] = xlds[kb0 + 0][pos];
      bu.u[1] = xlds[kb0 + 1][pos];
      bu.u[2] = xlds[kb0 + 2][pos];
      bu.u[3] = xlds[kb0 + 3][pos];
      #pragma unroll
      for (int g = 0; g < 2; g++)
        acc[g][f] = __builtin_amdgcn_mfma_f32_16x16x32_bf16(af[g], bu.v, acc[g][f], 0, 0, 0);
    }
  }
  #pragma unroll
  for (int g = 0; g < 2; g++) {
    #pragma unroll
    for (int f = 0; f < 4; f++) {
      #pragma unroll
      for (int r = 0; r < 4; r++) {
        const int co = wv * 32 + g * 16 + lanek * 4 + r;
        float v = acc[g][f][r] + bias[co];
        out[((size_t)b * 128 + co) * N_ + n0 + f * 16 + laneco] = v;
      }
    }
  }
}

// ---------------- grouped conv 3x3(pad1) + 5x5(pad2), groups=64: 4 sets via blockIdx.y ----------------
__global__ __launch_bounds__(256) void k_gconv35_4(
    const float* __restrict__ inQ, const float* __restrict__ w3Q, const float* __restrict__ w5Q, float* __restrict__ outQ,
    const float* __restrict__ inK, const float* __restrict__ w3K, const float* __restrict__ w5K, float* __restrict__ outK,
    const float* __restrict__ inV, const float* __restrict__ w3V, const float* __restrict__ w5V, float* __restrict__ outV,
    const float* __restrict__ inC2, const float* __restrict__ w3C, const float* __restrict__ w5C, float* __restrict__ outC2) {
  __shared__ float tt[2][44][84];
  const float* in; const float* w3; const float* w5; float* out;
  if (blockIdx.y == 0)      { in = inQ;  w3 = w3Q; w5 = w5Q; out = outQ; }
  else if (blockIdx.y == 1) { in = inK;  w3 = w3K; w5 = w5K; out = outK; }
  else if (blockIdx.y == 2) { in = inV;  w3 = w3V; w5 = w5V; out = outV; }
  else                      { in = inC2; w3 = w3C; w5 = w5C; out = outC2; }
  const int blk = blockIdx.x;
  const int b = blk / 128;
  const int rem = blk % 128;
  const int o = rem >> 1, half = rem & 1;
  const int y0 = half * 40;
  const float* i0 = in + ((size_t)b * C_ + 2 * o) * N_;
  const int tid = threadIdx.x;
  for (int i = tid; i < 2 * 44 * 84; i += 256) {
    int ic = i / (44 * 84);
    int r = (i % (44 * 84)) / 84;
    int cc = i % 84;
    int gy = y0 + r - 2, gx = cc - 2;
    float v = 0.f;
    if (gy >= 0 && gy < 80 && gx >= 0 && gx < 80) v = i0[(size_t)ic * N_ + gy * 80 + gx];
    tt[ic][r][cc] = v;
  }
  float w3r[2][9], w5r[2][25];
  #pragma unroll
  for (int ic = 0; ic < 2; ic++) {
    #pragma unroll
    for (int k = 0; k < 9; k++) w3r[ic][k] = w3[(o * 2 + ic) * 9 + k];
    #pragma unroll
    for (int k = 0; k < 25; k++) w5r[ic][k] = w5[(o * 2 + ic) * 25 + k];
  }
  __syncthreads();
  for (int p = tid; p < 3200; p += 256) {
    const int ly = p / 80, x = p % 80;
    float a3 = 0.f, a5 = 0.f;
    #pragma unroll
    for (int ky = 0; ky < 5; ky++) {
      #pragma unroll
      for (int kx = 0; kx < 5; kx++) {
        float v0 = tt[0][ly + ky][x + kx];
        float v1 = tt[1][ly + ky][x + kx];
        a5 = fmaf(v0, w5r[0][ky * 5 + kx], a5);
        a5 = fmaf(v1, w5r[1][ky * 5 + kx], a5);
        if (ky >= 1 && ky < 4 && kx >= 1 && kx < 4) {
          int k3 = (ky - 1) * 3 + (kx - 1);
          a3 = fmaf(v0, w3r[0][k3], a3);
          a3 = fmaf(v1, w3r[1][k3], a3);
        }
      }
    }
    const int yy = y0 + ly;
    out[((size_t)b * C_ + o) * N_ + yy * 80 + x] = a3;
    out[((size_t)b * C_ + 64 + o) * N_ + yy * 80 + x] = a5;
  }
}

// ---------------- depthwise conv3x3 (pad1) + gelu(x)*x: zero-padded halo, 40-row halves ----------------
__global__ __launch_bounds__(256) void k_dwconv3_gelu(const float* __restrict__ in, const float* __restrict__ w,
    float* __restrict__ out, int Cn, int outCtot, int outCoff) {
  __shared__ float tt[42][82];
  const int blk = blockIdx.x;
  const int b = blk / (2 * Cn);
  const int rem = blk % (2 * Cn);
  const int c = rem >> 1, half = rem & 1;
  const int y0 = half * 40;
  const float* ip = in + ((size_t)b * Cn + c) * N_;
  const int tid = threadIdx.x;
  for (int i = tid; i < 42 * 82; i += 256) {
    int r = i / 82, cc = i % 82;
    int gy = y0 + r - 1, gx = cc - 1;
    float v = 0.f;
    if (gy >= 0 && gy < 80 && gx >= 0 && gx < 80) v = ip[gy * 80 + gx];
    tt[r][cc] = v;
  }
  float wr[9];
  #pragma unroll
  for (int k = 0; k < 9; k++) wr[k] = w[c * 9 + k];
  __syncthreads();
  float* op = out + ((size_t)b * outCtot + outCoff + c) * N_;
  for (int p = tid; p < 3200; p += 256) {
    const int ly = p / 80, x = p % 80;
    float a = 0.f;
    #pragma unroll
    for (int ky = 0; ky < 3; ky++) {
      #pragma unroll
      for (int kx = 0; kx < 3; kx++)
        a = fmaf(tt[ly + ky][x + kx], wr[ky * 3 + kx], a);
    }
    op[(y0 + ly) * 80 + x] = gelu_mul(a);
  }
}

// ---------------- ff_dw2: groups=128, 2-in/2-out per group, 3x3 pad1: zero-padded halo, halves ----------------
__global__ __launch_bounds__(256) void k_ffdw2(const float* __restrict__ in, const float* __restrict__ w,
                                               float* __restrict__ out) {
  __shared__ float tt[2][42][82];
  const int blk = blockIdx.x;
  const int b = blk / 256;
  const int rem = blk % 256;
  const int g = rem >> 1, half = rem & 1;
  const int y0 = half * 40;
  const float* i0 = in + ((size_t)b * 256 + 2 * g) * N_;
  const int tid = threadIdx.x;
  for (int i = tid; i < 2 * 42 * 82; i += 256) {
    int ic = i / (42 * 82);
    int r = (i % (42 * 82)) / 82;
    int cc = i % 82;
    int gy = y0 + r - 1, gx = cc - 1;
    float v = 0.f;
    if (gy >= 0 && gy < 80 && gx >= 0 && gx < 80) v = i0[(size_t)ic * N_ + gy * 80 + gx];
    tt[ic][r][cc] = v;
  }
  float w0[2][9], w1[2][9];
  #pragma unroll
  for (int ic = 0; ic < 2; ic++) {
    #pragma unroll
    for (int k = 0; k < 9; k++) {
      w0[ic][k] = w[((2 * g) * 2 + ic) * 9 + k];
      w1[ic][k] = w[((2 * g + 1) * 2 + ic) * 9 + k];
    }
  }
  __syncthreads();
  for (int p = tid; p < 3200; p += 256) {
    const int ly = p / 80, x = p % 80;
    float a0 = 0.f, a1 = 0.f;
    #pragma unroll
    for (int ky = 0; ky < 3; ky++) {
      #pragma unroll
      for (int kx = 0; kx < 3; kx++) {
        float v0 = tt[0][ly + ky][x + kx], v1 = tt[1][ly + ky][x + kx];
        int k = ky * 3 + kx;
        a0 = fmaf(v0, w0[0][k], a0); a0 = fmaf(v1, w0[1][k], a0);
        a1 = fmaf(v0, w1[0][k], a1); a1 = fmaf(v1, w1[1][k], a1);
      }
    }
    const int yy = y0 + ly;
    out[((size_t)b * 256 + 2 * g) * N_ + yy * 80 + x] = a0;
    out[((size_t)b * 256 + 2 * g + 1) * N_ + yy * 80 + x] = a1;
  }
}

// ---------------- merged per-row L2 norms (two input sets via blockIdx routing) ----------------
__global__ __launch_bounds__(256) void k_rownorm_r2(const float* __restrict__ inA, float* __restrict__ nrmA,
                                                    const float* __restrict__ inB, float* __restrict__ nrmB) {
  __shared__ float red[256];
  int row = blockIdx.x;
  const float* p; float* o;
  if (row < B_ * C_) { p = inA + (size_t)row * N_; o = nrmA + row; }
  else { row -= B_ * C_; p = inB + (size_t)row * N_; o = nrmB + row; }
  float s = 0.f;
  for (int i = threadIdx.x; i < N_; i += 256) { float v = p[i]; s = fmaf(v, v, s); }
  red[threadIdx.x] = s; __syncthreads();
  for (int st = 128; st > 0; st >>= 1) { if (threadIdx.x < st) red[threadIdx.x] += red[threadIdx.x + st]; __syncthreads(); }
  if (threadIdx.x == 0) *o = fmaxf(sqrtf(red[0]), 1e-12f);
}

// ---------------- attention partials: coalesced wave-per-tile ----------------
__global__ __launch_bounds__(256) void k_attn_part_c(const float2* __restrict__ Ab, const float2* __restrict__ Bb,
                                                     float2* __restrict__ part) {
  const int bh = blockIdx.z;
  const int b = bh / H_, h = bh % H_;
  const int wave = threadIdx.x >> 6, lane = threadIdx.x & 63;
  const int tile = blockIdx.x * 4 + wave;      // 0..63
  const int c0 = (tile >> 3) * 4, d0 = (tile & 7) * 4;
  const size_t hb = ((size_t)b * C_ + h * 32) * N_;
  const float2* Ap = Ab + hb;
  const float2* Bp = Bb + hb;
  float2 acc[4][4];
  #pragma unroll
  for (int j = 0; j < 4; j++)
    #pragma unroll
    for (int i = 0; i < 4; i++) acc[j][i] = make_float2(0.f, 0.f);
  const int nb = blockIdx.y * (N_ / NSPL) + lane;
  for (int it = 0; it < (N_ / NSPL) / 64; ++it) {
    const int n = nb + it * 64;
    float2 av[4], bv[4];
    #pragma unroll
    for (int j = 0; j < 4; j++) av[j] = Ap[(size_t)(c0 + j) * N_ + n];
    #pragma unroll
    for (int i = 0; i < 4; i++) bv[i] = Bp[(size_t)(d0 + i) * N_ + n];
    #pragma unroll
    for (int j = 0; j < 4; j++)
      #pragma unroll
      for (int i = 0; i < 4; i++) cfma(acc[j][i], av[j], bv[i]);
  }
  float2* pp = part + (size_t)(bh * NSPL + blockIdx.y) * 1024;
  #pragma unroll
  for (int j = 0; j < 4; j++) {
    #pragma unroll
    for (int i = 0; i < 4; i++) {
      float rx = acc[j][i].x, ry = acc[j][i].y;
      for (int off = 32; off; off >>= 1) { rx += __shfl_xor(rx, off); ry += __shfl_xor(ry, off); }
      if (lane == 0) pp[(c0 + j) * 32 + d0 + i] = make_float2(rx, ry);
    }
  }
}
__global__ __launch_bounds__(256) void k_attn_part_r(const float* __restrict__ Ab, const float* __restrict__ Bb,
                                                     float* __restrict__ part) {
  const int bh = blockIdx.z;
  const int b = bh / H_, h = bh % H_;
  const int wave = threadIdx.x >> 6, lane = threadIdx.x & 63;
  const int tile = blockIdx.x * 4 + wave;
  const int c0 = (tile >> 3) * 4, d0 = (tile & 7) * 4;
  const size_t hb = ((size_t)b * C_ + h * 32) * N_;
  const float* Ap = Ab + hb;
  const float* Bp = Bb + hb;
  float acc[4][4];
  #pragma unroll
  for (int j = 0; j < 4; j++)
    #pragma unroll
    for (int i = 0; i < 4; i++) acc[j][i] = 0.f;
  const int nb = blockIdx.y * (N_ / NSPL) + lane;
  for (int it = 0; it < (N_ / NSPL) / 64; ++it) {
    const int n = nb + it * 64;
    float av[4], bv[4];
    #pragma unroll
    for (int j = 0; j < 4; j++) av[j] = Ap[(size_t)(c0 + j) * N_ + n];
    #pragma unroll
    for (int i = 0; i < 4; i++) bv[i] = Bp[(size_t)(d0 + i) * N_ + n];
    #pragma unroll
    for (int j = 0; j < 4; j++)
      #pragma unroll
      for (int i = 0; i < 4; i++) acc[j][i] = fmaf(av[j], bv[i], acc[j][i]);
  }
  float* pp = part + (size_t)(bh * NSPL + blockIdx.y) * 1024;
  #pragma unroll
  for (int j = 0; j < 4; j++) {
    #pragma unroll
    for (int i = 0; i < 4; i++) {
      float r = acc[j][i];
      for (int off = 32; off; off >>= 1) r += __shfl_xor(r, off);
      if (lane == 0) pp[(c0 + j) * 32 + d0 + i] = r;
    }
  }
}

// ---------------- reduce partials, scale, softmax ----------------
template <int CPLX>
__global__ void k_attn_soft(const float* __restrict__ part, const float* __restrict__ nA,
                            const float* __restrict__ nB, const float* __restrict__ temp,
                            float* __restrict__ attn) {
  const int rc = blockIdx.x;          // bh*32 + c
  const int bh = rc >> 5, c = rc & 31;
  const int b = bh / H_, h = bh % H_;
  const int d = threadIdx.x;          // 64 threads; group >=32 unused
  float re = -1e30f, im = -1e30f;
  if (d < 32) {
    re = 0.f; im = 0.f;
    if (CPLX) {
      const float2* pp = (const float2*)part;
      for (int kc = 0; kc < NSPL; kc++) { float2 v = pp[(size_t)(bh * NSPL + kc) * 1024 + c * 32 + d]; re += v.x; im += v.y; }
    } else {
      for (int kc = 0; kc < NSPL; kc++) re += part[(size_t)(bh * NSPL + kc) * 1024 + c * 32 + d];
    }
    float sc = temp[h] / (nA[b * C_ + h * 32 + c] * nB[b * C_ + h * 32 + d]);
    re *= sc; im *= sc;
  }
  float m = re;
  for (int o = 16; o; o >>= 1) m = fmaxf(m, __shfl_xor(m, o, 32));
  float e = expf(re - m);
  float s = e;
  for (int o = 16; o; o >>= 1) s += __shfl_xor(s, o, 32);
  float vr = e / s;
  float mi = im;
  for (int o = 16; o; o >>= 1) mi = fmaxf(mi, __shfl_xor(mi, o, 32));
  float ei = expf(im - mi);
  float si = ei;
  for (int o = 16; o; o >>= 1) si += __shfl_xor(si, o, 32);
  float vi = ei / si;
  if (d < 32) {
    if (CPLX) ((float2*)attn)[(size_t)(bh * 32 + c) * 32 + d] = make_float2(vr, vi);
    else attn[(size_t)(bh * 32 + c) * 32 + d] = vr;
  }
}

// ---------------- fused PV + 32-point IDFT along c: out[cp,n] = (1/32) sum_c pv[c,n] e^{2pi i c cp/32} ----------------
__global__ __launch_bounds__(256) void k_pv_idft32(const float2* __restrict__ attn, const float2* __restrict__ V,
                                                   float2* __restrict__ out) {
  __shared__ float2 at[32][32];
  __shared__ float2 tw[32];
  const int bh = blockIdx.x;
  const int b = bh / H_, h = bh % H_;
  const int n = blockIdx.y * 256 + threadIdx.x;
  if (threadIdx.x < 32) { float a = PI2 * (float)threadIdx.x * (1.f / 32.f); float sv, cv; sincosf(a, &sv, &cv); tw[threadIdx.x] = make_float2(cv, sv); }
  for (int i = threadIdx.x; i < 1024; i += 256) at[i >> 5][i & 31] = attn[(size_t)bh * 1024 + i];
  __syncthreads();
  const size_t hb = ((size_t)b * C_ + h * 32) * N_;
  const float2* Vp = V + hb;
  float2 acc[32];
  #pragma unroll
  for (int c = 0; c < 32; c++) acc[c] = make_float2(0.f, 0.f);
  for (int dd = 0; dd < 32; dd++) {
    float2 v = Vp[(size_t)dd * N_ + n];
    #pragma unroll
    for (int c = 0; c < 32; c++) cfma(acc[c], at[c][dd], v);
  }
  // in-register radix-2 32-point IDFT along c (same summation order as the old k_idft32)
  float2* Op = out + hb;
  for (int cp = 0; cp < 16; cp++) {
    float2 E = make_float2(0.f, 0.f), O = make_float2(0.f, 0.f);
    const int inc = (2 * cp) & 31;
    int idx = 0;
    #pragma unroll
    for (int m = 0; m < 16; m++) {
      cfma(E, acc[2 * m], tw[idx]);
      cfma(O, acc[2 * m + 1], tw[idx]);
      idx = (idx + inc) & 31;
    }
    float2 u = cmul(tw[cp], O);
    Op[(size_t)cp * N_ + n]        = make_float2((E.x + u.x) * (1.f / 32.f), (E.y + u.y) * (1.f / 32.f));
    Op[(size_t)(cp + 16) * N_ + n] = make_float2((E.x - u.x) * (1.f / 32.f), (E.y - u.y) * (1.f / 32.f));
  }
}

__global__ __launch_bounds__(256) void k_pv_r(const float* __restrict__ attn, const float* __restrict__ V,
                                              float* __restrict__ out) {
  __shared__ float at[32][32];
  const int bh = blockIdx.x;
  const int b = bh / H_, h = bh % H_;
  const int n = blockIdx.y * 256 + threadIdx.x;
  for (int i = threadIdx.x; i < 1024; i += 256) at[i >> 5][i & 31] = attn[(size_t)bh * 1024 + i];
  __syncthreads();
  const size_t hb = ((size_t)b * C_ + h * 32) * N_;
  const float* Vp = V + hb;
  float acc[32];
  #pragma unroll
  for (int c = 0; c < 32; c++) acc[c] = 0.f;
  for (int dd = 0; dd < 32; dd++) {
    float v = Vp[(size_t)dd * N_ + n];
    #pragma unroll
    for (int c = 0; c < 32; c++) acc[c] = fmaf(at[c][dd], v, acc[c]);
  }
  float* Op = out + hb;
  #pragma unroll
  for (int c = 0; c < 32; c++) Op[(size_t)c * N_ + n] = acc[c];
}

extern "C" void kernel_launch(void* const* d_in, const int* in_sizes, int n_in,
                              void* d_out, int out_size, void* d_ws, size_t ws_size,
                              hipStream_t stream) {
  (void)in_sizes; (void)n_in; (void)out_size; (void)ws_size;
  const float* x       = (const float*)d_in[0];
  const float* ln1_w   = (const float*)d_in[1];
  const float* ln2_w   = (const float*)d_in[2];
  const float* ln1_b   = (const float*)d_in[3];
  const float* ln2_b   = (const float*)d_in[4];
  const float* f_temp  = (const float*)d_in[5];
  const float* s_temp  = (const float*)d_in[6];
  const float* f_proj  = (const float*)d_in[7];
  const float* s_proj  = (const float*)d_in[8];
  const float* f_w1    = (const float*)d_in[9];
  const float* f_wb1   = (const float*)d_in[10];
  const float* f_bng   = (const float*)d_in[11];
  const float* f_bnb   = (const float*)d_in[12];
  const float* f_w2    = (const float*)d_in[13];
  const float* f_wb2   = (const float*)d_in[14];
  const float* s_q1_w  = (const float*)d_in[15];
  const float* s_q1_b  = (const float*)d_in[16];
  const float* s_k1_w  = (const float*)d_in[17];
  const float* s_k1_b  = (const float*)d_in[18];
  const float* s_v1_w  = (const float*)d_in[19];
  const float* s_v1_b  = (const float*)d_in[20];
  const float* s_q3_w  = (const float*)d_in[21];
  const float* s_k3_w  = (const float*)d_in[22];
  const float* s_v3_w  = (const float*)d_in[23];
  const float* s_c3_w  = (const float*)d_in[24];
  const float* s_q5_w  = (const float*)d_in[25];
  const float* s_k5_w  = (const float*)d_in[26];
  const float* s_v5_w  = (const float*)d_in[27];
  const float* s_c5_w  = (const float*)d_in[28];
  const float* ffdw1_w = (const float*)d_in[29];
  const float* ffdw2_w = (const float*)d_in[30];
  const float* ffproj  = (const float*)d_in[31];
  const float* ffg_w1  = (const float*)d_in[32];
  const float* ffg_b1  = (const float*)d_in[33];
  const float* ffg_bng = (const float*)d_in[34];
  const float* ffg_bnb = (const float*)d_in[35];
  const float* ffg_w2  = (const float*)d_in[36];
  const float* ffg_b2  = (const float*)d_in[37];
  const float* ffg1_w1 = (const float*)d_in[38];
  const float* ffg1_b1 = (const float*)d_in[39];
  const float* ffg1_bng= (const float*)d_in[40];
  const float* ffg1_bnb= (const float*)d_in[41];
  const float* ffg1_w2 = (const float*)d_in[42];
  const float* ffg1_b2 = (const float*)d_in[43];

  // workspace layout (floats). Requires ~267 MB of d_ws.
  float* ws = (float*)d_ws;
  const size_t R = (size_t)B_ * C_ * N_;   // 6,553,600 floats per [B,128,N] image set
  float* xn   = ws;            // R
  float* acc  = ws + R;        // R
  float* bufA = ws + 2 * R;    // 2R (complex [B,128,N] or real [B,256,N])
  float* bufB = ws + 4 * R;    // 2R
  float* bufC = ws + 6 * R;    // 2R
  float* bufD = ws + 8 * R;    // 2R
  float* sm   = ws + 10 * R;   // small pool
  float* nrmQ = sm;                    // 1024
  float* nrmK = sm + 1024;             // 1024
  float* hid  = sm + 2048;             // B*8*N = 409600
  float* part = sm + 2048 + 409600;    // 524288 (float2[131072] used for cplx)
  float* attb = part + 524288;         // 65536 (float2[32768] for cplx)

  dim3 blk(256);
  const int GCONV = P_ / 64;   // 800 blocks, 128co x 64pos MFMA tiles
  const int GLN = P_ / 64;     // 800 blocks for layernorm / gateA
  const int NIMG = B_ * C_;    // 1024
  const dim3 gattn(16, NSPL, B_ * H_);

  // ===== xn = LayerNorm(x) ; xf = fft2(xn) with fused row-norm =====
  k_layernorm<<<GLN, blk, 0, stream>>>(x, ln1_w, ln1_b, xn);
  k_fft2_r2c<<<NIMG, blk, 0, stream>>>(xn, (float2*)bufA, C_, C_, 0, nullptr, 0, NIMG, nrmQ);

  // ===== Attention_F =====
  k_attn_part_c<<<gattn, blk, 0, stream>>>((const float2*)bufA, (const float2*)bufA, (float2*)part);
  k_attn_soft<1><<<B_ * C_, 64, 0, stream>>>(part, nrmQ, nrmQ, f_temp, attb);
  // fused PV + idft32: writes bufC directly (bufB roundtrip eliminated)
  k_pv_idft32<<<dim3(B_ * H_, N_ / 256), blk, 0, stream>>>((const float2*)attb, (const float2*)bufA, (float2*)bufC);
  // gated branch first (reads bufA pre/post scale), then merged idft6400+ifft2
  k_gateA<<<GLN, blk, 0, stream>>>((const float2*)bufA, (const float2*)bufA, C_, C_, f_w1, f_wb1, f_bng, f_bnb, hid);
  k_gateB<0><<<dim3(P_ / 256, 2), blk, 0, stream>>>((float2*)bufA, (float2*)bufA, C_, C_, f_w2, f_wb2, hid, nullptr, 0, 0);
  k_iff_combo<<<2 * NIMG, blk, 0, stream>>>((const float2*)bufC, bufD, (const float2*)bufA, bufD + R);
  // a_f: acc = x + f_proj(concat(out_f, out_f_l))
  k_conv1x1<<<GCONV, blk, 0, stream>>>(bufD, bufD + R, 128, 256, 128, f_proj, nullptr, x, acc);

  // ===== Attention_S =====
  // fused q1/k1/v1 (one 2400-block dispatch; blockIdx.y routes weight/output set)
  k_conv1x1_qkv<<<dim3(GCONV, 3), blk, 0, stream>>>(xn,
      s_q1_w, s_q1_b, bufA, s_k1_w, s_k1_b, bufA + R, s_v1_w, s_v1_b, bufB);
  // fused qs/ks/vs/cs grouped convs (4 sets; cs output redirected to bufD+R -> no conflicts)
  k_gconv35_4<<<dim3(B_ * 128, 4), blk, 0, stream>>>(
      bufA,     s_q3_w, s_q5_w, bufB + R,
      bufA + R, s_k3_w, s_k5_w, bufC,
      bufB,     s_v3_w, s_v5_w, bufC + R,
      xn,       s_c3_w, s_c5_w, bufD + R);
  // merged rownorms (qs -> nrmQ, ks -> nrmK)
  k_rownorm_r2<<<2 * B_ * C_, blk, 0, stream>>>(bufB + R, nrmQ, bufC, nrmK);
  k_attn_part_r<<<gattn, blk, 0, stream>>>(bufB + R, bufC, part);
  k_attn_soft<0><<<B_ * C_, 64, 0, stream>>>(part, nrmQ, nrmK, s_temp, attb);
  k_pv_r<<<dim3(B_ * H_, N_ / 256), blk, 0, stream>>>(attb, bufC + R, bufA);      // out_s -> A.lo
  // a_s: acc += s_proj(concat(out_s, out_s_l))  (out_s_l lives in bufD+R)
  k_conv1x1<<<GCONV, blk, 0, stream>>>(bufA, bufD + R, 128, 256, 128, s_proj, nullptr, acc, acc);

  // ===== FeedForward =====
  k_layernorm<<<GLN, blk, 0, stream>>>(acc, ln2_w, ln2_b, xn);                    // xn2
  k_fft2_r2c<<<NIMG, blk, 0, stream>>>(xn, (float2*)bufA, C_, C_, 0, nullptr, 0, NIMG, nullptr);  // xf2
  k_gateA<<<GLN, blk, 0, stream>>>((const float2*)bufA, (const float2*)bufA, C_, C_, ffg_w1, ffg_b1, ffg_bng, ffg_bnb, hid);
  k_gateB<1><<<dim3(P_ / 256, 2), blk, 0, stream>>>((float2*)bufA, (float2*)bufA, C_, C_, ffg_w2, ffg_b2, hid, bufB, 256, 0); // x_f_g -> cat.lo
  k_dwconv3_gelu<<<B_ * 256, blk, 0, stream>>>(xn, ffdw1_w, bufB, 128, 256, 128); // x_s_g -> cat.hi
  // cf = fft2(cat): one merged 2048-block dispatch (lo -> bufA, hi -> bufC)
  k_fft2_r2c<<<2 * NIMG, blk, 0, stream>>>(bufB, (float2*)bufA, 128, 256, 0, (float2*)bufC, 128, NIMG, nullptr);
  k_gateA<<<GLN, blk, 0, stream>>>((const float2*)bufA, (const float2*)bufC, 128, 256, ffg1_w1, ffg1_b1, ffg1_bng, ffg1_bnb, hid);
  k_gateB<0><<<dim3(P_ / 256, 4), blk, 0, stream>>>((float2*)bufA, (float2*)bufC, 128, 256, ffg1_w2, ffg1_b2, hid, nullptr, 0, 0);
  // x_f2b: merged 2048-block ifft2 pair (bufA -> bufD coff0, bufC -> bufD coff128)
  k_ifft2_abs<<<2 * NIMG, blk, 0, stream>>>((const float2*)bufA, bufD, 128, 256, 0, (const float2*)bufC, 128, NIMG);
  k_ffdw2<<<B_ * 256, blk, 0, stream>>>(bufB, ffdw2_w, bufA);                     // x_s2b (real [B,256,N] in A)
  // out = x1 + ff_proj(concat(x_f2b, x_s2b))
  k_conv1x1<<<GCONV, blk, 0, stream>>>(bufD, bufA, 256, 512, 128, ffproj, nullptr, acc, (float*)d_out);
}

// Round 21
// 989.375 us; speedup vs baseline: 1.2391x; 1.0521x over previous
//
#include <hip/hip_runtime.h>
#include <math.h>

#define DI __device__ __forceinline__

constexpr int B_ = 8, C_ = 128, H_ = 4, S_ = 80, N_ = 6400;
constexpr int P_ = B_ * N_;                 // 51200 spatial positions
constexpr int NSPL = 2;                     // n-chunks for attention partials
constexpr float PI2 = 6.283185307179586f;
constexpr float BN_SC = 0.9999950000374997f;  // 1/sqrt(1+1e-5)

typedef __attribute__((ext_vector_type(8))) short bf16x8;
typedef __attribute__((ext_vector_type(4))) float f32x4;

DI void cfma(float2& a, float2 u, float2 v) {
  a.x = fmaf(u.x, v.x, a.x); a.x = fmaf(-u.y, v.y, a.x);
  a.y = fmaf(u.x, v.y, a.y); a.y = fmaf(u.y, v.x, a.y);
}
DI float2 cmul(float2 u, float2 v) {
  return make_float2(u.x * v.x - u.y * v.y, u.x * v.y + u.y * v.x);
}
DI float gelu_mul(float m) {  // gelu(m, exact) * m
  return 0.5f * m * (1.f + erff(m * 0.7071067811865476f)) * m;
}
DI unsigned short bf16_rn(float f) {  // round-to-nearest-even fp32 -> bf16
  union { float f; unsigned int u; } v; v.f = f;
  unsigned int u = v.u;
  return (unsigned short)((u + 0x7fffu + ((u >> 16) & 1u)) >> 16);
}

// ---------------- LayerNorm over channel dim (4-way channel-split, 800 blocks) ----------------
__global__ __launch_bounds__(256) void k_layernorm(const float* __restrict__ in,
    const float* __restrict__ w, const float* __restrict__ bb, float* __restrict__ out) {
  __shared__ float redS[4][64], redS2[4][64];
  __shared__ float muv[64], invv[64];
  const int tid = threadIdx.x;
  const int g = tid >> 6, l = tid & 63;
  const int p = blockIdx.x * 64 + l;
  const int b = p / N_, n = p % N_;
  const float* xp = in + (size_t)b * C_ * N_ + n;
  float s = 0.f, s2 = 0.f;
  for (int c = g * 32; c < g * 32 + 32; c++) {
    float v = xp[(size_t)c * N_];
    s += v; s2 = fmaf(v, v, s2);
  }
  redS[g][l] = s; redS2[g][l] = s2;
  __syncthreads();
  if (g == 0) {
    float ts  = redS[0][l] + redS[1][l] + redS[2][l] + redS[3][l];
    float ts2 = redS2[0][l] + redS2[1][l] + redS2[2][l] + redS2[3][l];
    float mu = ts * (1.f / C_);
    float var = ts2 * (1.f / C_) - mu * mu;
    muv[l] = mu; invv[l] = rsqrtf(var + 1e-5f);
  }
  __syncthreads();
  const float mu = muv[l], inv = invv[l];
  float* op = out + (size_t)b * C_ * N_ + n;
  for (int c = g * 32; c < g * 32 + 32; c++) {
    float v = xp[(size_t)c * N_];
    op[(size_t)c * N_] = (v - mu) * inv * w[c] + bb[c];
  }
}

// ============ register-tiled 80x80 2D DFT kernels (5x16 Cooley-Tukey) ============

// ---------------- 2D FFT (80x80) real->complex, 5x16 CT both passes ----------------
__global__ __launch_bounds__(256) void k_fft2_r2c(const float* __restrict__ in, float2* __restrict__ out,
                                                  int nCh, int inCtot, int inCoff,
                                                  float2* __restrict__ out2, int inCoff2, int nimg,
                                                  float* __restrict__ nrm) {
  __shared__ float2 data[N_];
  __shared__ float2 tw[80];
  int img = blockIdx.x;
  float2* op;
  int coff;
  if (img >= nimg) { img -= nimg; op = out2 + (size_t)img * N_; coff = inCoff2; }
  else { op = out + (size_t)img * N_; coff = inCoff; }
  const int b = img / nCh, ch = img % nCh;
  const float* ip = in + ((size_t)b * inCtot + coff + ch) * N_;
  const int tid = threadIdx.x;
  float* dataR = (float*)data;
  if (tid < 80) { float a = -PI2 * (float)tid * (1.f / 80.f); float sv, cv; sincosf(a, &sv, &cv); tw[tid] = make_float2(cv, sv); }
  for (int i = tid; i < N_; i += 256) dataR[i] = ip[i];
  __syncthreads();
  // ---- pass 1: rows. thread = (rg: 5 rows, kap in [0,16)) ----
  const int rg = tid >> 4;
  const int kap = tid & 15;
  const int r0 = rg * 5;
  {
    float2 F[5][5];   // [j][q]
    #pragma unroll
    for (int j = 0; j < 5; j++)
      #pragma unroll
      for (int q = 0; q < 5; q++) F[j][q] = make_float2(0.f, 0.f);
    int m16 = 0;
    for (int m = 0; m < 16; ++m) {
      float2 t = tw[5 * m16];
      #pragma unroll
      for (int j = 0; j < 5; j++) {
        const float* row = &dataR[(r0 + j) * 80 + 5 * m];
        #pragma unroll
        for (int q = 0; q < 5; q++) {
          float xv = row[q];
          F[j][q].x = fmaf(xv, t.x, F[j][q].x);
          F[j][q].y = fmaf(xv, t.y, F[j][q].y);
        }
      }
      m16 += kap; if (m16 >= 16) m16 -= 16;
    }
    __syncthreads();   // all real reads done before complex overwrite
    #pragma unroll
    for (int s = 0; s < 5; ++s) {
      const int k = kap + 16 * s;
      if (k <= 40) {
        float2 t1 = tw[k];
        float2 t2 = tw[(2 * k) % 80];
        float2 t3 = tw[(3 * k) % 80];
        float2 t4 = tw[(4 * k) % 80];
        #pragma unroll
        for (int j = 0; j < 5; j++) {
          float2 a = F[j][0];
          cfma(a, F[j][1], t1);
          cfma(a, F[j][2], t2);
          cfma(a, F[j][3], t3);
          cfma(a, F[j][4], t4);
          data[(r0 + j) * 80 + k] = a;
          if (k >= 1 && k <= 39) data[(r0 + j) * 80 + 80 - k] = make_float2(a.x, -a.y);
        }
      }
    }
  }
  __syncthreads();
  // ---- pass 2: columns. thread = (k0: 5 cols, kap2 in [0,16)) ----
  const int k0 = (tid & 15) * 5;
  const int kap2 = tid >> 4;
  float snrm = 0.f;
  {
    float2 G[5][5];   // [q][i]
    #pragma unroll
    for (int q = 0; q < 5; q++)
      #pragma unroll
      for (int i = 0; i < 5; i++) G[q][i] = make_float2(0.f, 0.f);
    int m16 = 0;
    for (int m = 0; m < 16; ++m) {
      float2 t = tw[5 * m16];
      #pragma unroll
      for (int q = 0; q < 5; q++) {
        const float2* rowp = &data[(5 * m + q) * 80 + k0];
        #pragma unroll
        for (int i = 0; i < 5; i++) cfma(G[q][i], rowp[i], t);
      }
      m16 += kap2; if (m16 >= 16) m16 -= 16;
    }
    #pragma unroll
    for (int s = 0; s < 5; ++s) {
      const int k1 = kap2 + 16 * s;
      if (k1 <= 40) {
        float2 t1 = tw[k1];
        float2 t2 = tw[(2 * k1) % 80];
        float2 t3 = tw[(3 * k1) % 80];
        float2 t4 = tw[(4 * k1) % 80];
        const float wgt = (k1 == 0 || k1 == 40) ? 1.f : 2.f;
        #pragma unroll
        for (int i = 0; i < 5; i++) {
          float2 y = G[0][i];
          cfma(y, G[1][i], t1);
          cfma(y, G[2][i], t2);
          cfma(y, G[3][i], t3);
          cfma(y, G[4][i], t4);
          const int k2 = k0 + i;
          op[k1 * 80 + k2] = y;
          if (k1 >= 1 && k1 <= 39) {
            const int m2 = (k2 == 0) ? 0 : 80 - k2;
            op[(80 - k1) * 80 + m2] = make_float2(y.x, -y.y);
          }
          snrm += wgt * (y.x * y.x + y.y * y.y);
        }
      }
    }
  }
  if (nrm) {   // fused per-image L2 norm (mirrored halves contribute 2x)
    __syncthreads();
    float* red = (float*)data;
    red[tid] = snrm;
    __syncthreads();
    for (int st = 128; st > 0; st >>= 1) { if (tid < st) red[tid] += red[tid + st]; __syncthreads(); }
    if (tid == 0) nrm[img] = fmaxf(sqrtf(red[0]), 1e-12f);
  }
}

// ---------------- 2D IFFT (80x80) of HERMITIAN input -> |real|; pass1 = 5x16 CT ----------------
__global__ __launch_bounds__(256) void k_ifft2_abs(const float2* __restrict__ in, float* __restrict__ out,
                                                   int inC, int outCtot, int outCoff,
                                                   const float2* __restrict__ in2, int outCoff2, int nimg) {
  __shared__ float2 data[N_];
  __shared__ float2 tw[80];
  int img = blockIdx.x;
  const float2* ip;
  int coff;
  if (img >= nimg) { img -= nimg; ip = in2 + (size_t)img * N_; coff = outCoff2; }
  else { ip = in + (size_t)img * N_; coff = outCoff; }
  const int b = img / inC, ch = img % inC;
  float* op = out + ((size_t)b * outCtot + coff + ch) * N_;
  const int tid = threadIdx.x;
  if (tid < 80) { float a = PI2 * (float)tid * (1.f / 80.f); float sv, cv; sincosf(a, &sv, &cv); tw[tid] = make_float2(cv, sv); }
  for (int i = tid; i < N_; i += 256) data[i] = ip[i];
  __syncthreads();
  // ---- pass 1 (CT): full-row IDFT for rows r = g1+16j (r<=40) ----
  {
    const int g1 = tid >> 4;
    const int kap = tid & 15;
    float2 F[3][5];
    #pragma unroll
    for (int j = 0; j < 3; j++)
      #pragma unroll
      for (int q = 0; q < 5; q++) F[j][q] = make_float2(0.f, 0.f);
    int m16 = 0;
    for (int m = 0; m < 16; ++m) {
      float2 t = tw[5 * m16];
      #pragma unroll
      for (int j = 0; j < 3; j++) {
        const float2* rowp = &data[(g1 + 16 * j) * 80 + 5 * m];
        #pragma unroll
        for (int q = 0; q < 5; q++) cfma(F[j][q], rowp[q], t);
      }
      m16 += kap; if (m16 >= 16) m16 -= 16;
    }
    __syncthreads();   // reads complete before overwrite
    #pragma unroll
    for (int s = 0; s < 5; ++s) {
      const int n2 = kap + 16 * s;
      float2 t1 = tw[n2];
      float2 t2 = tw[(2 * n2) % 80];
      float2 t3 = tw[(3 * n2) % 80];
      float2 t4 = tw[(4 * n2) % 80];
      #pragma unroll
      for (int j = 0; j < 3; j++) {
        const int r = g1 + 16 * j;
        if (r <= 40) {
          float2 a = F[j][0];
          cfma(a, F[j][1], t1);
          cfma(a, F[j][2], t2);
          cfma(a, F[j][3], t3);
          cfma(a, F[j][4], t4);
          data[r * 80 + n2] = a;
        }
      }
    }
  }
  __syncthreads();
  // ---- pass 2 (real output, Hermitian-in-row) ----
  const int r0 = (tid >> 4) * 5;
  const int k0 = (tid & 15) * 5;
  float accR[5][5];
  for (int j = 0; j < 5; j++)
    for (int i = 0; i < 5; i++) accR[j][i] = 0.f;
  {
    int idx[5];
    #pragma unroll
    for (int j = 0; j < 5; j++) idx[j] = r0 + j;
    for (int r = 1; r <= 39; ++r) {
      float2 d[5]; float2 t[5];
      #pragma unroll
      for (int i = 0; i < 5; i++) d[i] = data[r * 80 + k0 + i];
      #pragma unroll
      for (int j = 0; j < 5; j++) t[j] = tw[idx[j]];
      #pragma unroll
      for (int j = 0; j < 5; j++) {
        #pragma unroll
        for (int i = 0; i < 5; i++) {
          accR[j][i] = fmaf(t[j].x, d[i].x, accR[j][i]);
          accR[j][i] = fmaf(-t[j].y, d[i].y, accR[j][i]);
        }
      }
      #pragma unroll
      for (int j = 0; j < 5; j++) { idx[j] += r0 + j; if (idx[j] >= 80) idx[j] -= 80; }
    }
  }
  #pragma unroll
  for (int i = 0; i < 5; i++) {
    float2 b0 = data[k0 + i];
    float2 b40 = data[40 * 80 + k0 + i];
    #pragma unroll
    for (int j = 0; j < 5; j++) {
      float s40 = ((r0 + j) & 1) ? -b40.x : b40.x;
      float res = 2.f * accR[j][i] + b0.x + s40;
      op[(r0 + j) * 80 + k0 + i] = fabsf(res) * (1.f / (float)N_);
    }
  }
}

// ---------------- combo: blocks <1024 do 6400-pt IDFT+abs (5x16 CT); blocks >=1024 do Hermitian ifft2+abs ----------------
__global__ __launch_bounds__(256) void k_iff_combo(const float2* __restrict__ in6400, float* __restrict__ out6400,
                                                   const float2* __restrict__ inF, float* __restrict__ outF) {
  __shared__ float2 data[N_];
  __shared__ float2 tw[80];
  __shared__ float2 tws[80];
  const int tid = threadIdx.x;
  if (blockIdx.x < (unsigned)(B_ * C_)) {
    // ---- idft6400_abs body: X[c2][c1] -> A (80pt IDFT over c2) -> *tw6400 -> 80pt IDFT over k1 -> abs ----
    const int row = blockIdx.x;
    const float2* ip = in6400 + (size_t)row * N_;
    float* op = out6400 + (size_t)row * N_;
    if (tid < 80) {
      float a = PI2 * (float)tid * (1.f / 80.f); float sv, cv; sincosf(a, &sv, &cv); tw[tid] = make_float2(cv, sv);
      float a2 = PI2 * (float)tid * (1.f / 6400.f); sincosf(a2, &sv, &cv); tws[tid] = make_float2(cv, sv);
    }
    for (int i = tid; i < N_; i += 256) data[i] = ip[i];
    __syncthreads();
    const int g = tid >> 4;
    const int kap = tid & 15;
    const int r0 = g * 5;
    // ---- pass A (CT): A[c1][n2] = sum_c2 X[c2][c1] tw[c2 n2]; then * e^{2pi i c1 n2/6400} ----
    {
      float2 F[5][5];   // [j: c1=r0+j][q]
      #pragma unroll
      for (int j = 0; j < 5; j++)
        #pragma unroll
        for (int q = 0; q < 5; q++) F[j][q] = make_float2(0.f, 0.f);
      int m16 = 0;
      for (int m = 0; m < 16; ++m) {
        float2 t = tw[5 * m16];
        #pragma unroll
        for (int q = 0; q < 5; q++) {
          const float2* col = &data[(5 * m + q) * 80 + r0];
          #pragma unroll
          for (int j = 0; j < 5; j++) cfma(F[j][q], col[j], t);
        }
        m16 += kap; if (m16 >= 16) m16 -= 16;
      }
      __syncthreads();   // reads complete before overwrite
      #pragma unroll
      for (int s = 0; s < 5; ++s) {
        const int n2 = kap + 16 * s;
        float2 t1 = tw[n2];
        float2 t2 = tw[(2 * n2) % 80];
        float2 t3 = tw[(3 * n2) % 80];
        float2 t4 = tw[(4 * n2) % 80];
        #pragma unroll
        for (int j = 0; j < 5; j++) {
          const int k1 = r0 + j;
          float2 a = F[j][0];
          cfma(a, F[j][1], t1);
          cfma(a, F[j][2], t2);
          cfma(a, F[j][3], t3);
          cfma(a, F[j][4], t4);
          int t6 = k1 * n2; int q6 = t6 / 80, s6 = t6 - q6 * 80;
          data[k1 * 80 + n2] = cmul(a, cmul(tw[q6], tws[s6]));
        }
      }
    }
    __syncthreads();
    // ---- pass B (CT): out[n1][n2] = |sum_k1 Y[k1][n2] tw[k1 n1]| / 6400 ----
    {
      float2 G[5][5];   // [q][i]
      #pragma unroll
      for (int q = 0; q < 5; q++)
        #pragma unroll
        for (int i = 0; i < 5; i++) G[q][i] = make_float2(0.f, 0.f);
      int m16 = 0;
      for (int m = 0; m < 16; ++m) {
        float2 t = tw[5 * m16];
        #pragma unroll
        for (int q = 0; q < 5; q++) {
          const float2* rowp = &data[(5 * m + q) * 80 + r0];
          #pragma unroll
          for (int i = 0; i < 5; i++) cfma(G[q][i], rowp[i], t);
        }
        m16 += kap; if (m16 >= 16) m16 -= 16;
      }
      #pragma unroll
      for (int s = 0; s < 5; ++s) {
        const int n1 = kap + 16 * s;
        float2 t1 = tw[n1];
        float2 t2 = tw[(2 * n1) % 80];
        float2 t3 = tw[(3 * n1) % 80];
        float2 t4 = tw[(4 * n1) % 80];
        #pragma unroll
        for (int i = 0; i < 5; i++) {
          float2 y = G[0][i];
          cfma(y, G[1][i], t1);
          cfma(y, G[2][i], t2);
          cfma(y, G[3][i], t3);
          cfma(y, G[4][i], t4);
          op[n1 * 80 + r0 + i] = sqrtf(y.x * y.x + y.y * y.y) * (1.f / 6400.f);
        }
      }
    }
  } else {
    // ---- Hermitian ifft2_abs body (pass1 = 5x16 CT) ----
    const int img = blockIdx.x - B_ * C_;
    const float2* ip = inF + (size_t)img * N_;
    float* op = outF + (size_t)img * N_;
    if (tid < 80) { float a = PI2 * (float)tid * (1.f / 80.f); float sv, cv; sincosf(a, &sv, &cv); tw[tid] = make_float2(cv, sv); }
    for (int i = tid; i < N_; i += 256) data[i] = ip[i];
    __syncthreads();
    {
      const int g1 = tid >> 4;
      const int kap = tid & 15;
      float2 F[3][5];
      #pragma unroll
      for (int j = 0; j < 3; j++)
        #pragma unroll
        for (int q = 0; q < 5; q++) F[j][q] = make_float2(0.f, 0.f);
      int m16 = 0;
      for (int m = 0; m < 16; ++m) {
        float2 t = tw[5 * m16];
        #pragma unroll
        for (int j = 0; j < 3; j++) {
          const float2* rowp = &data[(g1 + 16 * j) * 80 + 5 * m];
          #pragma unroll
          for (int q = 0; q < 5; q++) cfma(F[j][q], rowp[q], t);
        }
        m16 += kap; if (m16 >= 16) m16 -= 16;
      }
      __syncthreads();
      #pragma unroll
      for (int s = 0; s < 5; ++s) {
        const int n2 = kap + 16 * s;
        float2 t1 = tw[n2];
        float2 t2 = tw[(2 * n2) % 80];
        float2 t3 = tw[(3 * n2) % 80];
        float2 t4 = tw[(4 * n2) % 80];
        #pragma unroll
        for (int j = 0; j < 3; j++) {
          const int r = g1 + 16 * j;
          if (r <= 40) {
            float2 a = F[j][0];
            cfma(a, F[j][1], t1);
            cfma(a, F[j][2], t2);
            cfma(a, F[j][3], t3);
            cfma(a, F[j][4], t4);
            data[r * 80 + n2] = a;
          }
        }
      }
    }
    __syncthreads();
    const int r0 = (tid >> 4) * 5;
    const int k0 = (tid & 15) * 5;
    float accR[5][5];
    for (int j = 0; j < 5; j++)
      for (int i = 0; i < 5; i++) accR[j][i] = 0.f;
    {
      int idx[5];
      #pragma unroll
      for (int j = 0; j < 5; j++) idx[j] = r0 + j;
      for (int r = 1; r <= 39; ++r) {
        float2 d[5]; float2 t[5];
        #pragma unroll
        for (int i = 0; i < 5; i++) d[i] = data[r * 80 + k0 + i];
        #pragma unroll
        for (int j = 0; j < 5; j++) t[j] = tw[idx[j]];
        #pragma unroll
        for (int j = 0; j < 5; j++) {
          #pragma unroll
          for (int i = 0; i < 5; i++) {
            accR[j][i] = fmaf(t[j].x, d[i].x, accR[j][i]);
            accR[j][i] = fmaf(-t[j].y, d[i].y, accR[j][i]);
          }
        }
        #pragma unroll
        for (int j = 0; j < 5; j++) { idx[j] += r0 + j; if (idx[j] >= 80) idx[j] -= 80; }
      }
    }
    #pragma unroll
    for (int i = 0; i < 5; i++) {
      float2 b0 = data[k0 + i];
      float2 b40 = data[40 * 80 + k0 + i];
      #pragma unroll
      for (int j = 0; j < 5; j++) {
        float s40 = ((r0 + j) & 1) ? -b40.x : b40.x;
        float res = 2.f * accR[j][i] + b0.x + s40;
        op[(r0 + j) * 80 + k0 + i] = fabsf(res) * (1.f / (float)N_);
      }
    }
  }
}

// ---------------- gate stage A (4-way channel-split, 800 blocks) ----------------
__global__ __launch_bounds__(256) void k_gateA(const float2* __restrict__ zA, const float2* __restrict__ zB,
    int split, int Cin, const float* __restrict__ W1, const float* __restrict__ b1,
    const float* __restrict__ g, const float* __restrict__ bt, float* __restrict__ hid) {
  __shared__ float w[8 * 256];
  __shared__ float red[4][64][9];  // padded to 9 to avoid bank conflicts
  const int tid = threadIdx.x;
  const int grp = tid >> 6, l = tid & 63;
  for (int i = tid; i < 8 * Cin; i += 256) w[i] = W1[i];
  __syncthreads();
  const int p = blockIdx.x * 64 + l;
  const int b = p / N_, n = p % N_;
  const int cpg = Cin / 4;
  float acc[8] = {0.f, 0.f, 0.f, 0.f, 0.f, 0.f, 0.f, 0.f};
  for (int ci = grp * cpg; ci < (grp + 1) * cpg; ci++) {
    const float2* src = (ci < split) ? (zA + ((size_t)b * split + ci) * N_ + n)
                                     : (zB + ((size_t)b * (Cin - split) + (ci - split)) * N_ + n);
    float v = src->x;
    #pragma unroll
    for (int j = 0; j < 8; j++) acc[j] = fmaf(w[j * Cin + ci], v, acc[j]);
  }
  #pragma unroll
  for (int j = 0; j < 8; j++) red[grp][l][j] = acc[j];
  __syncthreads();
  if (grp == 0) {
    #pragma unroll
    for (int j = 0; j < 8; j++) {
      float t = red[0][l][j] + red[1][l][j] + red[2][l][j] + red[3][l][j];
      float y = (t + b1[j]) * (g[j] * BN_SC) + bt[j];
      hid[((size_t)b * 8 + j) * N_ + n] = fmaxf(y, 0.f);
    }
  }
}

// ---------------- gate stage B (co-split over gridDim.y, 64 co per block) ----------------
template <int MODE>
__global__ __launch_bounds__(256) void k_gateB(float2* __restrict__ zA, float2* __restrict__ zB,
    int split, int Cout, const float* __restrict__ W2, const float* __restrict__ b2,
    const float* __restrict__ hid, float* __restrict__ outR, int outCtot, int outCoff) {
  __shared__ float w[64 * 8];
  __shared__ float bb[64];
  const int tid = threadIdx.x;
  const int cobase = blockIdx.y * 64;
  for (int i = tid; i < 64 * 8; i += 256) w[i] = W2[cobase * 8 + i];
  for (int i = tid; i < 64; i += 256) bb[i] = b2[cobase + i];
  __syncthreads();
  const int p = blockIdx.x * 256 + tid;
  const int b = p / N_, n = p % N_;
  float h[8];
  #pragma unroll
  for (int j = 0; j < 8; j++) h[j] = hid[((size_t)b * 8 + j) * N_ + n];
  for (int co = 0; co < 64; co++) {
    const int gco = cobase + co;
    float t = bb[co];
    #pragma unroll
    for (int j = 0; j < 8; j++) t = fmaf(w[co * 8 + j], h[j], t);
    float sg = 1.f / (1.f + expf(-t));
    float2* zp = (gco < split) ? (zA + ((size_t)b * split + gco) * N_ + n)
                               : (zB + ((size_t)b * (Cout - split) + (gco - split)) * N_ + n);
    float2 z = *zp;
    if (MODE == 0) {
      zp->x = z.x * sg; zp->y = z.y * sg;
    } else {
      float m = sg * sqrtf(z.x * z.x + z.y * z.y);
      outR[((size_t)b * outCtot + outCoff + gco) * N_ + n] = gelu_mul(m);
    }
  }
}

// ---------------- 1x1 conv as bf16 MFMA GEMM: 128co x 64pos per block ----------------
__global__ __launch_bounds__(256) void k_conv1x1(const float* __restrict__ inA, const float* __restrict__ inB,
    int split, int Cin, int Cout, const float* __restrict__ W, const float* __restrict__ bias,
    const float* __restrict__ resid, float* __restrict__ out) {
  __shared__ unsigned int xlds[16][68];    // 4.25 KB
  const int tid = threadIdx.x;
  const int lane = tid & 63, wv = tid >> 6;
  const int p0 = blockIdx.x * 64;
  const int b = p0 / N_, n0 = p0 % N_;
  const int laneco = lane & 15, lanek = lane >> 4;
  const int kA = lanek * 8;
  f32x4 acc[2][4];
  #pragma unroll
  for (int g = 0; g < 2; g++)
    #pragma unroll
    for (int f = 0; f < 4; f++) acc[g][f] = (f32x4){0.f, 0.f, 0.f, 0.f};
  for (int cb = 0; cb < Cin; cb += 32) {
    const float* src = (cb < split) ? (inA + ((size_t)b * split + cb) * N_)
                                    : (inB + ((size_t)b * (Cin - split) + (cb - split)) * N_);
    bf16x8 af[2];
    #pragma unroll
    for (int g = 0; g < 2; g++) {
      const float* wp = W + (size_t)(wv * 32 + g * 16 + laneco) * Cin + cb + kA;
      float4 w0 = *(const float4*)wp;
      float4 w1 = *(const float4*)(wp + 4);
      af[g][0] = (short)bf16_rn(w0.x); af[g][1] = (short)bf16_rn(w0.y);
      af[g][2] = (short)bf16_rn(w0.z); af[g][3] = (short)bf16_rn(w0.w);
      af[g][4] = (short)bf16_rn(w1.x); af[g][5] = (short)bf16_rn(w1.y);
      af[g][6] = (short)bf16_rn(w1.z); af[g][7] = (short)bf16_rn(w1.w);
    }
    __syncthreads();   // previous-iter xlds reads complete
    #pragma unroll
    for (int r = 0; r < 4; r++) {
      const int kb = wv * 4 + r;
      float e = src[(size_t)(2 * kb) * N_ + n0 + lane];
      float o = src[(size_t)(2 * kb + 1) * N_ + n0 + lane];
      xlds[kb][lane] = (unsigned int)bf16_rn(e) | ((unsigned int)bf16_rn(o) << 16);
    }
    __syncthreads();
    #pragma unroll
    for (int f = 0; f < 4; f++) {
      const int pos = f * 16 + laneco;
      const int kb0 = lanek * 4;
      union { bf16x8 v; unsigned int u[4]; } bu;
      bu.u[0] = xlds[kb0 + 0][pos];
      bu.u[1] = xlds[kb0 + 1][pos];
      bu.u[2] = xlds[kb0 + 2][pos];
      bu.u[3] = xlds[kb0 + 3][pos];
      #pragma unroll
      for (int g = 0; g < 2; g++)
        acc[g][f] = __builtin_amdgcn_mfma_f32_16x16x32_bf16(af[g], bu.v, acc[g][f], 0, 0, 0);
    }
  }
  #pragma unroll
  for (int g = 0; g < 2; g++) {
    #pragma unroll
    for (int f = 0; f < 4; f++) {
      #pragma unroll
      for (int r = 0; r < 4; r++) {
        const int co = wv * 32 + g * 16 + lanek * 4 + r;
        float v = acc[g][f][r];
        if (bias) v += bias[co];
        const size_t off = ((size_t)b * Cout + co) * N_ + n0 + f * 16 + laneco;
        if (resid) v += resid[off];
        out[off] = v;
      }
    }
  }
}

// ---------------- fused q1/k1/v1 1x1 convs: blockIdx.y selects weight/output set ----------------
__global__ __launch_bounds__(256) void k_conv1x1_qkv(const float* __restrict__ in,
    const float* __restrict__ W0, const float* __restrict__ b0, float* __restrict__ o0,
    const float* __restrict__ W1, const float* __restrict__ b1, float* __restrict__ o1,
    const float* __restrict__ W2, const float* __restrict__ b2, float* __restrict__ o2) {
  __shared__ unsigned int xlds[16][68];
  const float* W    = (blockIdx.y == 0) ? W0 : (blockIdx.y == 1) ? W1 : W2;
  const float* bias = (blockIdx.y == 0) ? b0 : (blockIdx.y == 1) ? b1 : b2;
  float* out        = (blockIdx.y == 0) ? o0 : (blockIdx.y == 1) ? o1 : o2;
  const int tid = threadIdx.x;
  const int lane = tid & 63, wv = tid >> 6;
  const int p0 = blockIdx.x * 64;
  const int b = p0 / N_, n0 = p0 % N_;
  const int laneco = lane & 15, lanek = lane >> 4;
  const int kA = lanek * 8;
  f32x4 acc[2][4];
  #pragma unroll
  for (int g = 0; g < 2; g++)
    #pragma unroll
    for (int f = 0; f < 4; f++) acc[g][f] = (f32x4){0.f, 0.f, 0.f, 0.f};
  for (int cb = 0; cb < 128; cb += 32) {
    const float* src = in + ((size_t)b * 128 + cb) * N_;
    bf16x8 af[2];
    #pragma unroll
    for (int g = 0; g < 2; g++) {
      const float* wp = W + (size_t)(wv * 32 + g * 16 + laneco) * 128 + cb + kA;
      float4 w0 = *(const float4*)wp;
      float4 w1 = *(const float4*)(wp + 4);
      af[g][0] = (short)bf16_rn(w0.x); af[g][1] = (short)bf16_rn(w0.y);
      af[g][2] = (short)bf16_rn(w0.z); af[g][3] = (short)bf16_rn(w0.w);
      af[g][4] = (short)bf16_rn(w1.x); af[g][5] = (short)bf16_rn(w1.y);
      af[g][6] = (short)bf16_rn(w1.z); af[g][7] = (short)bf16_rn(w1.w);
    }
    __syncthreads();
    #pragma unroll
    for (int r = 0; r < 4; r++) {
      const int kb = wv * 4 + r;
      float e = src[(size_t)(2 * kb) * N_ + n0 + lane];
      float o = src[(size_t)(2 * kb + 1) * N_ + n0 + lane];
      xlds[kb][lane] = (unsigned int)bf16_rn(e) | ((unsigned int)bf16_rn(o) << 16);
    }
    __syncthreads();
    #pragma unroll
    for (int f = 0; f < 4; f++) {
      const int pos = f * 16 + laneco;
      const int kb0 = lanek * 4;
      union { bf16x8 v; unsigned int u[4]; } bu;
      bu.u[0] = xlds[kb0 + 0][pos];
      bu.u[1] = xlds[kb0 + 1][pos];
      bu.u[2] = xlds[kb0 + 2][pos];
      bu.u[3] = xlds[kb0 + 3][pos];
      #pragma unroll
      for (int g = 0; g < 2; g++)
        acc[g][f] = __builtin_amdgcn_mfma_f32_16x16x32_bf16(af[g], bu.v, acc[g][f], 0, 0, 0);
    }
  }
  #pragma unroll
  for (int g = 0; g < 2; g++) {
    #pragma unroll
    for (int f = 0; f < 4; f++) {
      #pragma unroll
      for (int r = 0; r < 4; r++) {
        const int co = wv * 32 + g * 16 + lanek * 4 + r;
        float v = acc[g][f][r] + bias[co];
        out[((size_t)b * 128 + co) * N_ + n0 + f * 16 + laneco] = v;
      }
    }
  }
}

// ---------------- grouped conv 3x3(pad1) + 5x5(pad2), groups=64: 4 sets via blockIdx.y ----------------
__global__ __launch_bounds__(256) void k_gconv35_4(
    const float* __restrict__ inQ, const float* __restrict__ w3Q, const float* __restrict__ w5Q, float* __restrict__ outQ,
    const float* __restrict__ inK, const float* __restrict__ w3K, const float* __restrict__ w5K, float* __restrict__ outK,
    const float* __restrict__ inV, const float* __restrict__ w3V, const float* __restrict__ w5V, float* __restrict__ outV,
    const float* __restrict__ inC2, const float* __restrict__ w3C, const float* __restrict__ w5C, float* __restrict__ outC2) {
  __shared__ float tt[2][44][84];
  const float* in; const float* w3; const float* w5; float* out;
  if (blockIdx.y == 0)      { in = inQ;  w3 = w3Q; w5 = w5Q; out = outQ; }
  else if (blockIdx.y == 1) { in = inK;  w3 = w3K; w5 = w5K; out = outK; }
  else if (blockIdx.y == 2) { in = inV;  w3 = w3V; w5 = w5V; out = outV; }
  else                      { in = inC2; w3 = w3C; w5 = w5C; out = outC2; }
  const int blk = blockIdx.x;
  const int b = blk / 128;
  const int rem = blk % 128;
  const int o = rem >> 1, half = rem & 1;
  const int y0 = half * 40;
  const float* i0 = in + ((size_t)b * C_ + 2 * o) * N_;
  const int tid = threadIdx.x;
  for (int i = tid; i < 2 * 44 * 84; i += 256) {
    int ic = i / (44 * 84);
    int r = (i % (44 * 84)) / 84;
    int cc = i % 84;
    int gy = y0 + r - 2, gx = cc - 2;
    float v = 0.f;
    if (gy >= 0 && gy < 80 && gx >= 0 && gx < 80) v = i0[(size_t)ic * N_ + gy * 80 + gx];
    tt[ic][r][cc] = v;
  }
  float w3r[2][9], w5r[2][25];
  #pragma unroll
  for (int ic = 0; ic < 2; ic++) {
    #pragma unroll
    for (int k = 0; k < 9; k++) w3r[ic][k] = w3[(o * 2 + ic) * 9 + k];
    #pragma unroll
    for (int k = 0; k < 25; k++) w5r[ic][k] = w5[(o * 2 + ic) * 25 + k];
  }
  __syncthreads();
  for (int p = tid; p < 3200; p += 256) {
    const int ly = p / 80, x = p % 80;
    float a3 = 0.f, a5 = 0.f;
    #pragma unroll
    for (int ky = 0; ky < 5; ky++) {
      #pragma unroll
      for (int kx = 0; kx < 5; kx++) {
        float v0 = tt[0][ly + ky][x + kx];
        float v1 = tt[1][ly + ky][x + kx];
        a5 = fmaf(v0, w5r[0][ky * 5 + kx], a5);
        a5 = fmaf(v1, w5r[1][ky * 5 + kx], a5);
        if (ky >= 1 && ky < 4 && kx >= 1 && kx < 4) {
          int k3 = (ky - 1) * 3 + (kx - 1);
          a3 = fmaf(v0, w3r[0][k3], a3);
          a3 = fmaf(v1, w3r[1][k3], a3);
        }
      }
    }
    const int yy = y0 + ly;
    out[((size_t)b * C_ + o) * N_ + yy * 80 + x] = a3;
    out[((size_t)b * C_ + 64 + o) * N_ + yy * 80 + x] = a5;
  }
}

// ---------------- depthwise conv3x3 (pad1) + gelu(x)*x: zero-padded halo, 40-row halves ----------------
__global__ __launch_bounds__(256) void k_dwconv3_gelu(const float* __restrict__ in, const float* __restrict__ w,
    float* __restrict__ out, int Cn, int outCtot, int outCoff) {
  __shared__ float tt[42][82];
  const int blk = blockIdx.x;
  const int b = blk / (2 * Cn);
  const int rem = blk % (2 * Cn);
  const int c = rem >> 1, half = rem & 1;
  const int y0 = half * 40;
  const float* ip = in + ((size_t)b * Cn + c) * N_;
  const int tid = threadIdx.x;
  for (int i = tid; i < 42 * 82; i += 256) {
    int r = i / 82, cc = i % 82;
    int gy = y0 + r - 1, gx = cc - 1;
    float v = 0.f;
    if (gy >= 0 && gy < 80 && gx >= 0 && gx < 80) v = ip[gy * 80 + gx];
    tt[r][cc] = v;
  }
  float wr[9];
  #pragma unroll
  for (int k = 0; k < 9; k++) wr[k] = w[c * 9 + k];
  __syncthreads();
  float* op = out + ((size_t)b * outCtot + outCoff + c) * N_;
  for (int p = tid; p < 3200; p += 256) {
    const int ly = p / 80, x = p % 80;
    float a = 0.f;
    #pragma unroll
    for (int ky = 0; ky < 3; ky++) {
      #pragma unroll
      for (int kx = 0; kx < 3; kx++)
        a = fmaf(tt[ly + ky][x + kx], wr[ky * 3 + kx], a);
    }
    op[(y0 + ly) * 80 + x] = gelu_mul(a);
  }
}

// ---------------- ff_dw2: groups=128, 2-in/2-out per group, 3x3 pad1: zero-padded halo, halves ----------------
__global__ __launch_bounds__(256) void k_ffdw2(const float* __restrict__ in, const float* __restrict__ w,
                                               float* __restrict__ out) {
  __shared__ float tt[2][42][82];
  const int blk = blockIdx.x;
  const int b = blk / 256;
  const int rem = blk % 256;
  const int g = rem >> 1, half = rem & 1;
  const int y0 = half * 40;
  const float* i0 = in + ((size_t)b * 256 + 2 * g) * N_;
  const int tid = threadIdx.x;
  for (int i = tid; i < 2 * 42 * 82; i += 256) {
    int ic = i / (42 * 82);
    int r = (i % (42 * 82)) / 82;
    int cc = i % 82;
    int gy = y0 + r - 1, gx = cc - 1;
    float v = 0.f;
    if (gy >= 0 && gy < 80 && gx >= 0 && gx < 80) v = i0[(size_t)ic * N_ + gy * 80 + gx];
    tt[ic][r][cc] = v;
  }
  float w0[2][9], w1[2][9];
  #pragma unroll
  for (int ic = 0; ic < 2; ic++) {
    #pragma unroll
    for (int k = 0; k < 9; k++) {
      w0[ic][k] = w[((2 * g) * 2 + ic) * 9 + k];
      w1[ic][k] = w[((2 * g + 1) * 2 + ic) * 9 + k];
    }
  }
  __syncthreads();
  for (int p = tid; p < 3200; p += 256) {
    const int ly = p / 80, x = p % 80;
    float a0 = 0.f, a1 = 0.f;
    #pragma unroll
    for (int ky = 0; ky < 3; ky++) {
      #pragma unroll
      for (int kx = 0; kx < 3; kx++) {
        float v0 = tt[0][ly + ky][x + kx], v1 = tt[1][ly + ky][x + kx];
        int k = ky * 3 + kx;
        a0 = fmaf(v0, w0[0][k], a0); a0 = fmaf(v1, w0[1][k], a0);
        a1 = fmaf(v0, w1[0][k], a1); a1 = fmaf(v1, w1[1][k], a1);
      }
    }
    const int yy = y0 + ly;
    out[((size_t)b * 256 + 2 * g) * N_ + yy * 80 + x] = a0;
    out[((size_t)b * 256 + 2 * g + 1) * N_ + yy * 80 + x] = a1;
  }
}

// ---------------- merged per-row L2 norms (two input sets via blockIdx routing) ----------------
__global__ __launch_bounds__(256) void k_rownorm_r2(const float* __restrict__ inA, float* __restrict__ nrmA,
                                                    const float* __restrict__ inB, float* __restrict__ nrmB) {
  __shared__ float red[256];
  int row = blockIdx.x;
  const float* p; float* o;
  if (row < B_ * C_) { p = inA + (size_t)row * N_; o = nrmA + row; }
  else { row -= B_ * C_; p = inB + (size_t)row * N_; o = nrmB + row; }
  float s = 0.f;
  for (int i = threadIdx.x; i < N_; i += 256) { float v = p[i]; s = fmaf(v, v, s); }
  red[threadIdx.x] = s; __syncthreads();
  for (int st = 128; st > 0; st >>= 1) { if (threadIdx.x < st) red[threadIdx.x] += red[threadIdx.x + st]; __syncthreads(); }
  if (threadIdx.x == 0) *o = fmaxf(sqrtf(red[0]), 1e-12f);
}

// ---------------- attention partials: coalesced wave-per-tile ----------------
__global__ __launch_bounds__(256) void k_attn_part_c(const float2* __restrict__ Ab, const float2* __restrict__ Bb,
                                                     float2* __restrict__ part) {
  const int bh = blockIdx.z;
  const int b = bh / H_, h = bh % H_;
  const int wave = threadIdx.x >> 6, lane = threadIdx.x & 63;
  const int tile = blockIdx.x * 4 + wave;      // 0..63
  const int c0 = (tile >> 3) * 4, d0 = (tile & 7) * 4;
  const size_t hb = ((size_t)b * C_ + h * 32) * N_;
  const float2* Ap = Ab + hb;
  const float2* Bp = Bb + hb;
  float2 acc[4][4];
  #pragma unroll
  for (int j = 0; j < 4; j++)
    #pragma unroll
    for (int i = 0; i < 4; i++) acc[j][i] = make_float2(0.f, 0.f);
  const int nb = blockIdx.y * (N_ / NSPL) + lane;
  for (int it = 0; it < (N_ / NSPL) / 64; ++it) {
    const int n = nb + it * 64;
    float2 av[4], bv[4];
    #pragma unroll
    for (int j = 0; j < 4; j++) av[j] = Ap[(size_t)(c0 + j) * N_ + n];
    #pragma unroll
    for (int i = 0; i < 4; i++) bv[i] = Bp[(size_t)(d0 + i) * N_ + n];
    #pragma unroll
    for (int j = 0; j < 4; j++)
      #pragma unroll
      for (int i = 0; i < 4; i++) cfma(acc[j][i], av[j], bv[i]);
  }
  float2* pp = part + (size_t)(bh * NSPL + blockIdx.y) * 1024;
  #pragma unroll
  for (int j = 0; j < 4; j++) {
    #pragma unroll
    for (int i = 0; i < 4; i++) {
      float rx = acc[j][i].x, ry = acc[j][i].y;
      for (int off = 32; off; off >>= 1) { rx += __shfl_xor(rx, off); ry += __shfl_xor(ry, off); }
      if (lane == 0) pp[(c0 + j) * 32 + d0 + i] = make_float2(rx, ry);
    }
  }
}
__global__ __launch_bounds__(256) void k_attn_part_r(const float* __restrict__ Ab, const float* __restrict__ Bb,
                                                     float* __restrict__ part) {
  const int bh = blockIdx.z;
  const int b = bh / H_, h = bh % H_;
  const int wave = threadIdx.x >> 6, lane = threadIdx.x & 63;
  const int tile = blockIdx.x * 4 + wave;
  const int c0 = (tile >> 3) * 4, d0 = (tile & 7) * 4;
  const size_t hb = ((size_t)b * C_ + h * 32) * N_;
  const float* Ap = Ab + hb;
  const float* Bp = Bb + hb;
  float acc[4][4];
  #pragma unroll
  for (int j = 0; j < 4; j++)
    #pragma unroll
    for (int i = 0; i < 4; i++) acc[j][i] = 0.f;
  const int nb = blockIdx.y * (N_ / NSPL) + lane;
  for (int it = 0; it < (N_ / NSPL) / 64; ++it) {
    const int n = nb + it * 64;
    float av[4], bv[4];
    #pragma unroll
    for (int j = 0; j < 4; j++) av[j] = Ap[(size_t)(c0 + j) * N_ + n];
    #pragma unroll
    for (int i = 0; i < 4; i++) bv[i] = Bp[(size_t)(d0 + i) * N_ + n];
    #pragma unroll
    for (int j = 0; j < 4; j++)
      #pragma unroll
      for (int i = 0; i < 4; i++) acc[j][i] = fmaf(av[j], bv[i], acc[j][i]);
  }
  float* pp = part + (size_t)(bh * NSPL + blockIdx.y) * 1024;
  #pragma unroll
  for (int j = 0; j < 4; j++) {
    #pragma unroll
    for (int i = 0; i < 4; i++) {
      float r = acc[j][i];
      for (int off = 32; off; off >>= 1) r += __shfl_xor(r, off);
      if (lane == 0) pp[(c0 + j) * 32 + d0 + i] = r;
    }
  }
}

// ---------------- reduce partials, scale, softmax ----------------
template <int CPLX>
__global__ void k_attn_soft(const float* __restrict__ part, const float* __restrict__ nA,
                            const float* __restrict__ nB, const float* __restrict__ temp,
                            float* __restrict__ attn) {
  const int rc = blockIdx.x;          // bh*32 + c
  const int bh = rc >> 5, c = rc & 31;
  const int b = bh / H_, h = bh % H_;
  const int d = threadIdx.x;          // 64 threads; group >=32 unused
  float re = -1e30f, im = -1e30f;
  if (d < 32) {
    re = 0.f; im = 0.f;
    if (CPLX) {
      const float2* pp = (const float2*)part;
      for (int kc = 0; kc < NSPL; kc++) { float2 v = pp[(size_t)(bh * NSPL + kc) * 1024 + c * 32 + d]; re += v.x; im += v.y; }
    } else {
      for (int kc = 0; kc < NSPL; kc++) re += part[(size_t)(bh * NSPL + kc) * 1024 + c * 32 + d];
    }
    float sc = temp[h] / (nA[b * C_ + h * 32 + c] * nB[b * C_ + h * 32 + d]);
    re *= sc; im *= sc;
  }
  float m = re;
  for (int o = 16; o; o >>= 1) m = fmaxf(m, __shfl_xor(m, o, 32));
  float e = expf(re - m);
  float s = e;
  for (int o = 16; o; o >>= 1) s += __shfl_xor(s, o, 32);
  float vr = e / s;
  float mi = im;
  for (int o = 16; o; o >>= 1) mi = fmaxf(mi, __shfl_xor(mi, o, 32));
  float ei = expf(im - mi);
  float si = ei;
  for (int o = 16; o; o >>= 1) si += __shfl_xor(si, o, 32);
  float vi = ei / si;
  if (d < 32) {
    if (CPLX) ((float2*)attn)[(size_t)(bh * 32 + c) * 32 + d] = make_float2(vr, vi);
    else attn[(size_t)(bh * 32 + c) * 32 + d] = vr;
  }
}

// ---------------- fused PV + 32-point IDFT along c: out[cp,n] = (1/32) sum_c pv[c,n] e^{2pi i c cp/32} ----------------
__global__ __launch_bounds__(256) void k_pv_idft32(const float2* __restrict__ attn, const float2* __restrict__ V,
                                                   float2* __restrict__ out) {
  __shared__ float2 at[32][32];
  __shared__ float2 tw[32];
  const int bh = blockIdx.x;
  const int b = bh / H_, h = bh % H_;
  const int n = blockIdx.y * 256 + threadIdx.x;
  if (threadIdx.x < 32) { float a = PI2 * (float)threadIdx.x * (1.f / 32.f); float sv, cv; sincosf(a, &sv, &cv); tw[threadIdx.x] = make_float2(cv, sv); }
  for (int i = threadIdx.x; i < 1024; i += 256) at[i >> 5][i & 31] = attn[(size_t)bh * 1024 + i];
  __syncthreads();
  const size_t hb = ((size_t)b * C_ + h * 32) * N_;
  const float2* Vp = V + hb;
  float2 acc[32];
  #pragma unroll
  for (int c = 0; c < 32; c++) acc[c] = make_float2(0.f, 0.f);
  for (int dd = 0; dd < 32; dd++) {
    float2 v = Vp[(size_t)dd * N_ + n];
    #pragma unroll
    for (int c = 0; c < 32; c++) cfma(acc[c], at[c][dd], v);
  }
  // in-register radix-2 32-point IDFT along c (same summation order as the old k_idft32)
  float2* Op = out + hb;
  for (int cp = 0; cp < 16; cp++) {
    float2 E = make_float2(0.f, 0.f), O = make_float2(0.f, 0.f);
    const int inc = (2 * cp) & 31;
    int idx = 0;
    #pragma unroll
    for (int m = 0; m < 16; m++) {
      cfma(E, acc[2 * m], tw[idx]);
      cfma(O, acc[2 * m + 1], tw[idx]);
      idx = (idx + inc) & 31;
    }
    float2 u = cmul(tw[cp], O);
    Op[(size_t)cp * N_ + n]        = make_float2((E.x + u.x) * (1.f / 32.f), (E.y + u.y) * (1.f / 32.f));
    Op[(size_t)(cp + 16) * N_ + n] = make_float2((E.x - u.x) * (1.f / 32.f), (E.y - u.y) * (1.f / 32.f));
  }
}

__global__ __launch_bounds__(256) void k_pv_r(const float* __restrict__ attn, const float* __restrict__ V,
                                              float* __restrict__ out) {
  __shared__ float at[32][32];
  const int bh = blockIdx.x;
  const int b = bh / H_, h = bh % H_;
  const int n = blockIdx.y * 256 + threadIdx.x;
  for (int i = threadIdx.x; i < 1024; i += 256) at[i >> 5][i & 31] = attn[(size_t)bh * 1024 + i];
  __syncthreads();
  const size_t hb = ((size_t)b * C_ + h * 32) * N_;
  const float* Vp = V + hb;
  float acc[32];
  #pragma unroll
  for (int c = 0; c < 32; c++) acc[c] = 0.f;
  for (int dd = 0; dd < 32; dd++) {
    float v = Vp[(size_t)dd * N_ + n];
    #pragma unroll
    for (int c = 0; c < 32; c++) acc[c] = fmaf(at[c][dd], v, acc[c]);
  }
  float* Op = out + hb;
  #pragma unroll
  for (int c = 0; c < 32; c++) Op[(size_t)c * N_ + n] = acc[c];
}

extern "C" void kernel_launch(void* const* d_in, const int* in_sizes, int n_in,
                              void* d_out, int out_size, void* d_ws, size_t ws_size,
                              hipStream_t stream) {
  (void)in_sizes; (void)n_in; (void)out_size; (void)ws_size;
  const float* x       = (const float*)d_in[0];
  const float* ln1_w   = (const float*)d_in[1];
  const float* ln2_w   = (const float*)d_in[2];
  const float* ln1_b   = (const float*)d_in[3];
  const float* ln2_b   = (const float*)d_in[4];
  const float* f_temp  = (const float*)d_in[5];
  const float* s_temp  = (const float*)d_in[6];
  const float* f_proj  = (const float*)d_in[7];
  const float* s_proj  = (const float*)d_in[8];
  const float* f_w1    = (const float*)d_in[9];
  const float* f_wb1   = (const float*)d_in[10];
  const float* f_bng   = (const float*)d_in[11];
  const float* f_bnb   = (const float*)d_in[12];
  const float* f_w2    = (const float*)d_in[13];
  const float* f_wb2   = (const float*)d_in[14];
  const float* s_q1_w  = (const float*)d_in[15];
  const float* s_q1_b  = (const float*)d_in[16];
  const float* s_k1_w  = (const float*)d_in[17];
  const float* s_k1_b  = (const float*)d_in[18];
  const float* s_v1_w  = (const float*)d_in[19];
  const float* s_v1_b  = (const float*)d_in[20];
  const float* s_q3_w  = (const float*)d_in[21];
  const float* s_k3_w  = (const float*)d_in[22];
  const float* s_v3_w  = (const float*)d_in[23];
  const float* s_c3_w  = (const float*)d_in[24];
  const float* s_q5_w  = (const float*)d_in[25];
  const float* s_k5_w  = (const float*)d_in[26];
  const float* s_v5_w  = (const float*)d_in[27];
  const float* s_c5_w  = (const float*)d_in[28];
  const float* ffdw1_w = (const float*)d_in[29];
  const float* ffdw2_w = (const float*)d_in[30];
  const float* ffproj  = (const float*)d_in[31];
  const float* ffg_w1  = (const float*)d_in[32];
  const float* ffg_b1  = (const float*)d_in[33];
  const float* ffg_bng = (const float*)d_in[34];
  const float* ffg_bnb = (const float*)d_in[35];
  const float* ffg_w2  = (const float*)d_in[36];
  const float* ffg_b2  = (const float*)d_in[37];
  const float* ffg1_w1 = (const float*)d_in[38];
  const float* ffg1_b1 = (const float*)d_in[39];
  const float* ffg1_bng= (const float*)d_in[40];
  const float* ffg1_bnb= (const float*)d_in[41];
  const float* ffg1_w2 = (const float*)d_in[42];
  const float* ffg1_b2 = (const float*)d_in[43];

  // workspace layout (floats). Requires ~267 MB of d_ws.
  float* ws = (float*)d_ws;
  const size_t R = (size_t)B_ * C_ * N_;   // 6,553,600 floats per [B,128,N] image set
  float* xn   = ws;            // R
  float* acc  = ws + R;        // R
  float* bufA = ws + 2 * R;    // 2R (complex [B,128,N] or real [B,256,N])
  float* bufB = ws + 4 * R;    // 2R
  float* bufC = ws + 6 * R;    // 2R
  float* bufD = ws + 8 * R;    // 2R
  float* sm   = ws + 10 * R;   // small pool
  float* nrmQ = sm;                    // 1024
  float* nrmK = sm + 1024;             // 1024
  float* hid  = sm + 2048;             // B*8*N = 409600
  float* part = sm + 2048 + 409600;    // 524288 (float2[131072] used for cplx)
  float* attb = part + 524288;         // 65536 (float2[32768] for cplx)

  dim3 blk(256);
  const int GCONV = P_ / 64;   // 800 blocks, 128co x 64pos MFMA tiles
  const int GLN = P_ / 64;     // 800 blocks for layernorm / gateA
  const int NIMG = B_ * C_;    // 1024
  const dim3 gattn(16, NSPL, B_ * H_);

  // ===== xn = LayerNorm(x) ; xf = fft2(xn) with fused row-norm =====
  k_layernorm<<<GLN, blk, 0, stream>>>(x, ln1_w, ln1_b, xn);
  k_fft2_r2c<<<NIMG, blk, 0, stream>>>(xn, (float2*)bufA, C_, C_, 0, nullptr, 0, NIMG, nrmQ);

  // ===== Attention_F =====
  k_attn_part_c<<<gattn, blk, 0, stream>>>((const float2*)bufA, (const float2*)bufA, (float2*)part);
  k_attn_soft<1><<<B_ * C_, 64, 0, stream>>>(part, nrmQ, nrmQ, f_temp, attb);
  // fused PV + idft32: writes bufC directly (bufB roundtrip eliminated)
  k_pv_idft32<<<dim3(B_ * H_, N_ / 256), blk, 0, stream>>>((const float2*)attb, (const float2*)bufA, (float2*)bufC);
  // gated branch first (reads bufA pre/post scale), then merged idft6400+ifft2
  k_gateA<<<GLN, blk, 0, stream>>>((const float2*)bufA, (const float2*)bufA, C_, C_, f_w1, f_wb1, f_bng, f_bnb, hid);
  k_gateB<0><<<dim3(P_ / 256, 2), blk, 0, stream>>>((float2*)bufA, (float2*)bufA, C_, C_, f_w2, f_wb2, hid, nullptr, 0, 0);
  k_iff_combo<<<2 * NIMG, blk, 0, stream>>>((const float2*)bufC, bufD, (const float2*)bufA, bufD + R);
  // a_f: acc = x + f_proj(concat(out_f, out_f_l))
  k_conv1x1<<<GCONV, blk, 0, stream>>>(bufD, bufD + R, 128, 256, 128, f_proj, nullptr, x, acc);

  // ===== Attention_S =====
  // fused q1/k1/v1 (one 2400-block dispatch; blockIdx.y routes weight/output set)
  k_conv1x1_qkv<<<dim3(GCONV, 3), blk, 0, stream>>>(xn,
      s_q1_w, s_q1_b, bufA, s_k1_w, s_k1_b, bufA + R, s_v1_w, s_v1_b, bufB);
  // fused qs/ks/vs/cs grouped convs (4 sets; cs output redirected to bufD+R -> no conflicts)
  k_gconv35_4<<<dim3(B_ * 128, 4), blk, 0, stream>>>(
      bufA,     s_q3_w, s_q5_w, bufB + R,
      bufA + R, s_k3_w, s_k5_w, bufC,
      bufB,     s_v3_w, s_v5_w, bufC + R,
      xn,       s_c3_w, s_c5_w, bufD + R);
  // merged rownorms (qs -> nrmQ, ks -> nrmK)
  k_rownorm_r2<<<2 * B_ * C_, blk, 0, stream>>>(bufB + R, nrmQ, bufC, nrmK);
  k_attn_part_r<<<gattn, blk, 0, stream>>>(bufB + R, bufC, part);
  k_attn_soft<0><<<B_ * C_, 64, 0, stream>>>(part, nrmQ, nrmK, s_temp, attb);
  k_pv_r<<<dim3(B_ * H_, N_ / 256), blk, 0, stream>>>(attb, bufC + R, bufA);      // out_s -> A.lo
  // a_s: acc += s_proj(concat(out_s, out_s_l))  (out_s_l lives in bufD+R)
  k_conv1x1<<<GCONV, blk, 0, stream>>>(bufA, bufD + R, 128, 256, 128, s_proj, nullptr, acc, acc);

  // ===== FeedForward =====
  k_layernorm<<<GLN, blk, 0, stream>>>(acc, ln2_w, ln2_b, xn);                    // xn2
  k_fft2_r2c<<<NIMG, blk, 0, stream>>>(xn, (float2*)bufA, C_, C_, 0, nullptr, 0, NIMG, nullptr);  // xf2
  k_gateA<<<GLN, blk, 0, stream>>>((const float2*)bufA, (const float2*)bufA, C_, C_, ffg_w1, ffg_b1, ffg_bng, ffg_bnb, hid);
  k_gateB<1><<<dim3(P_ / 256, 2), blk, 0, stream>>>((float2*)bufA, (float2*)bufA, C_, C_, ffg_w2, ffg_b2, hid, bufB, 256, 0); // x_f_g -> cat.lo
  k_dwconv3_gelu<<<B_ * 256, blk, 0, stream>>>(xn, ffdw1_w, bufB, 128, 256, 128); // x_s_g -> cat.hi
  // cf = fft2(cat): one merged 2048-block dispatch (lo -> bufA, hi -> bufC)
  k_fft2_r2c<<<2 * NIMG, blk, 0, stream>>>(bufB, (float2*)bufA, 128, 256, 0, (float2*)bufC, 128, NIMG, nullptr);
  k_gateA<<<GLN, blk, 0, stream>>>((const float2*)bufA, (const float2*)bufC, 128, 256, ffg1_w1, ffg1_b1, ffg1_bng, ffg1_bnb, hid);
  k_gateB<0><<<dim3(P_ / 256, 4), blk, 0, stream>>>((float2*)bufA, (float2*)bufC, 128, 256, ffg1_w2, ffg1_b2, hid, nullptr, 0, 0);
  // x_f2b: merged 2048-block ifft2 pair (bufA -> bufD coff0, bufC -> bufD coff128)
  k_ifft2_abs<<<2 * NIMG, blk, 0, stream>>>((const float2*)bufA, bufD, 128, 256, 0, (const float2*)bufC, 128, NIMG);
  k_ffdw2<<<B_ * 256, blk, 0, stream>>>(bufB, ffdw2_w, bufA);                     // x_s2b (real [B,256,N] in A)
  // out = x1 + ff_proj(concat(x_f2b, x_s2b))
  k_conv1x1<<<GCONV, blk, 0, stream>>>(bufD, bufA, 256, 512, 128, ffproj, nullptr, acc, (float*)d_out);
}

// Round 22
// 962.861 us; speedup vs baseline: 1.2732x; 1.0275x over previous
//
#include <hip/hip_runtime.h>
#include <math.h>

#define DI __device__ __forceinline__

constexpr int B_ = 8, C_ = 128, H_ = 4, S_ = 80, N_ = 6400;
constexpr int P_ = B_ * N_;                 // 51200 spatial positions
constexpr int NSPL = 2;                     // n-chunks for attention partials
constexpr float PI2 = 6.283185307179586f;
constexpr float BN_SC = 0.9999950000374997f;  // 1/sqrt(1+1e-5)

typedef __attribute__((ext_vector_type(8))) short bf16x8;
typedef __attribute__((ext_vector_type(4))) float f32x4;

DI void cfma(float2& a, float2 u, float2 v) {
  a.x = fmaf(u.x, v.x, a.x); a.x = fmaf(-u.y, v.y, a.x);
  a.y = fmaf(u.x, v.y, a.y); a.y = fmaf(u.y, v.x, a.y);
}
DI float2 cmul(float2 u, float2 v) {
  return make_float2(u.x * v.x - u.y * v.y, u.x * v.y + u.y * v.x);
}
DI float gelu_mul(float m) {  // gelu(m, exact) * m
  return 0.5f * m * (1.f + erff(m * 0.7071067811865476f)) * m;
}
DI unsigned short bf16_rn(float f) {  // round-to-nearest-even fp32 -> bf16
  union { float f; unsigned int u; } v; v.f = f;
  unsigned int u = v.u;
  return (unsigned short)((u + 0x7fffu + ((u >> 16) & 1u)) >> 16);
}

// ---------------- LayerNorm over channel dim (4-way channel-split, 800 blocks) ----------------
__global__ __launch_bounds__(256) void k_layernorm(const float* __restrict__ in,
    const float* __restrict__ w, const float* __restrict__ bb, float* __restrict__ out) {
  __shared__ float redS[4][64], redS2[4][64];
  __shared__ float muv[64], invv[64];
  const int tid = threadIdx.x;
  const int g = tid >> 6, l = tid & 63;
  const int p = blockIdx.x * 64 + l;
  const int b = p / N_, n = p % N_;
  const float* xp = in + (size_t)b * C_ * N_ + n;
  float s = 0.f, s2 = 0.f;
  for (int c = g * 32; c < g * 32 + 32; c++) {
    float v = xp[(size_t)c * N_];
    s += v; s2 = fmaf(v, v, s2);
  }
  redS[g][l] = s; redS2[g][l] = s2;
  __syncthreads();
  if (g == 0) {
    float ts  = redS[0][l] + redS[1][l] + redS[2][l] + redS[3][l];
    float ts2 = redS2[0][l] + redS2[1][l] + redS2[2][l] + redS2[3][l];
    float mu = ts * (1.f / C_);
    float var = ts2 * (1.f / C_) - mu * mu;
    muv[l] = mu; invv[l] = rsqrtf(var + 1e-5f);
  }
  __syncthreads();
  const float mu = muv[l], inv = invv[l];
  float* op = out + (size_t)b * C_ * N_ + n;
  for (int c = g * 32; c < g * 32 + 32; c++) {
    float v = xp[(size_t)c * N_];
    op[(size_t)c * N_] = (v - mu) * inv * w[c] + bb[c];
  }
}

// ============ register-tiled 80x80 2D DFT kernels (5x16 Cooley-Tukey) ============

// ---------------- 2D FFT (80x80) real->complex, 5x16 CT both passes ----------------
__global__ __launch_bounds__(256) void k_fft2_r2c(const float* __restrict__ in, float2* __restrict__ out,
                                                  int nCh, int inCtot, int inCoff,
                                                  float2* __restrict__ out2, int inCoff2, int nimg,
                                                  float* __restrict__ nrm) {
  __shared__ float2 data[N_];
  __shared__ float2 tw[80];
  int img = blockIdx.x;
  float2* op;
  int coff;
  if (img >= nimg) { img -= nimg; op = out2 + (size_t)img * N_; coff = inCoff2; }
  else { op = out + (size_t)img * N_; coff = inCoff; }
  const int b = img / nCh, ch = img % nCh;
  const float* ip = in + ((size_t)b * inCtot + coff + ch) * N_;
  const int tid = threadIdx.x;
  float* dataR = (float*)data;
  if (tid < 80) { float a = -PI2 * (float)tid * (1.f / 80.f); float sv, cv; sincosf(a, &sv, &cv); tw[tid] = make_float2(cv, sv); }
  for (int i = tid; i < N_; i += 256) dataR[i] = ip[i];
  __syncthreads();
  // ---- pass 1: rows. thread = (rg: 5 rows, kap in [0,16)) ----
  const int rg = tid >> 4;
  const int kap = tid & 15;
  const int r0 = rg * 5;
  {
    float2 F[5][5];   // [j][q]
    #pragma unroll
    for (int j = 0; j < 5; j++)
      #pragma unroll
      for (int q = 0; q < 5; q++) F[j][q] = make_float2(0.f, 0.f);
    int m16 = 0;
    for (int m = 0; m < 16; ++m) {
      float2 t = tw[5 * m16];
      #pragma unroll
      for (int j = 0; j < 5; j++) {
        const float* row = &dataR[(r0 + j) * 80 + 5 * m];
        #pragma unroll
        for (int q = 0; q < 5; q++) {
          float xv = row[q];
          F[j][q].x = fmaf(xv, t.x, F[j][q].x);
          F[j][q].y = fmaf(xv, t.y, F[j][q].y);
        }
      }
      m16 += kap; if (m16 >= 16) m16 -= 16;
    }
    __syncthreads();   // all real reads done before complex overwrite
    #pragma unroll
    for (int s = 0; s < 5; ++s) {
      const int k = kap + 16 * s;
      if (k <= 40) {
        float2 t1 = tw[k];
        float2 t2 = tw[(2 * k) % 80];
        float2 t3 = tw[(3 * k) % 80];
        float2 t4 = tw[(4 * k) % 80];
        #pragma unroll
        for (int j = 0; j < 5; j++) {
          float2 a = F[j][0];
          cfma(a, F[j][1], t1);
          cfma(a, F[j][2], t2);
          cfma(a, F[j][3], t3);
          cfma(a, F[j][4], t4);
          data[(r0 + j) * 80 + k] = a;
          if (k >= 1 && k <= 39) data[(r0 + j) * 80 + 80 - k] = make_float2(a.x, -a.y);
        }
      }
    }
  }
  __syncthreads();
  // ---- pass 2: columns. thread = (k0: 5 cols, kap2 in [0,16)) ----
  const int k0 = (tid & 15) * 5;
  const int kap2 = tid >> 4;
  float snrm = 0.f;
  {
    float2 G[5][5];   // [q][i]
    #pragma unroll
    for (int q = 0; q < 5; q++)
      #pragma unroll
      for (int i = 0; i < 5; i++) G[q][i] = make_float2(0.f, 0.f);
    int m16 = 0;
    for (int m = 0; m < 16; ++m) {
      float2 t = tw[5 * m16];
      #pragma unroll
      for (int q = 0; q < 5; q++) {
        const float2* rowp = &data[(5 * m + q) * 80 + k0];
        #pragma unroll
        for (int i = 0; i < 5; i++) cfma(G[q][i], rowp[i], t);
      }
      m16 += kap2; if (m16 >= 16) m16 -= 16;
    }
    #pragma unroll
    for (int s = 0; s < 5; ++s) {
      const int k1 = kap2 + 16 * s;
      if (k1 <= 40) {
        float2 t1 = tw[k1];
        float2 t2 = tw[(2 * k1) % 80];
        float2 t3 = tw[(3 * k1) % 80];
        float2 t4 = tw[(4 * k1) % 80];
        const float wgt = (k1 == 0 || k1 == 40) ? 1.f : 2.f;
        #pragma unroll
        for (int i = 0; i < 5; i++) {
          float2 y = G[0][i];
          cfma(y, G[1][i], t1);
          cfma(y, G[2][i], t2);
          cfma(y, G[3][i], t3);
          cfma(y, G[4][i], t4);
          const int k2 = k0 + i;
          op[k1 * 80 + k2] = y;
          if (k1 >= 1 && k1 <= 39) {
            const int m2 = (k2 == 0) ? 0 : 80 - k2;
            op[(80 - k1) * 80 + m2] = make_float2(y.x, -y.y);
          }
          snrm += wgt * (y.x * y.x + y.y * y.y);
        }
      }
    }
  }
  if (nrm) {   // fused per-image L2 norm (mirrored halves contribute 2x)
    __syncthreads();
    float* red = (float*)data;
    red[tid] = snrm;
    __syncthreads();
    for (int st = 128; st > 0; st >>= 1) { if (tid < st) red[tid] += red[tid + st]; __syncthreads(); }
    if (tid == 0) nrm[img] = fmaxf(sqrtf(red[0]), 1e-12f);
  }
}

// ---------------- 2D IFFT (80x80) of HERMITIAN input -> |real|; rows 0..40 only (26.9 KB LDS) ----------------
__global__ __launch_bounds__(256) void k_ifft2_abs(const float2* __restrict__ in, float* __restrict__ out,
                                                   int inC, int outCtot, int outCoff,
                                                   const float2* __restrict__ in2, int outCoff2, int nimg) {
  __shared__ float2 data[41 * 80];   // only rows 0..40 are ever used
  __shared__ float2 tw[80];
  int img = blockIdx.x;
  const float2* ip;
  int coff;
  if (img >= nimg) { img -= nimg; ip = in2 + (size_t)img * N_; coff = outCoff2; }
  else { ip = in + (size_t)img * N_; coff = outCoff; }
  const int b = img / inC, ch = img % inC;
  float* op = out + ((size_t)b * outCtot + coff + ch) * N_;
  const int tid = threadIdx.x;
  if (tid < 80) { float a = PI2 * (float)tid * (1.f / 80.f); float sv, cv; sincosf(a, &sv, &cv); tw[tid] = make_float2(cv, sv); }
  for (int i = tid; i < 41 * 80; i += 256) data[i] = ip[i];
  __syncthreads();
  // ---- pass 1 (CT): full-row IDFT for rows r = g1+16j (r<=40), in-place ----
  {
    const int g1 = tid >> 4;
    const int kap = tid & 15;
    float2 F[3][5];
    #pragma unroll
    for (int j = 0; j < 3; j++)
      #pragma unroll
      for (int q = 0; q < 5; q++) F[j][q] = make_float2(0.f, 0.f);
    int rr[3];
    #pragma unroll
    for (int j = 0; j < 3; j++) { int r = g1 + 16 * j; rr[j] = (r <= 40) ? r : 0; }
    int m16 = 0;
    for (int m = 0; m < 16; ++m) {
      float2 t = tw[5 * m16];
      #pragma unroll
      for (int j = 0; j < 3; j++) {
        const float2* rowp = &data[rr[j] * 80 + 5 * m];
        #pragma unroll
        for (int q = 0; q < 5; q++) cfma(F[j][q], rowp[q], t);
      }
      m16 += kap; if (m16 >= 16) m16 -= 16;
    }
    __syncthreads();   // reads complete before overwrite
    #pragma unroll
    for (int s = 0; s < 5; ++s) {
      const int n2 = kap + 16 * s;
      float2 t1 = tw[n2];
      float2 t2 = tw[(2 * n2) % 80];
      float2 t3 = tw[(3 * n2) % 80];
      float2 t4 = tw[(4 * n2) % 80];
      #pragma unroll
      for (int j = 0; j < 3; j++) {
        const int r = g1 + 16 * j;
        if (r <= 40) {
          float2 a = F[j][0];
          cfma(a, F[j][1], t1);
          cfma(a, F[j][2], t2);
          cfma(a, F[j][3], t3);
          cfma(a, F[j][4], t4);
          data[r * 80 + n2] = a;
        }
      }
    }
  }
  __syncthreads();
  // ---- pass 2 (real output, Hermitian-in-row) ----
  const int r0 = (tid >> 4) * 5;
  const int k0 = (tid & 15) * 5;
  float accR[5][5];
  for (int j = 0; j < 5; j++)
    for (int i = 0; i < 5; i++) accR[j][i] = 0.f;
  {
    int idx[5];
    #pragma unroll
    for (int j = 0; j < 5; j++) idx[j] = r0 + j;
    for (int r = 1; r <= 39; ++r) {
      float2 d[5]; float2 t[5];
      #pragma unroll
      for (int i = 0; i < 5; i++) d[i] = data[r * 80 + k0 + i];
      #pragma unroll
      for (int j = 0; j < 5; j++) t[j] = tw[idx[j]];
      #pragma unroll
      for (int j = 0; j < 5; j++) {
        #pragma unroll
        for (int i = 0; i < 5; i++) {
          accR[j][i] = fmaf(t[j].x, d[i].x, accR[j][i]);
          accR[j][i] = fmaf(-t[j].y, d[i].y, accR[j][i]);
        }
      }
      #pragma unroll
      for (int j = 0; j < 5; j++) { idx[j] += r0 + j; if (idx[j] >= 80) idx[j] -= 80; }
    }
  }
  #pragma unroll
  for (int i = 0; i < 5; i++) {
    float2 b0 = data[k0 + i];
    float2 b40 = data[40 * 80 + k0 + i];
    #pragma unroll
    for (int j = 0; j < 5; j++) {
      float s40 = ((r0 + j) & 1) ? -b40.x : b40.x;
      float res = 2.f * accR[j][i] + b0.x + s40;
      op[(r0 + j) * 80 + k0 + i] = fabsf(res) * (1.f / (float)N_);
    }
  }
}

// ---------------- combo: blocks <1024 do 6400-pt IDFT+abs (5x16 CT); blocks >=1024 do Hermitian ifft2+abs ----------------
__global__ __launch_bounds__(256) void k_iff_combo(const float2* __restrict__ in6400, float* __restrict__ out6400,
                                                   const float2* __restrict__ inF, float* __restrict__ outF) {
  __shared__ float2 data[N_];
  __shared__ float2 tw[80];
  __shared__ float2 tws[80];
  const int tid = threadIdx.x;
  if (blockIdx.x < (unsigned)(B_ * C_)) {
    // ---- idft6400_abs body: X[c2][c1] -> A (80pt IDFT over c2) -> *tw6400 -> 80pt IDFT over k1 -> abs ----
    const int row = blockIdx.x;
    const float2* ip = in6400 + (size_t)row * N_;
    float* op = out6400 + (size_t)row * N_;
    if (tid < 80) {
      float a = PI2 * (float)tid * (1.f / 80.f); float sv, cv; sincosf(a, &sv, &cv); tw[tid] = make_float2(cv, sv);
      float a2 = PI2 * (float)tid * (1.f / 6400.f); sincosf(a2, &sv, &cv); tws[tid] = make_float2(cv, sv);
    }
    for (int i = tid; i < N_; i += 256) data[i] = ip[i];
    __syncthreads();
    const int g = tid >> 4;
    const int kap = tid & 15;
    const int r0 = g * 5;
    // ---- pass A (CT): A[c1][n2] = sum_c2 X[c2][c1] tw[c2 n2]; then * e^{2pi i c1 n2/6400} ----
    {
      float2 F[5][5];   // [j: c1=r0+j][q]
      #pragma unroll
      for (int j = 0; j < 5; j++)
        #pragma unroll
        for (int q = 0; q < 5; q++) F[j][q] = make_float2(0.f, 0.f);
      int m16 = 0;
      for (int m = 0; m < 16; ++m) {
        float2 t = tw[5 * m16];
        #pragma unroll
        for (int q = 0; q < 5; q++) {
          const float2* col = &data[(5 * m + q) * 80 + r0];
          #pragma unroll
          for (int j = 0; j < 5; j++) cfma(F[j][q], col[j], t);
        }
        m16 += kap; if (m16 >= 16) m16 -= 16;
      }
      __syncthreads();   // reads complete before overwrite
      #pragma unroll
      for (int s = 0; s < 5; ++s) {
        const int n2 = kap + 16 * s;
        float2 t1 = tw[n2];
        float2 t2 = tw[(2 * n2) % 80];
        float2 t3 = tw[(3 * n2) % 80];
        float2 t4 = tw[(4 * n2) % 80];
        #pragma unroll
        for (int j = 0; j < 5; j++) {
          const int k1 = r0 + j;
          float2 a = F[j][0];
          cfma(a, F[j][1], t1);
          cfma(a, F[j][2], t2);
          cfma(a, F[j][3], t3);
          cfma(a, F[j][4], t4);
          int t6 = k1 * n2; int q6 = t6 / 80, s6 = t6 - q6 * 80;
          data[k1 * 80 + n2] = cmul(a, cmul(tw[q6], tws[s6]));
        }
      }
    }
    __syncthreads();
    // ---- pass B (CT): out[n1][n2] = |sum_k1 Y[k1][n2] tw[k1 n1]| / 6400 ----
    {
      float2 G[5][5];   // [q][i]
      #pragma unroll
      for (int q = 0; q < 5; q++)
        #pragma unroll
        for (int i = 0; i < 5; i++) G[q][i] = make_float2(0.f, 0.f);
      int m16 = 0;
      for (int m = 0; m < 16; ++m) {
        float2 t = tw[5 * m16];
        #pragma unroll
        for (int q = 0; q < 5; q++) {
          const float2* rowp = &data[(5 * m + q) * 80 + r0];
          #pragma unroll
          for (int i = 0; i < 5; i++) cfma(G[q][i], rowp[i], t);
        }
        m16 += kap; if (m16 >= 16) m16 -= 16;
      }
      #pragma unroll
      for (int s = 0; s < 5; ++s) {
        const int n1 = kap + 16 * s;
        float2 t1 = tw[n1];
        float2 t2 = tw[(2 * n1) % 80];
        float2 t3 = tw[(3 * n1) % 80];
        float2 t4 = tw[(4 * n1) % 80];
        #pragma unroll
        for (int i = 0; i < 5; i++) {
          float2 y = G[0][i];
          cfma(y, G[1][i], t1);
          cfma(y, G[2][i], t2);
          cfma(y, G[3][i], t3);
          cfma(y, G[4][i], t4);
          op[n1 * 80 + r0 + i] = sqrtf(y.x * y.x + y.y * y.y) * (1.f / 6400.f);
        }
      }
    }
  } else {
    // ---- Hermitian ifft2_abs body (pass1 = 5x16 CT); only rows 0..40 loaded/used ----
    const int img = blockIdx.x - B_ * C_;
    const float2* ip = inF + (size_t)img * N_;
    float* op = outF + (size_t)img * N_;
    if (tid < 80) { float a = PI2 * (float)tid * (1.f / 80.f); float sv, cv; sincosf(a, &sv, &cv); tw[tid] = make_float2(cv, sv); }
    for (int i = tid; i < 41 * 80; i += 256) data[i] = ip[i];
    __syncthreads();
    {
      const int g1 = tid >> 4;
      const int kap = tid & 15;
      float2 F[3][5];
      #pragma unroll
      for (int j = 0; j < 3; j++)
        #pragma unroll
        for (int q = 0; q < 5; q++) F[j][q] = make_float2(0.f, 0.f);
      int rr[3];
      #pragma unroll
      for (int j = 0; j < 3; j++) { int r = g1 + 16 * j; rr[j] = (r <= 40) ? r : 0; }
      int m16 = 0;
      for (int m = 0; m < 16; ++m) {
        float2 t = tw[5 * m16];
        #pragma unroll
        for (int j = 0; j < 3; j++) {
          const float2* rowp = &data[rr[j] * 80 + 5 * m];
          #pragma unroll
          for (int q = 0; q < 5; q++) cfma(F[j][q], rowp[q], t);
        }
        m16 += kap; if (m16 >= 16) m16 -= 16;
      }
      __syncthreads();
      #pragma unroll
      for (int s = 0; s < 5; ++s) {
        const int n2 = kap + 16 * s;
        float2 t1 = tw[n2];
        float2 t2 = tw[(2 * n2) % 80];
        float2 t3 = tw[(3 * n2) % 80];
        float2 t4 = tw[(4 * n2) % 80];
        #pragma unroll
        for (int j = 0; j < 3; j++) {
          const int r = g1 + 16 * j;
          if (r <= 40) {
            float2 a = F[j][0];
            cfma(a, F[j][1], t1);
            cfma(a, F[j][2], t2);
            cfma(a, F[j][3], t3);
            cfma(a, F[j][4], t4);
            data[r * 80 + n2] = a;
          }
        }
      }
    }
    __syncthreads();
    const int r0 = (tid >> 4) * 5;
    const int k0 = (tid & 15) * 5;
    float accR[5][5];
    for (int j = 0; j < 5; j++)
      for (int i = 0; i < 5; i++) accR[j][i] = 0.f;
    {
      int idx[5];
      #pragma unroll
      for (int j = 0; j < 5; j++) idx[j] = r0 + j;
      for (int r = 1; r <= 39; ++r) {
        float2 d[5]; float2 t[5];
        #pragma unroll
        for (int i = 0; i < 5; i++) d[i] = data[r * 80 + k0 + i];
        #pragma unroll
        for (int j = 0; j < 5; j++) t[j] = tw[idx[j]];
        #pragma unroll
        for (int j = 0; j < 5; j++) {
          #pragma unroll
          for (int i = 0; i < 5; i++) {
            accR[j][i] = fmaf(t[j].x, d[i].x, accR[j][i]);
            accR[j][i] = fmaf(-t[j].y, d[i].y, accR[j][i]);
          }
        }
        #pragma unroll
        for (int j = 0; j < 5; j++) { idx[j] += r0 + j; if (idx[j] >= 80) idx[j] -= 80; }
      }
    }
    #pragma unroll
    for (int i = 0; i < 5; i++) {
      float2 b0 = data[k0 + i];
      float2 b40 = data[40 * 80 + k0 + i];
      #pragma unroll
      for (int j = 0; j < 5; j++) {
        float s40 = ((r0 + j) & 1) ? -b40.x : b40.x;
        float res = 2.f * accR[j][i] + b0.x + s40;
        op[(r0 + j) * 80 + k0 + i] = fabsf(res) * (1.f / (float)N_);
      }
    }
  }
}

// ---------------- gate stage A (4-way channel-split, 800 blocks) ----------------
__global__ __launch_bounds__(256) void k_gateA(const float2* __restrict__ zA, const float2* __restrict__ zB,
    int split, int Cin, const float* __restrict__ W1, const float* __restrict__ b1,
    const float* __restrict__ g, const float* __restrict__ bt, float* __restrict__ hid) {
  __shared__ float w[8 * 256];
  __shared__ float red[4][64][9];  // padded to 9 to avoid bank conflicts
  const int tid = threadIdx.x;
  const int grp = tid >> 6, l = tid & 63;
  for (int i = tid; i < 8 * Cin; i += 256) w[i] = W1[i];
  __syncthreads();
  const int p = blockIdx.x * 64 + l;
  const int b = p / N_, n = p % N_;
  const int cpg = Cin / 4;
  float acc[8] = {0.f, 0.f, 0.f, 0.f, 0.f, 0.f, 0.f, 0.f};
  for (int ci = grp * cpg; ci < (grp + 1) * cpg; ci++) {
    const float2* src = (ci < split) ? (zA + ((size_t)b * split + ci) * N_ + n)
                                     : (zB + ((size_t)b * (Cin - split) + (ci - split)) * N_ + n);
    float v = src->x;
    #pragma unroll
    for (int j = 0; j < 8; j++) acc[j] = fmaf(w[j * Cin + ci], v, acc[j]);
  }
  #pragma unroll
  for (int j = 0; j < 8; j++) red[grp][l][j] = acc[j];
  __syncthreads();
  if (grp == 0) {
    #pragma unroll
    for (int j = 0; j < 8; j++) {
      float t = red[0][l][j] + red[1][l][j] + red[2][l][j] + red[3][l][j];
      float y = (t + b1[j]) * (g[j] * BN_SC) + bt[j];
      hid[((size_t)b * 8 + j) * N_ + n] = fmaxf(y, 0.f);
    }
  }
}

// ---------------- gate stage B (co-split over gridDim.y, 64 co per block) ----------------
template <int MODE>
__global__ __launch_bounds__(256) void k_gateB(float2* __restrict__ zA, float2* __restrict__ zB,
    int split, int Cout, const float* __restrict__ W2, const float* __restrict__ b2,
    const float* __restrict__ hid, float* __restrict__ outR, int outCtot, int outCoff) {
  __shared__ float w[64 * 8];
  __shared__ float bb[64];
  const int tid = threadIdx.x;
  const int cobase = blockIdx.y * 64;
  for (int i = tid; i < 64 * 8; i += 256) w[i] = W2[cobase * 8 + i];
  for (int i = tid; i < 64; i += 256) bb[i] = b2[cobase + i];
  __syncthreads();
  const int p = blockIdx.x * 256 + tid;
  const int b = p / N_, n = p % N_;
  float h[8];
  #pragma unroll
  for (int j = 0; j < 8; j++) h[j] = hid[((size_t)b * 8 + j) * N_ + n];
  for (int co = 0; co < 64; co++) {
    const int gco = cobase + co;
    float t = bb[co];
    #pragma unroll
    for (int j = 0; j < 8; j++) t = fmaf(w[co * 8 + j], h[j], t);
    float sg = 1.f / (1.f + expf(-t));
    float2* zp = (gco < split) ? (zA + ((size_t)b * split + gco) * N_ + n)
                               : (zB + ((size_t)b * (Cout - split) + (gco - split)) * N_ + n);
    float2 z = *zp;
    if (MODE == 0) {
      zp->x = z.x * sg; zp->y = z.y * sg;
    } else {
      float m = sg * sqrtf(z.x * z.x + z.y * z.y);
      outR[((size_t)b * outCtot + outCoff + gco) * N_ + n] = gelu_mul(m);
    }
  }
}

// ---------------- 1x1 conv as bf16 MFMA GEMM: 128co x 64pos per block ----------------
__global__ __launch_bounds__(256) void k_conv1x1(const float* __restrict__ inA, const float* __restrict__ inB,
    int split, int Cin, int Cout, const float* __restrict__ W, const float* __restrict__ bias,
    const float* __restrict__ resid, float* __restrict__ out) {
  __shared__ unsigned int xlds[16][68];    // 4.25 KB
  const int tid = threadIdx.x;
  const int lane = tid & 63, wv = tid >> 6;
  const int p0 = blockIdx.x * 64;
  const int b = p0 / N_, n0 = p0 % N_;
  const int laneco = lane & 15, lanek = lane >> 4;
  const int kA = lanek * 8;
  f32x4 acc[2][4];
  #pragma unroll
  for (int g = 0; g < 2; g++)
    #pragma unroll
    for (int f = 0; f < 4; f++) acc[g][f] = (f32x4){0.f, 0.f, 0.f, 0.f};
  for (int cb = 0; cb < Cin; cb += 32) {
    const float* src = (cb < split) ? (inA + ((size_t)b * split + cb) * N_)
                                    : (inB + ((size_t)b * (Cin - split) + (cb - split)) * N_);
    bf16x8 af[2];
    #pragma unroll
    for (int g = 0; g < 2; g++) {
      const float* wp = W + (size_t)(wv * 32 + g * 16 + laneco) * Cin + cb + kA;
      float4 w0 = *(const float4*)wp;
      float4 w1 = *(const float4*)(wp + 4);
      af[g][0] = (short)bf16_rn(w0.x); af[g][1] = (short)bf16_rn(w0.y);
      af[g][2] = (short)bf16_rn(w0.z); af[g][3] = (short)bf16_rn(w0.w);
      af[g][4] = (short)bf16_rn(w1.x); af[g][5] = (short)bf16_rn(w1.y);
      af[g][6] = (short)bf16_rn(w1.z); af[g][7] = (short)bf16_rn(w1.w);
    }
    __syncthreads();   // previous-iter xlds reads complete
    #pragma unroll
    for (int r = 0; r < 4; r++) {
      const int kb = wv * 4 + r;
      float e = src[(size_t)(2 * kb) * N_ + n0 + lane];
      float o = src[(size_t)(2 * kb + 1) * N_ + n0 + lane];
      xlds[kb][lane] = (unsigned int)bf16_rn(e) | ((unsigned int)bf16_rn(o) << 16);
    }
    __syncthreads();
    #pragma unroll
    for (int f = 0; f < 4; f++) {
      const int pos = f * 16 + laneco;
      const int kb0 = lanek * 4;
      union { bf16x8 v; unsigned int u[4]; } bu;
      bu.u[0] = xlds[kb0 + 0][pos];
      bu.u[1] = xlds[kb0 + 1][pos];
      bu.u[2] = xlds[kb0 + 2][pos];
      bu.u[3] = xlds[kb0 + 3][pos];
      #pragma unroll
      for (int g = 0; g < 2; g++)
        acc[g][f] = __builtin_amdgcn_mfma_f32_16x16x32_bf16(af[g], bu.v, acc[g][f], 0, 0, 0);
    }
  }
  #pragma unroll
  for (int g = 0; g < 2; g++) {
    #pragma unroll
    for (int f = 0; f < 4; f++) {
      #pragma unroll
      for (int r = 0; r < 4; r++) {
        const int co = wv * 32 + g * 16 + lanek * 4 + r;
        float v = acc[g][f][r];
        if (bias) v += bias[co];
        const size_t off = ((size_t)b * Cout + co) * N_ + n0 + f * 16 + laneco;
        if (resid) v += resid[off];
        out[off] = v;
      }
    }
  }
}

// ---------------- fused q1/k1/v1 1x1 convs: blockIdx.y selects weight/output set ----------------
__global__ __launch_bounds__(256) void k_conv1x1_qkv(const float* __restrict__ in,
    const float* __restrict__ W0, const float* __restrict__ b0, float* __restrict__ o0,
    const float* __restrict__ W1, const float* __restrict__ b1, float* __restrict__ o1,
    const float* __restrict__ W2, const float* __restrict__ b2, float* __restrict__ o2) {
  __shared__ unsigned int xlds[16][68];
  const float* W    = (blockIdx.y == 0) ? W0 : (blockIdx.y == 1) ? W1 : W2;
  const float* bias = (blockIdx.y == 0) ? b0 : (blockIdx.y == 1) ? b1 : b2;
  float* out        = (blockIdx.y == 0) ? o0 : (blockIdx.y == 1) ? o1 : o2;
  const int tid = threadIdx.x;
  const int lane = tid & 63, wv = tid >> 6;
  const int p0 = blockIdx.x * 64;
  const int b = p0 / N_, n0 = p0 % N_;
  const int laneco = lane & 15, lanek = lane >> 4;
  const int kA = lanek * 8;
  f32x4 acc[2][4];
  #pragma unroll
  for (int g = 0; g < 2; g++)
    #pragma unroll
    for (int f = 0; f < 4; f++) acc[g][f] = (f32x4){0.f, 0.f, 0.f, 0.f};
  for (int cb = 0; cb < 128; cb += 32) {
    const float* src = in + ((size_t)b * 128 + cb) * N_;
    bf16x8 af[2];
    #pragma unroll
    for (int g = 0; g < 2; g++) {
      const float* wp = W + (size_t)(wv * 32 + g * 16 + laneco) * 128 + cb + kA;
      float4 w0 = *(const float4*)wp;
      float4 w1 = *(const float4*)(wp + 4);
      af[g][0] = (short)bf16_rn(w0.x); af[g][1] = (short)bf16_rn(w0.y);
      af[g][2] = (short)bf16_rn(w0.z); af[g][3] = (short)bf16_rn(w0.w);
      af[g][4] = (short)bf16_rn(w1.x); af[g][5] = (short)bf16_rn(w1.y);
      af[g][6] = (short)bf16_rn(w1.z); af[g][7] = (short)bf16_rn(w1.w);
    }
    __syncthreads();
    #pragma unroll
    for (int r = 0; r < 4; r++) {
      const int kb = wv * 4 + r;
      float e = src[(size_t)(2 * kb) * N_ + n0 + lane];
      float o = src[(size_t)(2 * kb + 1) * N_ + n0 + lane];
      xlds[kb][lane] = (unsigned int)bf16_rn(e) | ((unsigned int)bf16_rn(o) << 16);
    }
    __syncthreads();
    #pragma unroll
    for (int f = 0; f < 4; f++) {
      const int pos = f * 16 + laneco;
      const int kb0 = lanek * 4;
      union { bf16x8 v; unsigned int u[4]; } bu;
      bu.u[0] = xlds[kb0 + 0][pos];
      bu.u[1] = xlds[kb0 + 1][pos];
      bu.u[2] = xlds[kb0 + 2][pos];
      bu.u[3] = xlds[kb0 + 3][pos];
      #pragma unroll
      for (int g = 0; g < 2; g++)
        acc[g][f] = __builtin_amdgcn_mfma_f32_16x16x32_bf16(af[g], bu.v, acc[g][f], 0, 0, 0);
    }
  }
  #pragma unroll
  for (int g = 0; g < 2; g++) {
    #pragma unroll
    for (int f = 0; f < 4; f++) {
      #pragma unroll
      for (int r = 0; r < 4; r++) {
        const int co = wv * 32 + g * 16 + lanek * 4 + r;
        float v = acc[g][f][r] + bias[co];
        out[((size_t)b * 128 + co) * N_ + n0 + f * 16 + laneco] = v;
      }
    }
  }
}

// ---------------- grouped conv 3x3(pad1) + 5x5(pad2), groups=64: 4 sets via blockIdx.y ----------------
__global__ __launch_bounds__(256) void k_gconv35_4(
    const float* __restrict__ inQ, const float* __restrict__ w3Q, const float* __restrict__ w5Q, float* __restrict__ outQ,
    const float* __restrict__ inK, const float* __restrict__ w3K, const float* __restrict__ w5K, float* __restrict__ outK,
    const float* __restrict__ inV, const float* __restrict__ w3V, const float* __restrict__ w5V, float* __restrict__ outV,
    const float* __restrict__ inC2, const float* __restrict__ w3C, const float* __restrict__ w5C, float* __restrict__ outC2) {
  __shared__ float tt[2][44][84];
  const float* in; const float* w3; const float* w5; float* out;
  if (blockIdx.y == 0)      { in = inQ;  w3 = w3Q; w5 = w5Q; out = outQ; }
  else if (blockIdx.y == 1) { in = inK;  w3 = w3K; w5 = w5K; out = outK; }
  else if (blockIdx.y == 2) { in = inV;  w3 = w3V; w5 = w5V; out = outV; }
  else                      { in = inC2; w3 = w3C; w5 = w5C; out = outC2; }
  const int blk = blockIdx.x;
  const int b = blk / 128;
  const int rem = blk % 128;
  const int o = rem >> 1, half = rem & 1;
  const int y0 = half * 40;
  const float* i0 = in + ((size_t)b * C_ + 2 * o) * N_;
  const int tid = threadIdx.x;
  for (int i = tid; i < 2 * 44 * 84; i += 256) {
    int ic = i / (44 * 84);
    int r = (i % (44 * 84)) / 84;
    int cc = i % 84;
    int gy = y0 + r - 2, gx = cc - 2;
    float v = 0.f;
    if (gy >= 0 && gy < 80 && gx >= 0 && gx < 80) v = i0[(size_t)ic * N_ + gy * 80 + gx];
    tt[ic][r][cc] = v;
  }
  float w3r[2][9], w5r[2][25];
  #pragma unroll
  for (int ic = 0; ic < 2; ic++) {
    #pragma unroll
    for (int k = 0; k < 9; k++) w3r[ic][k] = w3[(o * 2 + ic) * 9 + k];
    #pragma unroll
    for (int k = 0; k < 25; k++) w5r[ic][k] = w5[(o * 2 + ic) * 25 + k];
  }
  __syncthreads();
  for (int p = tid; p < 3200; p += 256) {
    const int ly = p / 80, x = p % 80;
    float a3 = 0.f, a5 = 0.f;
    #pragma unroll
    for (int ky = 0; ky < 5; ky++) {
      #pragma unroll
      for (int kx = 0; kx < 5; kx++) {
        float v0 = tt[0][ly + ky][x + kx];
        float v1 = tt[1][ly + ky][x + kx];
        a5 = fmaf(v0, w5r[0][ky * 5 + kx], a5);
        a5 = fmaf(v1, w5r[1][ky * 5 + kx], a5);
        if (ky >= 1 && ky < 4 && kx >= 1 && kx < 4) {
          int k3 = (ky - 1) * 3 + (kx - 1);
          a3 = fmaf(v0, w3r[0][k3], a3);
          a3 = fmaf(v1, w3r[1][k3], a3);
        }
      }
    }
    const int yy = y0 + ly;
    out[((size_t)b * C_ + o) * N_ + yy * 80 + x] = a3;
    out[((size_t)b * C_ + 64 + o) * N_ + yy * 80 + x] = a5;
  }
}

// ---------------- depthwise conv3x3 (pad1) + gelu(x)*x: zero-padded halo, 40-row halves ----------------
__global__ __launch_bounds__(256) void k_dwconv3_gelu(const float* __restrict__ in, const float* __restrict__ w,
    float* __restrict__ out, int Cn, int outCtot, int outCoff) {
  __shared__ float tt[42][82];
  const int blk = blockIdx.x;
  const int b = blk / (2 * Cn);
  const int rem = blk % (2 * Cn);
  const int c = rem >> 1, half = rem & 1;
  const int y0 = half * 40;
  const float* ip = in + ((size_t)b * Cn + c) * N_;
  const int tid = threadIdx.x;
  for (int i = tid; i < 42 * 82; i += 256) {
    int r = i / 82, cc = i % 82;
    int gy = y0 + r - 1, gx = cc - 1;
    float v = 0.f;
    if (gy >= 0 && gy < 80 && gx >= 0 && gx < 80) v = ip[gy * 80 + gx];
    tt[r][cc] = v;
  }
  float wr[9];
  #pragma unroll
  for (int k = 0; k < 9; k++) wr[k] = w[c * 9 + k];
  __syncthreads();
  float* op = out + ((size_t)b * outCtot + outCoff + c) * N_;
  for (int p = tid; p < 3200; p += 256) {
    const int ly = p / 80, x = p % 80;
    float a = 0.f;
    #pragma unroll
    for (int ky = 0; ky < 3; ky++) {
      #pragma unroll
      for (int kx = 0; kx < 3; kx++)
        a = fmaf(tt[ly + ky][x + kx], wr[ky * 3 + kx], a);
    }
    op[(y0 + ly) * 80 + x] = gelu_mul(a);
  }
}

// ---------------- ff_dw2: groups=128, 2-in/2-out per group, 3x3 pad1: zero-padded halo, halves ----------------
__global__ __launch_bounds__(256) void k_ffdw2(const float* __restrict__ in, const float* __restrict__ w,
                                               float* __restrict__ out) {
  __shared__ float tt[2][42][82];
  const int blk = blockIdx.x;
  const int b = blk / 256;
  const int rem = blk % 256;
  const int g = rem >> 1, half = rem & 1;
  const int y0 = half * 40;
  const float* i0 = in + ((size_t)b * 256 + 2 * g) * N_;
  const int tid = threadIdx.x;
  for (int i = tid; i < 2 * 42 * 82; i += 256) {
    int ic = i / (42 * 82);
    int r = (i % (42 * 82)) / 82;
    int cc = i % 82;
    int gy = y0 + r - 1, gx = cc - 1;
    float v = 0.f;
    if (gy >= 0 && gy < 80 && gx >= 0 && gx < 80) v = i0[(size_t)ic * N_ + gy * 80 + gx];
    tt[ic][r][cc] = v;
  }
  float w0[2][9], w1[2][9];
  #pragma unroll
  for (int ic = 0; ic < 2; ic++) {
    #pragma unroll
    for (int k = 0; k < 9; k++) {
      w0[ic][k] = w[((2 * g) * 2 + ic) * 9 + k];
      w1[ic][k] = w[((2 * g + 1) * 2 + ic) * 9 + k];
    }
  }
  __syncthreads();
  for (int p = tid; p < 3200; p += 256) {
    const int ly = p / 80, x = p % 80;
    float a0 = 0.f, a1 = 0.f;
    #pragma unroll
    for (int ky = 0; ky < 3; ky++) {
      #pragma unroll
      for (int kx = 0; kx < 3; kx++) {
        float v0 = tt[0][ly + ky][x + kx], v1 = tt[1][ly + ky][x + kx];
        int k = ky * 3 + kx;
        a0 = fmaf(v0, w0[0][k], a0); a0 = fmaf(v1, w0[1][k], a0);
        a1 = fmaf(v0, w1[0][k], a1); a1 = fmaf(v1, w1[1][k], a1);
      }
    }
    const int yy = y0 + ly;
    out[((size_t)b * 256 + 2 * g) * N_ + yy * 80 + x] = a0;
    out[((size_t)b * 256 + 2 * g + 1) * N_ + yy * 80 + x] = a1;
  }
}

// ---------------- merged per-row L2 norms (two input sets via blockIdx routing) ----------------
__global__ __launch_bounds__(256) void k_rownorm_r2(const float* __restrict__ inA, float* __restrict__ nrmA,
                                                    const float* __restrict__ inB, float* __restrict__ nrmB) {
  __shared__ float red[256];
  int row = blockIdx.x;
  const float* p; float* o;
  if (row < B_ * C_) { p = inA + (size_t)row * N_; o = nrmA + row; }
  else { row -= B_ * C_; p = inB + (size_t)row * N_; o = nrmB + row; }
  float s = 0.f;
  for (int i = threadIdx.x; i < N_; i += 256) { float v = p[i]; s = fmaf(v, v, s); }
  red[threadIdx.x] = s; __syncthreads();
  for (int st = 128; st > 0; st >>= 1) { if (threadIdx.x < st) red[threadIdx.x] += red[threadIdx.x + st]; __syncthreads(); }
  if (threadIdx.x == 0) *o = fmaxf(sqrtf(red[0]), 1e-12f);
}

// ---------------- F-attention partials, symmetric (Q==K): 36 upper-triangle tiles ----------------
__global__ __launch_bounds__(256) void k_attn_part_sym(const float2* __restrict__ Ab, float2* __restrict__ part) {
  const int bh = blockIdx.z;
  const int b = bh / H_, h = bh % H_;
  const int wave = threadIdx.x >> 6, lane = threadIdx.x & 63;
  int w = blockIdx.x * 4 + wave;      // 0..35 upper-triangle tile id
  int ci = 0;
  while (w >= 8 - ci) { w -= 8 - ci; ci++; }
  const int c0 = ci * 4, d0 = (ci + w) * 4;
  const size_t hb = ((size_t)b * C_ + h * 32) * N_;
  const float2* Ap = Ab + hb;
  float2 acc[4][4];
  #pragma unroll
  for (int j = 0; j < 4; j++)
    #pragma unroll
    for (int i = 0; i < 4; i++) acc[j][i] = make_float2(0.f, 0.f);
  const int nb = blockIdx.y * (N_ / NSPL) + lane;
  for (int it = 0; it < (N_ / NSPL) / 64; ++it) {
    const int n = nb + it * 64;
    float2 av[4], bv[4];
    #pragma unroll
    for (int j = 0; j < 4; j++) av[j] = Ap[(size_t)(c0 + j) * N_ + n];
    #pragma unroll
    for (int i = 0; i < 4; i++) bv[i] = Ap[(size_t)(d0 + i) * N_ + n];
    #pragma unroll
    for (int j = 0; j < 4; j++)
      #pragma unroll
      for (int i = 0; i < 4; i++) cfma(acc[j][i], av[j], bv[i]);
  }
  float2* pp = part + (size_t)(bh * NSPL + blockIdx.y) * 1024;
  #pragma unroll
  for (int j = 0; j < 4; j++) {
    #pragma unroll
    for (int i = 0; i < 4; i++) {
      float rx = acc[j][i].x, ry = acc[j][i].y;
      for (int off = 32; off; off >>= 1) { rx += __shfl_xor(rx, off); ry += __shfl_xor(ry, off); }
      if (lane == 0) {
        float2 v = make_float2(rx, ry);
        pp[(d0 + i) * 32 + (c0 + j)] = v;   // mirror (S symmetric)
        pp[(c0 + j) * 32 + (d0 + i)] = v;
      }
    }
  }
}
__global__ __launch_bounds__(256) void k_attn_part_r(const float* __restrict__ Ab, const float* __restrict__ Bb,
                                                     float* __restrict__ part) {
  const int bh = blockIdx.z;
  const int b = bh / H_, h = bh % H_;
  const int wave = threadIdx.x >> 6, lane = threadIdx.x & 63;
  const int tile = blockIdx.x * 4 + wave;
  const int c0 = (tile >> 3) * 4, d0 = (tile & 7) * 4;
  const size_t hb = ((size_t)b * C_ + h * 32) * N_;
  const float* Ap = Ab + hb;
  const float* Bp = Bb + hb;
  float acc[4][4];
  #pragma unroll
  for (int j = 0; j < 4; j++)
    #pragma unroll
    for (int i = 0; i < 4; i++) acc[j][i] = 0.f;
  const int nb = blockIdx.y * (N_ / NSPL) + lane;
  for (int it = 0; it < (N_ / NSPL) / 64; ++it) {
    const int n = nb + it * 64;
    float av[4], bv[4];
    #pragma unroll
    for (int j = 0; j < 4; j++) av[j] = Ap[(size_t)(c0 + j) * N_ + n];
    #pragma unroll
    for (int i = 0; i < 4; i++) bv[i] = Bp[(size_t)(d0 + i) * N_ + n];
    #pragma unroll
    for (int j = 0; j < 4; j++)
      #pragma unroll
      for (int i = 0; i < 4; i++) acc[j][i] = fmaf(av[j], bv[i], acc[j][i]);
  }
  float* pp = part + (size_t)(bh * NSPL + blockIdx.y) * 1024;
  #pragma unroll
  for (int j = 0; j < 4; j++) {
    #pragma unroll
    for (int i = 0; i < 4; i++) {
      float r = acc[j][i];
      for (int off = 32; off; off >>= 1) r += __shfl_xor(r, off);
      if (lane == 0) pp[(c0 + j) * 32 + d0 + i] = r;
    }
  }
}

// ---------------- reduce partials, scale, softmax ----------------
template <int CPLX>
__global__ void k_attn_soft(const float* __restrict__ part, const float* __restrict__ nA,
                            const float* __restrict__ nB, const float* __restrict__ temp,
                            float* __restrict__ attn) {
  const int rc = blockIdx.x;          // bh*32 + c
  const int bh = rc >> 5, c = rc & 31;
  const int b = bh / H_, h = bh % H_;
  const int d = threadIdx.x;          // 64 threads; group >=32 unused
  float re = -1e30f, im = -1e30f;
  if (d < 32) {
    re = 0.f; im = 0.f;
    if (CPLX) {
      const float2* pp = (const float2*)part;
      for (int kc = 0; kc < NSPL; kc++) { float2 v = pp[(size_t)(bh * NSPL + kc) * 1024 + c * 32 + d]; re += v.x; im += v.y; }
    } else {
      for (int kc = 0; kc < NSPL; kc++) re += part[(size_t)(bh * NSPL + kc) * 1024 + c * 32 + d];
    }
    float sc = temp[h] / (nA[b * C_ + h * 32 + c] * nB[b * C_ + h * 32 + d]);
    re *= sc; im *= sc;
  }
  float m = re;
  for (int o = 16; o; o >>= 1) m = fmaxf(m, __shfl_xor(m, o, 32));
  float e = expf(re - m);
  float s = e;
  for (int o = 16; o; o >>= 1) s += __shfl_xor(s, o, 32);
  float vr = e / s;
  float mi = im;
  for (int o = 16; o; o >>= 1) mi = fmaxf(mi, __shfl_xor(mi, o, 32));
  float ei = expf(im - mi);
  float si = ei;
  for (int o = 16; o; o >>= 1) si += __shfl_xor(si, o, 32);
  float vi = ei / si;
  if (d < 32) {
    if (CPLX) ((float2*)attn)[(size_t)(bh * 32 + c) * 32 + d] = make_float2(vr, vi);
    else attn[(size_t)(bh * 32 + c) * 32 + d] = vr;
  }
}

// ---------------- fused PV + 32-point IDFT along c: out[cp,n] = (1/32) sum_c pv[c,n] e^{2pi i c cp/32} ----------------
__global__ __launch_bounds__(256) void k_pv_idft32(const float2* __restrict__ attn, const float2* __restrict__ V,
                                                   float2* __restrict__ out) {
  __shared__ float2 at[32][32];
  __shared__ float2 tw[32];
  const int bh = blockIdx.x;
  const int b = bh / H_, h = bh % H_;
  const int n = blockIdx.y * 256 + threadIdx.x;
  if (threadIdx.x < 32) { float a = PI2 * (float)threadIdx.x * (1.f / 32.f); float sv, cv; sincosf(a, &sv, &cv); tw[threadIdx.x] = make_float2(cv, sv); }
  for (int i = threadIdx.x; i < 1024; i += 256) at[i >> 5][i & 31] = attn[(size_t)bh * 1024 + i];
  __syncthreads();
  const size_t hb = ((size_t)b * C_ + h * 32) * N_;
  const float2* Vp = V + hb;
  float2 acc[32];
  #pragma unroll
  for (int c = 0; c < 32; c++) acc[c] = make_float2(0.f, 0.f);
  for (int dd = 0; dd < 32; dd++) {
    float2 v = Vp[(size_t)dd * N_ + n];
    #pragma unroll
    for (int c = 0; c < 32; c++) cfma(acc[c], at[c][dd], v);
  }
  // in-register radix-2 32-point IDFT along c (same summation order as the old k_idft32)
  float2* Op = out + hb;
  for (int cp = 0; cp < 16; cp++) {
    float2 E = make_float2(0.f, 0.f), O = make_float2(0.f, 0.f);
    const int inc = (2 * cp) & 31;
    int idx = 0;
    #pragma unroll
    for (int m = 0; m < 16; m++) {
      cfma(E, acc[2 * m], tw[idx]);
      cfma(O, acc[2 * m + 1], tw[idx]);
      idx = (idx + inc) & 31;
    }
    float2 u = cmul(tw[cp], O);
    Op[(size_t)cp * N_ + n]        = make_float2((E.x + u.x) * (1.f / 32.f), (E.y + u.y) * (1.f / 32.f));
    Op[(size_t)(cp + 16) * N_ + n] = make_float2((E.x - u.x) * (1.f / 32.f), (E.y - u.y) * (1.f / 32.f));
  }
}

__global__ __launch_bounds__(256) void k_pv_r(const float* __restrict__ attn, const float* __restrict__ V,
                                              float* __restrict__ out) {
  __shared__ float at[32][32];
  const int bh = blockIdx.x;
  const int b = bh / H_, h = bh % H_;
  const int n = blockIdx.y * 256 + threadIdx.x;
  for (int i = threadIdx.x; i < 1024; i += 256) at[i >> 5][i & 31] = attn[(size_t)bh * 1024 + i];
  __syncthreads();
  const size_t hb = ((size_t)b * C_ + h * 32) * N_;
  const float* Vp = V + hb;
  float acc[32];
  #pragma unroll
  for (int c = 0; c < 32; c++) acc[c] = 0.f;
  for (int dd = 0; dd < 32; dd++) {
    float v = Vp[(size_t)dd * N_ + n];
    #pragma unroll
    for (int c = 0; c < 32; c++) acc[c] = fmaf(at[c][dd], v, acc[c]);
  }
  float* Op = out + hb;
  #pragma unroll
  for (int c = 0; c < 32; c++) Op[(size_t)c * N_ + n] = acc[c];
}

extern "C" void kernel_launch(void* const* d_in, const int* in_sizes, int n_in,
                              void* d_out, int out_size, void* d_ws, size_t ws_size,
                              hipStream_t stream) {
  (void)in_sizes; (void)n_in; (void)out_size; (void)ws_size;
  const float* x       = (const float*)d_in[0];
  const float* ln1_w   = (const float*)d_in[1];
  const float* ln2_w   = (const float*)d_in[2];
  const float* ln1_b   = (const float*)d_in[3];
  const float* ln2_b   = (const float*)d_in[4];
  const float* f_temp  = (const float*)d_in[5];
  const float* s_temp  = (const float*)d_in[6];
  const float* f_proj  = (const float*)d_in[7];
  const float* s_proj  = (const float*)d_in[8];
  const float* f_w1    = (const float*)d_in[9];
  const float* f_wb1   = (const float*)d_in[10];
  const float* f_bng   = (const float*)d_in[11];
  const float* f_bnb   = (const float*)d_in[12];
  const float* f_w2    = (const float*)d_in[13];
  const float* f_wb2   = (const float*)d_in[14];
  const float* s_q1_w  = (const float*)d_in[15];
  const float* s_q1_b  = (const float*)d_in[16];
  const float* s_k1_w  = (const float*)d_in[17];
  const float* s_k1_b  = (const float*)d_in[18];
  const float* s_v1_w  = (const float*)d_in[19];
  const float* s_v1_b  = (const float*)d_in[20];
  const float* s_q3_w  = (const float*)d_in[21];
  const float* s_k3_w  = (const float*)d_in[22];
  const float* s_v3_w  = (const float*)d_in[23];
  const float* s_c3_w  = (const float*)d_in[24];
  const float* s_q5_w  = (const float*)d_in[25];
  const float* s_k5_w  = (const float*)d_in[26];
  const float* s_v5_w  = (const float*)d_in[27];
  const float* s_c5_w  = (const float*)d_in[28];
  const float* ffdw1_w = (const float*)d_in[29];
  const float* ffdw2_w = (const float*)d_in[30];
  const float* ffproj  = (const float*)d_in[31];
  const float* ffg_w1  = (const float*)d_in[32];
  const float* ffg_b1  = (const float*)d_in[33];
  const float* ffg_bng = (const float*)d_in[34];
  const float* ffg_bnb = (const float*)d_in[35];
  const float* ffg_w2  = (const float*)d_in[36];
  const float* ffg_b2  = (const float*)d_in[37];
  const float* ffg1_w1 = (const float*)d_in[38];
  const float* ffg1_b1 = (const float*)d_in[39];
  const float* ffg1_bng= (const float*)d_in[40];
  const float* ffg1_bnb= (const float*)d_in[41];
  const float* ffg1_w2 = (const float*)d_in[42];
  const float* ffg1_b2 = (const float*)d_in[43];

  // workspace layout (floats). Requires ~267 MB of d_ws.
  float* ws = (float*)d_ws;
  const size_t R = (size_t)B_ * C_ * N_;   // 6,553,600 floats per [B,128,N] image set
  float* xn   = ws;            // R
  float* acc  = ws + R;        // R
  float* bufA = ws + 2 * R;    // 2R (complex [B,128,N] or real [B,256,N])
  float* bufB = ws + 4 * R;    // 2R
  float* bufC = ws + 6 * R;    // 2R
  float* bufD = ws + 8 * R;    // 2R
  float* sm   = ws + 10 * R;   // small pool
  float* nrmQ = sm;                    // 1024
  float* nrmK = sm + 1024;             // 1024
  float* hid  = sm + 2048;             // B*8*N = 409600
  float* part = sm + 2048 + 409600;    // 524288 (float2[131072] used for cplx)
  float* attb = part + 524288;         // 65536 (float2[32768] for cplx)

  dim3 blk(256);
  const int GCONV = P_ / 64;   // 800 blocks, 128co x 64pos MFMA tiles
  const int GLN = P_ / 64;     // 800 blocks for layernorm / gateA
  const int NIMG = B_ * C_;    // 1024
  const dim3 gattn(16, NSPL, B_ * H_);
  const dim3 gattn_sym(9, NSPL, B_ * H_);   // 36 upper-triangle tiles / 4 waves

  // ===== xn = LayerNorm(x) ; xf = fft2(xn) with fused row-norm =====
  k_layernorm<<<GLN, blk, 0, stream>>>(x, ln1_w, ln1_b, xn);
  k_fft2_r2c<<<NIMG, blk, 0, stream>>>(xn, (float2*)bufA, C_, C_, 0, nullptr, 0, NIMG, nrmQ);

  // ===== Attention_F =====
  k_attn_part_sym<<<gattn_sym, blk, 0, stream>>>((const float2*)bufA, (float2*)part);
  k_attn_soft<1><<<B_ * C_, 64, 0, stream>>>(part, nrmQ, nrmQ, f_temp, attb);
  // fused PV + idft32: writes bufC directly (bufB roundtrip eliminated)
  k_pv_idft32<<<dim3(B_ * H_, N_ / 256), blk, 0, stream>>>((const float2*)attb, (const float2*)bufA, (float2*)bufC);
  // gated branch first (reads bufA pre/post scale), then merged idft6400+ifft2
  k_gateA<<<GLN, blk, 0, stream>>>((const float2*)bufA, (const float2*)bufA, C_, C_, f_w1, f_wb1, f_bng, f_bnb, hid);
  k_gateB<0><<<dim3(P_ / 256, 2), blk, 0, stream>>>((float2*)bufA, (float2*)bufA, C_, C_, f_w2, f_wb2, hid, nullptr, 0, 0);
  k_iff_combo<<<2 * NIMG, blk, 0, stream>>>((const float2*)bufC, bufD, (const float2*)bufA, bufD + R);
  // a_f: acc = x + f_proj(concat(out_f, out_f_l))
  k_conv1x1<<<GCONV, blk, 0, stream>>>(bufD, bufD + R, 128, 256, 128, f_proj, nullptr, x, acc);

  // ===== Attention_S =====
  // fused q1/k1/v1 (one 2400-block dispatch; blockIdx.y routes weight/output set)
  k_conv1x1_qkv<<<dim3(GCONV, 3), blk, 0, stream>>>(xn,
      s_q1_w, s_q1_b, bufA, s_k1_w, s_k1_b, bufA + R, s_v1_w, s_v1_b, bufB);
  // fused qs/ks/vs/cs grouped convs (4 sets; cs output redirected to bufD+R -> no conflicts)
  k_gconv35_4<<<dim3(B_ * 128, 4), blk, 0, stream>>>(
      bufA,     s_q3_w, s_q5_w, bufB + R,
      bufA + R, s_k3_w, s_k5_w, bufC,
      bufB,     s_v3_w, s_v5_w, bufC + R,
      xn,       s_c3_w, s_c5_w, bufD + R);
  // merged rownorms (qs -> nrmQ, ks -> nrmK)
  k_rownorm_r2<<<2 * B_ * C_, blk, 0, stream>>>(bufB + R, nrmQ, bufC, nrmK);
  k_attn_part_r<<<gattn, blk, 0, stream>>>(bufB + R, bufC, part);
  k_attn_soft<0><<<B_ * C_, 64, 0, stream>>>(part, nrmQ, nrmK, s_temp, attb);
  k_pv_r<<<dim3(B_ * H_, N_ / 256), blk, 0, stream>>>(attb, bufC + R, bufA);      // out_s -> A.lo
  // a_s: acc += s_proj(concat(out_s, out_s_l))  (out_s_l lives in bufD+R)
  k_conv1x1<<<GCONV, blk, 0, stream>>>(bufA, bufD + R, 128, 256, 128, s_proj, nullptr, acc, acc);

  // ===== FeedForward =====
  k_layernorm<<<GLN, blk, 0, stream>>>(acc, ln2_w, ln2_b, xn);                    // xn2
  k_fft2_r2c<<<NIMG, blk, 0, stream>>>(xn, (float2*)bufA, C_, C_, 0, nullptr, 0, NIMG, nullptr);  // xf2
  k_gateA<<<GLN, blk, 0, stream>>>((const float2*)bufA, (const float2*)bufA, C_, C_, ffg_w1, ffg_b1, ffg_bng, ffg_bnb, hid);
  k_gateB<1><<<dim3(P_ / 256, 2), blk, 0, stream>>>((float2*)bufA, (float2*)bufA, C_, C_, ffg_w2, ffg_b2, hid, bufB, 256, 0); // x_f_g -> cat.lo
  k_dwconv3_gelu<<<B_ * 256, blk, 0, stream>>>(xn, ffdw1_w, bufB, 128, 256, 128); // x_s_g -> cat.hi
  // cf = fft2(cat): one merged 2048-block dispatch (lo -> bufA, hi -> bufC)
  k_fft2_r2c<<<2 * NIMG, blk, 0, stream>>>(bufB, (float2*)bufA, 128, 256, 0, (float2*)bufC, 128, NIMG, nullptr);
  k_gateA<<<GLN, blk, 0, stream>>>((const float2*)bufA, (const float2*)bufC, 128, 256, ffg1_w1, ffg1_b1, ffg1_bng, ffg1_bnb, hid);
  k_gateB<0><<<dim3(P_ / 256, 4), blk, 0, stream>>>((float2*)bufA, (float2*)bufC, 128, 256, ffg1_w2, ffg1_b2, hid, nullptr, 0, 0);
  // x_f2b: merged 2048-block ifft2 pair (bufA -> bufD coff0, bufC -> bufD coff128)
  k_ifft2_abs<<<2 * NIMG, blk, 0, stream>>>((const float2*)bufA, bufD, 128, 256, 0, (const float2*)bufC, 128, NIMG);
  k_ffdw2<<<B_ * 256, blk, 0, stream>>>(bufB, ffdw2_w, bufA);                     // x_s2b (real [B,256,N] in A)
  // out = x1 + ff_proj(concat(x_f2b, x_s2b))
  k_conv1x1<<<GCONV, blk, 0, stream>>>(bufD, bufA, 256, 512, 128, ffproj, nullptr, acc, (float*)d_out);
}

// Round 23
// 946.046 us; speedup vs baseline: 1.2959x; 1.0178x over previous
//
#include <hip/hip_runtime.h>
#include <math.h>

#define DI __device__ __forceinline__

constexpr int B_ = 8, C_ = 128, H_ = 4, S_ = 80, N_ = 6400;
constexpr int P_ = B_ * N_;                 // 51200 spatial positions
constexpr int NSPL = 2;                     // n-chunks for attention partials
constexpr float PI2 = 6.283185307179586f;
constexpr float BN_SC = 0.9999950000374997f;  // 1/sqrt(1+1e-5)

typedef __attribute__((ext_vector_type(8))) short bf16x8;
typedef __attribute__((ext_vector_type(4))) float f32x4;

DI void cfma(float2& a, float2 u, float2 v) {
  a.x = fmaf(u.x, v.x, a.x); a.x = fmaf(-u.y, v.y, a.x);
  a.y = fmaf(u.x, v.y, a.y); a.y = fmaf(u.y, v.x, a.y);
}
DI float2 cmul(float2 u, float2 v) {
  return make_float2(u.x * v.x - u.y * v.y, u.x * v.y + u.y * v.x);
}
DI float gelu_mul(float m) {  // gelu(m, exact) * m
  return 0.5f * m * (1.f + erff(m * 0.7071067811865476f)) * m;
}
DI unsigned short bf16_rn(float f) {  // round-to-nearest-even fp32 -> bf16
  union { float f; unsigned int u; } v; v.f = f;
  unsigned int u = v.u;
  return (unsigned short)((u + 0x7fffu + ((u >> 16) & 1u)) >> 16);
}

// ---------------- LayerNorm over channel dim (4-way channel-split, 800 blocks) ----------------
__global__ __launch_bounds__(256) void k_layernorm(const float* __restrict__ in,
    const float* __restrict__ w, const float* __restrict__ bb, float* __restrict__ out) {
  __shared__ float redS[4][64], redS2[4][64];
  __shared__ float muv[64], invv[64];
  const int tid = threadIdx.x;
  const int g = tid >> 6, l = tid & 63;
  const int p = blockIdx.x * 64 + l;
  const int b = p / N_, n = p % N_;
  const float* xp = in + (size_t)b * C_ * N_ + n;
  float s = 0.f, s2 = 0.f;
  for (int c = g * 32; c < g * 32 + 32; c++) {
    float v = xp[(size_t)c * N_];
    s += v; s2 = fmaf(v, v, s2);
  }
  redS[g][l] = s; redS2[g][l] = s2;
  __syncthreads();
  if (g == 0) {
    float ts  = redS[0][l] + redS[1][l] + redS[2][l] + redS[3][l];
    float ts2 = redS2[0][l] + redS2[1][l] + redS2[2][l] + redS2[3][l];
    float mu = ts * (1.f / C_);
    float var = ts2 * (1.f / C_) - mu * mu;
    muv[l] = mu; invv[l] = rsqrtf(var + 1e-5f);
  }
  __syncthreads();
  const float mu = muv[l], inv = invv[l];
  float* op = out + (size_t)b * C_ * N_ + n;
  for (int c = g * 32; c < g * 32 + 32; c++) {
    float v = xp[(size_t)c * N_];
    op[(size_t)c * N_] = (v - mu) * inv * w[c] + bb[c];
  }
}

// ============ register-tiled 80x80 2D DFT kernels (5x16 Cooley-Tukey) ============

// ---------------- 2D FFT (80x80) real->complex, 5x16 CT both passes ----------------
__global__ __launch_bounds__(256) void k_fft2_r2c(const float* __restrict__ in, float2* __restrict__ out,
                                                  int nCh, int inCtot, int inCoff,
                                                  float2* __restrict__ out2, int inCoff2, int nimg,
                                                  float* __restrict__ nrm) {
  __shared__ float2 data[N_];
  __shared__ float2 tw[80];
  int img = blockIdx.x;
  float2* op;
  int coff;
  if (img >= nimg) { img -= nimg; op = out2 + (size_t)img * N_; coff = inCoff2; }
  else { op = out + (size_t)img * N_; coff = inCoff; }
  const int b = img / nCh, ch = img % nCh;
  const float* ip = in + ((size_t)b * inCtot + coff + ch) * N_;
  const int tid = threadIdx.x;
  float* dataR = (float*)data;
  if (tid < 80) { float a = -PI2 * (float)tid * (1.f / 80.f); float sv, cv; sincosf(a, &sv, &cv); tw[tid] = make_float2(cv, sv); }
  for (int i = tid; i < N_; i += 256) dataR[i] = ip[i];
  __syncthreads();
  const int rg = tid >> 4;
  const int kap = tid & 15;
  const int r0 = rg * 5;
  {
    float2 F[5][5];   // [j][q]
    #pragma unroll
    for (int j = 0; j < 5; j++)
      #pragma unroll
      for (int q = 0; q < 5; q++) F[j][q] = make_float2(0.f, 0.f);
    int m16 = 0;
    for (int m = 0; m < 16; ++m) {
      float2 t = tw[5 * m16];
      #pragma unroll
      for (int j = 0; j < 5; j++) {
        const float* row = &dataR[(r0 + j) * 80 + 5 * m];
        #pragma unroll
        for (int q = 0; q < 5; q++) {
          float xv = row[q];
          F[j][q].x = fmaf(xv, t.x, F[j][q].x);
          F[j][q].y = fmaf(xv, t.y, F[j][q].y);
        }
      }
      m16 += kap; if (m16 >= 16) m16 -= 16;
    }
    __syncthreads();   // all real reads done before complex overwrite
    #pragma unroll
    for (int s = 0; s < 5; ++s) {
      const int k = kap + 16 * s;
      if (k <= 40) {
        float2 t1 = tw[k];
        float2 t2 = tw[(2 * k) % 80];
        float2 t3 = tw[(3 * k) % 80];
        float2 t4 = tw[(4 * k) % 80];
        #pragma unroll
        for (int j = 0; j < 5; j++) {
          float2 a = F[j][0];
          cfma(a, F[j][1], t1);
          cfma(a, F[j][2], t2);
          cfma(a, F[j][3], t3);
          cfma(a, F[j][4], t4);
          data[(r0 + j) * 80 + k] = a;
          if (k >= 1 && k <= 39) data[(r0 + j) * 80 + 80 - k] = make_float2(a.x, -a.y);
        }
      }
    }
  }
  __syncthreads();
  const int k0 = (tid & 15) * 5;
  const int kap2 = tid >> 4;
  float snrm = 0.f;
  {
    float2 G[5][5];   // [q][i]
    #pragma unroll
    for (int q = 0; q < 5; q++)
      #pragma unroll
      for (int i = 0; i < 5; i++) G[q][i] = make_float2(0.f, 0.f);
    int m16 = 0;
    for (int m = 0; m < 16; ++m) {
      float2 t = tw[5 * m16];
      #pragma unroll
      for (int q = 0; q < 5; q++) {
        const float2* rowp = &data[(5 * m + q) * 80 + k0];
        #pragma unroll
        for (int i = 0; i < 5; i++) cfma(G[q][i], rowp[i], t);
      }
      m16 += kap2; if (m16 >= 16) m16 -= 16;
    }
    #pragma unroll
    for (int s = 0; s < 5; ++s) {
      const int k1 = kap2 + 16 * s;
      if (k1 <= 40) {
        float2 t1 = tw[k1];
        float2 t2 = tw[(2 * k1) % 80];
        float2 t3 = tw[(3 * k1) % 80];
        float2 t4 = tw[(4 * k1) % 80];
        const float wgt = (k1 == 0 || k1 == 40) ? 1.f : 2.f;
        #pragma unroll
        for (int i = 0; i < 5; i++) {
          float2 y = G[0][i];
          cfma(y, G[1][i], t1);
          cfma(y, G[2][i], t2);
          cfma(y, G[3][i], t3);
          cfma(y, G[4][i], t4);
          const int k2 = k0 + i;
          op[k1 * 80 + k2] = y;
          if (k1 >= 1 && k1 <= 39) {
            const int m2 = (k2 == 0) ? 0 : 80 - k2;
            op[(80 - k1) * 80 + m2] = make_float2(y.x, -y.y);
          }
          snrm += wgt * (y.x * y.x + y.y * y.y);
        }
      }
    }
  }
  if (nrm) {   // fused per-image L2 norm (mirrored halves contribute 2x)
    __syncthreads();
    float* red = (float*)data;
    red[tid] = snrm;
    __syncthreads();
    for (int st = 128; st > 0; st >>= 1) { if (tid < st) red[tid] += red[tid + st]; __syncthreads(); }
    if (tid == 0) nrm[img] = fmaxf(sqrtf(red[0]), 1e-12f);
  }
}

// ---------------- 2D IFFT (80x80) of HERMITIAN input -> |real|; rows 0..40 only (26.9 KB LDS) ----------------
__global__ __launch_bounds__(256) void k_ifft2_abs(const float2* __restrict__ in, float* __restrict__ out,
                                                   int inC, int outCtot, int outCoff,
                                                   const float2* __restrict__ in2, int outCoff2, int nimg) {
  __shared__ float2 data[41 * 80];   // only rows 0..40 are ever used
  __shared__ float2 tw[80];
  int img = blockIdx.x;
  const float2* ip;
  int coff;
  if (img >= nimg) { img -= nimg; ip = in2 + (size_t)img * N_; coff = outCoff2; }
  else { ip = in + (size_t)img * N_; coff = outCoff; }
  const int b = img / inC, ch = img % inC;
  float* op = out + ((size_t)b * outCtot + coff + ch) * N_;
  const int tid = threadIdx.x;
  if (tid < 80) { float a = PI2 * (float)tid * (1.f / 80.f); float sv, cv; sincosf(a, &sv, &cv); tw[tid] = make_float2(cv, sv); }
  for (int i = tid; i < 41 * 80; i += 256) data[i] = ip[i];
  __syncthreads();
  {
    const int g1 = tid >> 4;
    const int kap = tid & 15;
    float2 F[3][5];
    #pragma unroll
    for (int j = 0; j < 3; j++)
      #pragma unroll
      for (int q = 0; q < 5; q++) F[j][q] = make_float2(0.f, 0.f);
    int rr[3];
    #pragma unroll
    for (int j = 0; j < 3; j++) { int r = g1 + 16 * j; rr[j] = (r <= 40) ? r : 0; }
    int m16 = 0;
    for (int m = 0; m < 16; ++m) {
      float2 t = tw[5 * m16];
      #pragma unroll
      for (int j = 0; j < 3; j++) {
        const float2* rowp = &data[rr[j] * 80 + 5 * m];
        #pragma unroll
        for (int q = 0; q < 5; q++) cfma(F[j][q], rowp[q], t);
      }
      m16 += kap; if (m16 >= 16) m16 -= 16;
    }
    __syncthreads();   // reads complete before overwrite
    #pragma unroll
    for (int s = 0; s < 5; ++s) {
      const int n2 = kap + 16 * s;
      float2 t1 = tw[n2];
      float2 t2 = tw[(2 * n2) % 80];
      float2 t3 = tw[(3 * n2) % 80];
      float2 t4 = tw[(4 * n2) % 80];
      #pragma unroll
      for (int j = 0; j < 3; j++) {
        const int r = g1 + 16 * j;
        if (r <= 40) {
          float2 a = F[j][0];
          cfma(a, F[j][1], t1);
          cfma(a, F[j][2], t2);
          cfma(a, F[j][3], t3);
          cfma(a, F[j][4], t4);
          data[r * 80 + n2] = a;
        }
      }
    }
  }
  __syncthreads();
  const int r0 = (tid >> 4) * 5;
  const int k0 = (tid & 15) * 5;
  float accR[5][5];
  for (int j = 0; j < 5; j++)
    for (int i = 0; i < 5; i++) accR[j][i] = 0.f;
  {
    int idx[5];
    #pragma unroll
    for (int j = 0; j < 5; j++) idx[j] = r0 + j;
    for (int r = 1; r <= 39; ++r) {
      float2 d[5]; float2 t[5];
      #pragma unroll
      for (int i = 0; i < 5; i++) d[i] = data[r * 80 + k0 + i];
      #pragma unroll
      for (int j = 0; j < 5; j++) t[j] = tw[idx[j]];
      #pragma unroll
      for (int j = 0; j < 5; j++) {
        #pragma unroll
        for (int i = 0; i < 5; i++) {
          accR[j][i] = fmaf(t[j].x, d[i].x, accR[j][i]);
          accR[j][i] = fmaf(-t[j].y, d[i].y, accR[j][i]);
        }
      }
      #pragma unroll
      for (int j = 0; j < 5; j++) { idx[j] += r0 + j; if (idx[j] >= 80) idx[j] -= 80; }
    }
  }
  #pragma unroll
  for (int i = 0; i < 5; i++) {
    float2 b0 = data[k0 + i];
    float2 b40 = data[40 * 80 + k0 + i];
    #pragma unroll
    for (int j = 0; j < 5; j++) {
      float s40 = ((r0 + j) & 1) ? -b40.x : b40.x;
      float res = 2.f * accR[j][i] + b0.x + s40;
      op[(r0 + j) * 80 + k0 + i] = fabsf(res) * (1.f / (float)N_);
    }
  }
}

// ---------------- combo: blocks <1024 do 6400-pt IDFT+abs (5x16 CT); blocks >=1024 do Hermitian ifft2+abs ----------------
__global__ __launch_bounds__(256) void k_iff_combo(const float2* __restrict__ in6400, float* __restrict__ out6400,
                                                   const float2* __restrict__ inF, float* __restrict__ outF) {
  __shared__ float2 data[N_];
  __shared__ float2 tw[80];
  __shared__ float2 tws[80];
  const int tid = threadIdx.x;
  if (blockIdx.x < (unsigned)(B_ * C_)) {
    const int row = blockIdx.x;
    const float2* ip = in6400 + (size_t)row * N_;
    float* op = out6400 + (size_t)row * N_;
    if (tid < 80) {
      float a = PI2 * (float)tid * (1.f / 80.f); float sv, cv; sincosf(a, &sv, &cv); tw[tid] = make_float2(cv, sv);
      float a2 = PI2 * (float)tid * (1.f / 6400.f); sincosf(a2, &sv, &cv); tws[tid] = make_float2(cv, sv);
    }
    for (int i = tid; i < N_; i += 256) data[i] = ip[i];
    __syncthreads();
    const int g = tid >> 4;
    const int kap = tid & 15;
    const int r0 = g * 5;
    {
      float2 F[5][5];   // [j: c1=r0+j][q]
      #pragma unroll
      for (int j = 0; j < 5; j++)
        #pragma unroll
        for (int q = 0; q < 5; q++) F[j][q] = make_float2(0.f, 0.f);
      int m16 = 0;
      for (int m = 0; m < 16; ++m) {
        float2 t = tw[5 * m16];
        #pragma unroll
        for (int q = 0; q < 5; q++) {
          const float2* col = &data[(5 * m + q) * 80 + r0];
          #pragma unroll
          for (int j = 0; j < 5; j++) cfma(F[j][q], col[j], t);
        }
        m16 += kap; if (m16 >= 16) m16 -= 16;
      }
      __syncthreads();   // reads complete before overwrite
      #pragma unroll
      for (int s = 0; s < 5; ++s) {
        const int n2 = kap + 16 * s;
        float2 t1 = tw[n2];
        float2 t2 = tw[(2 * n2) % 80];
        float2 t3 = tw[(3 * n2) % 80];
        float2 t4 = tw[(4 * n2) % 80];
        #pragma unroll
        for (int j = 0; j < 5; j++) {
          const int k1 = r0 + j;
          float2 a = F[j][0];
          cfma(a, F[j][1], t1);
          cfma(a, F[j][2], t2);
          cfma(a, F[j][3], t3);
          cfma(a, F[j][4], t4);
          int t6 = k1 * n2; int q6 = t6 / 80, s6 = t6 - q6 * 80;
          data[k1 * 80 + n2] = cmul(a, cmul(tw[q6], tws[s6]));
        }
      }
    }
    __syncthreads();
    {
      float2 G[5][5];   // [q][i]
      #pragma unroll
      for (int q = 0; q < 5; q++)
        #pragma unroll
        for (int i = 0; i < 5; i++) G[q][i] = make_float2(0.f, 0.f);
      int m16 = 0;
      for (int m = 0; m < 16; ++m) {
        float2 t = tw[5 * m16];
        #pragma unroll
        for (int q = 0; q < 5; q++) {
          const float2* rowp = &data[(5 * m + q) * 80 + r0];
          #pragma unroll
          for (int i = 0; i < 5; i++) cfma(G[q][i], rowp[i], t);
        }
        m16 += kap; if (m16 >= 16) m16 -= 16;
      }
      #pragma unroll
      for (int s = 0; s < 5; ++s) {
        const int n1 = kap + 16 * s;
        float2 t1 = tw[n1];
        float2 t2 = tw[(2 * n1) % 80];
        float2 t3 = tw[(3 * n1) % 80];
        float2 t4 = tw[(4 * n1) % 80];
        #pragma unroll
        for (int i = 0; i < 5; i++) {
          float2 y = G[0][i];
          cfma(y, G[1][i], t1);
          cfma(y, G[2][i], t2);
          cfma(y, G[3][i], t3);
          cfma(y, G[4][i], t4);
          op[n1 * 80 + r0 + i] = sqrtf(y.x * y.x + y.y * y.y) * (1.f / 6400.f);
        }
      }
    }
  } else {
    // ---- Hermitian ifft2_abs body (pass1 = 5x16 CT); only rows 0..40 loaded/used ----
    const int img = blockIdx.x - B_ * C_;
    const float2* ip = inF + (size_t)img * N_;
    float* op = outF + (size_t)img * N_;
    if (tid < 80) { float a = PI2 * (float)tid * (1.f / 80.f); float sv, cv; sincosf(a, &sv, &cv); tw[tid] = make_float2(cv, sv); }
    for (int i = tid; i < 41 * 80; i += 256) data[i] = ip[i];
    __syncthreads();
    {
      const int g1 = tid >> 4;
      const int kap = tid & 15;
      float2 F[3][5];
      #pragma unroll
      for (int j = 0; j < 3; j++)
        #pragma unroll
        for (int q = 0; q < 5; q++) F[j][q] = make_float2(0.f, 0.f);
      int rr[3];
      #pragma unroll
      for (int j = 0; j < 3; j++) { int r = g1 + 16 * j; rr[j] = (r <= 40) ? r : 0; }
      int m16 = 0;
      for (int m = 0; m < 16; ++m) {
        float2 t = tw[5 * m16];
        #pragma unroll
        for (int j = 0; j < 3; j++) {
          const float2* rowp = &data[rr[j] * 80 + 5 * m];
          #pragma unroll
          for (int q = 0; q < 5; q++) cfma(F[j][q], rowp[q], t);
        }
        m16 += kap; if (m16 >= 16) m16 -= 16;
      }
      __syncthreads();
      #pragma unroll
      for (int s = 0; s < 5; ++s) {
        const int n2 = kap + 16 * s;
        float2 t1 = tw[n2];
        float2 t2 = tw[(2 * n2) % 80];
        float2 t3 = tw[(3 * n2) % 80];
        float2 t4 = tw[(4 * n2) % 80];
        #pragma unroll
        for (int j = 0; j < 3; j++) {
          const int r = g1 + 16 * j;
          if (r <= 40) {
            float2 a = F[j][0];
            cfma(a, F[j][1], t1);
            cfma(a, F[j][2], t2);
            cfma(a, F[j][3], t3);
            cfma(a, F[j][4], t4);
            data[r * 80 + n2] = a;
          }
        }
      }
    }
    __syncthreads();
    const int r0 = (tid >> 4) * 5;
    const int k0 = (tid & 15) * 5;
    float accR[5][5];
    for (int j = 0; j < 5; j++)
      for (int i = 0; i < 5; i++) accR[j][i] = 0.f;
    {
      int idx[5];
      #pragma unroll
      for (int j = 0; j < 5; j++) idx[j] = r0 + j;
      for (int r = 1; r <= 39; ++r) {
        float2 d[5]; float2 t[5];
        #pragma unroll
        for (int i = 0; i < 5; i++) d[i] = data[r * 80 + k0 + i];
        #pragma unroll
        for (int j = 0; j < 5; j++) t[j] = tw[idx[j]];
        #pragma unroll
        for (int j = 0; j < 5; j++) {
          #pragma unroll
          for (int i = 0; i < 5; i++) {
            accR[j][i] = fmaf(t[j].x, d[i].x, accR[j][i]);
            accR[j][i] = fmaf(-t[j].y, d[i].y, accR[j][i]);
          }
        }
        #pragma unroll
        for (int j = 0; j < 5; j++) { idx[j] += r0 + j; if (idx[j] >= 80) idx[j] -= 80; }
      }
    }
    #pragma unroll
    for (int i = 0; i < 5; i++) {
      float2 b0 = data[k0 + i];
      float2 b40 = data[40 * 80 + k0 + i];
      #pragma unroll
      for (int j = 0; j < 5; j++) {
        float s40 = ((r0 + j) & 1) ? -b40.x : b40.x;
        float res = 2.f * accR[j][i] + b0.x + s40;
        op[(r0 + j) * 80 + k0 + i] = fabsf(res) * (1.f / (float)N_);
      }
    }
  }
}

// ---------------- gate stage A (4-way channel-split, 800 blocks) ----------------
__global__ __launch_bounds__(256) void k_gateA(const float2* __restrict__ zA, const float2* __restrict__ zB,
    int split, int Cin, const float* __restrict__ W1, const float* __restrict__ b1,
    const float* __restrict__ g, const float* __restrict__ bt, float* __restrict__ hid) {
  __shared__ float w[8 * 256];
  __shared__ float red[4][64][9];  // padded to 9 to avoid bank conflicts
  const int tid = threadIdx.x;
  const int grp = tid >> 6, l = tid & 63;
  for (int i = tid; i < 8 * Cin; i += 256) w[i] = W1[i];
  __syncthreads();
  const int p = blockIdx.x * 64 + l;
  const int b = p / N_, n = p % N_;
  const int cpg = Cin / 4;
  float acc[8] = {0.f, 0.f, 0.f, 0.f, 0.f, 0.f, 0.f, 0.f};
  for (int ci = grp * cpg; ci < (grp + 1) * cpg; ci++) {
    const float2* src = (ci < split) ? (zA + ((size_t)b * split + ci) * N_ + n)
                                     : (zB + ((size_t)b * (Cin - split) + (ci - split)) * N_ + n);
    float v = src->x;
    #pragma unroll
    for (int j = 0; j < 8; j++) acc[j] = fmaf(w[j * Cin + ci], v, acc[j]);
  }
  #pragma unroll
  for (int j = 0; j < 8; j++) red[grp][l][j] = acc[j];
  __syncthreads();
  if (grp == 0) {
    #pragma unroll
    for (int j = 0; j < 8; j++) {
      float t = red[0][l][j] + red[1][l][j] + red[2][l][j] + red[3][l][j];
      float y = (t + b1[j]) * (g[j] * BN_SC) + bt[j];
      hid[((size_t)b * 8 + j) * N_ + n] = fmaxf(y, 0.f);
    }
  }
}

// ---------------- gate stage B (co-split over gridDim.y, 64 co per block) ----------------
template <int MODE>
__global__ __launch_bounds__(256) void k_gateB(float2* __restrict__ zA, float2* __restrict__ zB,
    int split, int Cout, const float* __restrict__ W2, const float* __restrict__ b2,
    const float* __restrict__ hid, float* __restrict__ outR, int outCtot, int outCoff) {
  __shared__ float w[64 * 8];
  __shared__ float bb[64];
  const int tid = threadIdx.x;
  const int cobase = blockIdx.y * 64;
  for (int i = tid; i < 64 * 8; i += 256) w[i] = W2[cobase * 8 + i];
  for (int i = tid; i < 64; i += 256) bb[i] = b2[cobase + i];
  __syncthreads();
  const int p = blockIdx.x * 256 + tid;
  const int b = p / N_, n = p % N_;
  float h[8];
  #pragma unroll
  for (int j = 0; j < 8; j++) h[j] = hid[((size_t)b * 8 + j) * N_ + n];
  for (int co = 0; co < 64; co++) {
    const int gco = cobase + co;
    float t = bb[co];
    #pragma unroll
    for (int j = 0; j < 8; j++) t = fmaf(w[co * 8 + j], h[j], t);
    float sg = 1.f / (1.f + expf(-t));
    float2* zp = (gco < split) ? (zA + ((size_t)b * split + gco) * N_ + n)
                               : (zB + ((size_t)b * (Cout - split) + (gco - split)) * N_ + n);
    float2 z = *zp;
    if (MODE == 0) {
      zp->x = z.x * sg; zp->y = z.y * sg;
    } else {
      float m = sg * sqrtf(z.x * z.x + z.y * z.y);
      outR[((size_t)b * outCtot + outCoff + gco) * N_ + n] = gelu_mul(m);
    }
  }
}

// ---------------- COMBO: pv_idft32 (blocks 0..799) || gateA-F (blocks 800..1599) ----------------
__global__ __launch_bounds__(256) void k_pvgA(const float2* __restrict__ attn, const float2* __restrict__ V,
                                              float2* __restrict__ outC,
                                              const float2* __restrict__ z, const float* __restrict__ W1,
                                              const float* __restrict__ b1, const float* __restrict__ gg,
                                              const float* __restrict__ bt, float* __restrict__ hid) {
  __shared__ float2 at[32][32];
  __shared__ float2 tw32[32];
  __shared__ float wg[8 * 128];
  __shared__ float red[4][64][9];
  const int tid = threadIdx.x;
  if (blockIdx.x < 800) {
    // ---- pv_idft32 body: bh = blk/25, ny = blk%25 ----
    const int bh = blockIdx.x / 25;
    const int ny = blockIdx.x % 25;
    const int b = bh / H_, h = bh % H_;
    const int n = ny * 256 + tid;
    if (tid < 32) { float a = PI2 * (float)tid * (1.f / 32.f); float sv, cv; sincosf(a, &sv, &cv); tw32[tid] = make_float2(cv, sv); }
    for (int i = tid; i < 1024; i += 256) at[i >> 5][i & 31] = attn[(size_t)bh * 1024 + i];
    __syncthreads();
    const size_t hb = ((size_t)b * C_ + h * 32) * N_;
    const float2* Vp = V + hb;
    float2 acc[32];
    #pragma unroll
    for (int c = 0; c < 32; c++) acc[c] = make_float2(0.f, 0.f);
    for (int dd = 0; dd < 32; dd++) {
      float2 v = Vp[(size_t)dd * N_ + n];
      #pragma unroll
      for (int c = 0; c < 32; c++) cfma(acc[c], at[c][dd], v);
    }
    float2* Op = outC + hb;
    for (int cp = 0; cp < 16; cp++) {
      float2 E = make_float2(0.f, 0.f), O = make_float2(0.f, 0.f);
      const int inc = (2 * cp) & 31;
      int idx = 0;
      #pragma unroll
      for (int m = 0; m < 16; m++) {
        cfma(E, acc[2 * m], tw32[idx]);
        cfma(O, acc[2 * m + 1], tw32[idx]);
        idx = (idx + inc) & 31;
      }
      float2 u = cmul(tw32[cp], O);
      Op[(size_t)cp * N_ + n]        = make_float2((E.x + u.x) * (1.f / 32.f), (E.y + u.y) * (1.f / 32.f));
      Op[(size_t)(cp + 16) * N_ + n] = make_float2((E.x - u.x) * (1.f / 32.f), (E.y - u.y) * (1.f / 32.f));
    }
  } else {
    // ---- gateA body (f-gate: Cin = split = 128) ----
    const int blkA = blockIdx.x - 800;
    const int grp = tid >> 6, l = tid & 63;
    for (int i = tid; i < 8 * 128; i += 256) wg[i] = W1[i];
    __syncthreads();
    const int p = blkA * 64 + l;
    const int b = p / N_, n = p % N_;
    float acc[8] = {0.f, 0.f, 0.f, 0.f, 0.f, 0.f, 0.f, 0.f};
    for (int ci = grp * 32; ci < grp * 32 + 32; ci++) {
      float v = z[((size_t)b * 128 + ci) * N_ + n].x;
      #pragma unroll
      for (int j = 0; j < 8; j++) acc[j] = fmaf(wg[j * 128 + ci], v, acc[j]);
    }
    #pragma unroll
    for (int j = 0; j < 8; j++) red[grp][l][j] = acc[j];
    __syncthreads();
    if (grp == 0) {
      #pragma unroll
      for (int j = 0; j < 8; j++) {
        float t = red[0][l][j] + red[1][l][j] + red[2][l][j] + red[3][l][j];
        float y = (t + b1[j]) * (gg[j] * BN_SC) + bt[j];
        hid[((size_t)b * 8 + j) * N_ + n] = fmaxf(y, 0.f);
      }
    }
  }
}

// ---------------- COMBO: gateB<1> ffg (blocks 0..399) || dwconv3_gelu (blocks 400..4495) ----------------
__global__ __launch_bounds__(256) void k_gBdw(const float2* __restrict__ z, const float* __restrict__ W2,
                                              const float* __restrict__ b2, const float* __restrict__ hid,
                                              float* __restrict__ outR,
                                              const float* __restrict__ dwin, const float* __restrict__ dww,
                                              float* __restrict__ dwout) {
  __shared__ float wB[64 * 8];
  __shared__ float bbB[64];
  __shared__ float tt[42][82];
  const int tid = threadIdx.x;
  if (blockIdx.x < 400) {
    // ---- gateB<1> body (split = Cout = 128; outCtot=256, outCoff=0) ----
    const int by = blockIdx.x / 200, bx = blockIdx.x % 200;
    const int cobase = by * 64;
    for (int i = tid; i < 64 * 8; i += 256) wB[i] = W2[cobase * 8 + i];
    for (int i = tid; i < 64; i += 256) bbB[i] = b2[cobase + i];
    __syncthreads();
    const int p = bx * 256 + tid;
    const int b = p / N_, n = p % N_;
    float h[8];
    #pragma unroll
    for (int j = 0; j < 8; j++) h[j] = hid[((size_t)b * 8 + j) * N_ + n];
    for (int co = 0; co < 64; co++) {
      const int gco = cobase + co;
      float t = bbB[co];
      #pragma unroll
      for (int j = 0; j < 8; j++) t = fmaf(wB[co * 8 + j], h[j], t);
      float sg = 1.f / (1.f + expf(-t));
      float2 zv = z[((size_t)b * 128 + gco) * N_ + n];
      float m = sg * sqrtf(zv.x * zv.x + zv.y * zv.y);
      outR[((size_t)b * 256 + gco) * N_ + n] = gelu_mul(m);
    }
  } else {
    // ---- dwconv3_gelu body (Cn=128, outCtot=256, outCoff=128) ----
    const int blk = blockIdx.x - 400;
    const int b = blk / 256;
    const int rem = blk % 256;
    const int c = rem >> 1, half = rem & 1;
    const int y0 = half * 40;
    const float* ip = dwin + ((size_t)b * 128 + c) * N_;
    for (int i = tid; i < 42 * 82; i += 256) {
      int r = i / 82, cc = i % 82;
      int gy = y0 + r - 1, gx = cc - 1;
      float v = 0.f;
      if (gy >= 0 && gy < 80 && gx >= 0 && gx < 80) v = ip[gy * 80 + gx];
      tt[r][cc] = v;
    }
    float wr[9];
    #pragma unroll
    for (int k = 0; k < 9; k++) wr[k] = dww[c * 9 + k];
    __syncthreads();
    float* op = dwout + ((size_t)b * 256 + 128 + c) * N_;
    for (int p = tid; p < 3200; p += 256) {
      const int ly = p / 80, x = p % 80;
      float a = 0.f;
      #pragma unroll
      for (int ky = 0; ky < 3; ky++) {
        #pragma unroll
        for (int kx = 0; kx < 3; kx++)
          a = fmaf(tt[ly + ky][x + kx], wr[ky * 3 + kx], a);
      }
      op[(y0 + ly) * 80 + x] = gelu_mul(a);
    }
  }
}

// ---------------- COMBO: rownorm x2 (blocks 0..2047) || attn_part_r (blocks 2048..3071) ----------------
__global__ __launch_bounds__(256) void k_rnap(const float* __restrict__ inA, float* __restrict__ nrmA,
                                              const float* __restrict__ inB, float* __restrict__ nrmB,
                                              float* __restrict__ part) {
  __shared__ float red1[256];
  const int tid = threadIdx.x;
  if (blockIdx.x < 2048) {
    int row = blockIdx.x;
    const float* p; float* o;
    if (row < B_ * C_) { p = inA + (size_t)row * N_; o = nrmA + row; }
    else { row -= B_ * C_; p = inB + (size_t)row * N_; o = nrmB + row; }
    float s = 0.f;
    for (int i = tid; i < N_; i += 256) { float v = p[i]; s = fmaf(v, v, s); }
    red1[tid] = s; __syncthreads();
    for (int st = 128; st > 0; st >>= 1) { if (tid < st) red1[tid] += red1[tid + st]; __syncthreads(); }
    if (tid == 0) *o = fmaxf(sqrtf(red1[0]), 1e-12f);
  } else {
    const int blkR = blockIdx.x - 2048;
    const int bh = blkR >> 5;
    const int rem = blkR & 31;
    const int by = rem >> 4;
    const int bx = rem & 15;
    const int b = bh / H_, h = bh % H_;
    const int wave = tid >> 6, lane = tid & 63;
    const int tile = bx * 4 + wave;
    const int c0 = (tile >> 3) * 4, d0 = (tile & 7) * 4;
    const size_t hb = ((size_t)b * C_ + h * 32) * N_;
    const float* Ap = inA + hb;
    const float* Bp = inB + hb;
    float acc[4][4];
    #pragma unroll
    for (int j = 0; j < 4; j++)
      #pragma unroll
      for (int i = 0; i < 4; i++) acc[j][i] = 0.f;
    const int nb = by * (N_ / NSPL) + lane;
    for (int it = 0; it < (N_ / NSPL) / 64; ++it) {
      const int n = nb + it * 64;
      float av[4], bv[4];
      #pragma unroll
      for (int j = 0; j < 4; j++) av[j] = Ap[(size_t)(c0 + j) * N_ + n];
      #pragma unroll
      for (int i = 0; i < 4; i++) bv[i] = Bp[(size_t)(d0 + i) * N_ + n];
      #pragma unroll
      for (int j = 0; j < 4; j++)
        #pragma unroll
        for (int i = 0; i < 4; i++) acc[j][i] = fmaf(av[j], bv[i], acc[j][i]);
    }
    float* pp = part + (size_t)(bh * NSPL + by) * 1024;
    #pragma unroll
    for (int j = 0; j < 4; j++) {
      #pragma unroll
      for (int i = 0; i < 4; i++) {
        float r = acc[j][i];
        for (int off = 32; off; off >>= 1) r += __shfl_xor(r, off);
        if (lane == 0) pp[(c0 + j) * 32 + d0 + i] = r;
      }
    }
  }
}

// ---------------- 1x1 conv as bf16 MFMA GEMM: 128co x 64pos per block ----------------
__global__ __launch_bounds__(256) void k_conv1x1(const float* __restrict__ inA, const float* __restrict__ inB,
    int split, int Cin, int Cout, const float* __restrict__ W, const float* __restrict__ bias,
    const float* __restrict__ resid, float* __restrict__ out) {
  __shared__ unsigned int xlds[16][68];    // 4.25 KB
  const int tid = threadIdx.x;
  const int lane = tid & 63, wv = tid >> 6;
  const int p0 = blockIdx.x * 64;
  const int b = p0 / N_, n0 = p0 % N_;
  const int laneco = lane & 15, lanek = lane >> 4;
  const int kA = lanek * 8;
  f32x4 acc[2][4];
  #pragma unroll
  for (int g = 0; g < 2; g++)
    #pragma unroll
    for (int f = 0; f < 4; f++) acc[g][f] = (f32x4){0.f, 0.f, 0.f, 0.f};
  for (int cb = 0; cb < Cin; cb += 32) {
    const float* src = (cb < split) ? (inA + ((size_t)b * split + cb) * N_)
                                    : (inB + ((size_t)b * (Cin - split) + (cb - split)) * N_);
    bf16x8 af[2];
    #pragma unroll
    for (int g = 0; g < 2; g++) {
      const float* wp = W + (size_t)(wv * 32 + g * 16 + laneco) * Cin + cb + kA;
      float4 w0 = *(const float4*)wp;
      float4 w1 = *(const float4*)(wp + 4);
      af[g][0] = (short)bf16_rn(w0.x); af[g][1] = (short)bf16_rn(w0.y);
      af[g][2] = (short)bf16_rn(w0.z); af[g][3] = (short)bf16_rn(w0.w);
      af[g][4] = (short)bf16_rn(w1.x); af[g][5] = (short)bf16_rn(w1.y);
      af[g][6] = (short)bf16_rn(w1.z); af[g][7] = (short)bf16_rn(w1.w);
    }
    __syncthreads();   // previous-iter xlds reads complete
    #pragma unroll
    for (int r = 0; r < 4; r++) {
      const int kb = wv * 4 + r;
      float e = src[(size_t)(2 * kb) * N_ + n0 + lane];
      float o = src[(size_t)(2 * kb + 1) * N_ + n0 + lane];
      xlds[kb][lane] = (unsigned int)bf16_rn(e) | ((unsigned int)bf16_rn(o) << 16);
    }
    __syncthreads();
    #pragma unroll
    for (int f = 0; f < 4; f++) {
      const int pos = f * 16 + laneco;
      const int kb0 = lanek * 4;
      union { bf16x8 v; unsigned int u[4]; } bu;
      bu.u[0] = xlds[kb0 + 0][pos];
      bu.u[1] = xlds[kb0 + 1][pos];
      bu.u[2] = xlds[kb0 + 2][pos];
      bu.u[3] = xlds[kb0 + 3][pos];
      #pragma unroll
      for (int g = 0; g < 2; g++)
        acc[g][f] = __builtin_amdgcn_mfma_f32_16x16x32_bf16(af[g], bu.v, acc[g][f], 0, 0, 0);
    }
  }
  #pragma unroll
  for (int g = 0; g < 2; g++) {
    #pragma unroll
    for (int f = 0; f < 4; f++) {
      #pragma unroll
      for (int r = 0; r < 4; r++) {
        const int co = wv * 32 + g * 16 + lanek * 4 + r;
        float v = acc[g][f][r];
        if (bias) v += bias[co];
        const size_t off = ((size_t)b * Cout + co) * N_ + n0 + f * 16 + laneco;
        if (resid) v += resid[off];
        out[off] = v;
      }
    }
  }
}

// ---------------- fused q1/k1/v1 1x1 convs: blockIdx.y selects weight/output set ----------------
__global__ __launch_bounds__(256) void k_conv1x1_qkv(const float* __restrict__ in,
    const float* __restrict__ W0, const float* __restrict__ b0, float* __restrict__ o0,
    const float* __restrict__ W1, const float* __restrict__ b1, float* __restrict__ o1,
    const float* __restrict__ W2, const float* __restrict__ b2, float* __restrict__ o2) {
  __shared__ unsigned int xlds[16][68];
  const float* W    = (blockIdx.y == 0) ? W0 : (blockIdx.y == 1) ? W1 : W2;
  const float* bias = (blockIdx.y == 0) ? b0 : (blockIdx.y == 1) ? b1 : b2;
  float* out        = (blockIdx.y == 0) ? o0 : (blockIdx.y == 1) ? o1 : o2;
  const int tid = threadIdx.x;
  const int lane = tid & 63, wv = tid >> 6;
  const int p0 = blockIdx.x * 64;
  const int b = p0 / N_, n0 = p0 % N_;
  const int laneco = lane & 15, lanek = lane >> 4;
  const int kA = lanek * 8;
  f32x4 acc[2][4];
  #pragma unroll
  for (int g = 0; g < 2; g++)
    #pragma unroll
    for (int f = 0; f < 4; f++) acc[g][f] = (f32x4){0.f, 0.f, 0.f, 0.f};
  for (int cb = 0; cb < 128; cb += 32) {
    const float* src = in + ((size_t)b * 128 + cb) * N_;
    bf16x8 af[2];
    #pragma unroll
    for (int g = 0; g < 2; g++) {
      const float* wp = W + (size_t)(wv * 32 + g * 16 + laneco) * 128 + cb + kA;
      float4 w0 = *(const float4*)wp;
      float4 w1 = *(const float4*)(wp + 4);
      af[g][0] = (short)bf16_rn(w0.x); af[g][1] = (short)bf16_rn(w0.y);
      af[g][2] = (short)bf16_rn(w0.z); af[g][3] = (short)bf16_rn(w0.w);
      af[g][4] = (short)bf16_rn(w1.x); af[g][5] = (short)bf16_rn(w1.y);
      af[g][6] = (short)bf16_rn(w1.z); af[g][7] = (short)bf16_rn(w1.w);
    }
    __syncthreads();
    #pragma unroll
    for (int r = 0; r < 4; r++) {
      const int kb = wv * 4 + r;
      float e = src[(size_t)(2 * kb) * N_ + n0 + lane];
      float o = src[(size_t)(2 * kb + 1) * N_ + n0 + lane];
      xlds[kb][lane] = (unsigned int)bf16_rn(e) | ((unsigned int)bf16_rn(o) << 16);
    }
    __syncthreads();
    #pragma unroll
    for (int f = 0; f < 4; f++) {
      const int pos = f * 16 + laneco;
      const int kb0 = lanek * 4;
      union { bf16x8 v; unsigned int u[4]; } bu;
      bu.u[0] = xlds[kb0 + 0][pos];
      bu.u[1] = xlds[kb0 + 1][pos];
      bu.u[2] = xlds[kb0 + 2][pos];
      bu.u[3] = xlds[kb0 + 3][pos];
      #pragma unroll
      for (int g = 0; g < 2; g++)
        acc[g][f] = __builtin_amdgcn_mfma_f32_16x16x32_bf16(af[g], bu.v, acc[g][f], 0, 0, 0);
    }
  }
  #pragma unroll
  for (int g = 0; g < 2; g++) {
    #pragma unroll
    for (int f = 0; f < 4; f++) {
      #pragma unroll
      for (int r = 0; r < 4; r++) {
        const int co = wv * 32 + g * 16 + lanek * 4 + r;
        float v = acc[g][f][r] + bias[co];
        out[((size_t)b * 128 + co) * N_ + n0 + f * 16 + laneco] = v;
      }
    }
  }
}

// ---------------- grouped conv 3x3(pad1) + 5x5(pad2), groups=64: 4 sets via blockIdx.y ----------------
__global__ __launch_bounds__(256) void k_gconv35_4(
    const float* __restrict__ inQ, const float* __restrict__ w3Q, const float* __restrict__ w5Q, float* __restrict__ outQ,
    const float* __restrict__ inK, const float* __restrict__ w3K, const float* __restrict__ w5K, float* __restrict__ outK,
    const float* __restrict__ inV, const float* __restrict__ w3V, const float* __restrict__ w5V, float* __restrict__ outV,
    const float* __restrict__ inC2, const float* __restrict__ w3C, const float* __restrict__ w5C, float* __restrict__ outC2) {
  __shared__ float tt[2][44][84];
  const float* in; const float* w3; const float* w5; float* out;
  if (blockIdx.y == 0)      { in = inQ;  w3 = w3Q; w5 = w5Q; out = outQ; }
  else if (blockIdx.y == 1) { in = inK;  w3 = w3K; w5 = w5K; out = outK; }
  else if (blockIdx.y == 2) { in = inV;  w3 = w3V; w5 = w5V; out = outV; }
  else                      { in = inC2; w3 = w3C; w5 = w5C; out = outC2; }
  const int blk = blockIdx.x;
  const int b = blk / 128;
  const int rem = blk % 128;
  const int o = rem >> 1, half = rem & 1;
  const int y0 = half * 40;
  const float* i0 = in + ((size_t)b * C_ + 2 * o) * N_;
  const int tid = threadIdx.x;
  for (int i = tid; i < 2 * 44 * 84; i += 256) {
    int ic = i / (44 * 84);
    int r = (i % (44 * 84)) / 84;
    int cc = i % 84;
    int gy = y0 + r - 2, gx = cc - 2;
    float v = 0.f;
    if (gy >= 0 && gy < 80 && gx >= 0 && gx < 80) v = i0[(size_t)ic * N_ + gy * 80 + gx];
    tt[ic][r][cc] = v;
  }
  float w3r[2][9], w5r[2][25];
  #pragma unroll
  for (int ic = 0; ic < 2; ic++) {
    #pragma unroll
    for (int k = 0; k < 9; k++) w3r[ic][k] = w3[(o * 2 + ic) * 9 + k];
    #pragma unroll
    for (int k = 0; k < 25; k++) w5r[ic][k] = w5[(o * 2 + ic) * 25 + k];
  }
  __syncthreads();
  for (int p = tid; p < 3200; p += 256) {
    const int ly = p / 80, x = p % 80;
    float a3 = 0.f, a5 = 0.f;
    #pragma unroll
    for (int ky = 0; ky < 5; ky++) {
      #pragma unroll
      for (int kx = 0; kx < 5; kx++) {
        float v0 = tt[0][ly + ky][x + kx];
        float v1 = tt[1][ly + ky][x + kx];
        a5 = fmaf(v0, w5r[0][ky * 5 + kx], a5);
        a5 = fmaf(v1, w5r[1][ky * 5 + kx], a5);
        if (ky >= 1 && ky < 4 && kx >= 1 && kx < 4) {
          int k3 = (ky - 1) * 3 + (kx - 1);
          a3 = fmaf(v0, w3r[0][k3], a3);
          a3 = fmaf(v1, w3r[1][k3], a3);
        }
      }
    }
    const int yy = y0 + ly;
    out[((size_t)b * C_ + o) * N_ + yy * 80 + x] = a3;
    out[((size_t)b * C_ + 64 + o) * N_ + yy * 80 + x] = a5;
  }
}

// ---------------- ff_dw2: groups=128, 2-in/2-out per group, 3x3 pad1: zero-padded halo, halves ----------------
__global__ __launch_bounds__(256) void k_ffdw2(const float* __restrict__ in, const float* __restrict__ w,
                                               float* __restrict__ out) {
  __shared__ float tt[2][42][82];
  const int blk = blockIdx.x;
  const int b = blk / 256;
  const int rem = blk % 256;
  const int g = rem >> 1, half = rem & 1;
  const int y0 = half * 40;
  const float* i0 = in + ((size_t)b * 256 + 2 * g) * N_;
  const int tid = threadIdx.x;
  for (int i = tid; i < 2 * 42 * 82; i += 256) {
    int ic = i / (42 * 82);
    int r = (i % (42 * 82)) / 82;
    int cc = i % 82;
    int gy = y0 + r - 1, gx = cc - 1;
    float v = 0.f;
    if (gy >= 0 && gy < 80 && gx >= 0 && gx < 80) v = i0[(size_t)ic * N_ + gy * 80 + gx];
    tt[ic][r][cc] = v;
  }
  float w0[2][9], w1[2][9];
  #pragma unroll
  for (int ic = 0; ic < 2; ic++) {
    #pragma unroll
    for (int k = 0; k < 9; k++) {
      w0[ic][k] = w[((2 * g) * 2 + ic) * 9 + k];
      w1[ic][k] = w[((2 * g + 1) * 2 + ic) * 9 + k];
    }
  }
  __syncthreads();
  for (int p = tid; p < 3200; p += 256) {
    const int ly = p / 80, x = p % 80;
    float a0 = 0.f, a1 = 0.f;
    #pragma unroll
    for (int ky = 0; ky < 3; ky++) {
      #pragma unroll
      for (int kx = 0; kx < 3; kx++) {
        float v0 = tt[0][ly + ky][x + kx], v1 = tt[1][ly + ky][x + kx];
        int k = ky * 3 + kx;
        a0 = fmaf(v0, w0[0][k], a0); a0 = fmaf(v1, w0[1][k], a0);
        a1 = fmaf(v0, w1[0][k], a1); a1 = fmaf(v1, w1[1][k], a1);
      }
    }
    const int yy = y0 + ly;
    out[((size_t)b * 256 + 2 * g) * N_ + yy * 80 + x] = a0;
    out[((size_t)b * 256 + 2 * g + 1) * N_ + yy * 80 + x] = a1;
  }
}

// ---------------- F-attention partials, symmetric (Q==K): 36 upper-triangle tiles ----------------
__global__ __launch_bounds__(256) void k_attn_part_sym(const float2* __restrict__ Ab, float2* __restrict__ part) {
  const int bh = blockIdx.z;
  const int b = bh / H_, h = bh % H_;
  const int wave = threadIdx.x >> 6, lane = threadIdx.x & 63;
  int w = blockIdx.x * 4 + wave;      // 0..35 upper-triangle tile id
  int ci = 0;
  while (w >= 8 - ci) { w -= 8 - ci; ci++; }
  const int c0 = ci * 4, d0 = (ci + w) * 4;
  const size_t hb = ((size_t)b * C_ + h * 32) * N_;
  const float2* Ap = Ab + hb;
  float2 acc[4][4];
  #pragma unroll
  for (int j = 0; j < 4; j++)
    #pragma unroll
    for (int i = 0; i < 4; i++) acc[j][i] = make_float2(0.f, 0.f);
  const int nb = blockIdx.y * (N_ / NSPL) + lane;
  for (int it = 0; it < (N_ / NSPL) / 64; ++it) {
    const int n = nb + it * 64;
    float2 av[4], bv[4];
    #pragma unroll
    for (int j = 0; j < 4; j++) av[j] = Ap[(size_t)(c0 + j) * N_ + n];
    #pragma unroll
    for (int i = 0; i < 4; i++) bv[i] = Ap[(size_t)(d0 + i) * N_ + n];
    #pragma unroll
    for (int j = 0; j < 4; j++)
      #pragma unroll
      for (int i = 0; i < 4; i++) cfma(acc[j][i], av[j], bv[i]);
  }
  float2* pp = part + (size_t)(bh * NSPL + blockIdx.y) * 1024;
  #pragma unroll
  for (int j = 0; j < 4; j++) {
    #pragma unroll
    for (int i = 0; i < 4; i++) {
      float rx = acc[j][i].x, ry = acc[j][i].y;
      for (int off = 32; off; off >>= 1) { rx += __shfl_xor(rx, off); ry += __shfl_xor(ry, off); }
      if (lane == 0) {
        float2 v = make_float2(rx, ry);
        pp[(d0 + i) * 32 + (c0 + j)] = v;   // mirror (S symmetric)
        pp[(c0 + j) * 32 + (d0 + i)] = v;
      }
    }
  }
}

// ---------------- reduce partials, scale, softmax ----------------
template <int CPLX>
__global__ void k_attn_soft(const float* __restrict__ part, const float* __restrict__ nA,
                            const float* __restrict__ nB, const float* __restrict__ temp,
                            float* __restrict__ attn) {
  const int rc = blockIdx.x;          // bh*32 + c
  const int bh = rc >> 5, c = rc & 31;
  const int b = bh / H_, h = bh % H_;
  const int d = threadIdx.x;          // 64 threads; group >=32 unused
  float re = -1e30f, im = -1e30f;
  if (d < 32) {
    re = 0.f; im = 0.f;
    if (CPLX) {
      const float2* pp = (const float2*)part;
      for (int kc = 0; kc < NSPL; kc++) { float2 v = pp[(size_t)(bh * NSPL + kc) * 1024 + c * 32 + d]; re += v.x; im += v.y; }
    } else {
      for (int kc = 0; kc < NSPL; kc++) re += part[(size_t)(bh * NSPL + kc) * 1024 + c * 32 + d];
    }
    float sc = temp[h] / (nA[b * C_ + h * 32 + c] * nB[b * C_ + h * 32 + d]);
    re *= sc; im *= sc;
  }
  float m = re;
  for (int o = 16; o; o >>= 1) m = fmaxf(m, __shfl_xor(m, o, 32));
  float e = expf(re - m);
  float s = e;
  for (int o = 16; o; o >>= 1) s += __shfl_xor(s, o, 32);
  float vr = e / s;
  float mi = im;
  for (int o = 16; o; o >>= 1) mi = fmaxf(mi, __shfl_xor(mi, o, 32));
  float ei = expf(im - mi);
  float si = ei;
  for (int o = 16; o; o >>= 1) si += __shfl_xor(si, o, 32);
  float vi = ei / si;
  if (d < 32) {
    if (CPLX) ((float2*)attn)[(size_t)(bh * 32 + c) * 32 + d] = make_float2(vr, vi);
    else attn[(size_t)(bh * 32 + c) * 32 + d] = vr;
  }
}

__global__ __launch_bounds__(256) void k_pv_r(const float* __restrict__ attn, const float* __restrict__ V,
                                              float* __restrict__ out) {
  __shared__ float at[32][32];
  const int bh = blockIdx.x;
  const int b = bh / H_, h = bh % H_;
  const int n = blockIdx.y * 256 + threadIdx.x;
  for (int i = threadIdx.x; i < 1024; i += 256) at[i >> 5][i & 31] = attn[(size_t)bh * 1024 + i];
  __syncthreads();
  const size_t hb = ((size_t)b * C_ + h * 32) * N_;
  const float* Vp = V + hb;
  float acc[32];
  #pragma unroll
  for (int c = 0; c < 32; c++) acc[c] = 0.f;
  for (int dd = 0; dd < 32; dd++) {
    float v = Vp[(size_t)dd * N_ + n];
    #pragma unroll
    for (int c = 0; c < 32; c++) acc[c] = fmaf(at[c][dd], v, acc[c]);
  }
  float* Op = out + hb;
  #pragma unroll
  for (int c = 0; c < 32; c++) Op[(size_t)c * N_ + n] = acc[c];
}

extern "C" void kernel_launch(void* const* d_in, const int* in_sizes, int n_in,
                              void* d_out, int out_size, void* d_ws, size_t ws_size,
                              hipStream_t stream) {
  (void)in_sizes; (void)n_in; (void)out_size; (void)ws_size;
  const float* x       = (const float*)d_in[0];
  const float* ln1_w   = (const float*)d_in[1];
  const float* ln2_w   = (const float*)d_in[2];
  const float* ln1_b   = (const float*)d_in[3];
  const float* ln2_b   = (const float*)d_in[4];
  const float* f_temp  = (const float*)d_in[5];
  const float* s_temp  = (const float*)d_in[6];
  const float* f_proj  = (const float*)d_in[7];
  const float* s_proj  = (const float*)d_in[8];
  const float* f_w1    = (const float*)d_in[9];
  const float* f_wb1   = (const float*)d_in[10];
  const float* f_bng   = (const float*)d_in[11];
  const float* f_bnb   = (const float*)d_in[12];
  const float* f_w2    = (const float*)d_in[13];
  const float* f_wb2   = (const float*)d_in[14];
  const float* s_q1_w  = (const float*)d_in[15];
  const float* s_q1_b  = (const float*)d_in[16];
  const float* s_k1_w  = (const float*)d_in[17];
  const float* s_k1_b  = (const float*)d_in[18];
  const float* s_v1_w  = (const float*)d_in[19];
  const float* s_v1_b  = (const float*)d_in[20];
  const float* s_q3_w  = (const float*)d_in[21];
  const float* s_k3_w  = (const float*)d_in[22];
  const float* s_v3_w  = (const float*)d_in[23];
  const float* s_c3_w  = (const float*)d_in[24];
  const float* s_q5_w  = (const float*)d_in[25];
  const float* s_k5_w  = (const float*)d_in[26];
  const float* s_v5_w  = (const float*)d_in[27];
  const float* s_c5_w  = (const float*)d_in[28];
  const float* ffdw1_w = (const float*)d_in[29];
  const float* ffdw2_w = (const float*)d_in[30];
  const float* ffproj  = (const float*)d_in[31];
  const float* ffg_w1  = (const float*)d_in[32];
  const float* ffg_b1  = (const float*)d_in[33];
  const float* ffg_bng = (const float*)d_in[34];
  const float* ffg_bnb = (const float*)d_in[35];
  const float* ffg_w2  = (const float*)d_in[36];
  const float* ffg_b2  = (const float*)d_in[37];
  const float* ffg1_w1 = (const float*)d_in[38];
  const float* ffg1_b1 = (const float*)d_in[39];
  const float* ffg1_bng= (const float*)d_in[40];
  const float* ffg1_bnb= (const float*)d_in[41];
  const float* ffg1_w2 = (const float*)d_in[42];
  const float* ffg1_b2 = (const float*)d_in[43];

  // workspace layout (floats). Requires ~267 MB of d_ws.
  float* ws = (float*)d_ws;
  const size_t R = (size_t)B_ * C_ * N_;   // 6,553,600 floats per [B,128,N] image set
  float* xn   = ws;            // R
  float* acc  = ws + R;        // R
  float* bufA = ws + 2 * R;    // 2R (complex [B,128,N] or real [B,256,N])
  float* bufB = ws + 4 * R;    // 2R
  float* bufC = ws + 6 * R;    // 2R
  float* bufD = ws + 8 * R;    // 2R
  float* sm   = ws + 10 * R;   // small pool
  float* nrmQ = sm;                    // 1024
  float* nrmK = sm + 1024;             // 1024
  float* hid  = sm + 2048;             // B*8*N = 409600
  float* part = sm + 2048 + 409600;    // 524288 (float2[131072] used for cplx)
  float* attb = part + 524288;         // 65536 (float2[32768] for cplx)

  dim3 blk(256);
  const int GCONV = P_ / 64;   // 800 blocks, 128co x 64pos MFMA tiles
  const int GLN = P_ / 64;     // 800 blocks for layernorm / gateA
  const int NIMG = B_ * C_;    // 1024
  const dim3 gattn_sym(9, NSPL, B_ * H_);   // 36 upper-triangle tiles / 4 waves

  // ===== xn = LayerNorm(x) ; xf = fft2(xn) with fused row-norm =====
  k_layernorm<<<GLN, blk, 0, stream>>>(x, ln1_w, ln1_b, xn);
  k_fft2_r2c<<<NIMG, blk, 0, stream>>>(xn, (float2*)bufA, C_, C_, 0, nullptr, 0, NIMG, nrmQ);

  // ===== Attention_F =====
  k_attn_part_sym<<<gattn_sym, blk, 0, stream>>>((const float2*)bufA, (float2*)part);
  k_attn_soft<1><<<B_ * C_, 64, 0, stream>>>(part, nrmQ, nrmQ, f_temp, attb);
  // COMBO: pv_idft32 (bufA -> bufC) || gateA-F (bufA -> hid); both only READ bufA
  k_pvgA<<<1600, blk, 0, stream>>>((const float2*)attb, (const float2*)bufA, (float2*)bufC,
                                   (const float2*)bufA, f_w1, f_wb1, f_bng, f_bnb, hid);
  k_gateB<0><<<dim3(P_ / 256, 2), blk, 0, stream>>>((float2*)bufA, (float2*)bufA, C_, C_, f_w2, f_wb2, hid, nullptr, 0, 0);
  k_iff_combo<<<2 * NIMG, blk, 0, stream>>>((const float2*)bufC, bufD, (const float2*)bufA, bufD + R);
  // a_f: acc = x + f_proj(concat(out_f, out_f_l))
  k_conv1x1<<<GCONV, blk, 0, stream>>>(bufD, bufD + R, 128, 256, 128, f_proj, nullptr, x, acc);

  // ===== Attention_S =====
  k_conv1x1_qkv<<<dim3(GCONV, 3), blk, 0, stream>>>(xn,
      s_q1_w, s_q1_b, bufA, s_k1_w, s_k1_b, bufA + R, s_v1_w, s_v1_b, bufB);
  k_gconv35_4<<<dim3(B_ * 128, 4), blk, 0, stream>>>(
      bufA,     s_q3_w, s_q5_w, bufB + R,
      bufA + R, s_k3_w, s_k5_w, bufC,
      bufB,     s_v3_w, s_v5_w, bufC + R,
      xn,       s_c3_w, s_c5_w, bufD + R);
  // COMBO: rownorm2 (qs->nrmQ, ks->nrmK) || attn_part_r (both read-only on qs/ks)
  k_rnap<<<3072, blk, 0, stream>>>(bufB + R, nrmQ, bufC, nrmK, part);
  k_attn_soft<0><<<B_ * C_, 64, 0, stream>>>(part, nrmQ, nrmK, s_temp, attb);
  k_pv_r<<<dim3(B_ * H_, N_ / 256), blk, 0, stream>>>(attb, bufC + R, bufA);      // out_s -> A.lo
  // a_s: acc += s_proj(concat(out_s, out_s_l))  (out_s_l lives in bufD+R)
  k_conv1x1<<<GCONV, blk, 0, stream>>>(bufA, bufD + R, 128, 256, 128, s_proj, nullptr, acc, acc);

  // ===== FeedForward =====
  k_layernorm<<<GLN, blk, 0, stream>>>(acc, ln2_w, ln2_b, xn);                    // xn2
  k_fft2_r2c<<<NIMG, blk, 0, stream>>>(xn, (float2*)bufA, C_, C_, 0, nullptr, 0, NIMG, nullptr);  // xf2
  k_gateA<<<GLN, blk, 0, stream>>>((const float2*)bufA, (const float2*)bufA, C_, C_, ffg_w1, ffg_b1, ffg_bng, ffg_bnb, hid);
  // COMBO: gateB<1> (bufA,hid -> bufB.lo) || dwconv3_gelu (xn -> bufB.hi); disjoint halves of bufB
  k_gBdw<<<400 + B_ * 256, blk, 0, stream>>>((const float2*)bufA, ffg_w2, ffg_b2, hid, bufB,
                                             xn, ffdw1_w, bufB);
  // cf = fft2(cat): one merged 2048-block dispatch (lo -> bufA, hi -> bufC)
  k_fft2_r2c<<<2 * NIMG, blk, 0, stream>>>(bufB, (float2*)bufA, 128, 256, 0, (float2*)bufC, 128, NIMG, nullptr);
  k_gateA<<<GLN, blk, 0, stream>>>((const float2*)bufA, (const float2*)bufC, 128, 256, ffg1_w1, ffg1_b1, ffg1_bng, ffg1_bnb, hid);
  k_gateB<0><<<dim3(P_ / 256, 4), blk, 0, stream>>>((float2*)bufA, (float2*)bufC, 128, 256, ffg1_w2, ffg1_b2, hid, nullptr, 0, 0);
  // x_f2b: merged 2048-block ifft2 pair (bufA -> bufD coff0, bufC -> bufD coff128)
  k_ifft2_abs<<<2 * NIMG, blk, 0, stream>>>((const float2*)bufA, bufD, 128, 256, 0, (const float2*)bufC, 128, NIMG);
  k_ffdw2<<<B_ * 256, blk, 0, stream>>>(bufB, ffdw2_w, bufA);                     // x_s2b (real [B,256,N] in A)
  // out = x1 + ff_proj(concat(x_f2b, x_s2b))
  k_conv1x1<<<GCONV, blk, 0, stream>>>(bufD, bufA, 256, 512, 128, ffproj, nullptr, acc, (float*)d_out);
}